// Round 2
// 3384.705 us; speedup vs baseline: 1.1248x; 1.1248x over previous
//
#include <hip/hip_runtime.h>
#include <stdint.h>
#include <math.h>

// Problem constants
#define BB   64
#define SS   196
#define BS   12544            // BB*SS
#define NOUT 6422528L         // BS*512
#define SLD  224              // score row ld (7*32)

typedef __attribute__((ext_vector_type(8))) short bf16x8;
typedef __attribute__((ext_vector_type(4))) float f32x4;

// ---------------- device helpers ----------------
__device__ __forceinline__ float block_red256(float v, float* red, bool ismax) {
#pragma unroll
  for (int o = 32; o > 0; o >>= 1) {
    float t = __shfl_down(v, o, 64);
    v = ismax ? fmaxf(v, t) : v + t;
  }
  int lane = threadIdx.x & 63, wid = threadIdx.x >> 6;
  if (lane == 0) red[wid] = v;
  __syncthreads();
  float r = ismax ? fmaxf(fmaxf(red[0], red[1]), fmaxf(red[2], red[3]))
                  : (red[0] + red[1]) + (red[2] + red[3]);
  __syncthreads();
  return r;
}

__device__ __forceinline__ short f2bf(float f) {
  union { float f; unsigned u; } v; v.f = f;
  unsigned r = v.u + 0x7fffu + ((v.u >> 16) & 1u);   // round-to-nearest-even
  return (short)(r >> 16);
}

__device__ __forceinline__ void cvt8(short* dst, float4 a, float4 b) {
  union { short s[8]; int4 v; } u;
  u.s[0] = f2bf(a.x); u.s[1] = f2bf(a.y); u.s[2] = f2bf(a.z); u.s[3] = f2bf(a.w);
  u.s[4] = f2bf(b.x); u.s[5] = f2bf(b.y); u.s[6] = f2bf(b.z); u.s[7] = f2bf(b.w);
  *(int4*)dst = u.v;
}

// Raw barrier: ds ops drained, global loads stay in flight (no vmcnt drain).
__device__ __forceinline__ void lds_barrier() {
  asm volatile("s_waitcnt lgkmcnt(0)" ::: "memory");
  __builtin_amdgcn_s_barrier();
  __builtin_amdgcn_sched_barrier(0);
}

// ---- bf16 MFMA GEMM: C[M,N] = A[M,K] @ W[N,K]^T + bias (opt relu) ----
// 128x128 tile, BK=32, 4 waves (2x2). M%128==0, N%128==0, K%32==0.
// 2-phase pipeline: dbuf LDS, 1-deep reg prefetch, 1 raw barrier/K-step.
__global__ __launch_bounds__(256) void k_mfma_nt(
    const float* __restrict__ A, const float* __restrict__ W,
    const float* __restrict__ bias, float* __restrict__ C,
    int M, int N, int K, int relu) {
  __shared__ short As[2][128][40];
  __shared__ short Bs[2][128][40];
  const int tid = threadIdx.x;
  const int lane = tid & 63, wave = tid >> 6;
  const int wm = wave >> 1, wn = wave & 1;
  const int m0 = blockIdx.y * 128, n0 = blockIdx.x * 128;
  const int srow = tid >> 1, skh = (tid & 1) * 16;
  const float* Ap = A + (long)(m0 + srow) * K + skh;
  const float* Wp = W + (long)(n0 + srow) * K + skh;
  const int fr = lane & 15, fq = lane >> 4;
  const int NK = K >> 5;
  f32x4 acc[4][4] = {};
  float4 xa[4], xw[4], ya[4], yw[4];

  auto ldt = [&](float4 (&ta)[4], float4 (&tw)[4], int t) {
    const float* ap = Ap + t * 32;
    const float* wp = Wp + t * 32;
#pragma unroll
    for (int i = 0; i < 4; ++i) {
      ta[i] = *(const float4*)(ap + i * 4);
      tw[i] = *(const float4*)(wp + i * 4);
    }
  };
  auto stage = [&](float4 (&ta)[4], float4 (&tw)[4], int p) {
    cvt8(&As[p][srow][skh], ta[0], ta[1]);
    cvt8(&As[p][srow][skh + 8], ta[2], ta[3]);
    cvt8(&Bs[p][srow][skh], tw[0], tw[1]);
    cvt8(&Bs[p][srow][skh + 8], tw[2], tw[3]);
  };
  auto step = [&](int t, float4 (&la)[4], float4 (&lw)[4],
                  float4 (&ca)[4], float4 (&cw)[4]) {
    const int par = t & 1;
    if (t + 2 < NK) ldt(la, lw, t + 2);            // prefetch tile t+2
    bf16x8 af[4], bfr[4];
#pragma unroll
    for (int i = 0; i < 4; ++i) af[i] = *(const bf16x8*)&As[par][wm * 64 + i * 16 + fr][fq * 8];
#pragma unroll
    for (int j = 0; j < 4; ++j) bfr[j] = *(const bf16x8*)&Bs[par][wn * 64 + j * 16 + fr][fq * 8];
    if (t + 1 < NK) stage(ca, cw, par ^ 1);        // stage tile t+1
#pragma unroll
    for (int i = 0; i < 4; ++i)
#pragma unroll
      for (int j = 0; j < 4; ++j)
        acc[i][j] = __builtin_amdgcn_mfma_f32_16x16x32_bf16(af[i], bfr[j], acc[i][j], 0, 0, 0);
    lds_barrier();
  };

  ldt(xa, xw, 0);
  stage(xa, xw, 0);
  if (NK > 1) ldt(xa, xw, 1);
  lds_barrier();
  int t = 0;
  for (; t + 1 < NK; t += 2) { step(t, ya, yw, xa, xw); step(t + 1, xa, xw, ya, yw); }
  if (t < NK) step(t, ya, yw, xa, xw);

#pragma unroll
  for (int i = 0; i < 4; ++i) {
    int mB = m0 + wm * 64 + i * 16 + fq * 4;
#pragma unroll
    for (int j = 0; j < 4; ++j) {
      int n = n0 + wn * 64 + j * 16 + fr;
      float bz = bias[n];
#pragma unroll
      for (int r2 = 0; r2 < 4; ++r2) {
        float v = acc[i][j][r2] + bz;
        if (relu) v = fmaxf(v, 0.f);
        C[(long)(mB + r2) * N + n] = v;
      }
    }
  }
}

// ---- bf16 MFMA embed: C[b,s,a] = sum_c X[b,c,s]*W[a,c] + bias + pe - sub ----
__global__ __launch_bounds__(256) void k_mfma_embed(
    const float* __restrict__ X,   // [B,1024,196]
    const float* __restrict__ W,   // [512,1024]
    const float* __restrict__ bias,
    const float* __restrict__ wemb, const float* __restrict__ hemb,
    const float* __restrict__ sub,  // nullptr or [BS,512]
    float* __restrict__ C) {        // [BS,512]
  __shared__ short As[2][128][40];
  __shared__ short Bs[2][128][40];
  const int tid = threadIdx.x;
  const int lane = tid & 63, wave = tid >> 6;
  const int wm = wave >> 1, wn = wave & 1;
  const int m0 = blockIdx.y * 128, n0 = blockIdx.x * 128;
  const int K = 1024, N = 512;
  const int srow = tid >> 1, skh = (tid & 1) * 16;
  const float* Wp = W + (long)(n0 + srow) * K + skh;
  const int arow = tid & 127, khalf = tid >> 7;
  const int am = m0 + arow;
  const int ab = am / 196, as_ = am % 196;
  const float* Xp = X + (long)ab * 200704 + as_;
  const int fr = lane & 15, fq = lane >> 4;
  const int NK = K >> 5;   // 32
  f32x4 acc[4][4] = {};
  float xx[16], yx[16];
  float4 xw[4], yw[4];

  auto ldt = [&](float (&tx)[16], float4 (&tw)[4], int t) {
    const int kb = t * 32;
#pragma unroll
    for (int i = 0; i < 16; ++i) tx[i] = Xp[(long)(kb + 2 * i + khalf) * 196];
    const float* wp = Wp + kb;
#pragma unroll
    for (int i = 0; i < 4; ++i) tw[i] = *(const float4*)(wp + i * 4);
  };
  auto stage = [&](float (&tx)[16], float4 (&tw)[4], int p) {
#pragma unroll
    for (int i = 0; i < 16; ++i) As[p][arow][2 * i + khalf] = f2bf(tx[i]);
    cvt8(&Bs[p][srow][skh], tw[0], tw[1]);
    cvt8(&Bs[p][srow][skh + 8], tw[2], tw[3]);
  };
  auto step = [&](int t, float (&lx)[16], float4 (&lw)[4],
                  float (&cx)[16], float4 (&cw)[4]) {
    const int par = t & 1;
    if (t + 2 < NK) ldt(lx, lw, t + 2);
    bf16x8 af[4], bfr[4];
#pragma unroll
    for (int i = 0; i < 4; ++i) af[i] = *(const bf16x8*)&As[par][wm * 64 + i * 16 + fr][fq * 8];
#pragma unroll
    for (int j = 0; j < 4; ++j) bfr[j] = *(const bf16x8*)&Bs[par][wn * 64 + j * 16 + fr][fq * 8];
    if (t + 1 < NK) stage(cx, cw, par ^ 1);
#pragma unroll
    for (int i = 0; i < 4; ++i)
#pragma unroll
      for (int j = 0; j < 4; ++j)
        acc[i][j] = __builtin_amdgcn_mfma_f32_16x16x32_bf16(af[i], bfr[j], acc[i][j], 0, 0, 0);
    lds_barrier();
  };

  ldt(xx, xw, 0);
  stage(xx, xw, 0);
  if (NK > 1) ldt(xx, xw, 1);
  lds_barrier();
  int t = 0;
  for (; t + 1 < NK; t += 2) { step(t, yx, yw, xx, xw); step(t + 1, xx, xw, yx, yw); }
  if (t < NK) step(t, yx, yw, xx, xw);

#pragma unroll
  for (int i = 0; i < 4; ++i) {
    int mB = m0 + wm * 64 + i * 16 + fq * 4;
#pragma unroll
    for (int j = 0; j < 4; ++j) {
      int n = n0 + wn * 64 + j * 16 + fr;
      float bz = bias[n];
#pragma unroll
      for (int r2 = 0; r2 < 4; ++r2) {
        int m = mB + r2;
        int s = m % 196;
        float pe = (n < 256) ? wemb[(s % 14) * 256 + n] : hemb[(s / 14) * 256 + (n - 256)];
        float v = acc[i][j][r2] + bz + pe;
        if (sub) v -= sub[(long)m * N + n];
        C[(long)m * N + n] = v;
      }
    }
  }
}

// ---- Batched bf16 MFMA NT: C[z][m,n] = scale*sum_k A[z][m,k]*B[z][n,k], opt clamp ----
// 64x64 tile, 4 waves (wave = n-frag). Row-clamped loads, bounded stores.
__global__ __launch_bounds__(256) void k_mfma_bnt(
    const float* __restrict__ A, const float* __restrict__ B, float* __restrict__ C,
    int M, int N, int K, int lda, int ldb, int ldc, int nz2,
    int64_t sA1, int64_t sA2, int64_t sB1, int64_t sB2, int64_t sC1, int64_t sC2,
    float scale, int clampf) {
  __shared__ short As[2][64][40];
  __shared__ short Bs[2][64][40];
  const int tid = threadIdx.x;
  const int lane = tid & 63, wave = tid >> 6;
  const int m0 = blockIdx.y * 64, n0 = blockIdx.x * 64;
  const int z = blockIdx.z, z1 = z / nz2, z2 = z % nz2;
  const float* Ab = A + z1 * sA1 + z2 * sA2;
  const float* Bb = B + z1 * sB1 + z2 * sB2;
  float* Cb = C + z1 * sC1 + z2 * sC2;
  const int sr = tid >> 2, skh = (tid & 3) * 8;
  const int ar = (m0 + sr < M) ? m0 + sr : M - 1;
  const int br = (n0 + sr < N) ? n0 + sr : N - 1;
  const float* Ap = Ab + (long)ar * lda + skh;
  const float* Bp = Bb + (long)br * ldb + skh;
  const int fr = lane & 15, fq = lane >> 4;
  const int NK = K >> 5;
  f32x4 acc[4] = {};
  float4 xa[2], xb[2], ya[2], yb[2];

  auto ldt = [&](float4 (&ta)[2], float4 (&tb)[2], int t) {
    const int kb = t * 32;
#pragma unroll
    for (int i = 0; i < 2; ++i) {
      ta[i] = *(const float4*)(Ap + kb + i * 4);
      tb[i] = *(const float4*)(Bp + kb + i * 4);
    }
  };
  auto stage = [&](float4 (&ta)[2], float4 (&tb)[2], int p) {
    cvt8(&As[p][sr][skh], ta[0], ta[1]);
    cvt8(&Bs[p][sr][skh], tb[0], tb[1]);
  };
  auto step = [&](int t, float4 (&la)[2], float4 (&lb)[2],
                  float4 (&ca)[2], float4 (&cb)[2]) {
    const int par = t & 1;
    if (t + 2 < NK) ldt(la, lb, t + 2);
    bf16x8 bfr = *(const bf16x8*)&Bs[par][wave * 16 + fr][fq * 8];
    bf16x8 af[4];
#pragma unroll
    for (int i = 0; i < 4; ++i) af[i] = *(const bf16x8*)&As[par][i * 16 + fr][fq * 8];
    if (t + 1 < NK) stage(ca, cb, par ^ 1);
#pragma unroll
    for (int i = 0; i < 4; ++i)
      acc[i] = __builtin_amdgcn_mfma_f32_16x16x32_bf16(af[i], bfr, acc[i], 0, 0, 0);
    lds_barrier();
  };

  ldt(xa, xb, 0);
  stage(xa, xb, 0);
  if (NK > 1) ldt(xa, xb, 1);
  lds_barrier();
  int t = 0;
  for (; t + 1 < NK; t += 2) { step(t, ya, yb, xa, xb); step(t + 1, xa, xb, ya, yb); }
  if (t < NK) step(t, ya, yb, xa, xb);

  const int n = n0 + wave * 16 + fr;
  if (n < N) {
#pragma unroll
    for (int i = 0; i < 4; ++i) {
      int mb = m0 + i * 16 + fq * 4;
#pragma unroll
      for (int r2 = 0; r2 < 4; ++r2) {
        int m = mb + r2;
        if (m < M) {
          float v = acc[i][r2] * scale;
          if (clampf) v = fminf(fmaxf(v, -100.f), 100.f);
          Cb[(long)m * ldc + n] = v;
        }
      }
    }
  }
}

// ---- Batched bf16 MFMA NN: C[z][m,n] = sum_k A[z][m,k]*B[z][k,n] ----
// A ld cols all valid (pads are zero); B k-rows clamped to KBvalid-1.
__global__ __launch_bounds__(256) void k_mfma_bnn(
    const float* __restrict__ A, const float* __restrict__ B, float* __restrict__ C,
    int M, int N, int K, int KBvalid, int lda, int ldb, int ldc, int nz2,
    int64_t sA1, int64_t sA2, int64_t sB1, int64_t sB2, int64_t sC1, int64_t sC2) {
  __shared__ short As[2][64][40];
  __shared__ short Bs[2][64][40];
  const int tid = threadIdx.x;
  const int lane = tid & 63, wave = tid >> 6;
  const int m0 = blockIdx.y * 64, n0 = blockIdx.x * 64;
  const int z = blockIdx.z, z1 = z / nz2, z2 = z % nz2;
  const float* Ab = A + z1 * sA1 + z2 * sA2;
  const float* Bb = B + z1 * sB1 + z2 * sB2;
  float* Cb = C + z1 * sC1 + z2 * sC2;
  const int sr = tid >> 2, skh = (tid & 3) * 8;
  const int ar = (m0 + sr < M) ? m0 + sr : M - 1;
  const float* Ap = Ab + (long)ar * lda + skh;
  const int bk = tid >> 3, bn = (tid & 7) * 8;   // B transposed staging
  const int fr = lane & 15, fq = lane >> 4;
  const int NK = K >> 5;   // K=SLD=224 -> 7 (odd, tail handled)
  f32x4 acc[4] = {};
  float4 xa[2], xb[2], ya[2], yb[2];

  auto ldt = [&](float4 (&ta)[2], float4 (&tb)[2], int t) {
    const int kb = t * 32;
#pragma unroll
    for (int i = 0; i < 2; ++i) ta[i] = *(const float4*)(Ap + kb + i * 4);
    int kc = kb + bk;
    if (kc >= KBvalid) kc = KBvalid - 1;
    const float* bp = Bb + (long)kc * ldb + n0 + bn;
#pragma unroll
    for (int i = 0; i < 2; ++i) tb[i] = *(const float4*)(bp + i * 4);
  };
  auto stage = [&](float4 (&ta)[2], float4 (&tb)[2], int p) {
    cvt8(&As[p][sr][skh], ta[0], ta[1]);
    short tmp[8];
    cvt8(tmp, tb[0], tb[1]);
#pragma unroll
    for (int j = 0; j < 8; ++j) Bs[p][bn + j][bk] = tmp[j];
  };
  auto step = [&](int t, float4 (&la)[2], float4 (&lb)[2],
                  float4 (&ca)[2], float4 (&cb)[2]) {
    const int par = t & 1;
    if (t + 2 < NK) ldt(la, lb, t + 2);
    bf16x8 bfr = *(const bf16x8*)&Bs[par][wave * 16 + fr][fq * 8];
    bf16x8 af[4];
#pragma unroll
    for (int i = 0; i < 4; ++i) af[i] = *(const bf16x8*)&As[par][i * 16 + fr][fq * 8];
    if (t + 1 < NK) stage(ca, cb, par ^ 1);
#pragma unroll
    for (int i = 0; i < 4; ++i)
      acc[i] = __builtin_amdgcn_mfma_f32_16x16x32_bf16(af[i], bfr, acc[i], 0, 0, 0);
    lds_barrier();
  };

  ldt(xa, xb, 0);
  stage(xa, xb, 0);
  if (NK > 1) ldt(xa, xb, 1);
  lds_barrier();
  int t = 0;
  for (; t + 1 < NK; t += 2) { step(t, ya, yb, xa, xb); step(t + 1, xa, xb, ya, yb); }
  if (t < NK) step(t, ya, yb, xa, xb);

  const int n = n0 + wave * 16 + fr;
  if (n < N) {
#pragma unroll
    for (int i = 0; i < 4; ++i) {
      int mb = m0 + i * 16 + fq * 4;
#pragma unroll
      for (int r2 = 0; r2 < 4; ++r2) {
        int m = mb + r2;
        if (m < M) Cb[(long)m * ldc + n] = acc[i][r2];
      }
    }
  }
}

// ---- MFMA correlation: C[i,j] += scale * sum_m Za[m,i]*Zb[m,j] (split-K atomic) ----
__global__ __launch_bounds__(256) void k_mfma_corr(
    const float* __restrict__ Za, const float* __restrict__ Zb,
    float* __restrict__ C, int mchunk, float scale) {
  __shared__ short As[2][64][40];
  __shared__ short Bs[2][64][40];
  const int tid = threadIdx.x;
  const int lane = tid & 63, wave = tid >> 6;
  const int i0 = blockIdx.y * 64, j0 = blockIdx.x * 64;
  const int mstart = blockIdx.z * mchunk;
  const int tm = tid >> 3, tcb = (tid & 7) * 8;
  const int fr = lane & 15, fq = lane >> 4;
  const int NK = mchunk >> 5;   // 28
  f32x4 acc[4] = {};
  float4 xa[2], xb[2], ya[2], yb[2];

  auto ldt = [&](float4 (&ta)[2], float4 (&tb)[2], int t) {
    const float* za = Za + (long)(mstart + t * 32 + tm) * 512;
    const float* zb = Zb + (long)(mstart + t * 32 + tm) * 512;
    ta[0] = *(const float4*)(za + i0 + tcb);
    ta[1] = *(const float4*)(za + i0 + tcb + 4);
    tb[0] = *(const float4*)(zb + j0 + tcb);
    tb[1] = *(const float4*)(zb + j0 + tcb + 4);
  };
  auto stage = [&](float4 (&ta)[2], float4 (&tb)[2], int p) {
    short u[8], v[8];
    cvt8(u, ta[0], ta[1]);
    cvt8(v, tb[0], tb[1]);
#pragma unroll
    for (int j = 0; j < 8; ++j) { As[p][tcb + j][tm] = u[j]; Bs[p][tcb + j][tm] = v[j]; }
  };
  auto step = [&](int t, float4 (&la)[2], float4 (&lb)[2],
                  float4 (&ca)[2], float4 (&cb)[2]) {
    const int par = t & 1;
    if (t + 2 < NK) ldt(la, lb, t + 2);
    bf16x8 bfr = *(const bf16x8*)&Bs[par][wave * 16 + fr][fq * 8];
    bf16x8 af[4];
#pragma unroll
    for (int i = 0; i < 4; ++i) af[i] = *(const bf16x8*)&As[par][i * 16 + fr][fq * 8];
    if (t + 1 < NK) stage(ca, cb, par ^ 1);
#pragma unroll
    for (int i = 0; i < 4; ++i)
      acc[i] = __builtin_amdgcn_mfma_f32_16x16x32_bf16(af[i], bfr, acc[i], 0, 0, 0);
    lds_barrier();
  };

  ldt(xa, xb, 0);
  stage(xa, xb, 0);
  if (NK > 1) ldt(xa, xb, 1);
  lds_barrier();
  int t = 0;
  for (; t + 1 < NK; t += 2) { step(t, ya, yb, xa, xb); step(t + 1, xa, xb, ya, yb); }
  if (t < NK) step(t, ya, yb, xa, xb);

  const int j = j0 + wave * 16 + fr;
#pragma unroll
  for (int i = 0; i < 4; ++i) {
    int ib = i0 + i * 16 + fq * 4;
#pragma unroll
    for (int r2 = 0; r2 < 4; ++r2)
      atomicAdd(&C[(long)(ib + r2) * 512 + j], acc[i][r2] * scale);
  }
}

// ---------------- fp32 GEMM fallback (small M) ----------------
__global__ __launch_bounds__(256) void k_gemm_nt(
    const float* __restrict__ A, const float* __restrict__ W,
    const float* __restrict__ bias, float* __restrict__ C,
    int M, int N, int K, int relu) {
  __shared__ float As[16][68];
  __shared__ float Ws[16][68];
  const int tx = threadIdx.x, ty = threadIdx.y;
  const int tid = ty * 16 + tx;
  const int m0 = blockIdx.y * 64, n0 = blockIdx.x * 64;
  const int lr = tid >> 2, lk = (tid & 3) << 2;
  const float* Ap = A + (long)(m0 + lr) * K + lk;
  const float* Wp = W + (long)(n0 + lr) * K + lk;
  float acc[4][4] = {};
  for (int k0 = 0; k0 < K; k0 += 16) {
    float4 av = *(const float4*)(Ap + k0);
    float4 wv = *(const float4*)(Wp + k0);
    As[lk + 0][lr] = av.x; As[lk + 1][lr] = av.y; As[lk + 2][lr] = av.z; As[lk + 3][lr] = av.w;
    Ws[lk + 0][lr] = wv.x; Ws[lk + 1][lr] = wv.y; Ws[lk + 2][lr] = wv.z; Ws[lk + 3][lr] = wv.w;
    __syncthreads();
#pragma unroll
    for (int kk = 0; kk < 16; ++kk) {
      float4 a4 = *(const float4*)&As[kk][ty * 4];
      float4 w4 = *(const float4*)&Ws[kk][tx * 4];
      float a[4] = {a4.x, a4.y, a4.z, a4.w};
      float w[4] = {w4.x, w4.y, w4.z, w4.w};
#pragma unroll
      for (int i = 0; i < 4; ++i)
#pragma unroll
        for (int j = 0; j < 4; ++j) acc[i][j] += a[i] * w[j];
    }
    __syncthreads();
  }
#pragma unroll
  for (int i = 0; i < 4; ++i) {
    int m = m0 + ty * 4 + i;
#pragma unroll
    for (int j = 0; j < 4; ++j) {
      int n = n0 + tx * 4 + j;
      float v = acc[i][j] + bias[n];
      if (relu) v = fmaxf(v, 0.f);
      C[(long)m * N + n] = v;
    }
  }
}

// ---- Row softmax over rows of width 196, ld=SLD(224); zeroes pad cols. 1 wave/row. ----
__global__ __launch_bounds__(256) void k_softmax_rows(float* __restrict__ S, int nrows) {
  int row = blockIdx.x * 4 + (threadIdx.x >> 6);
  int lane = threadIdx.x & 63;
  if (row >= nrows) return;
  float* p = S + (long)row * SLD;
  float v0 = p[lane];
  float v1 = p[lane + 64];
  float v2 = p[lane + 128];
  float v3 = (lane + 192 < 196) ? p[lane + 192] : -1e30f;
  float mx = fmaxf(fmaxf(v0, v1), fmaxf(v2, v3));
#pragma unroll
  for (int o = 32; o > 0; o >>= 1) mx = fmaxf(mx, __shfl_down(mx, o, 64));
  mx = __shfl(mx, 0, 64);
  float e0 = expf(v0 - mx), e1 = expf(v1 - mx), e2 = expf(v2 - mx);
  float e3 = (lane + 192 < 196) ? expf(v3 - mx) : 0.f;
  float s = e0 + e1 + e2 + e3;
#pragma unroll
  for (int o = 32; o > 0; o >>= 1) s += __shfl_down(s, o, 64);
  s = __shfl(s, 0, 64);
  float inv = 1.0f / s;
  p[lane] = e0 * inv;
  p[lane + 64] = e1 * inv;
  p[lane + 128] = e2 * inv;
  if (lane + 192 < SLD) p[lane + 192] = (lane + 192 < 196) ? e3 * inv : 0.f;
}

// ---- Residual + LayerNorm (in place into h) ----
__global__ __launch_bounds__(256) void k_addln(
    float* __restrict__ h, const float* __restrict__ o,
    const float* __restrict__ g, const float* __restrict__ be) {
  __shared__ float red[4];
  long row = blockIdx.x;
  float* hr = h + row * 512;
  const float* orow = o + row * 512;
  int t = threadIdx.x;
  float v0 = hr[t] + orow[t];
  float v1 = hr[t + 256] + orow[t + 256];
  float mean = block_red256(v0 + v1, red, false) * (1.0f / 512.0f);
  float d0 = v0 - mean, d1 = v1 - mean;
  float var = block_red256(d0 * d0 + d1 * d1, red, false) * (1.0f / 512.0f);
  float inv = 1.0f / sqrtf(var + 1e-5f);
  hr[t] = d0 * inv * g[t] + be[t];
  hr[t + 256] = d1 * inv * g[t + 256] + be[t + 256];
}

// ---- small utility kernels ----
__global__ void k_zero(float* __restrict__ p, int n) {
  int i = blockIdx.x * 256 + threadIdx.x;
  if (i < n) p[i] = 0.f;
}

__global__ __launch_bounds__(256) void k_colstats(
    const float* __restrict__ f, float* __restrict__ sums, float* __restrict__ sqs) {
  int c = blockIdx.x * 32 + (threadIdx.x & 31);
  int rbase = blockIdx.y * 256;
  int r0 = rbase + (threadIdx.x >> 5);
  float s = 0.f, s2 = 0.f;
  for (int r = r0; r < rbase + 256; r += 8) {
    float v = f[(long)r * 512 + c];
    s += v; s2 += v * v;
  }
  __shared__ float sh[256], sh2[256];
  sh[threadIdx.x] = s; sh2[threadIdx.x] = s2;
  __syncthreads();
  if (threadIdx.x < 32) {
    for (int i = 1; i < 8; ++i) { s += sh[i * 32 + threadIdx.x]; s2 += sh2[i * 32 + threadIdx.x]; }
    atomicAdd(&sums[c], s);
    atomicAdd(&sqs[c], s2);
  }
}

__global__ void k_finstats(const float* __restrict__ sums, const float* __restrict__ sqs,
                           float* __restrict__ mean, float* __restrict__ istd) {
  int c = blockIdx.x * 256 + threadIdx.x;
  float mu = sums[c] / 12544.0f;
  float var = (sqs[c] - 12544.0f * mu * mu) / 12543.0f;
  mean[c] = mu;
  istd[c] = 1.0f / sqrtf(var);
}

__global__ __launch_bounds__(256) void k_znorm(float* __restrict__ f, const float* __restrict__ mean,
                                               const float* __restrict__ istd) {
  long i = (long)blockIdx.x * 256 + threadIdx.x;
  int c = (int)(i & 511);
  f[i] = (f[i] - mean[c]) * istd[c];
}

// CDCR loss: 256-block partial reduce + final combine
__global__ __launch_bounds__(256) void k_cdcr_part(const float* __restrict__ Cm,
                                                   double* __restrict__ part) {
  int base = blockIdx.x * 1024;
  double on = 0, off = 0;
  for (int i = base + threadIdx.x; i < base + 1024; i += 256) {
    float v = Cm[i];
    int r = i >> 9, c = i & 511;
    if (r == c) { double d = (double)v - 1.0; on += d * d; }
    else        { off += (double)v * (double)v; }
  }
  __shared__ double s_on[256], s_off[256];
  s_on[threadIdx.x] = on; s_off[threadIdx.x] = off;
  __syncthreads();
  for (int st = 128; st > 0; st >>= 1) {
    if (threadIdx.x < st) { s_on[threadIdx.x] += s_on[threadIdx.x + st]; s_off[threadIdx.x] += s_off[threadIdx.x + st]; }
    __syncthreads();
  }
  if (threadIdx.x == 0) { part[blockIdx.x] = s_on[0]; part[256 + blockIdx.x] = s_off[0]; }
}

__global__ void k_cdcr_fin(const double* __restrict__ part, float* __restrict__ out) {
  __shared__ double s_on[256], s_off[256];
  s_on[threadIdx.x] = part[threadIdx.x];
  s_off[threadIdx.x] = part[256 + threadIdx.x];
  __syncthreads();
  for (int st = 128; st > 0; st >>= 1) {
    if (threadIdx.x < st) { s_on[threadIdx.x] += s_on[threadIdx.x + st]; s_off[threadIdx.x] += s_off[threadIdx.x + st]; }
    __syncthreads();
  }
  if (threadIdx.x == 0) out[0] = (float)(s_on[0] + 0.003 * s_off[0]);
}

__global__ __launch_bounds__(64) void k_mask(const float* __restrict__ capo, float* __restrict__ mask) {
  int pidx = blockIdx.x;
  float s = 0.f;
  for (int i = threadIdx.x; i < 512; i += 64) s += capo[(long)pidx * 512 + i];
#pragma unroll
  for (int o = 32; o > 0; o >>= 1) s += __shfl_down(s, o, 64);
  if (threadIdx.x == 0) mask[pidx] = (s != 0.f) ? 1.f : 0.f;
}

__global__ __launch_bounds__(256) void k_meannc(const float* __restrict__ src, const float* __restrict__ mask,
                                                float* __restrict__ vec) {
  int d = blockIdx.x * 256 + threadIdx.x;
  int b = blockIdx.y;
  float acc = 0.f, ms = 0.f;
  for (int nc = 0; nc < 16; ++nc) {
    float mk = mask ? mask[b * 16 + nc] : 1.f;
    acc += src[((long)b * 16 + nc) * 512 + d] * mk;
    ms += mk;
  }
  vec[(long)b * 512 + d] = acc / fmaxf(ms, 1e-6f);
}

__global__ __launch_bounds__(256) void k_mse(const float* __restrict__ full, const float* __restrict__ vec,
                                             double* __restrict__ part) {
  double loc = 0;
  const long n = NOUT;
  for (long i = (long)blockIdx.x * 256 + threadIdx.x; i < n; i += 256L * 1024) {
    int d = (int)(i & 511);
    int b = (int)(i >> 9) / 196;
    float df = full[i] - vec[b * 512 + d];
    loc += (double)df * (double)df;
  }
  __shared__ double sh[256];
  sh[threadIdx.x] = loc;
  __syncthreads();
  for (int st = 128; st > 0; st >>= 1) {
    if (threadIdx.x < st) sh[threadIdx.x] += sh[threadIdx.x + st];
    __syncthreads();
  }
  if (threadIdx.x == 0) part[blockIdx.x] = sh[0];
}

__global__ void k_finloss(const double* __restrict__ part, float* __restrict__ out) {
  __shared__ double sh[256];
  double s = 0;
  for (int i = threadIdx.x; i < 4096; i += 256) s += part[i];
  sh[threadIdx.x] = s;
  __syncthreads();
  for (int st = 128; st > 0; st >>= 1) {
    if (threadIdx.x < st) sh[threadIdx.x] += sh[threadIdx.x + st];
    __syncthreads();
  }
  if (threadIdx.x == 0) out[0] = (float)(sh[0] / (64.0 * 196.0 * 512.0));
}

__global__ __launch_bounds__(256) void k_concat2(float* __restrict__ dst, const float* __restrict__ a,
                                                 const float* __restrict__ b) {
  int i = blockIdx.x * 256 + threadIdx.x;   // 64*1024
  int col = i & 1023, row = i >> 10;
  dst[i] = (col < 512) ? a[row * 512 + col] : b[row * 512 + col - 512];
}

// comb chunk: rows [r0, r0+6272) of [BS,2048] into dst
__global__ __launch_bounds__(256) void k_comb_chunk(
    float* __restrict__ dst, const float* __restrict__ d1, const float* __restrict__ d2,
    const float* __restrict__ txt, const float* __restrict__ al, long r0) {
  long i = (long)blockIdx.x * 256 + threadIdx.x;  // 6272*2048
  int col = (int)(i & 2047);
  long m = r0 + (i >> 11);
  int b = (int)(m / 196);
  float v;
  if (col < 512)       v = d1[m * 512 + col];
  else if (col < 1024) v = d2[m * 512 + col - 512];
  else if (col < 1536) v = txt[(long)b * 512 + col - 1024];
  else                 v = al[(long)b * 512 + col - 1536];
  dst[i] = v;
}

// ---------------- host ----------------
extern "C" void kernel_launch(void* const* d_in, const int* in_sizes, int n_in,
                              void* d_out, int out_size, void* d_ws, size_t ws_size,
                              hipStream_t stream) {
  (void)in_sizes; (void)n_in; (void)out_size; (void)ws_size;
  const float* in1    = (const float*)d_in[0];
  const float* in2    = (const float*)d_in[1];
  const float* cap1   = (const float*)d_in[2];
  const float* cap2   = (const float*)d_in[3];
  const float* imgw   = (const float*)d_in[4];
  const float* imgb   = (const float*)d_in[5];
  const float* wemb   = (const float*)d_in[6];
  const float* hemb   = (const float*)d_in[7];
  const float* mlpw1  = (const float*)d_in[8];
  const float* mlpb1  = (const float*)d_in[9];
  const float* mlpw2  = (const float*)d_in[10];
  const float* mlpb2  = (const float*)d_in[11];
  const float* fcw    = (const float*)d_in[12];
  const float* fcb    = (const float*)d_in[13];
  const float* efcw   = (const float*)d_in[14];
  const float* efcb   = (const float*)d_in[15];
  const float* efc2w  = (const float*)d_in[16];
  const float* efc2b  = (const float*)d_in[17];
  const float* trinw  = (const float*)d_in[18];
  const float* trinb  = (const float*)d_in[19];
  const float* troutw = (const float*)d_in[20];
  const float* troutb = (const float*)d_in[21];
  const float* trlng  = (const float*)d_in[22];
  const float* trlnb  = (const float*)d_in[23];
  const float* itqw = (const float*)d_in[24]; const float* itqb = (const float*)d_in[25];
  const float* itkw = (const float*)d_in[26]; const float* itkb = (const float*)d_in[27];
  const float* itvw = (const float*)d_in[28]; const float* itvb = (const float*)d_in[29];
  const float* caqw = (const float*)d_in[30]; const float* caqb = (const float*)d_in[31];
  const float* cakw = (const float*)d_in[32]; const float* cakb = (const float*)d_in[33];
  const float* cavw = (const float*)d_in[34]; const float* cavb = (const float*)d_in[35];
  const float* saqw = (const float*)d_in[36]; const float* saqb = (const float*)d_in[37];
  const float* sakw = (const float*)d_in[38]; const float* sakb = (const float*)d_in[39];
  const float* savw = (const float*)d_in[40]; const float* savb = (const float*)d_in[41];

  float* out = (float*)d_out;

  // ---- workspace carve (~190 MB total) ----
  const size_t SZ = (size_t)BS * 512;        // 6,422,528 floats (24.5 MB)
  float* w = (float*)d_ws;
  auto alloc = [&](size_t n) { float* p = w; w += n; return p; };
  float* h1 = alloc(SZ);
  float* h2 = alloc(SZ);
  float* tA = alloc(SZ);
  float* tB = alloc(SZ);
  float* tC = alloc(SZ);
  float* tD = alloc(SZ);
  float* sbuf = alloc((size_t)128 * 196 * SLD);  // attention scores (22.5 MB)
  float* cap1o = alloc(64 * 16 * 512);
  float* cap2o = alloc(64 * 16 * 512);
  float* qc1   = alloc(64 * 16 * 512);
  float* qc2   = alloc(64 * 16 * 512);
  float* attb  = alloc(64 * 16 * 512);
  float* cmat  = alloc(512 * 512);
  float* colsum1 = alloc(512); float* colsq1 = alloc(512);
  float* colsum2 = alloc(512); float* colsq2 = alloc(512);
  float* mean1 = alloc(512); float* istd1 = alloc(512);
  float* mean2 = alloc(512); float* istd2 = alloc(512);
  float* mask1 = alloc(1024); float* mask2 = alloc(1024);
  float* vdbef = alloc(64 * 512); float* vdaft = alloc(64 * 512);
  float* vsbef = alloc(64 * 512); float* vsaft = alloc(64 * 512);
  float* cm1 = alloc(64 * 512); float* cm2 = alloc(64 * 512);
  float* vdyn = alloc(64 * 512); float* vsta = alloc(64 * 512);
  float* valign = alloc(64 * 512); float* vtxt = alloc(64 * 512);
  float* ccat = alloc(64 * 1024);
  double* msepart = (double*)alloc(4096 * 2);   // 4096 doubles
  double* cdcrpart = (double*)alloc(1024);      // 512 doubles

  auto gemm = [&](const float* Aa, const float* Ww, const float* bb, float* Cc,
                  int M, int N, int K, int relu) {
    if ((M % 128) == 0 && (N % 128) == 0 && (K % 32) == 0)
      k_mfma_nt<<<dim3(N / 128, M / 128), 256, 0, stream>>>(Aa, Ww, bb, Cc, M, N, K, relu);
    else
      k_gemm_nt<<<dim3(N / 64, (M + 63) / 64), dim3(16, 16), 0, stream>>>(Aa, Ww, bb, Cc, M, N, K, relu);
  };
  auto embed = [&](const float* X, const float* sub, float* Cc) {
    k_mfma_embed<<<dim3(4, BS / 128), 256, 0, stream>>>(X, imgw, imgb, wemb, hemb, sub, Cc);
  };
  const int64_t RB = (int64_t)SS * 512;   // 100352
  const int64_t QB = 16 * 512;            // 8192
  const int64_t ZS = (int64_t)196 * SLD;  // scores per (b,h)
  // GEMM-ized attention for D=512 single-head cases (ECA: M=196, ITDA: M=16)
  auto attn512 = [&](const float* Qp, const float* Kp, const float* Vp, float* Op,
                     int M, int64_t qZ, int64_t oZ, float scale) {
    int mt = (M + 63) / 64;
    int64_t sS = (int64_t)M * SLD;
    k_mfma_bnt<<<dim3(4, mt, 64), 256, 0, stream>>>(
        Qp, Kp, sbuf, M, 196, 512, 512, 512, SLD, 1,
        qZ, 0, RB, 0, sS, 0, scale, 1);
    k_softmax_rows<<<(64 * M + 3) / 4, 256, 0, stream>>>(sbuf, 64 * M);
    k_mfma_bnn<<<dim3(8, mt, 64), 256, 0, stream>>>(
        sbuf, Vp, Op, M, 512, SLD, 196, SLD, 512, 512, 1,
        sS, 0, RB, 0, oZ, 0);
  };
  // GEMM-ized MHA attention: D=64, H=8, chunked 16 batches at a time.
  auto attn_mha = [&](const float* Qp, const float* Kp, const float* Vp, float* Op) {
    for (int cb = 0; cb < 4; ++cb) {
      const float* Qb = Qp + (size_t)cb * 16 * RB;
      const float* Kb = Kp + (size_t)cb * 16 * RB;
      const float* Vb = Vp + (size_t)cb * 16 * RB;
      float* Ob = Op + (size_t)cb * 16 * RB;
      k_mfma_bnt<<<dim3(4, 4, 128), 256, 0, stream>>>(
          Qb, Kb, sbuf, 196, 196, 64, 512, 512, SLD, 8,
          RB, 64, RB, 64, ZS * 8, ZS, 0.125f, 0);
      k_softmax_rows<<<6272, 256, 0, stream>>>(sbuf, 25088);
      k_mfma_bnn<<<dim3(1, 4, 128), 256, 0, stream>>>(
          sbuf, Vb, Ob, 196, 64, SLD, 196, SLD, 512, 512, 8,
          ZS * 8, ZS, RB, 64, RB, 64);
    }
  };

  const float scalE = 1.0f / sqrtf(512.0f);

  // ---- Phase 1: embed (h starts as x) + caption projections ----
  embed(in1, nullptr, h1);
  embed(in2, nullptr, h2);
  gemm(cap1, fcw, fcb, cap1o, 1024, 512, 768, 0);
  gemm(cap2, fcw, fcb, cap2o, 1024, 512, 768, 0);
  k_meannc<<<dim3(2, 64), 256, 0, stream>>>(cap1o, nullptr, cm1);
  k_meannc<<<dim3(2, 64), 256, 0, stream>>>(cap2o, nullptr, cm2);

  // ---- Phase 2: CDCR loss (f1->tA, f2->tB, hidden chunk in tC..tD) ----
  for (int c = 0; c < 2; ++c) {
    const size_t off = (size_t)c * 6272 * 512;
    gemm(h1 + off, mlpw1, mlpb1, tC, 6272, 2048, 512, 1);
    gemm(tC, mlpw2, mlpb2, tA + off, 6272, 512, 2048, 0);
  }
  for (int c = 0; c < 2; ++c) {
    const size_t off = (size_t)c * 6272 * 512;
    gemm(h2 + off, mlpw1, mlpb1, tC, 6272, 2048, 512, 1);
    gemm(tC, mlpw2, mlpb2, tB + off, 6272, 512, 2048, 0);
  }
  k_zero<<<8, 256, 0, stream>>>(colsum1, 2048);  // colsum1..colsq2 contiguous
  k_colstats<<<dim3(16, 49), 256, 0, stream>>>(tA, colsum1, colsq1);
  k_colstats<<<dim3(16, 49), 256, 0, stream>>>(tB, colsum2, colsq2);
  k_finstats<<<2, 256, 0, stream>>>(colsum1, colsq1, mean1, istd1);
  k_finstats<<<2, 256, 0, stream>>>(colsum2, colsq2, mean2, istd2);
  k_znorm<<<25088, 256, 0, stream>>>(tA, mean1, istd1);
  k_znorm<<<25088, 256, 0, stream>>>(tB, mean2, istd2);
  k_zero<<<1024, 256, 0, stream>>>(cmat, 262144);
  k_mfma_corr<<<dim3(8, 8, 14), 256, 0, stream>>>(tA, tB, cmat, BS / 14, 1.0f / (float)BS);
  k_cdcr_part<<<256, 256, 0, stream>>>(cmat, cdcrpart);
  k_cdcr_fin<<<1, 256, 0, stream>>>(cdcrpart, out + NOUT);

  // ---- Phase 3: cross-transformer (2 layers, simultaneous update) ----
  for (int l = 0; l < 2; ++l) {
    const float* Wq = trinw + (size_t)l * 1536 * 512;
    const float* Wk = Wq + 512 * 512;
    const float* Wv = Wq + 2 * 512 * 512;
    const float* bq = trinb + l * 1536;
    const float* bk = bq + 512;
    const float* bv = bq + 1024;
    const float* Wo = troutw + (size_t)l * 512 * 512;
    const float* bo = troutb + l * 512;
    const float* g  = trlng + l * 512;
    const float* be = trlnb + l * 512;
    // dir1: q=h1, kv=h2
    gemm(h1, Wq, bq, tA, BS, 512, 512, 0);
    gemm(h2, Wk, bk, tB, BS, 512, 512, 0);
    gemm(h2, Wv, bv, tC, BS, 512, 512, 0);
    attn_mha(tA, tB, tC, tA);
    gemm(tA, Wo, bo, tD, BS, 512, 512, 0);       // o1 -> tD
    // dir2 projections from ORIGINAL h1,h2
    gemm(h2, Wq, bq, tA, BS, 512, 512, 0);
    gemm(h1, Wk, bk, tB, BS, 512, 512, 0);
    gemm(h1, Wv, bv, tC, BS, 512, 512, 0);
    k_addln<<<BS, 256, 0, stream>>>(h1, tD, g, be);  // h1 consumed above; update now
    attn_mha(tA, tB, tC, tA);
    gemm(tA, Wo, bo, tD, BS, 512, 512, 0);       // o2 -> tD
    k_addln<<<BS, 256, 0, stream>>>(h2, tD, g, be);
  }

  // ---- Phase 4: diffs via embed recompute (deterministic, bitwise-equal x) ----
  embed(in1, h1, tC);   // diff1 = x1 - h1
  embed(in2, h2, tD);   // diff2 = x2 - h2
  // h1, h2 now free

  // ---- Phase 5: ITDA (queries constant over S -> per-(b,nc) attention + masked mean) ----
  gemm(cap1o, itqw, itqb, qc1, 1024, 512, 512, 0);
  gemm(cap2o, itqw, itqb, qc2, 1024, 512, 512, 0);
  k_mask<<<1024, 64, 0, stream>>>(cap1o, mask1);
  k_mask<<<1024, 64, 0, stream>>>(cap2o, mask2);
  // K1,V1 from diff1
  gemm(tC, itkw, itkb, tA, BS, 512, 512, 0);
  gemm(tC, itvw, itvb, tB, BS, 512, 512, 0);
  attn512(qc2, tA, tB, attb, 16, QB, QB, scalE);
  k_meannc<<<dim3(2, 64), 256, 0, stream>>>(attb, mask2, vdbef);   // d_bef
  attn512(qc1, tA, tB, attb, 16, QB, QB, scalE);
  k_meannc<<<dim3(2, 64), 256, 0, stream>>>(attb, mask1, vsbef);   // s_bef
  // K2,V2 from diff2
  gemm(tD, itkw, itkb, tA, BS, 512, 512, 0);
  gemm(tD, itvw, itvb, tB, BS, 512, 512, 0);
  attn512(qc1, tA, tB, attb, 16, QB, QB, scalE);
  k_meannc<<<dim3(2, 64), 256, 0, stream>>>(attb, mask1, vdaft);   // d_aft
  attn512(qc2, tA, tB, attb, 16, QB, QB, scalE);
  k_meannc<<<dim3(2, 64), 256, 0, stream>>>(attb, mask2, vsaft);   // s_aft

  // ---- Phase 6: ECA x4 with immediate MSE vs ITDA vector ----
  auto eca_mse = [&](const float* xq, const float* xkv,
                     const float* qw2, const float* qb2, const float* kw2, const float* kb2,
                     const float* vw2, const float* vb2, const float* vec, double* part) {
    gemm(xq,  qw2, qb2, tA, BS, 512, 512, 0);
    gemm(xkv, kw2, kb2, tB, BS, 512, 512, 0);
    gemm(xkv, vw2, vb2, h1, BS, 512, 512, 0);
    attn512(tA, tB, h1, tA, 196, RB, RB, scalE);
    k_mse<<<1024, 256, 0, stream>>>(tA, vec, part);
  };
  eca_mse(tC, tD, caqw, caqb, cakw, cakb, cavw, cavb, vdbef, msepart);          // c12 vs d_bef
  eca_mse(tD, tC, caqw, caqb, cakw, cakb, cavw, cavb, vdaft, msepart + 1024);   // c21 vs d_aft
  eca_mse(tC, tC, saqw, saqb, sakw, sakb, savw, savb, vsbef, msepart + 2048);   // s11 vs s_bef
  eca_mse(tD, tD, saqw, saqb, sakw, sakb, savw, savb, vsaft, msepart + 3072);   // s22 vs s_aft
  k_finloss<<<1, 256, 0, stream>>>(msepart, out + NOUT + 1);

  // ---- Phase 7: efc chain (per-batch vectors, fp32 path M=64) ----
  k_concat2<<<256, 256, 0, stream>>>(ccat, vdbef, vdaft);
  gemm(ccat, efcw, efcb, vdyn, 64, 512, 1024, 1);
  k_concat2<<<256, 256, 0, stream>>>(ccat, vsbef, vsaft);
  gemm(ccat, efcw, efcb, vsta, 64, 512, 1024, 1);
  k_concat2<<<256, 256, 0, stream>>>(ccat, vdyn, vsta);
  gemm(ccat, efcw, efcb, valign, 64, 512, 1024, 1);
  k_concat2<<<256, 256, 0, stream>>>(ccat, cm1, cm2);
  gemm(ccat, efcw, efcb, vtxt, 64, 512, 1024, 1);

  // ---- Phase 8: final projection, chunked comb (6272 rows/chunk in tA..tB) ----
  for (int c = 0; c < 2; ++c) {
    long r0 = (long)c * 6272;
    k_comb_chunk<<<50176, 256, 0, stream>>>(tA, tC, tD, vtxt, valign, r0);
    gemm(tA, efc2w, efc2b, out + r0 * 512, 6272, 512, 2048, 1);
  }
}

// Round 3
// 3226.234 us; speedup vs baseline: 1.1800x; 1.0491x over previous
//
#include <hip/hip_runtime.h>
#include <hip/hip_bf16.h>
#include <stdint.h>
#include <math.h>

// Problem constants
#define BB   64
#define SS   196
#define BS   12544            // BB*SS
#define NOUT 6422528L         // BS*512
#define SLD  224              // score row ld (7*32)

typedef __attribute__((ext_vector_type(8))) short bf16x8;
typedef __attribute__((ext_vector_type(4))) float f32x4;

// ---------------- device helpers ----------------
__device__ __forceinline__ float block_red256(float v, float* red, bool ismax) {
#pragma unroll
  for (int o = 32; o > 0; o >>= 1) {
    float t = __shfl_down(v, o, 64);
    v = ismax ? fmaxf(v, t) : v + t;
  }
  int lane = threadIdx.x & 63, wid = threadIdx.x >> 6;
  if (lane == 0) red[wid] = v;
  __syncthreads();
  float r = ismax ? fmaxf(fmaxf(red[0], red[1]), fmaxf(red[2], red[3]))
                  : (red[0] + red[1]) + (red[2] + red[3]);
  __syncthreads();
  return r;
}

// HW RNE conversion (v_cvt_pk_bf16_f32 via compiler) — bit-identical to the
// old add-0x7fff bit-trick for all finite values.
__device__ __forceinline__ short f2bf(float f) {
  __hip_bfloat16 h = __float2bfloat16(f);
  short s;
  __builtin_memcpy(&s, &h, 2);
  return s;
}

__device__ __forceinline__ void cvt8(short* dst, float4 a, float4 b) {
  union { short s[8]; int4 v; } u;
  u.s[0] = f2bf(a.x); u.s[1] = f2bf(a.y); u.s[2] = f2bf(a.z); u.s[3] = f2bf(a.w);
  u.s[4] = f2bf(b.x); u.s[5] = f2bf(b.y); u.s[6] = f2bf(b.z); u.s[7] = f2bf(b.w);
  *(int4*)dst = u.v;
}

// Raw barrier: ds ops drained, global loads stay in flight (no vmcnt drain).
__device__ __forceinline__ void lds_barrier() {
  asm volatile("s_waitcnt lgkmcnt(0)" ::: "memory");
  __builtin_amdgcn_s_barrier();
  __builtin_amdgcn_sched_barrier(0);
}

// ---- bf16 MFMA GEMM: C[M,N] = A[M,K] @ W[N,K]^T + bias (opt relu) ----
// 128x128 tile, BK=32, 4 waves (2x2). M%128==0, N%128==0, K%32==0.
// 2-phase pipeline: dbuf LDS, 1-deep reg prefetch, 1 raw barrier/K-step.
__global__ __launch_bounds__(256) void k_mfma_nt(
    const float* __restrict__ A, const float* __restrict__ W,
    const float* __restrict__ bias, float* __restrict__ C,
    int M, int N, int K, int relu) {
  __shared__ short As[2][128][40];
  __shared__ short Bs[2][128][40];
  const int tid = threadIdx.x;
  const int lane = tid & 63, wave = tid >> 6;
  const int wm = wave >> 1, wn = wave & 1;
  const int m0 = blockIdx.y * 128, n0 = blockIdx.x * 128;
  const int srow = tid >> 1, skh = (tid & 1) * 16;
  const float* Ap = A + (long)(m0 + srow) * K + skh;
  const float* Wp = W + (long)(n0 + srow) * K + skh;
  const int fr = lane & 15, fq = lane >> 4;
  const int NK = K >> 5;
  f32x4 acc[4][4] = {};
  float4 xa[4], xw[4], ya[4], yw[4];

  auto ldt = [&](float4 (&ta)[4], float4 (&tw)[4], int t) {
    const float* ap = Ap + t * 32;
    const float* wp = Wp + t * 32;
#pragma unroll
    for (int i = 0; i < 4; ++i) {
      ta[i] = *(const float4*)(ap + i * 4);
      tw[i] = *(const float4*)(wp + i * 4);
    }
  };
  auto stage = [&](float4 (&ta)[4], float4 (&tw)[4], int p) {
    cvt8(&As[p][srow][skh], ta[0], ta[1]);
    cvt8(&As[p][srow][skh + 8], ta[2], ta[3]);
    cvt8(&Bs[p][srow][skh], tw[0], tw[1]);
    cvt8(&Bs[p][srow][skh + 8], tw[2], tw[3]);
  };
  auto step = [&](int t, float4 (&la)[4], float4 (&lw)[4],
                  float4 (&ca)[4], float4 (&cw)[4]) {
    const int par = t & 1;
    if (t + 2 < NK) ldt(la, lw, t + 2);            // prefetch tile t+2
    bf16x8 af[4], bfr[4];
#pragma unroll
    for (int i = 0; i < 4; ++i) af[i] = *(const bf16x8*)&As[par][wm * 64 + i * 16 + fr][fq * 8];
#pragma unroll
    for (int j = 0; j < 4; ++j) bfr[j] = *(const bf16x8*)&Bs[par][wn * 64 + j * 16 + fr][fq * 8];
    if (t + 1 < NK) stage(ca, cw, par ^ 1);        // stage tile t+1
#pragma unroll
    for (int i = 0; i < 4; ++i)
#pragma unroll
      for (int j = 0; j < 4; ++j)
        acc[i][j] = __builtin_amdgcn_mfma_f32_16x16x32_bf16(af[i], bfr[j], acc[i][j], 0, 0, 0);
    lds_barrier();
  };

  ldt(xa, xw, 0);
  stage(xa, xw, 0);
  if (NK > 1) ldt(xa, xw, 1);
  lds_barrier();
  int t = 0;
  for (; t + 1 < NK; t += 2) { step(t, ya, yw, xa, xw); step(t + 1, xa, xw, ya, yw); }
  if (t < NK) step(t, ya, yw, xa, xw);

#pragma unroll
  for (int i = 0; i < 4; ++i) {
    int mB = m0 + wm * 64 + i * 16 + fq * 4;
#pragma unroll
    for (int j = 0; j < 4; ++j) {
      int n = n0 + wn * 64 + j * 16 + fr;
      float bz = bias[n];
#pragma unroll
      for (int r2 = 0; r2 < 4; ++r2) {
        float v = acc[i][j][r2] + bz;
        if (relu) v = fmaxf(v, 0.f);
        C[(long)(mB + r2) * N + n] = v;
      }
    }
  }
}

// ---- bf16 MFMA embed: C[b,s,a] = sum_c X[b,c,s]*W[a,c] + bias + pe - sub ----
__global__ __launch_bounds__(256) void k_mfma_embed(
    const float* __restrict__ X,   // [B,1024,196]
    const float* __restrict__ W,   // [512,1024]
    const float* __restrict__ bias,
    const float* __restrict__ wemb, const float* __restrict__ hemb,
    const float* __restrict__ sub,  // nullptr or [BS,512]
    float* __restrict__ C) {        // [BS,512]
  __shared__ short As[2][128][40];
  __shared__ short Bs[2][128][40];
  const int tid = threadIdx.x;
  const int lane = tid & 63, wave = tid >> 6;
  const int wm = wave >> 1, wn = wave & 1;
  const int m0 = blockIdx.y * 128, n0 = blockIdx.x * 128;
  const int K = 1024, N = 512;
  const int srow = tid >> 1, skh = (tid & 1) * 16;
  const float* Wp = W + (long)(n0 + srow) * K + skh;
  const int arow = tid & 127, khalf = tid >> 7;
  const int am = m0 + arow;
  const int ab = am / 196, as_ = am % 196;
  const float* Xp = X + (long)ab * 200704 + as_;
  const int fr = lane & 15, fq = lane >> 4;
  const int NK = K >> 5;   // 32
  f32x4 acc[4][4] = {};
  float xx[16], yx[16];
  float4 xw[4], yw[4];

  auto ldt = [&](float (&tx)[16], float4 (&tw)[4], int t) {
    const int kb = t * 32 + khalf * 16;
#pragma unroll
    for (int i = 0; i < 16; ++i) tx[i] = Xp[(long)(kb + i) * 196];
    const float* wp = Wp + t * 32;
#pragma unroll
    for (int i = 0; i < 4; ++i) tw[i] = *(const float4*)(wp + i * 4);
  };
  auto stage = [&](float (&tx)[16], float4 (&tw)[4], int p) {
    union { short s[16]; int4 v[2]; } u;
#pragma unroll
    for (int i = 0; i < 16; ++i) u.s[i] = f2bf(tx[i]);
    int4* dst = (int4*)&As[p][arow][khalf * 16];
    dst[0] = u.v[0]; dst[1] = u.v[1];
    cvt8(&Bs[p][srow][skh], tw[0], tw[1]);
    cvt8(&Bs[p][srow][skh + 8], tw[2], tw[3]);
  };
  auto step = [&](int t, float (&lx)[16], float4 (&lw)[4],
                  float (&cx)[16], float4 (&cw)[4]) {
    const int par = t & 1;
    if (t + 2 < NK) ldt(lx, lw, t + 2);
    bf16x8 af[4], bfr[4];
#pragma unroll
    for (int i = 0; i < 4; ++i) af[i] = *(const bf16x8*)&As[par][wm * 64 + i * 16 + fr][fq * 8];
#pragma unroll
    for (int j = 0; j < 4; ++j) bfr[j] = *(const bf16x8*)&Bs[par][wn * 64 + j * 16 + fr][fq * 8];
    if (t + 1 < NK) stage(cx, cw, par ^ 1);
#pragma unroll
    for (int i = 0; i < 4; ++i)
#pragma unroll
      for (int j = 0; j < 4; ++j)
        acc[i][j] = __builtin_amdgcn_mfma_f32_16x16x32_bf16(af[i], bfr[j], acc[i][j], 0, 0, 0);
    lds_barrier();
  };

  ldt(xx, xw, 0);
  stage(xx, xw, 0);
  if (NK > 1) ldt(xx, xw, 1);
  lds_barrier();
  int t = 0;
  for (; t + 1 < NK; t += 2) { step(t, yx, yw, xx, xw); step(t + 1, xx, xw, yx, yw); }
  if (t < NK) step(t, yx, yw, xx, xw);

#pragma unroll
  for (int i = 0; i < 4; ++i) {
    int mB = m0 + wm * 64 + i * 16 + fq * 4;
#pragma unroll
    for (int j = 0; j < 4; ++j) {
      int n = n0 + wn * 64 + j * 16 + fr;
      float bz = bias[n];
#pragma unroll
      for (int r2 = 0; r2 < 4; ++r2) {
        int m = mB + r2;
        int s = m % 196;
        float pe = (n < 256) ? wemb[(s % 14) * 256 + n] : hemb[(s / 14) * 256 + (n - 256)];
        float v = acc[i][j][r2] + bz + pe;
        if (sub) v -= sub[(long)m * N + n];
        C[(long)m * N + n] = v;
      }
    }
  }
}

// ---- Batched bf16 MFMA NT: C[z][m,n] = scale*sum_k A[z][m,k]*B[z][n,k] ----
// Optional clamp, optional bias+relu. 64x64 tile, 4 waves.
__global__ __launch_bounds__(256) void k_mfma_bnt(
    const float* __restrict__ A, const float* __restrict__ B, float* __restrict__ C,
    int M, int N, int K, int lda, int ldb, int ldc, int nz2,
    int64_t sA1, int64_t sA2, int64_t sB1, int64_t sB2, int64_t sC1, int64_t sC2,
    float scale, int clampf, const float* __restrict__ bias2, int relu2) {
  __shared__ short As[2][64][40];
  __shared__ short Bs[2][64][40];
  const int tid = threadIdx.x;
  const int lane = tid & 63, wave = tid >> 6;
  const int m0 = blockIdx.y * 64, n0 = blockIdx.x * 64;
  const int z = blockIdx.z, z1 = z / nz2, z2 = z % nz2;
  const float* Ab = A + z1 * sA1 + z2 * sA2;
  const float* Bb = B + z1 * sB1 + z2 * sB2;
  float* Cb = C + z1 * sC1 + z2 * sC2;
  const int sr = tid >> 2, skh = (tid & 3) * 8;
  const int ar = (m0 + sr < M) ? m0 + sr : M - 1;
  const int br = (n0 + sr < N) ? n0 + sr : N - 1;
  const float* Ap = Ab + (long)ar * lda + skh;
  const float* Bp = Bb + (long)br * ldb + skh;
  const int fr = lane & 15, fq = lane >> 4;
  const int NK = K >> 5;
  f32x4 acc[4] = {};
  float4 xa[2], xb[2], ya[2], yb[2];

  auto ldt = [&](float4 (&ta)[2], float4 (&tb)[2], int t) {
    const int kb = t * 32;
#pragma unroll
    for (int i = 0; i < 2; ++i) {
      ta[i] = *(const float4*)(Ap + kb + i * 4);
      tb[i] = *(const float4*)(Bp + kb + i * 4);
    }
  };
  auto stage = [&](float4 (&ta)[2], float4 (&tb)[2], int p) {
    cvt8(&As[p][sr][skh], ta[0], ta[1]);
    cvt8(&Bs[p][sr][skh], tb[0], tb[1]);
  };
  auto step = [&](int t, float4 (&la)[2], float4 (&lb)[2],
                  float4 (&ca)[2], float4 (&cb)[2]) {
    const int par = t & 1;
    if (t + 2 < NK) ldt(la, lb, t + 2);
    bf16x8 bfr = *(const bf16x8*)&Bs[par][wave * 16 + fr][fq * 8];
    bf16x8 af[4];
#pragma unroll
    for (int i = 0; i < 4; ++i) af[i] = *(const bf16x8*)&As[par][i * 16 + fr][fq * 8];
    if (t + 1 < NK) stage(ca, cb, par ^ 1);
#pragma unroll
    for (int i = 0; i < 4; ++i)
      acc[i] = __builtin_amdgcn_mfma_f32_16x16x32_bf16(af[i], bfr, acc[i], 0, 0, 0);
    lds_barrier();
  };

  ldt(xa, xb, 0);
  stage(xa, xb, 0);
  if (NK > 1) ldt(xa, xb, 1);
  lds_barrier();
  int t = 0;
  for (; t + 1 < NK; t += 2) { step(t, ya, yb, xa, xb); step(t + 1, xa, xb, ya, yb); }
  if (t < NK) step(t, ya, yb, xa, xb);

  const int n = n0 + wave * 16 + fr;
  if (n < N) {
    float bz = bias2 ? bias2[n] : 0.f;
#pragma unroll
    for (int i = 0; i < 4; ++i) {
      int mb = m0 + i * 16 + fq * 4;
#pragma unroll
      for (int r2 = 0; r2 < 4; ++r2) {
        int m = mb + r2;
        if (m < M) {
          float v = acc[i][r2] * scale + bz;
          if (relu2) v = fmaxf(v, 0.f);
          if (clampf) v = fminf(fmaxf(v, -100.f), 100.f);
          Cb[(long)m * ldc + n] = v;
        }
      }
    }
  }
}

// ---- Batched bf16 MFMA NN: C[z][m,n] = sum_k A[z][m,k]*B[z][k,n] ----
// A ld cols all valid (pads are zero); B k-rows clamped to KBvalid-1.
__global__ __launch_bounds__(256) void k_mfma_bnn(
    const float* __restrict__ A, const float* __restrict__ B, float* __restrict__ C,
    int M, int N, int K, int KBvalid, int lda, int ldb, int ldc, int nz2,
    int64_t sA1, int64_t sA2, int64_t sB1, int64_t sB2, int64_t sC1, int64_t sC2) {
  __shared__ short As[2][64][40];
  __shared__ short Bs[2][64][40];
  const int tid = threadIdx.x;
  const int lane = tid & 63, wave = tid >> 6;
  const int m0 = blockIdx.y * 64, n0 = blockIdx.x * 64;
  const int z = blockIdx.z, z1 = z / nz2, z2 = z % nz2;
  const float* Ab = A + z1 * sA1 + z2 * sA2;
  const float* Bb = B + z1 * sB1 + z2 * sB2;
  float* Cb = C + z1 * sC1 + z2 * sC2;
  const int sr = tid >> 2, skh = (tid & 3) * 8;
  const int ar = (m0 + sr < M) ? m0 + sr : M - 1;
  const float* Ap = Ab + (long)ar * lda + skh;
  const int bk = tid >> 3, bn = (tid & 7) * 8;   // B transposed staging
  const int fr = lane & 15, fq = lane >> 4;
  const int NK = K >> 5;   // K=SLD=224 -> 7 (odd, tail handled)
  f32x4 acc[4] = {};
  float4 xa[2], xb[2], ya[2], yb[2];

  auto ldt = [&](float4 (&ta)[2], float4 (&tb)[2], int t) {
    const int kb = t * 32;
#pragma unroll
    for (int i = 0; i < 2; ++i) ta[i] = *(const float4*)(Ap + kb + i * 4);
    int kc = kb + bk;
    if (kc >= KBvalid) kc = KBvalid - 1;
    const float* bp = Bb + (long)kc * ldb + n0 + bn;
#pragma unroll
    for (int i = 0; i < 2; ++i) tb[i] = *(const float4*)(bp + i * 4);
  };
  auto stage = [&](float4 (&ta)[2], float4 (&tb)[2], int p) {
    cvt8(&As[p][sr][skh], ta[0], ta[1]);
    short tmp[8];
    cvt8(tmp, tb[0], tb[1]);
#pragma unroll
    for (int j = 0; j < 8; ++j) Bs[p][bn + j][bk] = tmp[j];
  };
  auto step = [&](int t, float4 (&la)[2], float4 (&lb)[2],
                  float4 (&ca)[2], float4 (&cb)[2]) {
    const int par = t & 1;
    if (t + 2 < NK) ldt(la, lb, t + 2);
    bf16x8 bfr = *(const bf16x8*)&Bs[par][wave * 16 + fr][fq * 8];
    bf16x8 af[4];
#pragma unroll
    for (int i = 0; i < 4; ++i) af[i] = *(const bf16x8*)&As[par][i * 16 + fr][fq * 8];
    if (t + 1 < NK) stage(ca, cb, par ^ 1);
#pragma unroll
    for (int i = 0; i < 4; ++i)
      acc[i] = __builtin_amdgcn_mfma_f32_16x16x32_bf16(af[i], bfr, acc[i], 0, 0, 0);
    lds_barrier();
  };

  ldt(xa, xb, 0);
  stage(xa, xb, 0);
  if (NK > 1) ldt(xa, xb, 1);
  lds_barrier();
  int t = 0;
  for (; t + 1 < NK; t += 2) { step(t, ya, yb, xa, xb); step(t + 1, xa, xb, ya, yb); }
  if (t < NK) step(t, ya, yb, xa, xb);

  const int n = n0 + wave * 16 + fr;
  if (n < N) {
#pragma unroll
    for (int i = 0; i < 4; ++i) {
      int mb = m0 + i * 16 + fq * 4;
#pragma unroll
      for (int r2 = 0; r2 < 4; ++r2) {
        int m = mb + r2;
        if (m < M) Cb[(long)m * ldc + n] = acc[i][r2];
      }
    }
  }
}

// ---- MFMA correlation: C[i,j] += scale * sum_m Za[m,i]*Zb[m,j] (split-K atomic) ----
__global__ __launch_bounds__(256) void k_mfma_corr(
    const float* __restrict__ Za, const float* __restrict__ Zb,
    float* __restrict__ C, int mchunk, float scale) {
  __shared__ short As[2][64][40];
  __shared__ short Bs[2][64][40];
  const int tid = threadIdx.x;
  const int lane = tid & 63, wave = tid >> 6;
  const int i0 = blockIdx.y * 64, j0 = blockIdx.x * 64;
  const int mstart = blockIdx.z * mchunk;
  const int tm = tid >> 3, tcb = (tid & 7) * 8;
  const int fr = lane & 15, fq = lane >> 4;
  const int NK = mchunk >> 5;   // 28
  f32x4 acc[4] = {};
  float4 xa[2], xb[2], ya[2], yb[2];

  auto ldt = [&](float4 (&ta)[2], float4 (&tb)[2], int t) {
    const float* za = Za + (long)(mstart + t * 32 + tm) * 512;
    const float* zb = Zb + (long)(mstart + t * 32 + tm) * 512;
    ta[0] = *(const float4*)(za + i0 + tcb);
    ta[1] = *(const float4*)(za + i0 + tcb + 4);
    tb[0] = *(const float4*)(zb + j0 + tcb);
    tb[1] = *(const float4*)(zb + j0 + tcb + 4);
  };
  auto stage = [&](float4 (&ta)[2], float4 (&tb)[2], int p) {
    short u[8], v[8];
    cvt8(u, ta[0], ta[1]);
    cvt8(v, tb[0], tb[1]);
#pragma unroll
    for (int j = 0; j < 8; ++j) { As[p][tcb + j][tm] = u[j]; Bs[p][tcb + j][tm] = v[j]; }
  };
  auto step = [&](int t, float4 (&la)[2], float4 (&lb)[2],
                  float4 (&ca)[2], float4 (&cb)[2]) {
    const int par = t & 1;
    if (t + 2 < NK) ldt(la, lb, t + 2);
    bf16x8 bfr = *(const bf16x8*)&Bs[par][wave * 16 + fr][fq * 8];
    bf16x8 af[4];
#pragma unroll
    for (int i = 0; i < 4; ++i) af[i] = *(const bf16x8*)&As[par][i * 16 + fr][fq * 8];
    if (t + 1 < NK) stage(ca, cb, par ^ 1);
#pragma unroll
    for (int i = 0; i < 4; ++i)
      acc[i] = __builtin_amdgcn_mfma_f32_16x16x32_bf16(af[i], bfr, acc[i], 0, 0, 0);
    lds_barrier();
  };

  ldt(xa, xb, 0);
  stage(xa, xb, 0);
  if (NK > 1) ldt(xa, xb, 1);
  lds_barrier();
  int t = 0;
  for (; t + 1 < NK; t += 2) { step(t, ya, yb, xa, xb); step(t + 1, xa, xb, ya, yb); }
  if (t < NK) step(t, ya, yb, xa, xb);

  const int j = j0 + wave * 16 + fr;
#pragma unroll
  for (int i = 0; i < 4; ++i) {
    int ib = i0 + i * 16 + fq * 4;
#pragma unroll
    for (int r2 = 0; r2 < 4; ++r2)
      atomicAdd(&C[(long)(ib + r2) * 512 + j], acc[i][r2] * scale);
  }
}

// ---------------- fp32 GEMM fallback (small M, unused hot path) ----------------
__global__ __launch_bounds__(256) void k_gemm_nt(
    const float* __restrict__ A, const float* __restrict__ W,
    const float* __restrict__ bias, float* __restrict__ C,
    int M, int N, int K, int relu) {
  __shared__ float As[16][68];
  __shared__ float Ws[16][68];
  const int tx = threadIdx.x, ty = threadIdx.y;
  const int tid = ty * 16 + tx;
  const int m0 = blockIdx.y * 64, n0 = blockIdx.x * 64;
  const int lr = tid >> 2, lk = (tid & 3) << 2;
  const float* Ap = A + (long)(m0 + lr) * K + lk;
  const float* Wp = W + (long)(n0 + lr) * K + lk;
  float acc[4][4] = {};
  for (int k0 = 0; k0 < K; k0 += 16) {
    float4 av = *(const float4*)(Ap + k0);
    float4 wv = *(const float4*)(Wp + k0);
    As[lk + 0][lr] = av.x; As[lk + 1][lr] = av.y; As[lk + 2][lr] = av.z; As[lk + 3][lr] = av.w;
    Ws[lk + 0][lr] = wv.x; Ws[lk + 1][lr] = wv.y; Ws[lk + 2][lr] = wv.z; Ws[lk + 3][lr] = wv.w;
    __syncthreads();
#pragma unroll
    for (int kk = 0; kk < 16; ++kk) {
      float4 a4 = *(const float4*)&As[kk][ty * 4];
      float4 w4 = *(const float4*)&Ws[kk][tx * 4];
      float a[4] = {a4.x, a4.y, a4.z, a4.w};
      float w[4] = {w4.x, w4.y, w4.z, w4.w};
#pragma unroll
      for (int i = 0; i < 4; ++i)
#pragma unroll
        for (int j = 0; j < 4; ++j) acc[i][j] += a[i] * w[j];
    }
    __syncthreads();
  }
#pragma unroll
  for (int i = 0; i < 4; ++i) {
    int m = m0 + ty * 4 + i;
#pragma unroll
    for (int j = 0; j < 4; ++j) {
      int n = n0 + tx * 4 + j;
      float v = acc[i][j] + bias[n];
      if (relu) v = fmaxf(v, 0.f);
      C[(long)m * N + n] = v;
    }
  }
}

// ---- Row softmax over rows of width 196, ld=SLD(224); zeroes pad cols. 1 wave/row. ----
__global__ __launch_bounds__(256) void k_softmax_rows(float* __restrict__ S, int nrows) {
  int row = blockIdx.x * 4 + (threadIdx.x >> 6);
  int lane = threadIdx.x & 63;
  if (row >= nrows) return;
  float* p = S + (long)row * SLD;
  float v0 = p[lane];
  float v1 = p[lane + 64];
  float v2 = p[lane + 128];
  float v3 = (lane + 192 < 196) ? p[lane + 192] : -1e30f;
  float mx = fmaxf(fmaxf(v0, v1), fmaxf(v2, v3));
#pragma unroll
  for (int o = 32; o > 0; o >>= 1) mx = fmaxf(mx, __shfl_down(mx, o, 64));
  mx = __shfl(mx, 0, 64);
  float e0 = expf(v0 - mx), e1 = expf(v1 - mx), e2 = expf(v2 - mx);
  float e3 = (lane + 192 < 196) ? expf(v3 - mx) : 0.f;
  float s = e0 + e1 + e2 + e3;
#pragma unroll
  for (int o = 32; o > 0; o >>= 1) s += __shfl_down(s, o, 64);
  s = __shfl(s, 0, 64);
  float inv = 1.0f / s;
  p[lane] = e0 * inv;
  p[lane + 64] = e1 * inv;
  p[lane + 128] = e2 * inv;
  if (lane + 192 < SLD) p[lane + 192] = (lane + 192 < 196) ? e3 * inv : 0.f;
}

// ---- Residual + LayerNorm (in place into h) ----
__global__ __launch_bounds__(256) void k_addln(
    float* __restrict__ h, const float* __restrict__ o,
    const float* __restrict__ g, const float* __restrict__ be) {
  __shared__ float red[4];
  long row = blockIdx.x;
  float* hr = h + row * 512;
  const float* orow = o + row * 512;
  int t = threadIdx.x;
  float v0 = hr[t] + orow[t];
  float v1 = hr[t + 256] + orow[t + 256];
  float mean = block_red256(v0 + v1, red, false) * (1.0f / 512.0f);
  float d0 = v0 - mean, d1 = v1 - mean;
  float var = block_red256(d0 * d0 + d1 * d1, red, false) * (1.0f / 512.0f);
  float inv = 1.0f / sqrtf(var + 1e-5f);
  hr[t] = d0 * inv * g[t] + be[t];
  hr[t + 256] = d1 * inv * g[t + 256] + be[t + 256];
}

// ---- small utility kernels ----
__global__ void k_zero(float* __restrict__ p, int n) {
  int i = blockIdx.x * 256 + threadIdx.x;
  if (i < n) p[i] = 0.f;
}

// concat two [512,512] weights into [1024,512] (+ biases into [1024])
__global__ __launch_bounds__(256) void k_catkv(
    float* __restrict__ dw, const float* __restrict__ kw, const float* __restrict__ vw,
    float* __restrict__ db, const float* __restrict__ kb, const float* __restrict__ vb) {
  int i = blockIdx.x * 256 + threadIdx.x;      // 1024*512
  int r = i >> 9;
  dw[i] = (r < 512) ? kw[i] : vw[i - 262144];
  if (i < 1024) db[i] = (i < 512) ? kb[i] : vb[i - 512];
}

__global__ __launch_bounds__(256) void k_colstats(
    const float* __restrict__ f, float* __restrict__ sums, float* __restrict__ sqs) {
  int c = blockIdx.x * 32 + (threadIdx.x & 31);
  int rbase = blockIdx.y * 256;
  int r0 = rbase + (threadIdx.x >> 5);
  float s = 0.f, s2 = 0.f;
  for (int r = r0; r < rbase + 256; r += 8) {
    float v = f[(long)r * 512 + c];
    s += v; s2 += v * v;
  }
  __shared__ float sh[256], sh2[256];
  sh[threadIdx.x] = s; sh2[threadIdx.x] = s2;
  __syncthreads();
  if (threadIdx.x < 32) {
    for (int i = 1; i < 8; ++i) { s += sh[i * 32 + threadIdx.x]; s2 += sh2[i * 32 + threadIdx.x]; }
    atomicAdd(&sums[c], s);
    atomicAdd(&sqs[c], s2);
  }
}

__global__ void k_finstats(const float* __restrict__ sums, const float* __restrict__ sqs,
                           float* __restrict__ mean, float* __restrict__ istd) {
  int c = blockIdx.x * 256 + threadIdx.x;
  float mu = sums[c] / 12544.0f;
  float var = (sqs[c] - 12544.0f * mu * mu) / 12543.0f;
  mean[c] = mu;
  istd[c] = 1.0f / sqrtf(var);
}

__global__ __launch_bounds__(256) void k_znorm(float* __restrict__ f, const float* __restrict__ mean,
                                               const float* __restrict__ istd) {
  long i = (long)blockIdx.x * 256 + threadIdx.x;
  int c = (int)(i & 511);
  f[i] = (f[i] - mean[c]) * istd[c];
}

// CDCR loss: 256-block partial reduce + final combine
__global__ __launch_bounds__(256) void k_cdcr_part(const float* __restrict__ Cm,
                                                   double* __restrict__ part) {
  int base = blockIdx.x * 1024;
  double on = 0, off = 0;
  for (int i = base + threadIdx.x; i < base + 1024; i += 256) {
    float v = Cm[i];
    int r = i >> 9, c = i & 511;
    if (r == c) { double d = (double)v - 1.0; on += d * d; }
    else        { off += (double)v * (double)v; }
  }
  __shared__ double s_on[256], s_off[256];
  s_on[threadIdx.x] = on; s_off[threadIdx.x] = off;
  __syncthreads();
  for (int st = 128; st > 0; st >>= 1) {
    if (threadIdx.x < st) { s_on[threadIdx.x] += s_on[threadIdx.x + st]; s_off[threadIdx.x] += s_off[threadIdx.x + st]; }
    __syncthreads();
  }
  if (threadIdx.x == 0) { part[blockIdx.x] = s_on[0]; part[256 + blockIdx.x] = s_off[0]; }
}

__global__ void k_cdcr_fin(const double* __restrict__ part, float* __restrict__ out) {
  __shared__ double s_on[256], s_off[256];
  s_on[threadIdx.x] = part[threadIdx.x];
  s_off[threadIdx.x] = part[256 + threadIdx.x];
  __syncthreads();
  for (int st = 128; st > 0; st >>= 1) {
    if (threadIdx.x < st) { s_on[threadIdx.x] += s_on[threadIdx.x + st]; s_off[threadIdx.x] += s_off[threadIdx.x + st]; }
    __syncthreads();
  }
  if (threadIdx.x == 0) out[0] = (float)(s_on[0] + 0.003 * s_off[0]);
}

__global__ __launch_bounds__(64) void k_mask(const float* __restrict__ capo, float* __restrict__ mask) {
  int pidx = blockIdx.x;
  float s = 0.f;
  for (int i = threadIdx.x; i < 512; i += 64) s += capo[(long)pidx * 512 + i];
#pragma unroll
  for (int o = 32; o > 0; o >>= 1) s += __shfl_down(s, o, 64);
  if (threadIdx.x == 0) mask[pidx] = (s != 0.f) ? 1.f : 0.f;
}

__global__ __launch_bounds__(256) void k_meannc(const float* __restrict__ src, const float* __restrict__ mask,
                                                float* __restrict__ vec) {
  int d = blockIdx.x * 256 + threadIdx.x;
  int b = blockIdx.y;
  float acc = 0.f, ms = 0.f;
  for (int nc = 0; nc < 16; ++nc) {
    float mk = mask ? mask[b * 16 + nc] : 1.f;
    acc += src[((long)b * 16 + nc) * 512 + d] * mk;
    ms += mk;
  }
  vec[(long)b * 512 + d] = acc / fmaxf(ms, 1e-6f);
}

__global__ __launch_bounds__(256) void k_mse(const float* __restrict__ full, const float* __restrict__ vec,
                                             double* __restrict__ part) {
  double loc = 0;
  const long n = NOUT;
  for (long i = (long)blockIdx.x * 256 + threadIdx.x; i < n; i += 256L * 1024) {
    int d = (int)(i & 511);
    int b = (int)(i >> 9) / 196;
    float df = full[i] - vec[b * 512 + d];
    loc += (double)df * (double)df;
  }
  __shared__ double sh[256];
  sh[threadIdx.x] = loc;
  __syncthreads();
  for (int st = 128; st > 0; st >>= 1) {
    if (threadIdx.x < st) sh[threadIdx.x] += sh[threadIdx.x + st];
    __syncthreads();
  }
  if (threadIdx.x == 0) part[blockIdx.x] = sh[0];
}

__global__ void k_finloss(const double* __restrict__ part, float* __restrict__ out) {
  __shared__ double sh[256];
  double s = 0;
  for (int i = threadIdx.x; i < 4096; i += 256) s += part[i];
  sh[threadIdx.x] = s;
  __syncthreads();
  for (int st = 128; st > 0; st >>= 1) {
    if (threadIdx.x < st) sh[threadIdx.x] += sh[threadIdx.x + st];
    __syncthreads();
  }
  if (threadIdx.x == 0) out[0] = (float)(sh[0] / (64.0 * 196.0 * 512.0));
}

__global__ __launch_bounds__(256) void k_concat2(float* __restrict__ dst, const float* __restrict__ a,
                                                 const float* __restrict__ b) {
  int i = blockIdx.x * 256 + threadIdx.x;   // 64*1024
  int col = i & 1023, row = i >> 10;
  dst[i] = (col < 512) ? a[row * 512 + col] : b[row * 512 + col - 512];
}

// comb chunk: rows [r0, r0+nrows) of [BS,2048] into dst
__global__ __launch_bounds__(256) void k_comb_chunk(
    float* __restrict__ dst, const float* __restrict__ d1, const float* __restrict__ d2,
    const float* __restrict__ txt, const float* __restrict__ al, long r0) {
  long i = (long)blockIdx.x * 256 + threadIdx.x;
  int col = (int)(i & 2047);
  long m = r0 + (i >> 11);
  int b = (int)(m / 196);
  float v;
  if (col < 512)       v = d1[m * 512 + col];
  else if (col < 1024) v = d2[m * 512 + col - 512];
  else if (col < 1536) v = txt[(long)b * 512 + col - 1024];
  else                 v = al[(long)b * 512 + col - 1536];
  dst[i] = v;
}

// ---------------- host ----------------
extern "C" void kernel_launch(void* const* d_in, const int* in_sizes, int n_in,
                              void* d_out, int out_size, void* d_ws, size_t ws_size,
                              hipStream_t stream) {
  (void)in_sizes; (void)n_in; (void)out_size; (void)ws_size;
  const float* in1    = (const float*)d_in[0];
  const float* in2    = (const float*)d_in[1];
  const float* cap1   = (const float*)d_in[2];
  const float* cap2   = (const float*)d_in[3];
  const float* imgw   = (const float*)d_in[4];
  const float* imgb   = (const float*)d_in[5];
  const float* wemb   = (const float*)d_in[6];
  const float* hemb   = (const float*)d_in[7];
  const float* mlpw1  = (const float*)d_in[8];
  const float* mlpb1  = (const float*)d_in[9];
  const float* mlpw2  = (const float*)d_in[10];
  const float* mlpb2  = (const float*)d_in[11];
  const float* fcw    = (const float*)d_in[12];
  const float* fcb    = (const float*)d_in[13];
  const float* efcw   = (const float*)d_in[14];
  const float* efcb   = (const float*)d_in[15];
  const float* efc2w  = (const float*)d_in[16];
  const float* efc2b  = (const float*)d_in[17];
  const float* trinw  = (const float*)d_in[18];
  const float* trinb  = (const float*)d_in[19];
  const float* troutw = (const float*)d_in[20];
  const float* troutb = (const float*)d_in[21];
  const float* trlng  = (const float*)d_in[22];
  const float* trlnb  = (const float*)d_in[23];
  const float* itqw = (const float*)d_in[24]; const float* itqb = (const float*)d_in[25];
  const float* itkw = (const float*)d_in[26]; const float* itkb = (const float*)d_in[27];
  const float* itvw = (const float*)d_in[28]; const float* itvb = (const float*)d_in[29];
  const float* caqw = (const float*)d_in[30]; const float* caqb = (const float*)d_in[31];
  const float* cakw = (const float*)d_in[32]; const float* cakb = (const float*)d_in[33];
  const float* cavw = (const float*)d_in[34]; const float* cavb = (const float*)d_in[35];
  const float* saqw = (const float*)d_in[36]; const float* saqb = (const float*)d_in[37];
  const float* sakw = (const float*)d_in[38]; const float* sakb = (const float*)d_in[39];
  const float* savw = (const float*)d_in[40]; const float* savb = (const float*)d_in[41];

  float* out = (float*)d_out;

  // ---- workspace carve ----
  const size_t SZ = (size_t)BS * 512;        // 6,422,528 floats (24.5 MB)
  float* w = (float*)d_ws;
  auto alloc = [&](size_t n) { float* p = w; w += n; return p; };
  float* h1 = alloc(SZ);
  float* h2 = alloc(SZ);
  float* tA = alloc(SZ);
  float* tB = alloc(SZ);
  float* tC = alloc(SZ);
  float* tD = alloc(SZ);
  float* sbuf = alloc((size_t)128 * 196 * SLD);  // attention scores (22.5 MB)
  float* cap1o = alloc(64 * 16 * 512);
  float* cap2o = alloc(64 * 16 * 512);
  float* qc1   = alloc(64 * 16 * 512);
  float* qc2   = alloc(64 * 16 * 512);
  float* attb  = alloc(64 * 16 * 512);
  float* cmat  = alloc(512 * 512);
  float* colsum1 = alloc(512); float* colsq1 = alloc(512);
  float* colsum2 = alloc(512); float* colsq2 = alloc(512);
  float* mean1 = alloc(512); float* istd1 = alloc(512);
  float* mean2 = alloc(512); float* istd2 = alloc(512);
  float* mask1 = alloc(1024); float* mask2 = alloc(1024);
  float* vdbef = alloc(64 * 512); float* vdaft = alloc(64 * 512);
  float* vsbef = alloc(64 * 512); float* vsaft = alloc(64 * 512);
  float* cm1 = alloc(64 * 512); float* cm2 = alloc(64 * 512);
  float* vdyn = alloc(64 * 512); float* vsta = alloc(64 * 512);
  float* valign = alloc(64 * 512); float* vtxt = alloc(64 * 512);
  float* ccat = alloc(64 * 1024);
  double* msepart = (double*)alloc(4096 * 2);   // 4096 doubles
  double* cdcrpart = (double*)alloc(1024);      // 512 doubles
  float* itkvw = alloc(1024 * 512); float* itkvb = alloc(1024);
  float* cakvw = alloc(1024 * 512); float* cakvb = alloc(1024);
  float* sakvw = alloc(1024 * 512); float* sakvb = alloc(1024);

  auto gemm = [&](const float* Aa, const float* Ww, const float* bb, float* Cc,
                  int M, int N, int K, int relu) {
    if ((M % 128) == 0 && (N % 128) == 0 && (K % 32) == 0)
      k_mfma_nt<<<dim3(N / 128, M / 128), 256, 0, stream>>>(Aa, Ww, bb, Cc, M, N, K, relu);
    else
      k_gemm_nt<<<dim3(N / 64, (M + 63) / 64), dim3(16, 16), 0, stream>>>(Aa, Ww, bb, Cc, M, N, K, relu);
  };
  auto embed = [&](const float* X, const float* sub, float* Cc) {
    k_mfma_embed<<<dim3(4, BS / 128), 256, 0, stream>>>(X, imgw, imgb, wemb, hemb, sub, Cc);
  };
  const int64_t RB = (int64_t)SS * 512;   // 100352
  const int64_t QB = 16 * 512;            // 8192
  const int64_t ZS = (int64_t)196 * SLD;  // scores per (b,h)
  // GEMM-ized attention, D=512 single-head, K|V packed in one [*,1024] buffer.
  auto attn512 = [&](const float* Qp, int64_t qZ, const float* KVp, int64_t kvZ,
                     float* Op, int64_t oZ, int M, float scale) {
    int mt = (M + 63) / 64;
    int64_t sS = (int64_t)M * SLD;
    k_mfma_bnt<<<dim3(4, mt, 64), 256, 0, stream>>>(
        Qp, KVp, sbuf, M, 196, 512, 512, 1024, SLD, 1,
        qZ, 0, kvZ, 0, sS, 0, scale, 1, nullptr, 0);
    k_softmax_rows<<<(64 * M + 3) / 4, 256, 0, stream>>>(sbuf, 64 * M);
    k_mfma_bnn<<<dim3(8, mt, 64), 256, 0, stream>>>(
        sbuf, KVp + 512, Op, M, 512, SLD, 196, SLD, 1024, 512, 1,
        sS, 0, kvZ, 0, oZ, 0);
  };
  // GEMM-ized MHA attention: D=64, H=8, K|V packed [BS,1024], chunks of 16 batches.
  auto attn_mha = [&](const float* Qp, const float* KVp, float* Op) {
    const int64_t sKV = 2 * RB;
    for (int cb = 0; cb < 4; ++cb) {
      const float* Qb = Qp + (size_t)cb * 16 * RB;
      const float* Kb = KVp + (size_t)cb * 16 * sKV;
      const float* Vb = KVp + 512 + (size_t)cb * 16 * sKV;
      float* Ob = Op + (size_t)cb * 16 * RB;
      k_mfma_bnt<<<dim3(4, 4, 128), 256, 0, stream>>>(
          Qb, Kb, sbuf, 196, 196, 64, 512, 1024, SLD, 8,
          RB, 64, sKV, 64, ZS * 8, ZS, 0.125f, 0, nullptr, 0);
      k_softmax_rows<<<6272, 256, 0, stream>>>(sbuf, 25088);
      k_mfma_bnn<<<dim3(1, 4, 128), 256, 0, stream>>>(
          sbuf, Vb, Ob, 196, 64, SLD, 196, SLD, 1024, 512, 8,
          ZS * 8, ZS, sKV, 64, RB, 64);
    }
  };
  // small M=64 GEMM via MFMA (bias+relu)
  auto efc64 = [&](const float* Aa, float* Cc) {
    k_mfma_bnt<<<dim3(8, 1, 1), 256, 0, stream>>>(
        Aa, efcw, Cc, 64, 512, 1024, 1024, 1024, 512, 1,
        0, 0, 0, 0, 0, 0, 1.0f, 0, efcb, 1);
  };

  const float scalE = 1.0f / sqrtf(512.0f);

  // ---- Phase 0: build concat K|V weights for itda/ca/sa ----
  k_catkv<<<2048, 256, 0, stream>>>(itkvw, itkw, itvw, itkvb, itkb, itvb);
  k_catkv<<<2048, 256, 0, stream>>>(cakvw, cakw, cavw, cakvb, cakb, cavb);
  k_catkv<<<2048, 256, 0, stream>>>(sakvw, sakw, savw, sakvb, sakb, savb);

  // ---- Phase 1: embed (h starts as x) + caption projections ----
  embed(in1, nullptr, h1);
  embed(in2, nullptr, h2);
  gemm(cap1, fcw, fcb, cap1o, 1024, 512, 768, 0);
  gemm(cap2, fcw, fcb, cap2o, 1024, 512, 768, 0);
  k_meannc<<<dim3(2, 64), 256, 0, stream>>>(cap1o, nullptr, cm1);
  k_meannc<<<dim3(2, 64), 256, 0, stream>>>(cap2o, nullptr, cm2);

  // ---- Phase 2: CDCR loss (f1->tA, f2->tB, hidden chunk in tC) ----
  for (int c = 0; c < 2; ++c) {
    const size_t off = (size_t)c * 6272 * 512;
    gemm(h1 + off, mlpw1, mlpb1, tC, 6272, 2048, 512, 1);
    gemm(tC, mlpw2, mlpb2, tA + off, 6272, 512, 2048, 0);
  }
  for (int c = 0; c < 2; ++c) {
    const size_t off = (size_t)c * 6272 * 512;
    gemm(h2 + off, mlpw1, mlpb1, tC, 6272, 2048, 512, 1);
    gemm(tC, mlpw2, mlpb2, tB + off, 6272, 512, 2048, 0);
  }
  k_zero<<<8, 256, 0, stream>>>(colsum1, 2048);  // colsum1..colsq2 contiguous
  k_colstats<<<dim3(16, 49), 256, 0, stream>>>(tA, colsum1, colsq1);
  k_colstats<<<dim3(16, 49), 256, 0, stream>>>(tB, colsum2, colsq2);
  k_finstats<<<2, 256, 0, stream>>>(colsum1, colsq1, mean1, istd1);
  k_finstats<<<2, 256, 0, stream>>>(colsum2, colsq2, mean2, istd2);
  k_znorm<<<25088, 256, 0, stream>>>(tA, mean1, istd1);
  k_znorm<<<25088, 256, 0, stream>>>(tB, mean2, istd2);
  k_zero<<<1024, 256, 0, stream>>>(cmat, 262144);
  k_mfma_corr<<<dim3(8, 8, 14), 256, 0, stream>>>(tA, tB, cmat, BS / 14, 1.0f / (float)BS);
  k_cdcr_part<<<256, 256, 0, stream>>>(cmat, cdcrpart);
  k_cdcr_fin<<<1, 256, 0, stream>>>(cdcrpart, out + NOUT);

  // ---- Phase 3: cross-transformer (2 layers, simultaneous update) ----
  // K|V fused per source (Wk,Wv contiguous in trinw; bk,bv contiguous in trinb).
  for (int l = 0; l < 2; ++l) {
    const float* Wq = trinw + (size_t)l * 1536 * 512;
    const float* Wkv = Wq + 512 * 512;               // [Wk;Wv] 1024 rows
    const float* bq = trinb + l * 1536;
    const float* bkv = bq + 512;                     // [bk|bv] 1024
    const float* Wo = troutw + (size_t)l * 512 * 512;
    const float* bo = troutb + l * 512;
    const float* g  = trlng + l * 512;
    const float* be = trlnb + l * 512;
    // dir1: q=h1, kv=h2
    gemm(h1, Wq, bq, tA, BS, 512, 512, 0);           // q1 -> tA
    gemm(h2, Wkv, bkv, tB, BS, 1024, 512, 0);        // kv1 -> tB..tC
    attn_mha(tA, tB, tA);                            // attn out -> tA
    gemm(tA, Wo, bo, tD, BS, 512, 512, 0);           // o1 -> tD
    // dir2 projections from ORIGINAL h1,h2
    gemm(h2, Wq, bq, tA, BS, 512, 512, 0);           // q2 -> tA
    gemm(h1, Wkv, bkv, tB, BS, 1024, 512, 0);        // kv2 -> tB..tC
    k_addln<<<BS, 256, 0, stream>>>(h1, tD, g, be);  // h1 consumed above; update now
    attn_mha(tA, tB, tA);
    gemm(tA, Wo, bo, tD, BS, 512, 512, 0);           // o2 -> tD
    k_addln<<<BS, 256, 0, stream>>>(h2, tD, g, be);
  }

  // ---- Phase 4: diffs via embed recompute (deterministic, bitwise-equal x) ----
  embed(in1, h1, tC);   // diff1 = x1 - h1
  embed(in2, h2, tD);   // diff2 = x2 - h2
  // h1, h2 now free

  // ---- Phase 5: ITDA (queries constant over S -> per-(b,nc) attention + masked mean) ----
  gemm(cap1o, itqw, itqb, qc1, 1024, 512, 512, 0);
  gemm(cap2o, itqw, itqb, qc2, 1024, 512, 512, 0);
  k_mask<<<1024, 64, 0, stream>>>(cap1o, mask1);
  k_mask<<<1024, 64, 0, stream>>>(cap2o, mask2);
  // K|V from diff1 (one N=1024 GEMM)
  gemm(tC, itkvw, itkvb, tA, BS, 1024, 512, 0);      // kv -> tA..tB
  attn512(qc2, QB, tA, 2 * RB, attb, QB, 16, scalE);
  k_meannc<<<dim3(2, 64), 256, 0, stream>>>(attb, mask2, vdbef);   // d_bef
  attn512(qc1, QB, tA, 2 * RB, attb, QB, 16, scalE);
  k_meannc<<<dim3(2, 64), 256, 0, stream>>>(attb, mask1, vsbef);   // s_bef
  // K|V from diff2
  gemm(tD, itkvw, itkvb, tA, BS, 1024, 512, 0);
  attn512(qc1, QB, tA, 2 * RB, attb, QB, 16, scalE);
  k_meannc<<<dim3(2, 64), 256, 0, stream>>>(attb, mask1, vdaft);   // d_aft
  attn512(qc2, QB, tA, 2 * RB, attb, QB, 16, scalE);
  k_meannc<<<dim3(2, 64), 256, 0, stream>>>(attb, mask2, vsaft);   // s_aft

  // ---- Phase 6: ECA x4 with immediate MSE vs ITDA vector ----
  auto eca_mse = [&](const float* xq, const float* xkv,
                     const float* qw2, const float* qb2,
                     const float* kvw2, const float* kvb2,
                     const float* vec, double* part) {
    gemm(xq,  qw2, qb2, h1, BS, 512, 512, 0);        // Q -> h1
    gemm(xkv, kvw2, kvb2, tA, BS, 1024, 512, 0);     // K|V -> tA..tB
    attn512(h1, RB, tA, 2 * RB, h2, RB, 196, scalE); // out -> h2
    k_mse<<<1024, 256, 0, stream>>>(h2, vec, part);
  };
  eca_mse(tC, tD, caqw, caqb, cakvw, cakvb, vdbef, msepart);          // c12 vs d_bef
  eca_mse(tD, tC, caqw, caqb, cakvw, cakvb, vdaft, msepart + 1024);   // c21 vs d_aft
  eca_mse(tC, tC, saqw, saqb, sakvw, sakvb, vsbef, msepart + 2048);   // s11 vs s_bef
  eca_mse(tD, tD, saqw, saqb, sakvw, sakvb, vsaft, msepart + 3072);   // s22 vs s_aft
  k_finloss<<<1, 256, 0, stream>>>(msepart, out + NOUT + 1);

  // ---- Phase 7: efc chain (per-batch vectors, MFMA path M=64) ----
  k_concat2<<<256, 256, 0, stream>>>(ccat, vdbef, vdaft);
  efc64(ccat, vdyn);
  k_concat2<<<256, 256, 0, stream>>>(ccat, vsbef, vsaft);
  efc64(ccat, vsta);
  k_concat2<<<256, 256, 0, stream>>>(ccat, vdyn, vsta);
  efc64(ccat, valign);
  k_concat2<<<256, 256, 0, stream>>>(ccat, cm1, cm2);
  efc64(ccat, vtxt);

  // ---- Phase 8: final projection, single full-M GEMM (comb in h1..tB, 4*SZ) ----
  k_comb_chunk<<<100352, 256, 0, stream>>>(h1, tC, tD, vtxt, valign, 0);
  gemm(h1, efc2w, efc2b, out, BS, 512, 2048, 1);
}

// Round 4
// 3034.313 us; speedup vs baseline: 1.2547x; 1.0633x over previous
//
#include <hip/hip_runtime.h>
#include <hip/hip_bf16.h>
#include <stdint.h>
#include <math.h>

// Problem constants
#define BB   64
#define SS   196
#define BS   12544            // BB*SS
#define NOUT 6422528L         // BS*512
#define SLD  224              // score row ld (7*32)

typedef __attribute__((ext_vector_type(8))) short bf16x8;
typedef __attribute__((ext_vector_type(4))) float f32x4;

// ---------------- device helpers ----------------
__device__ __forceinline__ float block_red256(float v, float* red, bool ismax) {
#pragma unroll
  for (int o = 32; o > 0; o >>= 1) {
    float t = __shfl_down(v, o, 64);
    v = ismax ? fmaxf(v, t) : v + t;
  }
  int lane = threadIdx.x & 63, wid = threadIdx.x >> 6;
  if (lane == 0) red[wid] = v;
  __syncthreads();
  float r = ismax ? fmaxf(fmaxf(red[0], red[1]), fmaxf(red[2], red[3]))
                  : (red[0] + red[1]) + (red[2] + red[3]);
  __syncthreads();
  return r;
}

// HW RNE conversion — bit-identical to the add-0x7fff bit-trick.
__device__ __forceinline__ short f2bf(float f) {
  __hip_bfloat16 h = __float2bfloat16(f);
  short s;
  __builtin_memcpy(&s, &h, 2);
  return s;
}

__device__ __forceinline__ void cvt8(short* dst, float4 a, float4 b) {
  union { short s[8]; int4 v; } u;
  u.s[0] = f2bf(a.x); u.s[1] = f2bf(a.y); u.s[2] = f2bf(a.z); u.s[3] = f2bf(a.w);
  u.s[4] = f2bf(b.x); u.s[5] = f2bf(b.y); u.s[6] = f2bf(b.z); u.s[7] = f2bf(b.w);
  *(int4*)dst = u.v;
}

// Raw barrier: ds ops drained, global loads stay in flight (no vmcnt drain).
__device__ __forceinline__ void lds_barrier() {
  asm volatile("s_waitcnt lgkmcnt(0)" ::: "memory");
  __builtin_amdgcn_s_barrier();
  __builtin_amdgcn_sched_barrier(0);
}

// Bijective XCD-chunked swizzle (m204): HW round-robins linear block id across
// 8 XCDs; remap so each XCD owns a CONTIGUOUS range of logical tiles. With
// row-major (m-major) tile decode, all n-tiles sharing an A-panel land on one
// XCD's L2 -> A fetched ~once instead of once per n-column.
__device__ __forceinline__ int xcd_swizzle(int flat, int nwg) {
  int q = nwg >> 3, r = nwg & 7;
  int xcd = flat & 7, pos = flat >> 3;
  return (xcd < r ? xcd * (q + 1) : r * (q + 1) + (xcd - r) * q) + pos;
}

// ---- bf16 MFMA GEMM: C[M,N] = A[M,K] @ W[N,K]^T + bias (opt relu) ----
// 128x128 tile, BK=32, 4 waves (2x2). M%128==0, N%128==0, K%32==0.
// 2-phase pipeline + XCD-chunked tile swizzle.
__global__ __launch_bounds__(256) void k_mfma_nt(
    const float* __restrict__ A, const float* __restrict__ W,
    const float* __restrict__ bias, float* __restrict__ C,
    int M, int N, int K, int relu) {
  __shared__ short As[2][128][40];
  __shared__ short Bs[2][128][40];
  const int tid = threadIdx.x;
  const int lane = tid & 63, wave = tid >> 6;
  const int wm = wave >> 1, wn = wave & 1;
  const int NX = gridDim.x;
  const int wg = xcd_swizzle(blockIdx.y * NX + blockIdx.x, NX * gridDim.y);
  const int m0 = (wg / NX) * 128, n0 = (wg % NX) * 128;
  const int srow = tid >> 1, skh = (tid & 1) * 16;
  const float* Ap = A + (long)(m0 + srow) * K + skh;
  const float* Wp = W + (long)(n0 + srow) * K + skh;
  const int fr = lane & 15, fq = lane >> 4;
  const int NK = K >> 5;
  f32x4 acc[4][4] = {};
  float4 xa[4], xw[4], ya[4], yw[4];

  auto ldt = [&](float4 (&ta)[4], float4 (&tw)[4], int t) {
    const float* ap = Ap + t * 32;
    const float* wp = Wp + t * 32;
#pragma unroll
    for (int i = 0; i < 4; ++i) {
      ta[i] = *(const float4*)(ap + i * 4);
      tw[i] = *(const float4*)(wp + i * 4);
    }
  };
  auto stage = [&](float4 (&ta)[4], float4 (&tw)[4], int p) {
    cvt8(&As[p][srow][skh], ta[0], ta[1]);
    cvt8(&As[p][srow][skh + 8], ta[2], ta[3]);
    cvt8(&Bs[p][srow][skh], tw[0], tw[1]);
    cvt8(&Bs[p][srow][skh + 8], tw[2], tw[3]);
  };
  auto step = [&](int t, float4 (&la)[4], float4 (&lw)[4],
                  float4 (&ca)[4], float4 (&cw)[4]) {
    const int par = t & 1;
    if (t + 2 < NK) ldt(la, lw, t + 2);            // prefetch tile t+2
    bf16x8 af[4], bfr[4];
#pragma unroll
    for (int i = 0; i < 4; ++i) af[i] = *(const bf16x8*)&As[par][wm * 64 + i * 16 + fr][fq * 8];
#pragma unroll
    for (int j = 0; j < 4; ++j) bfr[j] = *(const bf16x8*)&Bs[par][wn * 64 + j * 16 + fr][fq * 8];
    if (t + 1 < NK) stage(ca, cw, par ^ 1);        // stage tile t+1
#pragma unroll
    for (int i = 0; i < 4; ++i)
#pragma unroll
      for (int j = 0; j < 4; ++j)
        acc[i][j] = __builtin_amdgcn_mfma_f32_16x16x32_bf16(af[i], bfr[j], acc[i][j], 0, 0, 0);
    lds_barrier();
  };

  ldt(xa, xw, 0);
  stage(xa, xw, 0);
  if (NK > 1) ldt(xa, xw, 1);
  lds_barrier();
  int t = 0;
  for (; t + 1 < NK; t += 2) { step(t, ya, yw, xa, xw); step(t + 1, xa, xw, ya, yw); }
  if (t < NK) step(t, ya, yw, xa, xw);

#pragma unroll
  for (int i = 0; i < 4; ++i) {
    int mB = m0 + wm * 64 + i * 16 + fq * 4;
#pragma unroll
    for (int j = 0; j < 4; ++j) {
      int n = n0 + wn * 64 + j * 16 + fr;
      float bz = bias[n];
#pragma unroll
      for (int r2 = 0; r2 < 4; ++r2) {
        float v = acc[i][j][r2] + bz;
        if (relu) v = fmaxf(v, 0.f);
        C[(long)(mB + r2) * N + n] = v;
      }
    }
  }
}

// ---- bf16 MFMA embed: C[b,s,a] = sum_c X[b,c,s]*W[a,c] + bias + pe - sub ----
__global__ __launch_bounds__(256) void k_mfma_embed(
    const float* __restrict__ X,   // [B,1024,196]
    const float* __restrict__ W,   // [512,1024]
    const float* __restrict__ bias,
    const float* __restrict__ wemb, const float* __restrict__ hemb,
    const float* __restrict__ sub,  // nullptr or [BS,512]
    float* __restrict__ C) {        // [BS,512]
  __shared__ short As[2][128][40];
  __shared__ short Bs[2][128][40];
  const int tid = threadIdx.x;
  const int lane = tid & 63, wave = tid >> 6;
  const int wm = wave >> 1, wn = wave & 1;
  const int NX = gridDim.x;
  const int wg = xcd_swizzle(blockIdx.y * NX + blockIdx.x, NX * gridDim.y);
  const int m0 = (wg / NX) * 128, n0 = (wg % NX) * 128;
  const int K = 1024, N = 512;
  const int srow = tid >> 1, skh = (tid & 1) * 16;
  const float* Wp = W + (long)(n0 + srow) * K + skh;
  const int arow = tid & 127, khalf = tid >> 7;
  const int am = m0 + arow;
  const int ab = am / 196, as_ = am % 196;
  const float* Xp = X + (long)ab * 200704 + as_;
  const int fr = lane & 15, fq = lane >> 4;
  const int NK = K >> 5;   // 32
  f32x4 acc[4][4] = {};
  float xx[16], yx[16];
  float4 xw[4], yw[4];

  auto ldt = [&](float (&tx)[16], float4 (&tw)[4], int t) {
    const int kb = t * 32 + khalf * 16;
#pragma unroll
    for (int i = 0; i < 16; ++i) tx[i] = Xp[(long)(kb + i) * 196];
    const float* wp = Wp + t * 32;
#pragma unroll
    for (int i = 0; i < 4; ++i) tw[i] = *(const float4*)(wp + i * 4);
  };
  auto stage = [&](float (&tx)[16], float4 (&tw)[4], int p) {
    union { short s[16]; int4 v[2]; } u;
#pragma unroll
    for (int i = 0; i < 16; ++i) u.s[i] = f2bf(tx[i]);
    int4* dst = (int4*)&As[p][arow][khalf * 16];
    dst[0] = u.v[0]; dst[1] = u.v[1];
    cvt8(&Bs[p][srow][skh], tw[0], tw[1]);
    cvt8(&Bs[p][srow][skh + 8], tw[2], tw[3]);
  };
  auto step = [&](int t, float (&lx)[16], float4 (&lw)[4],
                  float (&cx)[16], float4 (&cw)[4]) {
    const int par = t & 1;
    if (t + 2 < NK) ldt(lx, lw, t + 2);
    bf16x8 af[4], bfr[4];
#pragma unroll
    for (int i = 0; i < 4; ++i) af[i] = *(const bf16x8*)&As[par][wm * 64 + i * 16 + fr][fq * 8];
#pragma unroll
    for (int j = 0; j < 4; ++j) bfr[j] = *(const bf16x8*)&Bs[par][wn * 64 + j * 16 + fr][fq * 8];
    if (t + 1 < NK) stage(cx, cw, par ^ 1);
#pragma unroll
    for (int i = 0; i < 4; ++i)
#pragma unroll
      for (int j = 0; j < 4; ++j)
        acc[i][j] = __builtin_amdgcn_mfma_f32_16x16x32_bf16(af[i], bfr[j], acc[i][j], 0, 0, 0);
    lds_barrier();
  };

  ldt(xx, xw, 0);
  stage(xx, xw, 0);
  if (NK > 1) ldt(xx, xw, 1);
  lds_barrier();
  int t = 0;
  for (; t + 1 < NK; t += 2) { step(t, yx, yw, xx, xw); step(t + 1, xx, xw, yx, yw); }
  if (t < NK) step(t, yx, yw, xx, xw);

#pragma unroll
  for (int i = 0; i < 4; ++i) {
    int mB = m0 + wm * 64 + i * 16 + fq * 4;
#pragma unroll
    for (int j = 0; j < 4; ++j) {
      int n = n0 + wn * 64 + j * 16 + fr;
      float bz = bias[n];
#pragma unroll
      for (int r2 = 0; r2 < 4; ++r2) {
        int m = mB + r2;
        int s = m % 196;
        float pe = (n < 256) ? wemb[(s % 14) * 256 + n] : hemb[(s / 14) * 256 + (n - 256)];
        float v = acc[i][j][r2] + bz + pe;
        if (sub) v -= sub[(long)m * N + n];
        C[(long)m * N + n] = v;
      }
    }
  }
}

// ---- Batched bf16 MFMA NT: C[z][m,n] = scale*sum_k A[z][m,k]*B[z][n,k] ----
// Optional clamp, optional bias+relu. 64x64 tile, 4 waves.
__global__ __launch_bounds__(256) void k_mfma_bnt(
    const float* __restrict__ A, const float* __restrict__ B, float* __restrict__ C,
    int M, int N, int K, int lda, int ldb, int ldc, int nz2,
    int64_t sA1, int64_t sA2, int64_t sB1, int64_t sB2, int64_t sC1, int64_t sC2,
    float scale, int clampf, const float* __restrict__ bias2, int relu2) {
  __shared__ short As[2][64][40];
  __shared__ short Bs[2][64][40];
  const int tid = threadIdx.x;
  const int lane = tid & 63, wave = tid >> 6;
  const int m0 = blockIdx.y * 64, n0 = blockIdx.x * 64;
  const int z = blockIdx.z, z1 = z / nz2, z2 = z % nz2;
  const float* Ab = A + z1 * sA1 + z2 * sA2;
  const float* Bb = B + z1 * sB1 + z2 * sB2;
  float* Cb = C + z1 * sC1 + z2 * sC2;
  const int sr = tid >> 2, skh = (tid & 3) * 8;
  const int ar = (m0 + sr < M) ? m0 + sr : M - 1;
  const int br = (n0 + sr < N) ? n0 + sr : N - 1;
  const float* Ap = Ab + (long)ar * lda + skh;
  const float* Bp = Bb + (long)br * ldb + skh;
  const int fr = lane & 15, fq = lane >> 4;
  const int NK = K >> 5;
  f32x4 acc[4] = {};
  float4 xa[2], xb[2], ya[2], yb[2];

  auto ldt = [&](float4 (&ta)[2], float4 (&tb)[2], int t) {
    const int kb = t * 32;
#pragma unroll
    for (int i = 0; i < 2; ++i) {
      ta[i] = *(const float4*)(Ap + kb + i * 4);
      tb[i] = *(const float4*)(Bp + kb + i * 4);
    }
  };
  auto stage = [&](float4 (&ta)[2], float4 (&tb)[2], int p) {
    cvt8(&As[p][sr][skh], ta[0], ta[1]);
    cvt8(&Bs[p][sr][skh], tb[0], tb[1]);
  };
  auto step = [&](int t, float4 (&la)[2], float4 (&lb)[2],
                  float4 (&ca)[2], float4 (&cb)[2]) {
    const int par = t & 1;
    if (t + 2 < NK) ldt(la, lb, t + 2);
    bf16x8 bfr = *(const bf16x8*)&Bs[par][wave * 16 + fr][fq * 8];
    bf16x8 af[4];
#pragma unroll
    for (int i = 0; i < 4; ++i) af[i] = *(const bf16x8*)&As[par][i * 16 + fr][fq * 8];
    if (t + 1 < NK) stage(ca, cb, par ^ 1);
#pragma unroll
    for (int i = 0; i < 4; ++i)
      acc[i] = __builtin_amdgcn_mfma_f32_16x16x32_bf16(af[i], bfr, acc[i], 0, 0, 0);
    lds_barrier();
  };

  ldt(xa, xb, 0);
  stage(xa, xb, 0);
  if (NK > 1) ldt(xa, xb, 1);
  lds_barrier();
  int t = 0;
  for (; t + 1 < NK; t += 2) { step(t, ya, yb, xa, xb); step(t + 1, xa, xb, ya, yb); }
  if (t < NK) step(t, ya, yb, xa, xb);

  const int n = n0 + wave * 16 + fr;
  if (n < N) {
    float bz = bias2 ? bias2[n] : 0.f;
#pragma unroll
    for (int i = 0; i < 4; ++i) {
      int mb = m0 + i * 16 + fq * 4;
#pragma unroll
      for (int r2 = 0; r2 < 4; ++r2) {
        int m = mb + r2;
        if (m < M) {
          float v = acc[i][r2] * scale + bz;
          if (relu2) v = fmaxf(v, 0.f);
          if (clampf) v = fminf(fmaxf(v, -100.f), 100.f);
          Cb[(long)m * ldc + n] = v;
        }
      }
    }
  }
}

// ---- Batched bf16 MFMA NN: C[z][m,n] = sum_k A[z][m,k]*B[z][k,n] ----
// A ld cols all valid (pads are zero); B k-rows clamped to KBvalid-1.
__global__ __launch_bounds__(256) void k_mfma_bnn(
    const float* __restrict__ A, const float* __restrict__ B, float* __restrict__ C,
    int M, int N, int K, int KBvalid, int lda, int ldb, int ldc, int nz2,
    int64_t sA1, int64_t sA2, int64_t sB1, int64_t sB2, int64_t sC1, int64_t sC2) {
  __shared__ short As[2][64][40];
  __shared__ short Bs[2][64][40];
  const int tid = threadIdx.x;
  const int lane = tid & 63, wave = tid >> 6;
  const int m0 = blockIdx.y * 64, n0 = blockIdx.x * 64;
  const int z = blockIdx.z, z1 = z / nz2, z2 = z % nz2;
  const float* Ab = A + z1 * sA1 + z2 * sA2;
  const float* Bb = B + z1 * sB1 + z2 * sB2;
  float* Cb = C + z1 * sC1 + z2 * sC2;
  const int sr = tid >> 2, skh = (tid & 3) * 8;
  const int ar = (m0 + sr < M) ? m0 + sr : M - 1;
  const float* Ap = Ab + (long)ar * lda + skh;
  const int bk = tid >> 3, bn = (tid & 7) * 8;   // B transposed staging
  const int fr = lane & 15, fq = lane >> 4;
  const int NK = K >> 5;   // K=SLD=224 -> 7 (odd, tail handled)
  f32x4 acc[4] = {};
  float4 xa[2], xb[2], ya[2], yb[2];

  auto ldt = [&](float4 (&ta)[2], float4 (&tb)[2], int t) {
    const int kb = t * 32;
#pragma unroll
    for (int i = 0; i < 2; ++i) ta[i] = *(const float4*)(Ap + kb + i * 4);
    int kc = kb + bk;
    if (kc >= KBvalid) kc = KBvalid - 1;
    const float* bp = Bb + (long)kc * ldb + n0 + bn;
#pragma unroll
    for (int i = 0; i < 2; ++i) tb[i] = *(const float4*)(bp + i * 4);
  };
  auto stage = [&](float4 (&ta)[2], float4 (&tb)[2], int p) {
    cvt8(&As[p][sr][skh], ta[0], ta[1]);
    short tmp[8];
    cvt8(tmp, tb[0], tb[1]);
#pragma unroll
    for (int j = 0; j < 8; ++j) Bs[p][bn + j][bk] = tmp[j];
  };
  auto step = [&](int t, float4 (&la)[2], float4 (&lb)[2],
                  float4 (&ca)[2], float4 (&cb)[2]) {
    const int par = t & 1;
    if (t + 2 < NK) ldt(la, lb, t + 2);
    bf16x8 bfr = *(const bf16x8*)&Bs[par][wave * 16 + fr][fq * 8];
    bf16x8 af[4];
#pragma unroll
    for (int i = 0; i < 4; ++i) af[i] = *(const bf16x8*)&As[par][i * 16 + fr][fq * 8];
    if (t + 1 < NK) stage(ca, cb, par ^ 1);
#pragma unroll
    for (int i = 0; i < 4; ++i)
      acc[i] = __builtin_amdgcn_mfma_f32_16x16x32_bf16(af[i], bfr, acc[i], 0, 0, 0);
    lds_barrier();
  };

  ldt(xa, xb, 0);
  stage(xa, xb, 0);
  if (NK > 1) ldt(xa, xb, 1);
  lds_barrier();
  int t = 0;
  for (; t + 1 < NK; t += 2) { step(t, ya, yb, xa, xb); step(t + 1, xa, xb, ya, yb); }
  if (t < NK) step(t, ya, yb, xa, xb);

  const int n = n0 + wave * 16 + fr;
  if (n < N) {
#pragma unroll
    for (int i = 0; i < 4; ++i) {
      int mb = m0 + i * 16 + fq * 4;
#pragma unroll
      for (int r2 = 0; r2 < 4; ++r2) {
        int m = mb + r2;
        if (m < M) Cb[(long)m * ldc + n] = acc[i][r2];
      }
    }
  }
}

// ---- MFMA correlation: C[i,j] += scale * sum_m Za[m,i]*Zb[m,j] (split-K atomic) ----
__global__ __launch_bounds__(256) void k_mfma_corr(
    const float* __restrict__ Za, const float* __restrict__ Zb,
    float* __restrict__ C, int mchunk, float scale) {
  __shared__ short As[2][64][40];
  __shared__ short Bs[2][64][40];
  const int tid = threadIdx.x;
  const int lane = tid & 63, wave = tid >> 6;
  const int i0 = blockIdx.y * 64, j0 = blockIdx.x * 64;
  const int mstart = blockIdx.z * mchunk;
  const int tm = tid >> 3, tcb = (tid & 7) * 8;
  const int fr = lane & 15, fq = lane >> 4;
  const int NK = mchunk >> 5;   // 28
  f32x4 acc[4] = {};
  float4 xa[2], xb[2], ya[2], yb[2];

  auto ldt = [&](float4 (&ta)[2], float4 (&tb)[2], int t) {
    const float* za = Za + (long)(mstart + t * 32 + tm) * 512;
    const float* zb = Zb + (long)(mstart + t * 32 + tm) * 512;
    ta[0] = *(const float4*)(za + i0 + tcb);
    ta[1] = *(const float4*)(za + i0 + tcb + 4);
    tb[0] = *(const float4*)(zb + j0 + tcb);
    tb[1] = *(const float4*)(zb + j0 + tcb + 4);
  };
  auto stage = [&](float4 (&ta)[2], float4 (&tb)[2], int p) {
    short u[8], v[8];
    cvt8(u, ta[0], ta[1]);
    cvt8(v, tb[0], tb[1]);
#pragma unroll
    for (int j = 0; j < 8; ++j) { As[p][tcb + j][tm] = u[j]; Bs[p][tcb + j][tm] = v[j]; }
  };
  auto step = [&](int t, float4 (&la)[2], float4 (&lb)[2],
                  float4 (&ca)[2], float4 (&cb)[2]) {
    const int par = t & 1;
    if (t + 2 < NK) ldt(la, lb, t + 2);
    bf16x8 bfr = *(const bf16x8*)&Bs[par][wave * 16 + fr][fq * 8];
    bf16x8 af[4];
#pragma unroll
    for (int i = 0; i < 4; ++i) af[i] = *(const bf16x8*)&As[par][i * 16 + fr][fq * 8];
    if (t + 1 < NK) stage(ca, cb, par ^ 1);
#pragma unroll
    for (int i = 0; i < 4; ++i)
      acc[i] = __builtin_amdgcn_mfma_f32_16x16x32_bf16(af[i], bfr, acc[i], 0, 0, 0);
    lds_barrier();
  };

  ldt(xa, xb, 0);
  stage(xa, xb, 0);
  if (NK > 1) ldt(xa, xb, 1);
  lds_barrier();
  int t = 0;
  for (; t + 1 < NK; t += 2) { step(t, ya, yb, xa, xb); step(t + 1, xa, xb, ya, yb); }
  if (t < NK) step(t, ya, yb, xa, xb);

  const int j = j0 + wave * 16 + fr;
#pragma unroll
  for (int i = 0; i < 4; ++i) {
    int ib = i0 + i * 16 + fq * 4;
#pragma unroll
    for (int r2 = 0; r2 < 4; ++r2)
      atomicAdd(&C[(long)(ib + r2) * 512 + j], acc[i][r2] * scale);
  }
}

// ---------------- fp32 GEMM fallback (small M, unused hot path) ----------------
__global__ __launch_bounds__(256) void k_gemm_nt(
    const float* __restrict__ A, const float* __restrict__ W,
    const float* __restrict__ bias, float* __restrict__ C,
    int M, int N, int K, int relu) {
  __shared__ float As[16][68];
  __shared__ float Ws[16][68];
  const int tx = threadIdx.x, ty = threadIdx.y;
  const int tid = ty * 16 + tx;
  const int m0 = blockIdx.y * 64, n0 = blockIdx.x * 64;
  const int lr = tid >> 2, lk = (tid & 3) << 2;
  const float* Ap = A + (long)(m0 + lr) * K + lk;
  const float* Wp = W + (long)(n0 + lr) * K + lk;
  float acc[4][4] = {};
  for (int k0 = 0; k0 < K; k0 += 16) {
    float4 av = *(const float4*)(Ap + k0);
    float4 wv = *(const float4*)(Wp + k0);
    As[lk + 0][lr] = av.x; As[lk + 1][lr] = av.y; As[lk + 2][lr] = av.z; As[lk + 3][lr] = av.w;
    Ws[lk + 0][lr] = wv.x; Ws[lk + 1][lr] = wv.y; Ws[lk + 2][lr] = wv.z; Ws[lk + 3][lr] = wv.w;
    __syncthreads();
#pragma unroll
    for (int kk = 0; kk < 16; ++kk) {
      float4 a4 = *(const float4*)&As[kk][ty * 4];
      float4 w4 = *(const float4*)&Ws[kk][tx * 4];
      float a[4] = {a4.x, a4.y, a4.z, a4.w};
      float w[4] = {w4.x, w4.y, w4.z, w4.w};
#pragma unroll
      for (int i = 0; i < 4; ++i)
#pragma unroll
        for (int j = 0; j < 4; ++j) acc[i][j] += a[i] * w[j];
    }
    __syncthreads();
  }
#pragma unroll
  for (int i = 0; i < 4; ++i) {
    int m = m0 + ty * 4 + i;
#pragma unroll
    for (int j = 0; j < 4; ++j) {
      int n = n0 + tx * 4 + j;
      float v = acc[i][j] + bias[n];
      if (relu) v = fmaxf(v, 0.f);
      C[(long)m * N + n] = v;
    }
  }
}

// ---- Row softmax over rows of width 196, ld=SLD(224); zeroes pad cols. 1 wave/row. ----
__global__ __launch_bounds__(256) void k_softmax_rows(float* __restrict__ S, int nrows) {
  int row = blockIdx.x * 4 + (threadIdx.x >> 6);
  int lane = threadIdx.x & 63;
  if (row >= nrows) return;
  float* p = S + (long)row * SLD;
  float v0 = p[lane];
  float v1 = p[lane + 64];
  float v2 = p[lane + 128];
  float v3 = (lane + 192 < 196) ? p[lane + 192] : -1e30f;
  float mx = fmaxf(fmaxf(v0, v1), fmaxf(v2, v3));
#pragma unroll
  for (int o = 32; o > 0; o >>= 1) mx = fmaxf(mx, __shfl_down(mx, o, 64));
  mx = __shfl(mx, 0, 64);
  float e0 = expf(v0 - mx), e1 = expf(v1 - mx), e2 = expf(v2 - mx);
  float e3 = (lane + 192 < 196) ? expf(v3 - mx) : 0.f;
  float s = e0 + e1 + e2 + e3;
#pragma unroll
  for (int o = 32; o > 0; o >>= 1) s += __shfl_down(s, o, 64);
  s = __shfl(s, 0, 64);
  float inv = 1.0f / s;
  p[lane] = e0 * inv;
  p[lane + 64] = e1 * inv;
  p[lane + 128] = e2 * inv;
  if (lane + 192 < SLD) p[lane + 192] = (lane + 192 < 196) ? e3 * inv : 0.f;
}

// ---- Residual + LayerNorm (in place into h) ----
__global__ __launch_bounds__(256) void k_addln(
    float* __restrict__ h, const float* __restrict__ o,
    const float* __restrict__ g, const float* __restrict__ be) {
  __shared__ float red[4];
  long row = blockIdx.x;
  float* hr = h + row * 512;
  const float* orow = o + row * 512;
  int t = threadIdx.x;
  float v0 = hr[t] + orow[t];
  float v1 = hr[t + 256] + orow[t + 256];
  float mean = block_red256(v0 + v1, red, false) * (1.0f / 512.0f);
  float d0 = v0 - mean, d1 = v1 - mean;
  float var = block_red256(d0 * d0 + d1 * d1, red, false) * (1.0f / 512.0f);
  float inv = 1.0f / sqrtf(var + 1e-5f);
  hr[t] = d0 * inv * g[t] + be[t];
  hr[t + 256] = d1 * inv * g[t + 256] + be[t + 256];
}

// ---- small utility kernels ----
__global__ void k_zero(float* __restrict__ p, int n) {
  int i = blockIdx.x * 256 + threadIdx.x;
  if (i < n) p[i] = 0.f;
}

// concat two [512,512] weights into [1024,512] (+ biases into [1024])
__global__ __launch_bounds__(256) void k_catkv(
    float* __restrict__ dw, const float* __restrict__ kw, const float* __restrict__ vw,
    float* __restrict__ db, const float* __restrict__ kb, const float* __restrict__ vb) {
  int i = blockIdx.x * 256 + threadIdx.x;      // 1024*512
  int r = i >> 9;
  dw[i] = (r < 512) ? kw[i] : vw[i - 262144];
  if (i < 1024) db[i] = (i < 512) ? kb[i] : vb[i - 512];
}

__global__ __launch_bounds__(256) void k_colstats(
    const float* __restrict__ f, float* __restrict__ sums, float* __restrict__ sqs) {
  int c = blockIdx.x * 32 + (threadIdx.x & 31);
  int rbase = blockIdx.y * 256;
  int r0 = rbase + (threadIdx.x >> 5);
  float s = 0.f, s2 = 0.f;
  for (int r = r0; r < rbase + 256; r += 8) {
    float v = f[(long)r * 512 + c];
    s += v; s2 += v * v;
  }
  __shared__ float sh[256], sh2[256];
  sh[threadIdx.x] = s; sh2[threadIdx.x] = s2;
  __syncthreads();
  if (threadIdx.x < 32) {
    for (int i = 1; i < 8; ++i) { s += sh[i * 32 + threadIdx.x]; s2 += sh2[i * 32 + threadIdx.x]; }
    atomicAdd(&sums[c], s);
    atomicAdd(&sqs[c], s2);
  }
}

__global__ void k_finstats(const float* __restrict__ sums, const float* __restrict__ sqs,
                           float* __restrict__ mean, float* __restrict__ istd) {
  int c = blockIdx.x * 256 + threadIdx.x;
  float mu = sums[c] / 12544.0f;
  float var = (sqs[c] - 12544.0f * mu * mu) / 12543.0f;
  mean[c] = mu;
  istd[c] = 1.0f / sqrtf(var);
}

__global__ __launch_bounds__(256) void k_znorm(float* __restrict__ f, const float* __restrict__ mean,
                                               const float* __restrict__ istd) {
  long i = (long)blockIdx.x * 256 + threadIdx.x;
  int c = (int)(i & 511);
  f[i] = (f[i] - mean[c]) * istd[c];
}

// CDCR loss: 256-block partial reduce + final combine
__global__ __launch_bounds__(256) void k_cdcr_part(const float* __restrict__ Cm,
                                                   double* __restrict__ part) {
  int base = blockIdx.x * 1024;
  double on = 0, off = 0;
  for (int i = base + threadIdx.x; i < base + 1024; i += 256) {
    float v = Cm[i];
    int r = i >> 9, c = i & 511;
    if (r == c) { double d = (double)v - 1.0; on += d * d; }
    else        { off += (double)v * (double)v; }
  }
  __shared__ double s_on[256], s_off[256];
  s_on[threadIdx.x] = on; s_off[threadIdx.x] = off;
  __syncthreads();
  for (int st = 128; st > 0; st >>= 1) {
    if (threadIdx.x < st) { s_on[threadIdx.x] += s_on[threadIdx.x + st]; s_off[threadIdx.x] += s_off[threadIdx.x + st]; }
    __syncthreads();
  }
  if (threadIdx.x == 0) { part[blockIdx.x] = s_on[0]; part[256 + blockIdx.x] = s_off[0]; }
}

__global__ void k_cdcr_fin(const double* __restrict__ part, float* __restrict__ out) {
  __shared__ double s_on[256], s_off[256];
  s_on[threadIdx.x] = part[threadIdx.x];
  s_off[threadIdx.x] = part[256 + threadIdx.x];
  __syncthreads();
  for (int st = 128; st > 0; st >>= 1) {
    if (threadIdx.x < st) { s_on[threadIdx.x] += s_on[threadIdx.x + st]; s_off[threadIdx.x] += s_off[threadIdx.x + st]; }
    __syncthreads();
  }
  if (threadIdx.x == 0) out[0] = (float)(s_on[0] + 0.003 * s_off[0]);
}

__global__ __launch_bounds__(64) void k_mask(const float* __restrict__ capo, float* __restrict__ mask) {
  int pidx = blockIdx.x;
  float s = 0.f;
  for (int i = threadIdx.x; i < 512; i += 64) s += capo[(long)pidx * 512 + i];
#pragma unroll
  for (int o = 32; o > 0; o >>= 1) s += __shfl_down(s, o, 64);
  if (threadIdx.x == 0) mask[pidx] = (s != 0.f) ? 1.f : 0.f;
}

__global__ __launch_bounds__(256) void k_meannc(const float* __restrict__ src, const float* __restrict__ mask,
                                                float* __restrict__ vec) {
  int d = blockIdx.x * 256 + threadIdx.x;
  int b = blockIdx.y;
  float acc = 0.f, ms = 0.f;
  for (int nc = 0; nc < 16; ++nc) {
    float mk = mask ? mask[b * 16 + nc] : 1.f;
    acc += src[((long)b * 16 + nc) * 512 + d] * mk;
    ms += mk;
  }
  vec[(long)b * 512 + d] = acc / fmaxf(ms, 1e-6f);
}

__global__ __launch_bounds__(256) void k_mse(const float* __restrict__ full, const float* __restrict__ vec,
                                             double* __restrict__ part) {
  double loc = 0;
  const long n = NOUT;
  for (long i = (long)blockIdx.x * 256 + threadIdx.x; i < n; i += 256L * 1024) {
    int d = (int)(i & 511);
    int b = (int)(i >> 9) / 196;
    float df = full[i] - vec[b * 512 + d];
    loc += (double)df * (double)df;
  }
  __shared__ double sh[256];
  sh[threadIdx.x] = loc;
  __syncthreads();
  for (int st = 128; st > 0; st >>= 1) {
    if (threadIdx.x < st) sh[threadIdx.x] += sh[threadIdx.x + st];
    __syncthreads();
  }
  if (threadIdx.x == 0) part[blockIdx.x] = sh[0];
}

__global__ void k_finloss(const double* __restrict__ part, float* __restrict__ out) {
  __shared__ double sh[256];
  double s = 0;
  for (int i = threadIdx.x; i < 4096; i += 256) s += part[i];
  sh[threadIdx.x] = s;
  __syncthreads();
  for (int st = 128; st > 0; st >>= 1) {
    if (threadIdx.x < st) sh[threadIdx.x] += sh[threadIdx.x + st];
    __syncthreads();
  }
  if (threadIdx.x == 0) out[0] = (float)(sh[0] / (64.0 * 196.0 * 512.0));
}

__global__ __launch_bounds__(256) void k_concat2(float* __restrict__ dst, const float* __restrict__ a,
                                                 const float* __restrict__ b) {
  int i = blockIdx.x * 256 + threadIdx.x;   // 64*1024
  int col = i & 1023, row = i >> 10;
  dst[i] = (col < 512) ? a[row * 512 + col] : b[row * 512 + col - 512];
}

// comb chunk: rows [r0, r0+nrows) of [BS,2048] into dst
__global__ __launch_bounds__(256) void k_comb_chunk(
    float* __restrict__ dst, const float* __restrict__ d1, const float* __restrict__ d2,
    const float* __restrict__ txt, const float* __restrict__ al, long r0) {
  long i = (long)blockIdx.x * 256 + threadIdx.x;
  int col = (int)(i & 2047);
  long m = r0 + (i >> 11);
  int b = (int)(m / 196);
  float v;
  if (col < 512)       v = d1[m * 512 + col];
  else if (col < 1024) v = d2[m * 512 + col - 512];
  else if (col < 1536) v = txt[(long)b * 512 + col - 1024];
  else                 v = al[(long)b * 512 + col - 1536];
  dst[i] = v;
}

// ---------------- host ----------------
extern "C" void kernel_launch(void* const* d_in, const int* in_sizes, int n_in,
                              void* d_out, int out_size, void* d_ws, size_t ws_size,
                              hipStream_t stream) {
  (void)in_sizes; (void)n_in; (void)out_size; (void)ws_size;
  const float* in1    = (const float*)d_in[0];
  const float* in2    = (const float*)d_in[1];
  const float* cap1   = (const float*)d_in[2];
  const float* cap2   = (const float*)d_in[3];
  const float* imgw   = (const float*)d_in[4];
  const float* imgb   = (const float*)d_in[5];
  const float* wemb   = (const float*)d_in[6];
  const float* hemb   = (const float*)d_in[7];
  const float* mlpw1  = (const float*)d_in[8];
  const float* mlpb1  = (const float*)d_in[9];
  const float* mlpw2  = (const float*)d_in[10];
  const float* mlpb2  = (const float*)d_in[11];
  const float* fcw    = (const float*)d_in[12];
  const float* fcb    = (const float*)d_in[13];
  const float* efcw   = (const float*)d_in[14];
  const float* efcb   = (const float*)d_in[15];
  const float* efc2w  = (const float*)d_in[16];
  const float* efc2b  = (const float*)d_in[17];
  const float* trinw  = (const float*)d_in[18];
  const float* trinb  = (const float*)d_in[19];
  const float* troutw = (const float*)d_in[20];
  const float* troutb = (const float*)d_in[21];
  const float* trlng  = (const float*)d_in[22];
  const float* trlnb  = (const float*)d_in[23];
  const float* itqw = (const float*)d_in[24]; const float* itqb = (const float*)d_in[25];
  const float* itkw = (const float*)d_in[26]; const float* itkb = (const float*)d_in[27];
  const float* itvw = (const float*)d_in[28]; const float* itvb = (const float*)d_in[29];
  const float* caqw = (const float*)d_in[30]; const float* caqb = (const float*)d_in[31];
  const float* cakw = (const float*)d_in[32]; const float* cakb = (const float*)d_in[33];
  const float* cavw = (const float*)d_in[34]; const float* cavb = (const float*)d_in[35];
  const float* saqw = (const float*)d_in[36]; const float* saqb = (const float*)d_in[37];
  const float* sakw = (const float*)d_in[38]; const float* sakb = (const float*)d_in[39];
  const float* savw = (const float*)d_in[40]; const float* savb = (const float*)d_in[41];

  float* out = (float*)d_out;

  // ---- workspace carve ----
  const size_t SZ = (size_t)BS * 512;        // 6,422,528 floats (24.5 MB)
  float* w = (float*)d_ws;
  auto alloc = [&](size_t n) { float* p = w; w += n; return p; };
  float* h1 = alloc(SZ);
  float* h2 = alloc(SZ);
  float* tA = alloc(SZ);
  float* tB = alloc(SZ);
  float* tC = alloc(SZ);
  float* tD = alloc(SZ);
  float* sbuf = alloc((size_t)128 * 196 * SLD);  // attention scores (22.5 MB)
  float* cap1o = alloc(64 * 16 * 512);
  float* cap2o = alloc(64 * 16 * 512);
  float* qc1   = alloc(64 * 16 * 512);
  float* qc2   = alloc(64 * 16 * 512);
  float* attb  = alloc(64 * 16 * 512);
  float* cmat  = alloc(512 * 512);
  float* colsum1 = alloc(512); float* colsq1 = alloc(512);
  float* colsum2 = alloc(512); float* colsq2 = alloc(512);
  float* mean1 = alloc(512); float* istd1 = alloc(512);
  float* mean2 = alloc(512); float* istd2 = alloc(512);
  float* mask1 = alloc(1024); float* mask2 = alloc(1024);
  float* vdbef = alloc(64 * 512); float* vdaft = alloc(64 * 512);
  float* vsbef = alloc(64 * 512); float* vsaft = alloc(64 * 512);
  float* cm1 = alloc(64 * 512); float* cm2 = alloc(64 * 512);
  float* vdyn = alloc(64 * 512); float* vsta = alloc(64 * 512);
  float* valign = alloc(64 * 512); float* vtxt = alloc(64 * 512);
  float* ccat = alloc(64 * 1024);
  double* msepart = (double*)alloc(4096 * 2);   // 4096 doubles
  double* cdcrpart = (double*)alloc(1024);      // 512 doubles
  float* itkvw = alloc(1024 * 512); float* itkvb = alloc(1024);
  float* cakvw = alloc(1024 * 512); float* cakvb = alloc(1024);
  float* sakvw = alloc(1024 * 512); float* sakvb = alloc(1024);

  auto gemm = [&](const float* Aa, const float* Ww, const float* bb, float* Cc,
                  int M, int N, int K, int relu) {
    if ((M % 128) == 0 && (N % 128) == 0 && (K % 32) == 0)
      k_mfma_nt<<<dim3(N / 128, M / 128), 256, 0, stream>>>(Aa, Ww, bb, Cc, M, N, K, relu);
    else
      k_gemm_nt<<<dim3(N / 64, (M + 63) / 64), dim3(16, 16), 0, stream>>>(Aa, Ww, bb, Cc, M, N, K, relu);
  };
  auto embed = [&](const float* X, const float* sub, float* Cc) {
    k_mfma_embed<<<dim3(4, BS / 128), 256, 0, stream>>>(X, imgw, imgb, wemb, hemb, sub, Cc);
  };
  const int64_t RB = (int64_t)SS * 512;   // 100352
  const int64_t QB = 16 * 512;            // 8192
  const int64_t ZS = (int64_t)196 * SLD;  // scores per (b,h)
  // GEMM-ized attention, D=512 single-head, K|V packed in one [*,1024] buffer.
  auto attn512 = [&](const float* Qp, int64_t qZ, const float* KVp, int64_t kvZ,
                     float* Op, int64_t oZ, int M, float scale) {
    int mt = (M + 63) / 64;
    int64_t sS = (int64_t)M * SLD;
    k_mfma_bnt<<<dim3(4, mt, 64), 256, 0, stream>>>(
        Qp, KVp, sbuf, M, 196, 512, 512, 1024, SLD, 1,
        qZ, 0, kvZ, 0, sS, 0, scale, 1, nullptr, 0);
    k_softmax_rows<<<(64 * M + 3) / 4, 256, 0, stream>>>(sbuf, 64 * M);
    k_mfma_bnn<<<dim3(8, mt, 64), 256, 0, stream>>>(
        sbuf, KVp + 512, Op, M, 512, SLD, 196, SLD, 1024, 512, 1,
        sS, 0, kvZ, 0, oZ, 0);
  };
  // GEMM-ized MHA attention: D=64, H=8, K|V packed [BS,1024], chunks of 16 batches.
  auto attn_mha = [&](const float* Qp, const float* KVp, float* Op) {
    const int64_t sKV = 2 * RB;
    for (int cb = 0; cb < 4; ++cb) {
      const float* Qb = Qp + (size_t)cb * 16 * RB;
      const float* Kb = KVp + (size_t)cb * 16 * sKV;
      const float* Vb = KVp + 512 + (size_t)cb * 16 * sKV;
      float* Ob = Op + (size_t)cb * 16 * RB;
      k_mfma_bnt<<<dim3(4, 4, 128), 256, 0, stream>>>(
          Qb, Kb, sbuf, 196, 196, 64, 512, 1024, SLD, 8,
          RB, 64, sKV, 64, ZS * 8, ZS, 0.125f, 0, nullptr, 0);
      k_softmax_rows<<<6272, 256, 0, stream>>>(sbuf, 25088);
      k_mfma_bnn<<<dim3(1, 4, 128), 256, 0, stream>>>(
          sbuf, Vb, Ob, 196, 64, SLD, 196, SLD, 1024, 512, 8,
          ZS * 8, ZS, sKV, 64, RB, 64);
    }
  };
  // small M=64 GEMM via MFMA (bias+relu)
  auto efc64 = [&](const float* Aa, float* Cc) {
    k_mfma_bnt<<<dim3(8, 1, 1), 256, 0, stream>>>(
        Aa, efcw, Cc, 64, 512, 1024, 1024, 1024, 512, 1,
        0, 0, 0, 0, 0, 0, 1.0f, 0, efcb, 1);
  };

  const float scalE = 1.0f / sqrtf(512.0f);

  // ---- Phase 0: build concat K|V weights for itda/ca/sa ----
  k_catkv<<<2048, 256, 0, stream>>>(itkvw, itkw, itvw, itkvb, itkb, itvb);
  k_catkv<<<2048, 256, 0, stream>>>(cakvw, cakw, cavw, cakvb, cakb, cavb);
  k_catkv<<<2048, 256, 0, stream>>>(sakvw, sakw, savw, sakvb, sakb, savb);

  // ---- Phase 1: embed (h starts as x) + caption projections ----
  embed(in1, nullptr, h1);
  embed(in2, nullptr, h2);
  gemm(cap1, fcw, fcb, cap1o, 1024, 512, 768, 0);
  gemm(cap2, fcw, fcb, cap2o, 1024, 512, 768, 0);
  k_meannc<<<dim3(2, 64), 256, 0, stream>>>(cap1o, nullptr, cm1);
  k_meannc<<<dim3(2, 64), 256, 0, stream>>>(cap2o, nullptr, cm2);

  // ---- Phase 2: CDCR loss (f1->tA, f2->tB, hidden chunk in tC) ----
  for (int c = 0; c < 2; ++c) {
    const size_t off = (size_t)c * 6272 * 512;
    gemm(h1 + off, mlpw1, mlpb1, tC, 6272, 2048, 512, 1);
    gemm(tC, mlpw2, mlpb2, tA + off, 6272, 512, 2048, 0);
  }
  for (int c = 0; c < 2; ++c) {
    const size_t off = (size_t)c * 6272 * 512;
    gemm(h2 + off, mlpw1, mlpb1, tC, 6272, 2048, 512, 1);
    gemm(tC, mlpw2, mlpb2, tB + off, 6272, 512, 2048, 0);
  }
  k_zero<<<8, 256, 0, stream>>>(colsum1, 2048);  // colsum1..colsq2 contiguous
  k_colstats<<<dim3(16, 49), 256, 0, stream>>>(tA, colsum1, colsq1);
  k_colstats<<<dim3(16, 49), 256, 0, stream>>>(tB, colsum2, colsq2);
  k_finstats<<<2, 256, 0, stream>>>(colsum1, colsq1, mean1, istd1);
  k_finstats<<<2, 256, 0, stream>>>(colsum2, colsq2, mean2, istd2);
  k_znorm<<<25088, 256, 0, stream>>>(tA, mean1, istd1);
  k_znorm<<<25088, 256, 0, stream>>>(tB, mean2, istd2);
  k_zero<<<1024, 256, 0, stream>>>(cmat, 262144);
  k_mfma_corr<<<dim3(8, 8, 14), 256, 0, stream>>>(tA, tB, cmat, BS / 14, 1.0f / (float)BS);
  k_cdcr_part<<<256, 256, 0, stream>>>(cmat, cdcrpart);
  k_cdcr_fin<<<1, 256, 0, stream>>>(cdcrpart, out + NOUT);

  // ---- Phase 3: cross-transformer (2 layers, simultaneous update) ----
  // K|V fused per source (Wk,Wv contiguous in trinw; bk,bv contiguous in trinb).
  for (int l = 0; l < 2; ++l) {
    const float* Wq = trinw + (size_t)l * 1536 * 512;
    const float* Wkv = Wq + 512 * 512;               // [Wk;Wv] 1024 rows
    const float* bq = trinb + l * 1536;
    const float* bkv = bq + 512;                     // [bk|bv] 1024
    const float* Wo = troutw + (size_t)l * 512 * 512;
    const float* bo = troutb + l * 512;
    const float* g  = trlng + l * 512;
    const float* be = trlnb + l * 512;
    // dir1: q=h1, kv=h2
    gemm(h1, Wq, bq, tA, BS, 512, 512, 0);           // q1 -> tA
    gemm(h2, Wkv, bkv, tB, BS, 1024, 512, 0);        // kv1 -> tB..tC
    attn_mha(tA, tB, tA);                            // attn out -> tA
    gemm(tA, Wo, bo, tD, BS, 512, 512, 0);           // o1 -> tD
    // dir2 projections from ORIGINAL h1,h2
    gemm(h2, Wq, bq, tA, BS, 512, 512, 0);           // q2 -> tA
    gemm(h1, Wkv, bkv, tB, BS, 1024, 512, 0);        // kv2 -> tB..tC
    k_addln<<<BS, 256, 0, stream>>>(h1, tD, g, be);  // h1 consumed above; update now
    attn_mha(tA, tB, tA);
    gemm(tA, Wo, bo, tD, BS, 512, 512, 0);           // o2 -> tD
    k_addln<<<BS, 256, 0, stream>>>(h2, tD, g, be);
  }

  // ---- Phase 4: diffs via embed recompute (deterministic, bitwise-equal x) ----
  embed(in1, h1, tC);   // diff1 = x1 - h1
  embed(in2, h2, tD);   // diff2 = x2 - h2
  // h1, h2 now free

  // ---- Phase 5: ITDA (queries constant over S -> per-(b,nc) attention + masked mean) ----
  gemm(cap1o, itqw, itqb, qc1, 1024, 512, 512, 0);
  gemm(cap2o, itqw, itqb, qc2, 1024, 512, 512, 0);
  k_mask<<<1024, 64, 0, stream>>>(cap1o, mask1);
  k_mask<<<1024, 64, 0, stream>>>(cap2o, mask2);
  // K|V from diff1 (one N=1024 GEMM)
  gemm(tC, itkvw, itkvb, tA, BS, 1024, 512, 0);      // kv -> tA..tB
  attn512(qc2, QB, tA, 2 * RB, attb, QB, 16, scalE);
  k_meannc<<<dim3(2, 64), 256, 0, stream>>>(attb, mask2, vdbef);   // d_bef
  attn512(qc1, QB, tA, 2 * RB, attb, QB, 16, scalE);
  k_meannc<<<dim3(2, 64), 256, 0, stream>>>(attb, mask1, vsbef);   // s_bef
  // K|V from diff2
  gemm(tD, itkvw, itkvb, tA, BS, 1024, 512, 0);
  attn512(qc1, QB, tA, 2 * RB, attb, QB, 16, scalE);
  k_meannc<<<dim3(2, 64), 256, 0, stream>>>(attb, mask1, vdaft);   // d_aft
  attn512(qc2, QB, tA, 2 * RB, attb, QB, 16, scalE);
  k_meannc<<<dim3(2, 64), 256, 0, stream>>>(attb, mask2, vsaft);   // s_aft

  // ---- Phase 6: ECA x4 with immediate MSE vs ITDA vector ----
  auto eca_mse = [&](const float* xq, const float* xkv,
                     const float* qw2, const float* qb2,
                     const float* kvw2, const float* kvb2,
                     const float* vec, double* part) {
    gemm(xq,  qw2, qb2, h1, BS, 512, 512, 0);        // Q -> h1
    gemm(xkv, kvw2, kvb2, tA, BS, 1024, 512, 0);     // K|V -> tA..tB
    attn512(h1, RB, tA, 2 * RB, h2, RB, 196, scalE); // out -> h2
    k_mse<<<1024, 256, 0, stream>>>(h2, vec, part);
  };
  eca_mse(tC, tD, caqw, caqb, cakvw, cakvb, vdbef, msepart);          // c12 vs d_bef
  eca_mse(tD, tC, caqw, caqb, cakvw, cakvb, vdaft, msepart + 1024);   // c21 vs d_aft
  eca_mse(tC, tC, saqw, saqb, sakvw, sakvb, vsbef, msepart + 2048);   // s11 vs s_bef
  eca_mse(tD, tD, saqw, saqb, sakvw, sakvb, vsaft, msepart + 3072);   // s22 vs s_aft
  k_finloss<<<1, 256, 0, stream>>>(msepart, out + NOUT + 1);

  // ---- Phase 7: efc chain (per-batch vectors, MFMA path M=64) ----
  k_concat2<<<256, 256, 0, stream>>>(ccat, vdbef, vdaft);
  efc64(ccat, vdyn);
  k_concat2<<<256, 256, 0, stream>>>(ccat, vsbef, vsaft);
  efc64(ccat, vsta);
  k_concat2<<<256, 256, 0, stream>>>(ccat, vdyn, vsta);
  efc64(ccat, valign);
  k_concat2<<<256, 256, 0, stream>>>(ccat, cm1, cm2);
  efc64(ccat, vtxt);

  // ---- Phase 8: final projection, single full-M GEMM (comb in h1..tB, 4*SZ) ----
  k_comb_chunk<<<100352, 256, 0, stream>>>(h1, tC, tD, vtxt, valign, 0);
  gemm(h1, efc2w, efc2b, out, BS, 512, 2048, 1);
}

// Round 5
// 2659.638 us; speedup vs baseline: 1.4314x; 1.1409x over previous
//
#include <hip/hip_runtime.h>
#include <hip/hip_bf16.h>
#include <stdint.h>
#include <math.h>

// Problem constants
#define BB   64
#define SS   196
#define BS   12544            // BB*SS
#define NOUT 6422528L         // BS*512
#define SLD  224              // score row ld (7*32)

typedef __attribute__((ext_vector_type(8))) short bf16x8;
typedef __attribute__((ext_vector_type(4))) float f32x4;

// ---------------- device helpers ----------------
__device__ __forceinline__ float block_red256(float v, float* red, bool ismax) {
#pragma unroll
  for (int o = 32; o > 0; o >>= 1) {
    float t = __shfl_down(v, o, 64);
    v = ismax ? fmaxf(v, t) : v + t;
  }
  int lane = threadIdx.x & 63, wid = threadIdx.x >> 6;
  if (lane == 0) red[wid] = v;
  __syncthreads();
  float r = ismax ? fmaxf(fmaxf(red[0], red[1]), fmaxf(red[2], red[3]))
                  : (red[0] + red[1]) + (red[2] + red[3]);
  __syncthreads();
  return r;
}

// HW RNE conversion — bit-identical to the add-0x7fff bit-trick.
__device__ __forceinline__ short f2bf(float f) {
  __hip_bfloat16 h = __float2bfloat16(f);
  short s;
  __builtin_memcpy(&s, &h, 2);
  return s;
}

__device__ __forceinline__ void cvt8(short* dst, float4 a, float4 b) {
  union { short s[8]; int4 v; } u;
  u.s[0] = f2bf(a.x); u.s[1] = f2bf(a.y); u.s[2] = f2bf(a.z); u.s[3] = f2bf(a.w);
  u.s[4] = f2bf(b.x); u.s[5] = f2bf(b.y); u.s[6] = f2bf(b.z); u.s[7] = f2bf(b.w);
  *(int4*)dst = u.v;
}

// Raw barrier: ds ops drained, global loads stay in flight (no vmcnt drain).
__device__ __forceinline__ void lds_barrier() {
  asm volatile("s_waitcnt lgkmcnt(0)" ::: "memory");
  __builtin_amdgcn_s_barrier();
  __builtin_amdgcn_sched_barrier(0);
}

// Bijective XCD-chunked swizzle (m204).
__device__ __forceinline__ int xcd_swizzle(int flat, int nwg) {
  int q = nwg >> 3, r = nwg & 7;
  int xcd = flat & 7, pos = flat >> 3;
  return (xcd < r ? xcd * (q + 1) : r * (q + 1) + (xcd - r) * q) + pos;
}

// ---- bf16 MFMA GEMM: C[M,N] = A[M,K] @ W[N,K]^T + bias (opt relu) ----
// 128x128 tile, BK=32, 4 waves (2x2). 2-phase pipeline + XCD swizzle.
__global__ __launch_bounds__(256) void k_mfma_nt(
    const float* __restrict__ A, const float* __restrict__ W,
    const float* __restrict__ bias, float* __restrict__ C,
    int M, int N, int K, int relu) {
  __shared__ short As[2][128][40];
  __shared__ short Bs[2][128][40];
  const int tid = threadIdx.x;
  const int lane = tid & 63, wave = tid >> 6;
  const int wm = wave >> 1, wn = wave & 1;
  const int NX = gridDim.x;
  const int wg = xcd_swizzle(blockIdx.y * NX + blockIdx.x, NX * gridDim.y);
  const int m0 = (wg / NX) * 128, n0 = (wg % NX) * 128;
  const int srow = tid >> 1, skh = (tid & 1) * 16;
  const float* Ap = A + (long)(m0 + srow) * K + skh;
  const float* Wp = W + (long)(n0 + srow) * K + skh;
  const int fr = lane & 15, fq = lane >> 4;
  const int NK = K >> 5;
  f32x4 acc[4][4] = {};
  float4 xa[4], xw[4], ya[4], yw[4];

  auto ldt = [&](float4 (&ta)[4], float4 (&tw)[4], int t) {
    const float* ap = Ap + t * 32;
    const float* wp = Wp + t * 32;
#pragma unroll
    for (int i = 0; i < 4; ++i) {
      ta[i] = *(const float4*)(ap + i * 4);
      tw[i] = *(const float4*)(wp + i * 4);
    }
  };
  auto stage = [&](float4 (&ta)[4], float4 (&tw)[4], int p) {
    cvt8(&As[p][srow][skh], ta[0], ta[1]);
    cvt8(&As[p][srow][skh + 8], ta[2], ta[3]);
    cvt8(&Bs[p][srow][skh], tw[0], tw[1]);
    cvt8(&Bs[p][srow][skh + 8], tw[2], tw[3]);
  };
  auto step = [&](int t, float4 (&la)[4], float4 (&lw)[4],
                  float4 (&ca)[4], float4 (&cw)[4]) {
    const int par = t & 1;
    if (t + 2 < NK) ldt(la, lw, t + 2);            // prefetch tile t+2
    bf16x8 af[4], bfr[4];
#pragma unroll
    for (int i = 0; i < 4; ++i) af[i] = *(const bf16x8*)&As[par][wm * 64 + i * 16 + fr][fq * 8];
#pragma unroll
    for (int j = 0; j < 4; ++j) bfr[j] = *(const bf16x8*)&Bs[par][wn * 64 + j * 16 + fr][fq * 8];
    if (t + 1 < NK) stage(ca, cw, par ^ 1);        // stage tile t+1
#pragma unroll
    for (int i = 0; i < 4; ++i)
#pragma unroll
      for (int j = 0; j < 4; ++j)
        acc[i][j] = __builtin_amdgcn_mfma_f32_16x16x32_bf16(af[i], bfr[j], acc[i][j], 0, 0, 0);
    lds_barrier();
  };

  ldt(xa, xw, 0);
  stage(xa, xw, 0);
  if (NK > 1) ldt(xa, xw, 1);
  lds_barrier();
  int t = 0;
  for (; t + 1 < NK; t += 2) { step(t, ya, yw, xa, xw); step(t + 1, xa, xw, ya, yw); }
  if (t < NK) step(t, ya, yw, xa, xw);

#pragma unroll
  for (int i = 0; i < 4; ++i) {
    int mB = m0 + wm * 64 + i * 16 + fq * 4;
#pragma unroll
    for (int j = 0; j < 4; ++j) {
      int n = n0 + wn * 64 + j * 16 + fr;
      float bz = bias[n];
#pragma unroll
      for (int r2 = 0; r2 < 4; ++r2) {
        float v = acc[i][j][r2] + bz;
        if (relu) v = fmaxf(v, 0.f);
        C[(long)(mB + r2) * N + n] = v;
      }
    }
  }
}

// ---- bf16 MFMA embed (z=2 fused): C[b,s,a] = sum_c X[b,c,s]*W[a,c]+bias+pe-sub ----
__global__ __launch_bounds__(256) void k_mfma_embed(
    const float* __restrict__ X1, const float* __restrict__ X2,  // [B,1024,196]
    const float* __restrict__ W,   // [512,1024]
    const float* __restrict__ bias,
    const float* __restrict__ wemb, const float* __restrict__ hemb,
    const float* __restrict__ sub1, const float* __restrict__ sub2,
    float* __restrict__ C1, float* __restrict__ C2) {
  __shared__ short As[2][128][40];
  __shared__ short Bs[2][128][40];
  const float* X = blockIdx.z ? X2 : X1;
  const float* sub = blockIdx.z ? sub2 : sub1;
  float* C = blockIdx.z ? C2 : C1;
  const int tid = threadIdx.x;
  const int lane = tid & 63, wave = tid >> 6;
  const int wm = wave >> 1, wn = wave & 1;
  const int NX = gridDim.x;
  const int wg = xcd_swizzle(blockIdx.y * NX + blockIdx.x, NX * gridDim.y);
  const int m0 = (wg / NX) * 128, n0 = (wg % NX) * 128;
  const int K = 1024, N = 512;
  const int srow = tid >> 1, skh = (tid & 1) * 16;
  const float* Wp = W + (long)(n0 + srow) * K + skh;
  const int arow = tid & 127, khalf = tid >> 7;
  const int am = m0 + arow;
  const int ab = am / 196, as_ = am % 196;
  const float* Xp = X + (long)ab * 200704 + as_;
  const int fr = lane & 15, fq = lane >> 4;
  const int NK = K >> 5;   // 32
  f32x4 acc[4][4] = {};
  float xx[16], yx[16];
  float4 xw[4], yw[4];

  auto ldt = [&](float (&tx)[16], float4 (&tw)[4], int t) {
    const int kb = t * 32 + khalf * 16;
#pragma unroll
    for (int i = 0; i < 16; ++i) tx[i] = Xp[(long)(kb + i) * 196];
    const float* wp = Wp + t * 32;
#pragma unroll
    for (int i = 0; i < 4; ++i) tw[i] = *(const float4*)(wp + i * 4);
  };
  auto stage = [&](float (&tx)[16], float4 (&tw)[4], int p) {
    union { short s[16]; int4 v[2]; } u;
#pragma unroll
    for (int i = 0; i < 16; ++i) u.s[i] = f2bf(tx[i]);
    int4* dst = (int4*)&As[p][arow][khalf * 16];
    dst[0] = u.v[0]; dst[1] = u.v[1];
    cvt8(&Bs[p][srow][skh], tw[0], tw[1]);
    cvt8(&Bs[p][srow][skh + 8], tw[2], tw[3]);
  };
  auto step = [&](int t, float (&lx)[16], float4 (&lw)[4],
                  float (&cx)[16], float4 (&cw)[4]) {
    const int par = t & 1;
    if (t + 2 < NK) ldt(lx, lw, t + 2);
    bf16x8 af[4], bfr[4];
#pragma unroll
    for (int i = 0; i < 4; ++i) af[i] = *(const bf16x8*)&As[par][wm * 64 + i * 16 + fr][fq * 8];
#pragma unroll
    for (int j = 0; j < 4; ++j) bfr[j] = *(const bf16x8*)&Bs[par][wn * 64 + j * 16 + fr][fq * 8];
    if (t + 1 < NK) stage(cx, cw, par ^ 1);
#pragma unroll
    for (int i = 0; i < 4; ++i)
#pragma unroll
      for (int j = 0; j < 4; ++j)
        acc[i][j] = __builtin_amdgcn_mfma_f32_16x16x32_bf16(af[i], bfr[j], acc[i][j], 0, 0, 0);
    lds_barrier();
  };

  ldt(xx, xw, 0);
  stage(xx, xw, 0);
  if (NK > 1) ldt(xx, xw, 1);
  lds_barrier();
  int t = 0;
  for (; t + 1 < NK; t += 2) { step(t, yx, yw, xx, xw); step(t + 1, xx, xw, yx, yw); }
  if (t < NK) step(t, yx, yw, xx, xw);

#pragma unroll
  for (int i = 0; i < 4; ++i) {
    int mB = m0 + wm * 64 + i * 16 + fq * 4;
#pragma unroll
    for (int j = 0; j < 4; ++j) {
      int n = n0 + wn * 64 + j * 16 + fr;
      float bz = bias[n];
#pragma unroll
      for (int r2 = 0; r2 < 4; ++r2) {
        int m = mB + r2;
        int s = m % 196;
        float pe = (n < 256) ? wemb[(s % 14) * 256 + n] : hemb[(s / 14) * 256 + (n - 256)];
        float v = acc[i][j][r2] + bz + pe;
        if (sub) v -= sub[(long)m * N + n];
        C[(long)m * N + n] = v;
      }
    }
  }
}

// ---- Fused flash-style MHA: B=64,H=8,S=196,D=64. One block per (b,h). ----
// Q,O: [BS,512] head col h*64. KV packed [BS,1024]: K col h*64, V col 512+h*64.
// Scores kept in registers per 16-row q-tile; softmax = same fp32 expf/1/s math
// as k_softmax_rows; PV via LDS-staged P tiles (transpose fix) + V^T in LDS.
__global__ __launch_bounds__(256) void k_fmha(
    const float* __restrict__ Q, const float* __restrict__ KV,
    float* __restrict__ O) {
  __shared__ short Vt[64][240];     // V^T bf16 (keys 0..223 used; 196..223 zeroed)
  __shared__ short Pt[4][16][40];   // per-wave P staging (32 keys + pad)
  const int tid = threadIdx.x;
  const int lane = tid & 63, wave = tid >> 6;
  const int b = blockIdx.x, h = blockIdx.y;
  const long brow = (long)b * 196;
  const float* Qb = Q + brow * 512 + h * 64;
  const float* Kb = KV + brow * 1024 + h * 64;
  const float* Vb = KV + brow * 1024 + 512 + h * 64;
  float* Ob = O + brow * 512 + h * 64;
  const int fr = lane & 15, fq = lane >> 4;

  // zero pad keys 196..223 (so P=0 x garbage can't make NaN)
  for (int i = tid; i < 64 * 32; i += 256) {
    int d = i >> 5, k = 192 + (i & 31);
    if (k >= 196) Vt[d][k] = 0;
  }
  // stage V^T (bf16)
  for (int i = tid; i < 196 * 16; i += 256) {
    int s = i >> 4, c4 = (i & 15) * 4;
    float4 v = *(const float4*)(Vb + (long)s * 1024 + c4);
    Vt[c4 + 0][s] = f2bf(v.x);
    Vt[c4 + 1][s] = f2bf(v.y);
    Vt[c4 + 2][s] = f2bf(v.z);
    Vt[c4 + 3][s] = f2bf(v.w);
  }
  __syncthreads();

  for (int qt = wave; qt < 13; qt += 4) {
    const int q0 = qt * 16;
    const int qr = (q0 + fr < 196) ? q0 + fr : 195;
    bf16x8 aq0, aq1;
    {
      const float* qp = Qb + (long)qr * 512 + fq * 8;
      float4 a = *(const float4*)(qp);
      float4 b2 = *(const float4*)(qp + 4);
      float4 c = *(const float4*)(qp + 32);
      float4 d = *(const float4*)(qp + 36);
      cvt8((short*)&aq0, a, b2);
      cvt8((short*)&aq1, c, d);
    }
    // scores: sc[t] covers keys 16t..16t+15; lane holds q-rows fq*4+r2, key col fr
    f32x4 sc[13];
#pragma unroll
    for (int t = 0; t < 13; ++t) {
      int kr = (t * 16 + fr < 196) ? t * 16 + fr : 195;
      const float* kp = Kb + (long)kr * 1024 + fq * 8;
      float4 a = *(const float4*)(kp);
      float4 b2 = *(const float4*)(kp + 4);
      float4 c = *(const float4*)(kp + 32);
      float4 d = *(const float4*)(kp + 36);
      bf16x8 bk0, bk1;
      cvt8((short*)&bk0, a, b2);
      cvt8((short*)&bk1, c, d);
      f32x4 z = {};
      z = __builtin_amdgcn_mfma_f32_16x16x32_bf16(aq0, bk0, z, 0, 0, 0);
      z = __builtin_amdgcn_mfma_f32_16x16x32_bf16(aq1, bk1, z, 0, 0, 0);
      sc[t] = z;
    }
#pragma unroll
    for (int t = 0; t < 13; ++t)
#pragma unroll
      for (int r2 = 0; r2 < 4; ++r2) sc[t][r2] *= 0.125f;
    if (fr >= 4) {   // tile 12 cols 196..207 invalid
#pragma unroll
      for (int r2 = 0; r2 < 4; ++r2) sc[12][r2] = -1e30f;
    }
    // softmax per q-row (rows live across the 16-lane fr group)
#pragma unroll
    for (int r2 = 0; r2 < 4; ++r2) {
      float m = sc[0][r2];
#pragma unroll
      for (int t = 1; t < 13; ++t) m = fmaxf(m, sc[t][r2]);
#pragma unroll
      for (int o = 1; o < 16; o <<= 1) m = fmaxf(m, __shfl_xor(m, o, 64));
      float s = 0.f;
#pragma unroll
      for (int t = 0; t < 13; ++t) { float e = expf(sc[t][r2] - m); sc[t][r2] = e; s += e; }
#pragma unroll
      for (int o = 1; o < 16; o <<= 1) s += __shfl_xor(s, o, 64);
      float inv = 1.0f / s;
#pragma unroll
      for (int t = 0; t < 13; ++t) sc[t][r2] *= inv;
    }
    // PV: O[16,64] = P[16,224] @ V[224,64], 7 K32 steps
    f32x4 acc_o[4] = {};
#pragma unroll
    for (int s7 = 0; s7 < 7; ++s7) {
      const int t0 = 2 * s7, t1 = 2 * s7 + 1;
#pragma unroll
      for (int r2 = 0; r2 < 4; ++r2) {
        Pt[wave][fq * 4 + r2][fr] = f2bf(sc[t0][r2]);
        Pt[wave][fq * 4 + r2][16 + fr] = (t1 < 13) ? f2bf(sc[t1][r2]) : (short)0;
      }
      asm volatile("s_waitcnt lgkmcnt(0)" ::: "memory");
      bf16x8 ap = *(const bf16x8*)&Pt[wave][fr][fq * 8];
#pragma unroll
      for (int dt = 0; dt < 4; ++dt) {
        bf16x8 bv = *(const bf16x8*)&Vt[dt * 16 + fr][32 * s7 + fq * 8];
        acc_o[dt] = __builtin_amdgcn_mfma_f32_16x16x32_bf16(ap, bv, acc_o[dt], 0, 0, 0);
      }
    }
    // store (C: row=fq*4+r2 (q), col=fr (d within dt tile))
#pragma unroll
    for (int r2 = 0; r2 < 4; ++r2) {
      int qrow = q0 + fq * 4 + r2;
      if (qrow < 196) {
        float* op = Ob + (long)qrow * 512;
#pragma unroll
        for (int dt = 0; dt < 4; ++dt) op[dt * 16 + fr] = acc_o[dt][r2];
      }
    }
  }
}

// ---- Batched bf16 MFMA NT: C[z][m,n] = scale*sum_k A[z][m,k]*B[z][n,k] ----
__global__ __launch_bounds__(256) void k_mfma_bnt(
    const float* __restrict__ A, const float* __restrict__ B, float* __restrict__ C,
    int M, int N, int K, int lda, int ldb, int ldc, int nz2,
    int64_t sA1, int64_t sA2, int64_t sB1, int64_t sB2, int64_t sC1, int64_t sC2,
    float scale, int clampf, const float* __restrict__ bias2, int relu2) {
  __shared__ short As[2][64][40];
  __shared__ short Bs[2][64][40];
  const int tid = threadIdx.x;
  const int lane = tid & 63, wave = tid >> 6;
  const int m0 = blockIdx.y * 64, n0 = blockIdx.x * 64;
  const int z = blockIdx.z, z1 = z / nz2, z2 = z % nz2;
  const float* Ab = A + z1 * sA1 + z2 * sA2;
  const float* Bb = B + z1 * sB1 + z2 * sB2;
  float* Cb = C + z1 * sC1 + z2 * sC2;
  const int sr = tid >> 2, skh = (tid & 3) * 8;
  const int ar = (m0 + sr < M) ? m0 + sr : M - 1;
  const int br = (n0 + sr < N) ? n0 + sr : N - 1;
  const float* Ap = Ab + (long)ar * lda + skh;
  const float* Bp = Bb + (long)br * ldb + skh;
  const int fr = lane & 15, fq = lane >> 4;
  const int NK = K >> 5;
  f32x4 acc[4] = {};
  float4 xa[2], xb[2], ya[2], yb[2];

  auto ldt = [&](float4 (&ta)[2], float4 (&tb)[2], int t) {
    const int kb = t * 32;
#pragma unroll
    for (int i = 0; i < 2; ++i) {
      ta[i] = *(const float4*)(Ap + kb + i * 4);
      tb[i] = *(const float4*)(Bp + kb + i * 4);
    }
  };
  auto stage = [&](float4 (&ta)[2], float4 (&tb)[2], int p) {
    cvt8(&As[p][sr][skh], ta[0], ta[1]);
    cvt8(&Bs[p][sr][skh], tb[0], tb[1]);
  };
  auto step = [&](int t, float4 (&la)[2], float4 (&lb)[2],
                  float4 (&ca)[2], float4 (&cb)[2]) {
    const int par = t & 1;
    if (t + 2 < NK) ldt(la, lb, t + 2);
    bf16x8 bfr = *(const bf16x8*)&Bs[par][wave * 16 + fr][fq * 8];
    bf16x8 af[4];
#pragma unroll
    for (int i = 0; i < 4; ++i) af[i] = *(const bf16x8*)&As[par][i * 16 + fr][fq * 8];
    if (t + 1 < NK) stage(ca, cb, par ^ 1);
#pragma unroll
    for (int i = 0; i < 4; ++i)
      acc[i] = __builtin_amdgcn_mfma_f32_16x16x32_bf16(af[i], bfr, acc[i], 0, 0, 0);
    lds_barrier();
  };

  ldt(xa, xb, 0);
  stage(xa, xb, 0);
  if (NK > 1) ldt(xa, xb, 1);
  lds_barrier();
  int t = 0;
  for (; t + 1 < NK; t += 2) { step(t, ya, yb, xa, xb); step(t + 1, xa, xb, ya, yb); }
  if (t < NK) step(t, ya, yb, xa, xb);

  const int n = n0 + wave * 16 + fr;
  if (n < N) {
    float bz = bias2 ? bias2[n] : 0.f;
#pragma unroll
    for (int i = 0; i < 4; ++i) {
      int mb = m0 + i * 16 + fq * 4;
#pragma unroll
      for (int r2 = 0; r2 < 4; ++r2) {
        int m = mb + r2;
        if (m < M) {
          float v = acc[i][r2] * scale + bz;
          if (relu2) v = fmaxf(v, 0.f);
          if (clampf) v = fminf(fmaxf(v, -100.f), 100.f);
          Cb[(long)m * ldc + n] = v;
        }
      }
    }
  }
}

// ---- Batched bf16 MFMA NN: C[z][m,n] = sum_k A[z][m,k]*B[z][k,n] ----
__global__ __launch_bounds__(256) void k_mfma_bnn(
    const float* __restrict__ A, const float* __restrict__ B, float* __restrict__ C,
    int M, int N, int K, int KBvalid, int lda, int ldb, int ldc, int nz2,
    int64_t sA1, int64_t sA2, int64_t sB1, int64_t sB2, int64_t sC1, int64_t sC2) {
  __shared__ short As[2][64][40];
  __shared__ short Bs[2][64][40];
  const int tid = threadIdx.x;
  const int lane = tid & 63, wave = tid >> 6;
  const int m0 = blockIdx.y * 64, n0 = blockIdx.x * 64;
  const int z = blockIdx.z, z1 = z / nz2, z2 = z % nz2;
  const float* Ab = A + z1 * sA1 + z2 * sA2;
  const float* Bb = B + z1 * sB1 + z2 * sB2;
  float* Cb = C + z1 * sC1 + z2 * sC2;
  const int sr = tid >> 2, skh = (tid & 3) * 8;
  const int ar = (m0 + sr < M) ? m0 + sr : M - 1;
  const float* Ap = Ab + (long)ar * lda + skh;
  const int bk = tid >> 3, bn = (tid & 7) * 8;   // B transposed staging
  const int fr = lane & 15, fq = lane >> 4;
  const int NK = K >> 5;
  f32x4 acc[4] = {};
  float4 xa[2], xb[2], ya[2], yb[2];

  auto ldt = [&](float4 (&ta)[2], float4 (&tb)[2], int t) {
    const int kb = t * 32;
#pragma unroll
    for (int i = 0; i < 2; ++i) ta[i] = *(const float4*)(Ap + kb + i * 4);
    int kc = kb + bk;
    if (kc >= KBvalid) kc = KBvalid - 1;
    const float* bp = Bb + (long)kc * ldb + n0 + bn;
#pragma unroll
    for (int i = 0; i < 2; ++i) tb[i] = *(const float4*)(bp + i * 4);
  };
  auto stage = [&](float4 (&ta)[2], float4 (&tb)[2], int p) {
    cvt8(&As[p][sr][skh], ta[0], ta[1]);
    short tmp[8];
    cvt8(tmp, tb[0], tb[1]);
#pragma unroll
    for (int j = 0; j < 8; ++j) Bs[p][bn + j][bk] = tmp[j];
  };
  auto step = [&](int t, float4 (&la)[2], float4 (&lb)[2],
                  float4 (&ca)[2], float4 (&cb)[2]) {
    const int par = t & 1;
    if (t + 2 < NK) ldt(la, lb, t + 2);
    bf16x8 bfr = *(const bf16x8*)&Bs[par][wave * 16 + fr][fq * 8];
    bf16x8 af[4];
#pragma unroll
    for (int i = 0; i < 4; ++i) af[i] = *(const bf16x8*)&As[par][i * 16 + fr][fq * 8];
    if (t + 1 < NK) stage(ca, cb, par ^ 1);
#pragma unroll
    for (int i = 0; i < 4; ++i)
      acc[i] = __builtin_amdgcn_mfma_f32_16x16x32_bf16(af[i], bfr, acc[i], 0, 0, 0);
    lds_barrier();
  };

  ldt(xa, xb, 0);
  stage(xa, xb, 0);
  if (NK > 1) ldt(xa, xb, 1);
  lds_barrier();
  int t = 0;
  for (; t + 1 < NK; t += 2) { step(t, ya, yb, xa, xb); step(t + 1, xa, xb, ya, yb); }
  if (t < NK) step(t, ya, yb, xa, xb);

  const int n = n0 + wave * 16 + fr;
  if (n < N) {
#pragma unroll
    for (int i = 0; i < 4; ++i) {
      int mb = m0 + i * 16 + fq * 4;
#pragma unroll
      for (int r2 = 0; r2 < 4; ++r2) {
        int m = mb + r2;
        if (m < M) Cb[(long)m * ldc + n] = acc[i][r2];
      }
    }
  }
}

// ---- MFMA correlation: C[i,j] += scale * sum_m Za[m,i]*Zb[m,j] (split-K atomic) ----
__global__ __launch_bounds__(256) void k_mfma_corr(
    const float* __restrict__ Za, const float* __restrict__ Zb,
    float* __restrict__ C, int mchunk, float scale) {
  __shared__ short As[2][64][40];
  __shared__ short Bs[2][64][40];
  const int tid = threadIdx.x;
  const int lane = tid & 63, wave = tid >> 6;
  const int i0 = blockIdx.y * 64, j0 = blockIdx.x * 64;
  const int mstart = blockIdx.z * mchunk;
  const int tm = tid >> 3, tcb = (tid & 7) * 8;
  const int fr = lane & 15, fq = lane >> 4;
  const int NK = mchunk >> 5;   // 28
  f32x4 acc[4] = {};
  float4 xa[2], xb[2], ya[2], yb[2];

  auto ldt = [&](float4 (&ta)[2], float4 (&tb)[2], int t) {
    const float* za = Za + (long)(mstart + t * 32 + tm) * 512;
    const float* zb = Zb + (long)(mstart + t * 32 + tm) * 512;
    ta[0] = *(const float4*)(za + i0 + tcb);
    ta[1] = *(const float4*)(za + i0 + tcb + 4);
    tb[0] = *(const float4*)(zb + j0 + tcb);
    tb[1] = *(const float4*)(zb + j0 + tcb + 4);
  };
  auto stage = [&](float4 (&ta)[2], float4 (&tb)[2], int p) {
    short u[8], v[8];
    cvt8(u, ta[0], ta[1]);
    cvt8(v, tb[0], tb[1]);
#pragma unroll
    for (int j = 0; j < 8; ++j) { As[p][tcb + j][tm] = u[j]; Bs[p][tcb + j][tm] = v[j]; }
  };
  auto step = [&](int t, float4 (&la)[2], float4 (&lb)[2],
                  float4 (&ca)[2], float4 (&cb)[2]) {
    const int par = t & 1;
    if (t + 2 < NK) ldt(la, lb, t + 2);
    bf16x8 bfr = *(const bf16x8*)&Bs[par][wave * 16 + fr][fq * 8];
    bf16x8 af[4];
#pragma unroll
    for (int i = 0; i < 4; ++i) af[i] = *(const bf16x8*)&As[par][i * 16 + fr][fq * 8];
    if (t + 1 < NK) stage(ca, cb, par ^ 1);
#pragma unroll
    for (int i = 0; i < 4; ++i)
      acc[i] = __builtin_amdgcn_mfma_f32_16x16x32_bf16(af[i], bfr, acc[i], 0, 0, 0);
    lds_barrier();
  };

  ldt(xa, xb, 0);
  stage(xa, xb, 0);
  if (NK > 1) ldt(xa, xb, 1);
  lds_barrier();
  int t = 0;
  for (; t + 1 < NK; t += 2) { step(t, ya, yb, xa, xb); step(t + 1, xa, xb, ya, yb); }
  if (t < NK) step(t, ya, yb, xa, xb);

  const int j = j0 + wave * 16 + fr;
#pragma unroll
  for (int i = 0; i < 4; ++i) {
    int ib = i0 + i * 16 + fq * 4;
#pragma unroll
    for (int r2 = 0; r2 < 4; ++r2)
      atomicAdd(&C[(long)(ib + r2) * 512 + j], acc[i][r2] * scale);
  }
}

// ---------------- fp32 GEMM fallback (small M, unused hot path) ----------------
__global__ __launch_bounds__(256) void k_gemm_nt(
    const float* __restrict__ A, const float* __restrict__ W,
    const float* __restrict__ bias, float* __restrict__ C,
    int M, int N, int K, int relu) {
  __shared__ float As[16][68];
  __shared__ float Ws[16][68];
  const int tx = threadIdx.x, ty = threadIdx.y;
  const int tid = ty * 16 + tx;
  const int m0 = blockIdx.y * 64, n0 = blockIdx.x * 64;
  const int lr = tid >> 2, lk = (tid & 3) << 2;
  const float* Ap = A + (long)(m0 + lr) * K + lk;
  const float* Wp = W + (long)(n0 + lr) * K + lk;
  float acc[4][4] = {};
  for (int k0 = 0; k0 < K; k0 += 16) {
    float4 av = *(const float4*)(Ap + k0);
    float4 wv = *(const float4*)(Wp + k0);
    As[lk + 0][lr] = av.x; As[lk + 1][lr] = av.y; As[lk + 2][lr] = av.z; As[lk + 3][lr] = av.w;
    Ws[lk + 0][lr] = wv.x; Ws[lk + 1][lr] = wv.y; Ws[lk + 2][lr] = wv.z; Ws[lk + 3][lr] = wv.w;
    __syncthreads();
#pragma unroll
    for (int kk = 0; kk < 16; ++kk) {
      float4 a4 = *(const float4*)&As[kk][ty * 4];
      float4 w4 = *(const float4*)&Ws[kk][tx * 4];
      float a[4] = {a4.x, a4.y, a4.z, a4.w};
      float w[4] = {w4.x, w4.y, w4.z, w4.w};
#pragma unroll
      for (int i = 0; i < 4; ++i)
#pragma unroll
        for (int j = 0; j < 4; ++j) acc[i][j] += a[i] * w[j];
    }
    __syncthreads();
  }
#pragma unroll
  for (int i = 0; i < 4; ++i) {
    int m = m0 + ty * 4 + i;
#pragma unroll
    for (int j = 0; j < 4; ++j) {
      int n = n0 + tx * 4 + j;
      float v = acc[i][j] + bias[n];
      if (relu) v = fmaxf(v, 0.f);
      C[(long)m * N + n] = v;
    }
  }
}

// ---- Row softmax over rows of width 196, ld=SLD(224); zeroes pad cols. ----
__global__ __launch_bounds__(256) void k_softmax_rows(float* __restrict__ S, int nrows) {
  int row = blockIdx.x * 4 + (threadIdx.x >> 6);
  int lane = threadIdx.x & 63;
  if (row >= nrows) return;
  float* p = S + (long)row * SLD;
  float v0 = p[lane];
  float v1 = p[lane + 64];
  float v2 = p[lane + 128];
  float v3 = (lane + 192 < 196) ? p[lane + 192] : -1e30f;
  float mx = fmaxf(fmaxf(v0, v1), fmaxf(v2, v3));
#pragma unroll
  for (int o = 32; o > 0; o >>= 1) mx = fmaxf(mx, __shfl_down(mx, o, 64));
  mx = __shfl(mx, 0, 64);
  float e0 = expf(v0 - mx), e1 = expf(v1 - mx), e2 = expf(v2 - mx);
  float e3 = (lane + 192 < 196) ? expf(v3 - mx) : 0.f;
  float s = e0 + e1 + e2 + e3;
#pragma unroll
  for (int o = 32; o > 0; o >>= 1) s += __shfl_down(s, o, 64);
  s = __shfl(s, 0, 64);
  float inv = 1.0f / s;
  p[lane] = e0 * inv;
  p[lane + 64] = e1 * inv;
  p[lane + 128] = e2 * inv;
  if (lane + 192 < SLD) p[lane + 192] = (lane + 192 < 196) ? e3 * inv : 0.f;
}

// ---- Residual + LayerNorm (in place into h) ----
__global__ __launch_bounds__(256) void k_addln(
    float* __restrict__ h, const float* __restrict__ o,
    const float* __restrict__ g, const float* __restrict__ be) {
  __shared__ float red[4];
  long row = blockIdx.x;
  float* hr = h + row * 512;
  const float* orow = o + row * 512;
  int t = threadIdx.x;
  float v0 = hr[t] + orow[t];
  float v1 = hr[t + 256] + orow[t + 256];
  float mean = block_red256(v0 + v1, red, false) * (1.0f / 512.0f);
  float d0 = v0 - mean, d1 = v1 - mean;
  float var = block_red256(d0 * d0 + d1 * d1, red, false) * (1.0f / 512.0f);
  float inv = 1.0f / sqrtf(var + 1e-5f);
  hr[t] = d0 * inv * g[t] + be[t];
  hr[t + 256] = d1 * inv * g[t + 256] + be[t + 256];
}

// ---- small utility kernels ----
__global__ void k_zero(float* __restrict__ p, int n) {
  int i = blockIdx.x * 256 + threadIdx.x;
  if (i < n) p[i] = 0.f;
}

// concat two [512,512] weights into [1024,512] (+ biases into [1024])
__global__ __launch_bounds__(256) void k_catkv(
    float* __restrict__ dw, const float* __restrict__ kw, const float* __restrict__ vw,
    float* __restrict__ db, const float* __restrict__ kb, const float* __restrict__ vb) {
  int i = blockIdx.x * 256 + threadIdx.x;      // 1024*512
  int r = i >> 9;
  dw[i] = (r < 512) ? kw[i] : vw[i - 262144];
  if (i < 1024) db[i] = (i < 512) ? kb[i] : vb[i - 512];
}

__global__ __launch_bounds__(256) void k_colstats(
    const float* __restrict__ f, float* __restrict__ sums, float* __restrict__ sqs) {
  int c = blockIdx.x * 32 + (threadIdx.x & 31);
  int rbase = blockIdx.y * 256;
  int r0 = rbase + (threadIdx.x >> 5);
  float s = 0.f, s2 = 0.f;
  for (int r = r0; r < rbase + 256; r += 8) {
    float v = f[(long)r * 512 + c];
    s += v; s2 += v * v;
  }
  __shared__ float sh[256], sh2[256];
  sh[threadIdx.x] = s; sh2[threadIdx.x] = s2;
  __syncthreads();
  if (threadIdx.x < 32) {
    for (int i = 1; i < 8; ++i) { s += sh[i * 32 + threadIdx.x]; s2 += sh2[i * 32 + threadIdx.x]; }
    atomicAdd(&sums[c], s);
    atomicAdd(&sqs[c], s2);
  }
}

__global__ void k_finstats(const float* __restrict__ sums, const float* __restrict__ sqs,
                           float* __restrict__ mean, float* __restrict__ istd) {
  int c = blockIdx.x * 256 + threadIdx.x;
  float mu = sums[c] / 12544.0f;
  float var = (sqs[c] - 12544.0f * mu * mu) / 12543.0f;
  mean[c] = mu;
  istd[c] = 1.0f / sqrtf(var);
}

__global__ __launch_bounds__(256) void k_znorm(float* __restrict__ f, const float* __restrict__ mean,
                                               const float* __restrict__ istd) {
  long i = (long)blockIdx.x * 256 + threadIdx.x;
  int c = (int)(i & 511);
  f[i] = (f[i] - mean[c]) * istd[c];
}

// CDCR loss: 256-block partial reduce + final combine
__global__ __launch_bounds__(256) void k_cdcr_part(const float* __restrict__ Cm,
                                                   double* __restrict__ part) {
  int base = blockIdx.x * 1024;
  double on = 0, off = 0;
  for (int i = base + threadIdx.x; i < base + 1024; i += 256) {
    float v = Cm[i];
    int r = i >> 9, c = i & 511;
    if (r == c) { double d = (double)v - 1.0; on += d * d; }
    else        { off += (double)v * (double)v; }
  }
  __shared__ double s_on[256], s_off[256];
  s_on[threadIdx.x] = on; s_off[threadIdx.x] = off;
  __syncthreads();
  for (int st = 128; st > 0; st >>= 1) {
    if (threadIdx.x < st) { s_on[threadIdx.x] += s_on[threadIdx.x + st]; s_off[threadIdx.x] += s_off[threadIdx.x + st]; }
    __syncthreads();
  }
  if (threadIdx.x == 0) { part[blockIdx.x] = s_on[0]; part[256 + blockIdx.x] = s_off[0]; }
}

__global__ void k_cdcr_fin(const double* __restrict__ part, float* __restrict__ out) {
  __shared__ double s_on[256], s_off[256];
  s_on[threadIdx.x] = part[threadIdx.x];
  s_off[threadIdx.x] = part[256 + threadIdx.x];
  __syncthreads();
  for (int st = 128; st > 0; st >>= 1) {
    if (threadIdx.x < st) { s_on[threadIdx.x] += s_on[threadIdx.x + st]; s_off[threadIdx.x] += s_off[threadIdx.x + st]; }
    __syncthreads();
  }
  if (threadIdx.x == 0) out[0] = (float)(s_on[0] + 0.003 * s_off[0]);
}

__global__ __launch_bounds__(64) void k_mask(const float* __restrict__ capo, float* __restrict__ mask) {
  int pidx = blockIdx.x;
  float s = 0.f;
  for (int i = threadIdx.x; i < 512; i += 64) s += capo[(long)pidx * 512 + i];
#pragma unroll
  for (int o = 32; o > 0; o >>= 1) s += __shfl_down(s, o, 64);
  if (threadIdx.x == 0) mask[pidx] = (s != 0.f) ? 1.f : 0.f;
}

__global__ __launch_bounds__(256) void k_meannc(const float* __restrict__ src, const float* __restrict__ mask,
                                                float* __restrict__ vec) {
  int d = blockIdx.x * 256 + threadIdx.x;
  int b = blockIdx.y;
  float acc = 0.f, ms = 0.f;
  for (int nc = 0; nc < 16; ++nc) {
    float mk = mask ? mask[b * 16 + nc] : 1.f;
    acc += src[((long)b * 16 + nc) * 512 + d] * mk;
    ms += mk;
  }
  vec[(long)b * 512 + d] = acc / fmaxf(ms, 1e-6f);
}

__global__ __launch_bounds__(256) void k_mse(const float* __restrict__ full, const float* __restrict__ vec,
                                             double* __restrict__ part) {
  double loc = 0;
  const long n = NOUT;
  for (long i = (long)blockIdx.x * 256 + threadIdx.x; i < n; i += 256L * 1024) {
    int d = (int)(i & 511);
    int b = (int)(i >> 9) / 196;
    float df = full[i] - vec[b * 512 + d];
    loc += (double)df * (double)df;
  }
  __shared__ double sh[256];
  sh[threadIdx.x] = loc;
  __syncthreads();
  for (int st = 128; st > 0; st >>= 1) {
    if (threadIdx.x < st) sh[threadIdx.x] += sh[threadIdx.x + st];
    __syncthreads();
  }
  if (threadIdx.x == 0) part[blockIdx.x] = sh[0];
}

__global__ void k_finloss(const double* __restrict__ part, float* __restrict__ out) {
  __shared__ double sh[256];
  double s = 0;
  for (int i = threadIdx.x; i < 4096; i += 256) s += part[i];
  sh[threadIdx.x] = s;
  __syncthreads();
  for (int st = 128; st > 0; st >>= 1) {
    if (threadIdx.x < st) sh[threadIdx.x] += sh[threadIdx.x + st];
    __syncthreads();
  }
  if (threadIdx.x == 0) out[0] = (float)(sh[0] / (64.0 * 196.0 * 512.0));
}

__global__ __launch_bounds__(256) void k_concat2(float* __restrict__ dst, const float* __restrict__ a,
                                                 const float* __restrict__ b) {
  int i = blockIdx.x * 256 + threadIdx.x;   // 64*1024
  int col = i & 1023, row = i >> 10;
  dst[i] = (col < 512) ? a[row * 512 + col] : b[row * 512 + col - 512];
}

// comb chunk: rows [r0, r0+nrows) of [BS,2048] into dst
__global__ __launch_bounds__(256) void k_comb_chunk(
    float* __restrict__ dst, const float* __restrict__ d1, const float* __restrict__ d2,
    const float* __restrict__ txt, const float* __restrict__ al, long r0) {
  long i = (long)blockIdx.x * 256 + threadIdx.x;
  int col = (int)(i & 2047);
  long m = r0 + (i >> 11);
  int b = (int)(m / 196);
  float v;
  if (col < 512)       v = d1[m * 512 + col];
  else if (col < 1024) v = d2[m * 512 + col - 512];
  else if (col < 1536) v = txt[(long)b * 512 + col - 1024];
  else                 v = al[(long)b * 512 + col - 1536];
  dst[i] = v;
}

// ---------------- host ----------------
extern "C" void kernel_launch(void* const* d_in, const int* in_sizes, int n_in,
                              void* d_out, int out_size, void* d_ws, size_t ws_size,
                              hipStream_t stream) {
  (void)in_sizes; (void)n_in; (void)out_size; (void)ws_size;
  const float* in1    = (const float*)d_in[0];
  const float* in2    = (const float*)d_in[1];
  const float* cap1   = (const float*)d_in[2];
  const float* cap2   = (const float*)d_in[3];
  const float* imgw   = (const float*)d_in[4];
  const float* imgb   = (const float*)d_in[5];
  const float* wemb   = (const float*)d_in[6];
  const float* hemb   = (const float*)d_in[7];
  const float* mlpw1  = (const float*)d_in[8];
  const float* mlpb1  = (const float*)d_in[9];
  const float* mlpw2  = (const float*)d_in[10];
  const float* mlpb2  = (const float*)d_in[11];
  const float* fcw    = (const float*)d_in[12];
  const float* fcb    = (const float*)d_in[13];
  const float* efcw   = (const float*)d_in[14];
  const float* efcb   = (const float*)d_in[15];
  const float* efc2w  = (const float*)d_in[16];
  const float* efc2b  = (const float*)d_in[17];
  const float* trinw  = (const float*)d_in[18];
  const float* trinb  = (const float*)d_in[19];
  const float* troutw = (const float*)d_in[20];
  const float* troutb = (const float*)d_in[21];
  const float* trlng  = (const float*)d_in[22];
  const float* trlnb  = (const float*)d_in[23];
  const float* itqw = (const float*)d_in[24]; const float* itqb = (const float*)d_in[25];
  const float* itkw = (const float*)d_in[26]; const float* itkb = (const float*)d_in[27];
  const float* itvw = (const float*)d_in[28]; const float* itvb = (const float*)d_in[29];
  const float* caqw = (const float*)d_in[30]; const float* caqb = (const float*)d_in[31];
  const float* cakw = (const float*)d_in[32]; const float* cakb = (const float*)d_in[33];
  const float* cavw = (const float*)d_in[34]; const float* cavb = (const float*)d_in[35];
  const float* saqw = (const float*)d_in[36]; const float* saqb = (const float*)d_in[37];
  const float* sakw = (const float*)d_in[38]; const float* sakb = (const float*)d_in[39];
  const float* savw = (const float*)d_in[40]; const float* savb = (const float*)d_in[41];

  float* out = (float*)d_out;

  // ---- workspace carve ----
  const size_t SZ = (size_t)BS * 512;        // 6,422,528 floats (24.5 MB)
  float* w = (float*)d_ws;
  auto alloc = [&](size_t n) { float* p = w; w += n; return p; };
  float* h1 = alloc(SZ);
  float* h2 = alloc(SZ);
  float* tA = alloc(SZ);
  float* tB = alloc(SZ);
  float* tC = alloc(SZ);
  float* tD = alloc(SZ);
  float* sbuf = alloc((size_t)128 * 196 * SLD);  // attention scores (ECA/ITDA)
  float* cap1o = alloc(64 * 16 * 512);
  float* cap2o = alloc(64 * 16 * 512);
  float* qc1   = alloc(64 * 16 * 512);
  float* qc2   = alloc(64 * 16 * 512);
  float* attb  = alloc(64 * 16 * 512);
  float* cmat  = alloc(512 * 512);
  float* colsum1 = alloc(512); float* colsq1 = alloc(512);
  float* colsum2 = alloc(512); float* colsq2 = alloc(512);
  float* mean1 = alloc(512); float* istd1 = alloc(512);
  float* mean2 = alloc(512); float* istd2 = alloc(512);
  float* mask1 = alloc(1024); float* mask2 = alloc(1024);
  float* vdbef = alloc(64 * 512); float* vdaft = alloc(64 * 512);
  float* vsbef = alloc(64 * 512); float* vsaft = alloc(64 * 512);
  float* cm1 = alloc(64 * 512); float* cm2 = alloc(64 * 512);
  float* vdyn = alloc(64 * 512); float* vsta = alloc(64 * 512);
  float* valign = alloc(64 * 512); float* vtxt = alloc(64 * 512);
  float* ccat = alloc(64 * 1024);
  double* msepart = (double*)alloc(4096 * 2);   // 4096 doubles
  double* cdcrpart = (double*)alloc(1024);      // 512 doubles
  float* itkvw = alloc(1024 * 512); float* itkvb = alloc(1024);
  float* cakvw = alloc(1024 * 512); float* cakvb = alloc(1024);
  float* sakvw = alloc(1024 * 512); float* sakvb = alloc(1024);

  auto gemm = [&](const float* Aa, const float* Ww, const float* bb, float* Cc,
                  int M, int N, int K, int relu) {
    if ((M % 128) == 0 && (N % 128) == 0 && (K % 32) == 0)
      k_mfma_nt<<<dim3(N / 128, M / 128), 256, 0, stream>>>(Aa, Ww, bb, Cc, M, N, K, relu);
    else
      k_gemm_nt<<<dim3(N / 64, (M + 63) / 64), dim3(16, 16), 0, stream>>>(Aa, Ww, bb, Cc, M, N, K, relu);
  };
  auto embed2 = [&](const float* sub1p, const float* sub2p, float* C1p, float* C2p) {
    k_mfma_embed<<<dim3(4, BS / 128, 2), 256, 0, stream>>>(
        in1, in2, imgw, imgb, wemb, hemb, sub1p, sub2p, C1p, C2p);
  };
  const int64_t RB = (int64_t)SS * 512;   // 100352
  const int64_t QB = 16 * 512;            // 8192
  // GEMM-ized attention, D=512 single-head, K|V packed in one [*,1024] buffer.
  auto attn512 = [&](const float* Qp, int64_t qZ, const float* KVp, int64_t kvZ,
                     float* Op, int64_t oZ, int M, float scale) {
    int mt = (M + 63) / 64;
    int64_t sS = (int64_t)M * SLD;
    k_mfma_bnt<<<dim3(4, mt, 64), 256, 0, stream>>>(
        Qp, KVp, sbuf, M, 196, 512, 512, 1024, SLD, 1,
        qZ, 0, kvZ, 0, sS, 0, scale, 1, nullptr, 0);
    k_softmax_rows<<<(64 * M + 3) / 4, 256, 0, stream>>>(sbuf, 64 * M);
    k_mfma_bnn<<<dim3(8, mt, 64), 256, 0, stream>>>(
        sbuf, KVp + 512, Op, M, 512, SLD, 196, SLD, 1024, 512, 1,
        sS, 0, kvZ, 0, oZ, 0);
  };
  // Fused flash-style MHA (replaces the 12-dispatch GEMM pipeline).
  auto attn_mha = [&](const float* Qp, const float* KVp, float* Op) {
    k_fmha<<<dim3(64, 8), 256, 0, stream>>>(Qp, KVp, Op);
  };
  // small M=64 GEMM via MFMA (bias+relu)
  auto efc64 = [&](const float* Aa, float* Cc) {
    k_mfma_bnt<<<dim3(8, 1, 1), 256, 0, stream>>>(
        Aa, efcw, Cc, 64, 512, 1024, 1024, 1024, 512, 1,
        0, 0, 0, 0, 0, 0, 1.0f, 0, efcb, 1);
  };

  const float scalE = 1.0f / sqrtf(512.0f);

  // ---- Phase 0: build concat K|V weights for itda/ca/sa ----
  k_catkv<<<2048, 256, 0, stream>>>(itkvw, itkw, itvw, itkvb, itkb, itvb);
  k_catkv<<<2048, 256, 0, stream>>>(cakvw, cakw, cavw, cakvb, cakb, cavb);
  k_catkv<<<2048, 256, 0, stream>>>(sakvw, sakw, savw, sakvb, sakb, savb);

  // ---- Phase 1: embed (h starts as x) + caption projections ----
  embed2(nullptr, nullptr, h1, h2);
  gemm(cap1, fcw, fcb, cap1o, 1024, 512, 768, 0);
  gemm(cap2, fcw, fcb, cap2o, 1024, 512, 768, 0);
  k_meannc<<<dim3(2, 64), 256, 0, stream>>>(cap1o, nullptr, cm1);
  k_meannc<<<dim3(2, 64), 256, 0, stream>>>(cap2o, nullptr, cm2);

  // ---- Phase 2: CDCR loss (f1->tA, f2->tB, hidden chunk in tC) ----
  for (int c = 0; c < 2; ++c) {
    const size_t off = (size_t)c * 6272 * 512;
    gemm(h1 + off, mlpw1, mlpb1, tC, 6272, 2048, 512, 1);
    gemm(tC, mlpw2, mlpb2, tA + off, 6272, 512, 2048, 0);
  }
  for (int c = 0; c < 2; ++c) {
    const size_t off = (size_t)c * 6272 * 512;
    gemm(h2 + off, mlpw1, mlpb1, tC, 6272, 2048, 512, 1);
    gemm(tC, mlpw2, mlpb2, tB + off, 6272, 512, 2048, 0);
  }
  k_zero<<<8, 256, 0, stream>>>(colsum1, 2048);  // colsum1..colsq2 contiguous
  k_colstats<<<dim3(16, 49), 256, 0, stream>>>(tA, colsum1, colsq1);
  k_colstats<<<dim3(16, 49), 256, 0, stream>>>(tB, colsum2, colsq2);
  k_finstats<<<2, 256, 0, stream>>>(colsum1, colsq1, mean1, istd1);
  k_finstats<<<2, 256, 0, stream>>>(colsum2, colsq2, mean2, istd2);
  k_znorm<<<25088, 256, 0, stream>>>(tA, mean1, istd1);
  k_znorm<<<25088, 256, 0, stream>>>(tB, mean2, istd2);
  k_zero<<<1024, 256, 0, stream>>>(cmat, 262144);
  k_mfma_corr<<<dim3(8, 8, 14), 256, 0, stream>>>(tA, tB, cmat, BS / 14, 1.0f / (float)BS);
  k_cdcr_part<<<256, 256, 0, stream>>>(cmat, cdcrpart);
  k_cdcr_fin<<<1, 256, 0, stream>>>(cdcrpart, out + NOUT);

  // ---- Phase 3: cross-transformer (2 layers, simultaneous update) ----
  for (int l = 0; l < 2; ++l) {
    const float* Wq = trinw + (size_t)l * 1536 * 512;
    const float* Wkv = Wq + 512 * 512;               // [Wk;Wv] 1024 rows
    const float* bq = trinb + l * 1536;
    const float* bkv = bq + 512;                     // [bk|bv] 1024
    const float* Wo = troutw + (size_t)l * 512 * 512;
    const float* bo = troutb + l * 512;
    const float* g  = trlng + l * 512;
    const float* be = trlnb + l * 512;
    // dir1: q=h1, kv=h2
    gemm(h1, Wq, bq, tA, BS, 512, 512, 0);           // q1 -> tA
    gemm(h2, Wkv, bkv, tB, BS, 1024, 512, 0);        // kv1 -> tB..tC
    attn_mha(tA, tB, tA);                            // attn out -> tA (in place)
    gemm(tA, Wo, bo, tD, BS, 512, 512, 0);           // o1 -> tD
    // dir2 projections from ORIGINAL h1,h2
    gemm(h2, Wq, bq, tA, BS, 512, 512, 0);           // q2 -> tA
    gemm(h1, Wkv, bkv, tB, BS, 1024, 512, 0);        // kv2 -> tB..tC
    k_addln<<<BS, 256, 0, stream>>>(h1, tD, g, be);  // h1 consumed above; update now
    attn_mha(tA, tB, tA);
    gemm(tA, Wo, bo, tD, BS, 512, 512, 0);           // o2 -> tD
    k_addln<<<BS, 256, 0, stream>>>(h2, tD, g, be);
  }

  // ---- Phase 4: diffs via embed recompute (deterministic, bitwise-equal x) ----
  embed2(h1, h2, tC, tD);   // diff1 = x1 - h1 -> tC; diff2 = x2 - h2 -> tD
  // h1, h2 now free

  // ---- Phase 5: ITDA (queries constant over S -> per-(b,nc) attention + masked mean) ----
  gemm(cap1o, itqw, itqb, qc1, 1024, 512, 512, 0);
  gemm(cap2o, itqw, itqb, qc2, 1024, 512, 512, 0);
  k_mask<<<1024, 64, 0, stream>>>(cap1o, mask1);
  k_mask<<<1024, 64, 0, stream>>>(cap2o, mask2);
  // K|V from diff1 (one N=1024 GEMM)
  gemm(tC, itkvw, itkvb, tA, BS, 1024, 512, 0);      // kv -> tA..tB
  attn512(qc2, QB, tA, 2 * RB, attb, QB, 16, scalE);
  k_meannc<<<dim3(2, 64), 256, 0, stream>>>(attb, mask2, vdbef);   // d_bef
  attn512(qc1, QB, tA, 2 * RB, attb, QB, 16, scalE);
  k_meannc<<<dim3(2, 64), 256, 0, stream>>>(attb, mask1, vsbef);   // s_bef
  // K|V from diff2
  gemm(tD, itkvw, itkvb, tA, BS, 1024, 512, 0);
  attn512(qc1, QB, tA, 2 * RB, attb, QB, 16, scalE);
  k_meannc<<<dim3(2, 64), 256, 0, stream>>>(attb, mask1, vdaft);   // d_aft
  attn512(qc2, QB, tA, 2 * RB, attb, QB, 16, scalE);
  k_meannc<<<dim3(2, 64), 256, 0, stream>>>(attb, mask2, vsaft);   // s_aft

  // ---- Phase 6: ECA x4 with immediate MSE vs ITDA vector ----
  auto eca_mse = [&](const float* xq, const float* xkv,
                     const float* qw2, const float* qb2,
                     const float* kvw2, const float* kvb2,
                     const float* vec, double* part) {
    gemm(xq,  qw2, qb2, h1, BS, 512, 512, 0);        // Q -> h1
    gemm(xkv, kvw2, kvb2, tA, BS, 1024, 512, 0);     // K|V -> tA..tB
    attn512(h1, RB, tA, 2 * RB, h2, RB, 196, scalE); // out -> h2
    k_mse<<<1024, 256, 0, stream>>>(h2, vec, part);
  };
  eca_mse(tC, tD, caqw, caqb, cakvw, cakvb, vdbef, msepart);          // c12 vs d_bef
  eca_mse(tD, tC, caqw, caqb, cakvw, cakvb, vdaft, msepart + 1024);   // c21 vs d_aft
  eca_mse(tC, tC, saqw, saqb, sakvw, sakvb, vsbef, msepart + 2048);   // s11 vs s_bef
  eca_mse(tD, tD, saqw, saqb, sakvw, sakvb, vsaft, msepart + 3072);   // s22 vs s_aft
  k_finloss<<<1, 256, 0, stream>>>(msepart, out + NOUT + 1);

  // ---- Phase 7: efc chain (per-batch vectors, MFMA path M=64) ----
  k_concat2<<<256, 256, 0, stream>>>(ccat, vdbef, vdaft);
  efc64(ccat, vdyn);
  k_concat2<<<256, 256, 0, stream>>>(ccat, vsbef, vsaft);
  efc64(ccat, vsta);
  k_concat2<<<256, 256, 0, stream>>>(ccat, vdyn, vsta);
  efc64(ccat, valign);
  k_concat2<<<256, 256, 0, stream>>>(ccat, cm1, cm2);
  efc64(ccat, vtxt);

  // ---- Phase 8: final projection, single full-M GEMM (comb in h1..tB, 4*SZ) ----
  k_comb_chunk<<<100352, 256, 0, stream>>>(h1, tC, tD, vtxt, valign, 0);
  gemm(h1, efc2w, efc2b, out, BS, 512, 2048, 1);
}

// Round 6
// 2544.375 us; speedup vs baseline: 1.4962x; 1.0453x over previous
//
#include <hip/hip_runtime.h>
#include <hip/hip_bf16.h>
#include <stdint.h>
#include <math.h>

// Problem constants
#define BB   64
#define SS   196
#define BS   12544            // BB*SS
#define NOUT 6422528L         // BS*512
#define SLD  224              // score row ld (7*32)

typedef __attribute__((ext_vector_type(8))) short bf16x8;
typedef __attribute__((ext_vector_type(4))) float f32x4;

// ---------------- device helpers ----------------
__device__ __forceinline__ float block_red256(float v, float* red, bool ismax) {
#pragma unroll
  for (int o = 32; o > 0; o >>= 1) {
    float t = __shfl_down(v, o, 64);
    v = ismax ? fmaxf(v, t) : v + t;
  }
  int lane = threadIdx.x & 63, wid = threadIdx.x >> 6;
  if (lane == 0) red[wid] = v;
  __syncthreads();
  float r = ismax ? fmaxf(fmaxf(red[0], red[1]), fmaxf(red[2], red[3]))
                  : (red[0] + red[1]) + (red[2] + red[3]);
  __syncthreads();
  return r;
}

// HW RNE conversion — bit-identical to the add-0x7fff bit-trick.
__device__ __forceinline__ short f2bf(float f) {
  __hip_bfloat16 h = __float2bfloat16(f);
  short s;
  __builtin_memcpy(&s, &h, 2);
  return s;
}

__device__ __forceinline__ void cvt8(short* dst, float4 a, float4 b) {
  union { short s[8]; int4 v; } u;
  u.s[0] = f2bf(a.x); u.s[1] = f2bf(a.y); u.s[2] = f2bf(a.z); u.s[3] = f2bf(a.w);
  u.s[4] = f2bf(b.x); u.s[5] = f2bf(b.y); u.s[6] = f2bf(b.z); u.s[7] = f2bf(b.w);
  *(int4*)dst = u.v;
}

// Raw barrier: ds ops drained, global loads stay in flight (no vmcnt drain).
__device__ __forceinline__ void lds_barrier() {
  asm volatile("s_waitcnt lgkmcnt(0)" ::: "memory");
  __builtin_amdgcn_s_barrier();
  __builtin_amdgcn_sched_barrier(0);
}

// Bijective XCD-chunked swizzle (m204).
__device__ __forceinline__ int xcd_swizzle(int flat, int nwg) {
  int q = nwg >> 3, r = nwg & 7;
  int xcd = flat & 7, pos = flat >> 3;
  return (xcd < r ? xcd * (q + 1) : r * (q + 1) + (xcd - r) * q) + pos;
}

// ---- bf16 MFMA GEMM: C[M,N] = A[M,K] @ W[N,K]^T + bias (opt relu) ----
// 128x128 tile, BK=32, 4 waves (2x2). 2-phase pipeline + XCD swizzle.
__global__ __launch_bounds__(256) void k_mfma_nt(
    const float* __restrict__ A, const float* __restrict__ W,
    const float* __restrict__ bias, float* __restrict__ C,
    int M, int N, int K, int relu) {
  __shared__ short As[2][128][40];
  __shared__ short Bs[2][128][40];
  const int tid = threadIdx.x;
  const int lane = tid & 63, wave = tid >> 6;
  const int wm = wave >> 1, wn = wave & 1;
  const int NX = gridDim.x;
  const int wg = xcd_swizzle(blockIdx.y * NX + blockIdx.x, NX * gridDim.y);
  const int m0 = (wg / NX) * 128, n0 = (wg % NX) * 128;
  const int srow = tid >> 1, skh = (tid & 1) * 16;
  const float* Ap = A + (long)(m0 + srow) * K + skh;
  const float* Wp = W + (long)(n0 + srow) * K + skh;
  const int fr = lane & 15, fq = lane >> 4;
  const int NK = K >> 5;
  f32x4 acc[4][4] = {};
  float4 xa[4], xw[4], ya[4], yw[4];

  auto ldt = [&](float4 (&ta)[4], float4 (&tw)[4], int t) {
    const float* ap = Ap + t * 32;
    const float* wp = Wp + t * 32;
#pragma unroll
    for (int i = 0; i < 4; ++i) {
      ta[i] = *(const float4*)(ap + i * 4);
      tw[i] = *(const float4*)(wp + i * 4);
    }
  };
  auto stage = [&](float4 (&ta)[4], float4 (&tw)[4], int p) {
    cvt8(&As[p][srow][skh], ta[0], ta[1]);
    cvt8(&As[p][srow][skh + 8], ta[2], ta[3]);
    cvt8(&Bs[p][srow][skh], tw[0], tw[1]);
    cvt8(&Bs[p][srow][skh + 8], tw[2], tw[3]);
  };
  auto step = [&](int t, float4 (&la)[4], float4 (&lw)[4],
                  float4 (&ca)[4], float4 (&cw)[4]) {
    const int par = t & 1;
    if (t + 2 < NK) ldt(la, lw, t + 2);            // prefetch tile t+2
    bf16x8 af[4], bfr[4];
#pragma unroll
    for (int i = 0; i < 4; ++i) af[i] = *(const bf16x8*)&As[par][wm * 64 + i * 16 + fr][fq * 8];
#pragma unroll
    for (int j = 0; j < 4; ++j) bfr[j] = *(const bf16x8*)&Bs[par][wn * 64 + j * 16 + fr][fq * 8];
    if (t + 1 < NK) stage(ca, cw, par ^ 1);        // stage tile t+1
#pragma unroll
    for (int i = 0; i < 4; ++i)
#pragma unroll
      for (int j = 0; j < 4; ++j)
        acc[i][j] = __builtin_amdgcn_mfma_f32_16x16x32_bf16(af[i], bfr[j], acc[i][j], 0, 0, 0);
    lds_barrier();
  };

  ldt(xa, xw, 0);
  stage(xa, xw, 0);
  if (NK > 1) ldt(xa, xw, 1);
  lds_barrier();
  int t = 0;
  for (; t + 1 < NK; t += 2) { step(t, ya, yw, xa, xw); step(t + 1, xa, xw, ya, yw); }
  if (t < NK) step(t, ya, yw, xa, xw);

#pragma unroll
  for (int i = 0; i < 4; ++i) {
    int mB = m0 + wm * 64 + i * 16 + fq * 4;
#pragma unroll
    for (int j = 0; j < 4; ++j) {
      int n = n0 + wn * 64 + j * 16 + fr;
      float bz = bias[n];
#pragma unroll
      for (int r2 = 0; r2 < 4; ++r2) {
        float v = acc[i][j][r2] + bz;
        if (relu) v = fmaxf(v, 0.f);
        C[(long)(mB + r2) * N + n] = v;
      }
    }
  }
}

// ---- bf16 MFMA embed (z=2 fused, opt dup-out): C = X@W^T + bias + pe - sub ----
__global__ __launch_bounds__(256) void k_mfma_embed(
    const float* __restrict__ X1, const float* __restrict__ X2,  // [B,1024,196]
    const float* __restrict__ W,   // [512,1024]
    const float* __restrict__ bias,
    const float* __restrict__ wemb, const float* __restrict__ hemb,
    const float* __restrict__ sub1, const float* __restrict__ sub2,
    float* __restrict__ C1, float* __restrict__ C2,
    float* __restrict__ D1, float* __restrict__ D2) {
  __shared__ short As[2][128][40];
  __shared__ short Bs[2][128][40];
  const float* X = blockIdx.z ? X2 : X1;
  const float* sub = blockIdx.z ? sub2 : sub1;
  float* C = blockIdx.z ? C2 : C1;
  float* D = blockIdx.z ? D2 : D1;
  const int tid = threadIdx.x;
  const int lane = tid & 63, wave = tid >> 6;
  const int wm = wave >> 1, wn = wave & 1;
  const int NX = gridDim.x;
  const int wg = xcd_swizzle(blockIdx.y * NX + blockIdx.x, NX * gridDim.y);
  const int m0 = (wg / NX) * 128, n0 = (wg % NX) * 128;
  const int K = 1024, N = 512;
  const int srow = tid >> 1, skh = (tid & 1) * 16;
  const float* Wp = W + (long)(n0 + srow) * K + skh;
  const int arow = tid & 127, khalf = tid >> 7;
  const int am = m0 + arow;
  const int ab = am / 196, as_ = am % 196;
  const float* Xp = X + (long)ab * 200704 + as_;
  const int fr = lane & 15, fq = lane >> 4;
  const int NK = K >> 5;   // 32
  f32x4 acc[4][4] = {};
  float xx[16], yx[16];
  float4 xw[4], yw[4];

  auto ldt = [&](float (&tx)[16], float4 (&tw)[4], int t) {
    const int kb = t * 32 + khalf * 16;
#pragma unroll
    for (int i = 0; i < 16; ++i) tx[i] = Xp[(long)(kb + i) * 196];
    const float* wp = Wp + t * 32;
#pragma unroll
    for (int i = 0; i < 4; ++i) tw[i] = *(const float4*)(wp + i * 4);
  };
  auto stage = [&](float (&tx)[16], float4 (&tw)[4], int p) {
    union { short s[16]; int4 v[2]; } u;
#pragma unroll
    for (int i = 0; i < 16; ++i) u.s[i] = f2bf(tx[i]);
    int4* dst = (int4*)&As[p][arow][khalf * 16];
    dst[0] = u.v[0]; dst[1] = u.v[1];
    cvt8(&Bs[p][srow][skh], tw[0], tw[1]);
    cvt8(&Bs[p][srow][skh + 8], tw[2], tw[3]);
  };
  auto step = [&](int t, float (&lx)[16], float4 (&lw)[4],
                  float (&cx)[16], float4 (&cw)[4]) {
    const int par = t & 1;
    if (t + 2 < NK) ldt(lx, lw, t + 2);
    bf16x8 af[4], bfr[4];
#pragma unroll
    for (int i = 0; i < 4; ++i) af[i] = *(const bf16x8*)&As[par][wm * 64 + i * 16 + fr][fq * 8];
#pragma unroll
    for (int j = 0; j < 4; ++j) bfr[j] = *(const bf16x8*)&Bs[par][wn * 64 + j * 16 + fr][fq * 8];
    if (t + 1 < NK) stage(cx, cw, par ^ 1);
#pragma unroll
    for (int i = 0; i < 4; ++i)
#pragma unroll
      for (int j = 0; j < 4; ++j)
        acc[i][j] = __builtin_amdgcn_mfma_f32_16x16x32_bf16(af[i], bfr[j], acc[i][j], 0, 0, 0);
    lds_barrier();
  };

  ldt(xx, xw, 0);
  stage(xx, xw, 0);
  if (NK > 1) ldt(xx, xw, 1);
  lds_barrier();
  int t = 0;
  for (; t + 1 < NK; t += 2) { step(t, yx, yw, xx, xw); step(t + 1, xx, xw, yx, yw); }
  if (t < NK) step(t, yx, yw, xx, xw);

#pragma unroll
  for (int i = 0; i < 4; ++i) {
    int mB = m0 + wm * 64 + i * 16 + fq * 4;
#pragma unroll
    for (int j = 0; j < 4; ++j) {
      int n = n0 + wn * 64 + j * 16 + fr;
      float bz = bias[n];
#pragma unroll
      for (int r2 = 0; r2 < 4; ++r2) {
        int m = mB + r2;
        int s = m % 196;
        float pe = (n < 256) ? wemb[(s % 14) * 256 + n] : hemb[(s / 14) * 256 + (n - 256)];
        float v = acc[i][j][r2] + bz + pe;
        if (sub) v -= sub[(long)m * N + n];
        C[(long)m * N + n] = v;
        if (D) D[(long)m * N + n] = v;
      }
    }
  }
}

// ---- Fused flash-style MHA: B=64,H=8,S=196,D=64. One block per (b,h). ----
__global__ __launch_bounds__(256) void k_fmha(
    const float* __restrict__ Q, const float* __restrict__ KV,
    float* __restrict__ O) {
  __shared__ short Vt[64][240];     // V^T bf16 (keys 196..223 zeroed)
  __shared__ short Pt[4][16][40];   // per-wave P staging
  const int tid = threadIdx.x;
  const int lane = tid & 63, wave = tid >> 6;
  const int b = blockIdx.x, h = blockIdx.y;
  const long brow = (long)b * 196;
  const float* Qb = Q + brow * 512 + h * 64;
  const float* Kb = KV + brow * 1024 + h * 64;
  const float* Vb = KV + brow * 1024 + 512 + h * 64;
  float* Ob = O + brow * 512 + h * 64;
  const int fr = lane & 15, fq = lane >> 4;

  for (int i = tid; i < 64 * 32; i += 256) {
    int d = i >> 5, k = 192 + (i & 31);
    if (k >= 196) Vt[d][k] = 0;
  }
  for (int i = tid; i < 196 * 16; i += 256) {
    int s = i >> 4, c4 = (i & 15) * 4;
    float4 v = *(const float4*)(Vb + (long)s * 1024 + c4);
    Vt[c4 + 0][s] = f2bf(v.x);
    Vt[c4 + 1][s] = f2bf(v.y);
    Vt[c4 + 2][s] = f2bf(v.z);
    Vt[c4 + 3][s] = f2bf(v.w);
  }
  __syncthreads();

  for (int qt = wave; qt < 13; qt += 4) {
    const int q0 = qt * 16;
    const int qr = (q0 + fr < 196) ? q0 + fr : 195;
    bf16x8 aq0, aq1;
    {
      const float* qp = Qb + (long)qr * 512 + fq * 8;
      float4 a = *(const float4*)(qp);
      float4 b2 = *(const float4*)(qp + 4);
      float4 c = *(const float4*)(qp + 32);
      float4 d = *(const float4*)(qp + 36);
      cvt8((short*)&aq0, a, b2);
      cvt8((short*)&aq1, c, d);
    }
    f32x4 sc[13];
#pragma unroll
    for (int t = 0; t < 13; ++t) {
      int kr = (t * 16 + fr < 196) ? t * 16 + fr : 195;
      const float* kp = Kb + (long)kr * 1024 + fq * 8;
      float4 a = *(const float4*)(kp);
      float4 b2 = *(const float4*)(kp + 4);
      float4 c = *(const float4*)(kp + 32);
      float4 d = *(const float4*)(kp + 36);
      bf16x8 bk0, bk1;
      cvt8((short*)&bk0, a, b2);
      cvt8((short*)&bk1, c, d);
      f32x4 z = {};
      z = __builtin_amdgcn_mfma_f32_16x16x32_bf16(aq0, bk0, z, 0, 0, 0);
      z = __builtin_amdgcn_mfma_f32_16x16x32_bf16(aq1, bk1, z, 0, 0, 0);
      sc[t] = z;
    }
#pragma unroll
    for (int t = 0; t < 13; ++t)
#pragma unroll
      for (int r2 = 0; r2 < 4; ++r2) sc[t][r2] *= 0.125f;
    if (fr >= 4) {
#pragma unroll
      for (int r2 = 0; r2 < 4; ++r2) sc[12][r2] = -1e30f;
    }
#pragma unroll
    for (int r2 = 0; r2 < 4; ++r2) {
      float m = sc[0][r2];
#pragma unroll
      for (int t = 1; t < 13; ++t) m = fmaxf(m, sc[t][r2]);
#pragma unroll
      for (int o = 1; o < 16; o <<= 1) m = fmaxf(m, __shfl_xor(m, o, 64));
      float s = 0.f;
#pragma unroll
      for (int t = 0; t < 13; ++t) { float e = expf(sc[t][r2] - m); sc[t][r2] = e; s += e; }
#pragma unroll
      for (int o = 1; o < 16; o <<= 1) s += __shfl_xor(s, o, 64);
      float inv = 1.0f / s;
#pragma unroll
      for (int t = 0; t < 13; ++t) sc[t][r2] *= inv;
    }
    f32x4 acc_o[4] = {};
#pragma unroll
    for (int s7 = 0; s7 < 7; ++s7) {
      const int t0 = 2 * s7, t1 = 2 * s7 + 1;
#pragma unroll
      for (int r2 = 0; r2 < 4; ++r2) {
        Pt[wave][fq * 4 + r2][fr] = f2bf(sc[t0][r2]);
        Pt[wave][fq * 4 + r2][16 + fr] = (t1 < 13) ? f2bf(sc[t1][r2]) : (short)0;
      }
      asm volatile("s_waitcnt lgkmcnt(0)" ::: "memory");
      bf16x8 ap = *(const bf16x8*)&Pt[wave][fr][fq * 8];
#pragma unroll
      for (int dt = 0; dt < 4; ++dt) {
        bf16x8 bv = *(const bf16x8*)&Vt[dt * 16 + fr][32 * s7 + fq * 8];
        acc_o[dt] = __builtin_amdgcn_mfma_f32_16x16x32_bf16(ap, bv, acc_o[dt], 0, 0, 0);
      }
    }
#pragma unroll
    for (int r2 = 0; r2 < 4; ++r2) {
      int qrow = q0 + fq * 4 + r2;
      if (qrow < 196) {
        float* op = Ob + (long)qrow * 512;
#pragma unroll
        for (int dt = 0; dt < 4; ++dt) op[dt * 16 + fr] = acc_o[dt][r2];
      }
    }
  }
}

// ---- Batched bf16 MFMA NT: C[z][m,n] = scale*sum_k A[z][m,k]*B[z][n,k] ----
// Optional clamp, bias+relu. 64x64 tile, 4 waves, XCD swizzle per z-plane.
__global__ __launch_bounds__(256) void k_mfma_bnt(
    const float* __restrict__ A, const float* __restrict__ B, float* __restrict__ C,
    int M, int N, int K, int lda, int ldb, int ldc, int nz2,
    int64_t sA1, int64_t sA2, int64_t sB1, int64_t sB2, int64_t sC1, int64_t sC2,
    float scale, int clampf, const float* __restrict__ bias2, int relu2) {
  __shared__ short As[2][64][40];
  __shared__ short Bs[2][64][40];
  const int tid = threadIdx.x;
  const int lane = tid & 63, wave = tid >> 6;
  const int NX = gridDim.x;
  const int wg = xcd_swizzle(blockIdx.y * NX + blockIdx.x, NX * gridDim.y);
  const int m0 = (wg / NX) * 64, n0 = (wg % NX) * 64;
  const int z = blockIdx.z, z1 = z / nz2, z2 = z % nz2;
  const float* Ab = A + z1 * sA1 + z2 * sA2;
  const float* Bb = B + z1 * sB1 + z2 * sB2;
  float* Cb = C + z1 * sC1 + z2 * sC2;
  const int sr = tid >> 2, skh = (tid & 3) * 8;
  const int ar = (m0 + sr < M) ? m0 + sr : M - 1;
  const int br = (n0 + sr < N) ? n0 + sr : N - 1;
  const float* Ap = Ab + (long)ar * lda + skh;
  const float* Bp = Bb + (long)br * ldb + skh;
  const int fr = lane & 15, fq = lane >> 4;
  const int NK = K >> 5;
  f32x4 acc[4] = {};
  float4 xa[2], xb[2], ya[2], yb[2];

  auto ldt = [&](float4 (&ta)[2], float4 (&tb)[2], int t) {
    const int kb = t * 32;
#pragma unroll
    for (int i = 0; i < 2; ++i) {
      ta[i] = *(const float4*)(Ap + kb + i * 4);
      tb[i] = *(const float4*)(Bp + kb + i * 4);
    }
  };
  auto stage = [&](float4 (&ta)[2], float4 (&tb)[2], int p) {
    cvt8(&As[p][sr][skh], ta[0], ta[1]);
    cvt8(&Bs[p][sr][skh], tb[0], tb[1]);
  };
  auto step = [&](int t, float4 (&la)[2], float4 (&lb)[2],
                  float4 (&ca)[2], float4 (&cb)[2]) {
    const int par = t & 1;
    if (t + 2 < NK) ldt(la, lb, t + 2);
    bf16x8 bfr = *(const bf16x8*)&Bs[par][wave * 16 + fr][fq * 8];
    bf16x8 af[4];
#pragma unroll
    for (int i = 0; i < 4; ++i) af[i] = *(const bf16x8*)&As[par][i * 16 + fr][fq * 8];
    if (t + 1 < NK) stage(ca, cb, par ^ 1);
#pragma unroll
    for (int i = 0; i < 4; ++i)
      acc[i] = __builtin_amdgcn_mfma_f32_16x16x32_bf16(af[i], bfr, acc[i], 0, 0, 0);
    lds_barrier();
  };

  ldt(xa, xb, 0);
  stage(xa, xb, 0);
  if (NK > 1) ldt(xa, xb, 1);
  lds_barrier();
  int t = 0;
  for (; t + 1 < NK; t += 2) { step(t, ya, yb, xa, xb); step(t + 1, xa, xb, ya, yb); }
  if (t < NK) step(t, ya, yb, xa, xb);

  const int n = n0 + wave * 16 + fr;
  if (n < N) {
    float bz = bias2 ? bias2[n] : 0.f;
#pragma unroll
    for (int i = 0; i < 4; ++i) {
      int mb = m0 + i * 16 + fq * 4;
#pragma unroll
      for (int r2 = 0; r2 < 4; ++r2) {
        int m = mb + r2;
        if (m < M) {
          float v = acc[i][r2] * scale + bz;
          if (relu2) v = fmaxf(v, 0.f);
          if (clampf) v = fminf(fmaxf(v, -100.f), 100.f);
          Cb[(long)m * ldc + n] = v;
        }
      }
    }
  }
}

// ---- Batched bf16 MFMA NN: C[z][m,n] = sum_k A[z][m,k]*B[z][k,n] ----
__global__ __launch_bounds__(256) void k_mfma_bnn(
    const float* __restrict__ A, const float* __restrict__ B, float* __restrict__ C,
    int M, int N, int K, int KBvalid, int lda, int ldb, int ldc, int nz2,
    int64_t sA1, int64_t sA2, int64_t sB1, int64_t sB2, int64_t sC1, int64_t sC2) {
  __shared__ short As[2][64][40];
  __shared__ short Bs[2][64][40];
  const int tid = threadIdx.x;
  const int lane = tid & 63, wave = tid >> 6;
  const int m0 = blockIdx.y * 64, n0 = blockIdx.x * 64;
  const int z = blockIdx.z, z1 = z / nz2, z2 = z % nz2;
  const float* Ab = A + z1 * sA1 + z2 * sA2;
  const float* Bb = B + z1 * sB1 + z2 * sB2;
  float* Cb = C + z1 * sC1 + z2 * sC2;
  const int sr = tid >> 2, skh = (tid & 3) * 8;
  const int ar = (m0 + sr < M) ? m0 + sr : M - 1;
  const float* Ap = Ab + (long)ar * lda + skh;
  const int bk = tid >> 3, bn = (tid & 7) * 8;   // B transposed staging
  const int fr = lane & 15, fq = lane >> 4;
  const int NK = K >> 5;
  f32x4 acc[4] = {};
  float4 xa[2], xb[2], ya[2], yb[2];

  auto ldt = [&](float4 (&ta)[2], float4 (&tb)[2], int t) {
    const int kb = t * 32;
#pragma unroll
    for (int i = 0; i < 2; ++i) ta[i] = *(const float4*)(Ap + kb + i * 4);
    int kc = kb + bk;
    if (kc >= KBvalid) kc = KBvalid - 1;
    const float* bp = Bb + (long)kc * ldb + n0 + bn;
#pragma unroll
    for (int i = 0; i < 2; ++i) tb[i] = *(const float4*)(bp + i * 4);
  };
  auto stage = [&](float4 (&ta)[2], float4 (&tb)[2], int p) {
    cvt8(&As[p][sr][skh], ta[0], ta[1]);
    short tmp[8];
    cvt8(tmp, tb[0], tb[1]);
#pragma unroll
    for (int j = 0; j < 8; ++j) Bs[p][bn + j][bk] = tmp[j];
  };
  auto step = [&](int t, float4 (&la)[2], float4 (&lb)[2],
                  float4 (&ca)[2], float4 (&cb)[2]) {
    const int par = t & 1;
    if (t + 2 < NK) ldt(la, lb, t + 2);
    bf16x8 bfr = *(const bf16x8*)&Bs[par][wave * 16 + fr][fq * 8];
    bf16x8 af[4];
#pragma unroll
    for (int i = 0; i < 4; ++i) af[i] = *(const bf16x8*)&As[par][i * 16 + fr][fq * 8];
    if (t + 1 < NK) stage(ca, cb, par ^ 1);
#pragma unroll
    for (int i = 0; i < 4; ++i)
      acc[i] = __builtin_amdgcn_mfma_f32_16x16x32_bf16(af[i], bfr, acc[i], 0, 0, 0);
    lds_barrier();
  };

  ldt(xa, xb, 0);
  stage(xa, xb, 0);
  if (NK > 1) ldt(xa, xb, 1);
  lds_barrier();
  int t = 0;
  for (; t + 1 < NK; t += 2) { step(t, ya, yb, xa, xb); step(t + 1, xa, xb, ya, yb); }
  if (t < NK) step(t, ya, yb, xa, xb);

  const int n = n0 + wave * 16 + fr;
  if (n < N) {
#pragma unroll
    for (int i = 0; i < 4; ++i) {
      int mb = m0 + i * 16 + fq * 4;
#pragma unroll
      for (int r2 = 0; r2 < 4; ++r2) {
        int m = mb + r2;
        if (m < M) Cb[(long)m * ldc + n] = acc[i][r2];
      }
    }
  }
}

// ---- MFMA correlation: C[i,j] += scale * sum_m Za[m,i]*Zb[m,j] (split-K atomic) ----
__global__ __launch_bounds__(256) void k_mfma_corr(
    const float* __restrict__ Za, const float* __restrict__ Zb,
    float* __restrict__ C, int mchunk, float scale) {
  __shared__ short As[2][64][40];
  __shared__ short Bs[2][64][40];
  const int tid = threadIdx.x;
  const int lane = tid & 63, wave = tid >> 6;
  const int i0 = blockIdx.y * 64, j0 = blockIdx.x * 64;
  const int mstart = blockIdx.z * mchunk;
  const int tm = tid >> 3, tcb = (tid & 7) * 8;
  const int fr = lane & 15, fq = lane >> 4;
  const int NK = mchunk >> 5;   // 28
  f32x4 acc[4] = {};
  float4 xa[2], xb[2], ya[2], yb[2];

  auto ldt = [&](float4 (&ta)[2], float4 (&tb)[2], int t) {
    const float* za = Za + (long)(mstart + t * 32 + tm) * 512;
    const float* zb = Zb + (long)(mstart + t * 32 + tm) * 512;
    ta[0] = *(const float4*)(za + i0 + tcb);
    ta[1] = *(const float4*)(za + i0 + tcb + 4);
    tb[0] = *(const float4*)(zb + j0 + tcb);
    tb[1] = *(const float4*)(zb + j0 + tcb + 4);
  };
  auto stage = [&](float4 (&ta)[2], float4 (&tb)[2], int p) {
    short u[8], v[8];
    cvt8(u, ta[0], ta[1]);
    cvt8(v, tb[0], tb[1]);
#pragma unroll
    for (int j = 0; j < 8; ++j) { As[p][tcb + j][tm] = u[j]; Bs[p][tcb + j][tm] = v[j]; }
  };
  auto step = [&](int t, float4 (&la)[2], float4 (&lb)[2],
                  float4 (&ca)[2], float4 (&cb)[2]) {
    const int par = t & 1;
    if (t + 2 < NK) ldt(la, lb, t + 2);
    bf16x8 bfr = *(const bf16x8*)&Bs[par][wave * 16 + fr][fq * 8];
    bf16x8 af[4];
#pragma unroll
    for (int i = 0; i < 4; ++i) af[i] = *(const bf16x8*)&As[par][i * 16 + fr][fq * 8];
    if (t + 1 < NK) stage(ca, cb, par ^ 1);
#pragma unroll
    for (int i = 0; i < 4; ++i)
      acc[i] = __builtin_amdgcn_mfma_f32_16x16x32_bf16(af[i], bfr, acc[i], 0, 0, 0);
    lds_barrier();
  };

  ldt(xa, xb, 0);
  stage(xa, xb, 0);
  if (NK > 1) ldt(xa, xb, 1);
  lds_barrier();
  int t = 0;
  for (; t + 1 < NK; t += 2) { step(t, ya, yb, xa, xb); step(t + 1, xa, xb, ya, yb); }
  if (t < NK) step(t, ya, yb, xa, xb);

  const int j = j0 + wave * 16 + fr;
#pragma unroll
  for (int i = 0; i < 4; ++i) {
    int ib = i0 + i * 16 + fq * 4;
#pragma unroll
    for (int r2 = 0; r2 < 4; ++r2)
      atomicAdd(&C[(long)(ib + r2) * 512 + j], acc[i][r2] * scale);
  }
}

// ---------------- fp32 GEMM fallback (unused hot path) ----------------
__global__ __launch_bounds__(256) void k_gemm_nt(
    const float* __restrict__ A, const float* __restrict__ W,
    const float* __restrict__ bias, float* __restrict__ C,
    int M, int N, int K, int relu) {
  __shared__ float As[16][68];
  __shared__ float Ws[16][68];
  const int tx = threadIdx.x, ty = threadIdx.y;
  const int tid = ty * 16 + tx;
  const int m0 = blockIdx.y * 64, n0 = blockIdx.x * 64;
  const int lr = tid >> 2, lk = (tid & 3) << 2;
  const float* Ap = A + (long)(m0 + lr) * K + lk;
  const float* Wp = W + (long)(n0 + lr) * K + lk;
  float acc[4][4] = {};
  for (int k0 = 0; k0 < K; k0 += 16) {
    float4 av = *(const float4*)(Ap + k0);
    float4 wv = *(const float4*)(Wp + k0);
    As[lk + 0][lr] = av.x; As[lk + 1][lr] = av.y; As[lk + 2][lr] = av.z; As[lk + 3][lr] = av.w;
    Ws[lk + 0][lr] = wv.x; Ws[lk + 1][lr] = wv.y; Ws[lk + 2][lr] = wv.z; Ws[lk + 3][lr] = wv.w;
    __syncthreads();
#pragma unroll
    for (int kk = 0; kk < 16; ++kk) {
      float4 a4 = *(const float4*)&As[kk][ty * 4];
      float4 w4 = *(const float4*)&Ws[kk][tx * 4];
      float a[4] = {a4.x, a4.y, a4.z, a4.w};
      float w[4] = {w4.x, w4.y, w4.z, w4.w};
#pragma unroll
      for (int i = 0; i < 4; ++i)
#pragma unroll
        for (int j = 0; j < 4; ++j) acc[i][j] += a[i] * w[j];
    }
    __syncthreads();
  }
#pragma unroll
  for (int i = 0; i < 4; ++i) {
    int m = m0 + ty * 4 + i;
#pragma unroll
    for (int j = 0; j < 4; ++j) {
      int n = n0 + tx * 4 + j;
      float v = acc[i][j] + bias[n];
      if (relu) v = fmaxf(v, 0.f);
      C[(long)m * N + n] = v;
    }
  }
}

// ---- Row softmax over rows of width 196, ld=SLD(224); zeroes pad cols. ----
__global__ __launch_bounds__(256) void k_softmax_rows(float* __restrict__ S, int nrows) {
  int row = blockIdx.x * 4 + (threadIdx.x >> 6);
  int lane = threadIdx.x & 63;
  if (row >= nrows) return;
  float* p = S + (long)row * SLD;
  float v0 = p[lane];
  float v1 = p[lane + 64];
  float v2 = p[lane + 128];
  float v3 = (lane + 192 < 196) ? p[lane + 192] : -1e30f;
  float mx = fmaxf(fmaxf(v0, v1), fmaxf(v2, v3));
#pragma unroll
  for (int o = 32; o > 0; o >>= 1) mx = fmaxf(mx, __shfl_down(mx, o, 64));
  mx = __shfl(mx, 0, 64);
  float e0 = expf(v0 - mx), e1 = expf(v1 - mx), e2 = expf(v2 - mx);
  float e3 = (lane + 192 < 196) ? expf(v3 - mx) : 0.f;
  float s = e0 + e1 + e2 + e3;
#pragma unroll
  for (int o = 32; o > 0; o >>= 1) s += __shfl_down(s, o, 64);
  s = __shfl(s, 0, 64);
  float inv = 1.0f / s;
  p[lane] = e0 * inv;
  p[lane + 64] = e1 * inv;
  p[lane + 128] = e2 * inv;
  if (lane + 192 < SLD) p[lane + 192] = (lane + 192 < 196) ? e3 * inv : 0.f;
}

// ---- Residual + LayerNorm (in place into h) ----
__global__ __launch_bounds__(256) void k_addln(
    float* __restrict__ h, const float* __restrict__ o,
    const float* __restrict__ g, const float* __restrict__ be) {
  __shared__ float red[4];
  long row = blockIdx.x;
  float* hr = h + row * 512;
  const float* orow = o + row * 512;
  int t = threadIdx.x;
  float v0 = hr[t] + orow[t];
  float v1 = hr[t + 256] + orow[t + 256];
  float mean = block_red256(v0 + v1, red, false) * (1.0f / 512.0f);
  float d0 = v0 - mean, d1 = v1 - mean;
  float var = block_red256(d0 * d0 + d1 * d1, red, false) * (1.0f / 512.0f);
  float inv = 1.0f / sqrtf(var + 1e-5f);
  hr[t] = d0 * inv * g[t] + be[t];
  hr[t + 256] = d1 * inv * g[t + 256] + be[t + 256];
}

// ---- small utility kernels ----
__global__ void k_zero(float* __restrict__ p, int n) {
  int i = blockIdx.x * 256 + threadIdx.x;
  if (i < n) p[i] = 0.f;
}

// d = x - h (vectorized)
__global__ __launch_bounds__(256) void k_diff(
    float* __restrict__ d, const float* __restrict__ x, const float* __restrict__ h) {
  long i = ((long)blockIdx.x * 256 + threadIdx.x) * 4;
  float4 xv = *(const float4*)(x + i);
  float4 hv = *(const float4*)(h + i);
  float4 r; r.x = xv.x - hv.x; r.y = xv.y - hv.y; r.z = xv.z - hv.z; r.w = xv.w - hv.w;
  *(float4*)(d + i) = r;
}

// concat two [512,512] weights into [1024,512] (+ biases into [1024])
__global__ __launch_bounds__(256) void k_catkv(
    float* __restrict__ dw, const float* __restrict__ kw, const float* __restrict__ vw,
    float* __restrict__ db, const float* __restrict__ kb, const float* __restrict__ vb) {
  int i = blockIdx.x * 256 + threadIdx.x;      // 1024*512
  int r = i >> 9;
  dw[i] = (r < 512) ? kw[i] : vw[i - 262144];
  if (i < 1024) db[i] = (i < 512) ? kb[i] : vb[i - 512];
}

__global__ __launch_bounds__(256) void k_colstats(
    const float* __restrict__ f, float* __restrict__ sums, float* __restrict__ sqs) {
  int c = blockIdx.x * 32 + (threadIdx.x & 31);
  int rbase = blockIdx.y * 256;
  int r0 = rbase + (threadIdx.x >> 5);
  float s = 0.f, s2 = 0.f;
  for (int r = r0; r < rbase + 256; r += 8) {
    float v = f[(long)r * 512 + c];
    s += v; s2 += v * v;
  }
  __shared__ float sh[256], sh2[256];
  sh[threadIdx.x] = s; sh2[threadIdx.x] = s2;
  __syncthreads();
  if (threadIdx.x < 32) {
    for (int i = 1; i < 8; ++i) { s += sh[i * 32 + threadIdx.x]; s2 += sh2[i * 32 + threadIdx.x]; }
    atomicAdd(&sums[c], s);
    atomicAdd(&sqs[c], s2);
  }
}

__global__ void k_finstats(const float* __restrict__ sums, const float* __restrict__ sqs,
                           float* __restrict__ mean, float* __restrict__ istd) {
  int c = blockIdx.x * 256 + threadIdx.x;
  float mu = sums[c] / 12544.0f;
  float var = (sqs[c] - 12544.0f * mu * mu) / 12543.0f;
  mean[c] = mu;
  istd[c] = 1.0f / sqrtf(var);
}

__global__ __launch_bounds__(256) void k_znorm(float* __restrict__ f, const float* __restrict__ mean,
                                               const float* __restrict__ istd) {
  long i = (long)blockIdx.x * 256 + threadIdx.x;
  int c = (int)(i & 511);
  f[i] = (f[i] - mean[c]) * istd[c];
}

// CDCR loss: 256-block partial reduce + final combine
__global__ __launch_bounds__(256) void k_cdcr_part(const float* __restrict__ Cm,
                                                   double* __restrict__ part) {
  int base = blockIdx.x * 1024;
  double on = 0, off = 0;
  for (int i = base + threadIdx.x; i < base + 1024; i += 256) {
    float v = Cm[i];
    int r = i >> 9, c = i & 511;
    if (r == c) { double d = (double)v - 1.0; on += d * d; }
    else        { off += (double)v * (double)v; }
  }
  __shared__ double s_on[256], s_off[256];
  s_on[threadIdx.x] = on; s_off[threadIdx.x] = off;
  __syncthreads();
  for (int st = 128; st > 0; st >>= 1) {
    if (threadIdx.x < st) { s_on[threadIdx.x] += s_on[threadIdx.x + st]; s_off[threadIdx.x] += s_off[threadIdx.x + st]; }
    __syncthreads();
  }
  if (threadIdx.x == 0) { part[blockIdx.x] = s_on[0]; part[256 + blockIdx.x] = s_off[0]; }
}

__global__ void k_cdcr_fin(const double* __restrict__ part, float* __restrict__ out) {
  __shared__ double s_on[256], s_off[256];
  s_on[threadIdx.x] = part[threadIdx.x];
  s_off[threadIdx.x] = part[256 + threadIdx.x];
  __syncthreads();
  for (int st = 128; st > 0; st >>= 1) {
    if (threadIdx.x < st) { s_on[threadIdx.x] += s_on[threadIdx.x + st]; s_off[threadIdx.x] += s_off[threadIdx.x + st]; }
    __syncthreads();
  }
  if (threadIdx.x == 0) out[0] = (float)(s_on[0] + 0.003 * s_off[0]);
}

__global__ __launch_bounds__(64) void k_mask(const float* __restrict__ capo, float* __restrict__ mask) {
  int pidx = blockIdx.x;
  float s = 0.f;
  for (int i = threadIdx.x; i < 512; i += 64) s += capo[(long)pidx * 512 + i];
#pragma unroll
  for (int o = 32; o > 0; o >>= 1) s += __shfl_down(s, o, 64);
  if (threadIdx.x == 0) mask[pidx] = (s != 0.f) ? 1.f : 0.f;
}

__global__ __launch_bounds__(256) void k_meannc(const float* __restrict__ src, const float* __restrict__ mask,
                                                float* __restrict__ vec) {
  int d = blockIdx.x * 256 + threadIdx.x;
  int b = blockIdx.y;
  float acc = 0.f, ms = 0.f;
  for (int nc = 0; nc < 16; ++nc) {
    float mk = mask ? mask[b * 16 + nc] : 1.f;
    acc += src[((long)b * 16 + nc) * 512 + d] * mk;
    ms += mk;
  }
  vec[(long)b * 512 + d] = acc / fmaxf(ms, 1e-6f);
}

__global__ __launch_bounds__(256) void k_mse(const float* __restrict__ full, const float* __restrict__ vec,
                                             double* __restrict__ part) {
  double loc = 0;
  const long n = NOUT;
  for (long i = (long)blockIdx.x * 256 + threadIdx.x; i < n; i += 256L * 1024) {
    int d = (int)(i & 511);
    int b = (int)(i >> 9) / 196;
    float df = full[i] - vec[b * 512 + d];
    loc += (double)df * (double)df;
  }
  __shared__ double sh[256];
  sh[threadIdx.x] = loc;
  __syncthreads();
  for (int st = 128; st > 0; st >>= 1) {
    if (threadIdx.x < st) sh[threadIdx.x] += sh[threadIdx.x + st];
    __syncthreads();
  }
  if (threadIdx.x == 0) part[blockIdx.x] = sh[0];
}

__global__ void k_finloss(const double* __restrict__ part, float* __restrict__ out) {
  __shared__ double sh[256];
  double s = 0;
  for (int i = threadIdx.x; i < 4096; i += 256) s += part[i];
  sh[threadIdx.x] = s;
  __syncthreads();
  for (int st = 128; st > 0; st >>= 1) {
    if (threadIdx.x < st) sh[threadIdx.x] += sh[threadIdx.x + st];
    __syncthreads();
  }
  if (threadIdx.x == 0) out[0] = (float)(sh[0] / (64.0 * 196.0 * 512.0));
}

__global__ __launch_bounds__(256) void k_concat2(float* __restrict__ dst, const float* __restrict__ a,
                                                 const float* __restrict__ b) {
  int i = blockIdx.x * 256 + threadIdx.x;   // 64*1024
  int col = i & 1023, row = i >> 10;
  dst[i] = (col < 512) ? a[row * 512 + col] : b[row * 512 + col - 512];
}

// comb chunk: rows [r0, r0+nrows) of [BS,2048] into dst
__global__ __launch_bounds__(256) void k_comb_chunk(
    float* __restrict__ dst, const float* __restrict__ d1, const float* __restrict__ d2,
    const float* __restrict__ txt, const float* __restrict__ al, long r0) {
  long i = (long)blockIdx.x * 256 + threadIdx.x;
  int col = (int)(i & 2047);
  long m = r0 + (i >> 11);
  int b = (int)(m / 196);
  float v;
  if (col < 512)       v = d1[m * 512 + col];
  else if (col < 1024) v = d2[m * 512 + col - 512];
  else if (col < 1536) v = txt[(long)b * 512 + col - 1024];
  else                 v = al[(long)b * 512 + col - 1536];
  dst[i] = v;
}

// ---------------- host ----------------
extern "C" void kernel_launch(void* const* d_in, const int* in_sizes, int n_in,
                              void* d_out, int out_size, void* d_ws, size_t ws_size,
                              hipStream_t stream) {
  (void)in_sizes; (void)n_in; (void)out_size;
  const float* in1    = (const float*)d_in[0];
  const float* in2    = (const float*)d_in[1];
  const float* cap1   = (const float*)d_in[2];
  const float* cap2   = (const float*)d_in[3];
  const float* imgw   = (const float*)d_in[4];
  const float* imgb   = (const float*)d_in[5];
  const float* wemb   = (const float*)d_in[6];
  const float* hemb   = (const float*)d_in[7];
  const float* mlpw1  = (const float*)d_in[8];
  const float* mlpb1  = (const float*)d_in[9];
  const float* mlpw2  = (const float*)d_in[10];
  const float* mlpb2  = (const float*)d_in[11];
  const float* fcw    = (const float*)d_in[12];
  const float* fcb    = (const float*)d_in[13];
  const float* efcw   = (const float*)d_in[14];
  const float* efcb   = (const float*)d_in[15];
  const float* efc2w  = (const float*)d_in[16];
  const float* efc2b  = (const float*)d_in[17];
  const float* trinw  = (const float*)d_in[18];
  const float* trinb  = (const float*)d_in[19];
  const float* troutw = (const float*)d_in[20];
  const float* troutb = (const float*)d_in[21];
  const float* trlng  = (const float*)d_in[22];
  const float* trlnb  = (const float*)d_in[23];
  const float* itqw = (const float*)d_in[24]; const float* itqb = (const float*)d_in[25];
  const float* itkw = (const float*)d_in[26]; const float* itkb = (const float*)d_in[27];
  const float* itvw = (const float*)d_in[28]; const float* itvb = (const float*)d_in[29];
  const float* caqw = (const float*)d_in[30]; const float* caqb = (const float*)d_in[31];
  const float* cakw = (const float*)d_in[32]; const float* cakb = (const float*)d_in[33];
  const float* cavw = (const float*)d_in[34]; const float* cavb = (const float*)d_in[35];
  const float* saqw = (const float*)d_in[36]; const float* saqb = (const float*)d_in[37];
  const float* sakw = (const float*)d_in[38]; const float* sakb = (const float*)d_in[39];
  const float* savw = (const float*)d_in[40]; const float* savb = (const float*)d_in[41];

  float* out = (float*)d_out;

  // ---- workspace carve ----
  const size_t SZ = (size_t)BS * 512;        // 6,422,528 floats (24.5 MB)
  float* w = (float*)d_ws;
  auto alloc = [&](size_t n) { float* p = w; w += n; return p; };
  float* h1 = alloc(SZ);
  float* h2 = alloc(SZ);       // contiguous with h1 (M=2BS fused GEMMs)
  float* tA = alloc(SZ);
  float* tB = alloc(SZ);       // contiguous with tA
  float* tC = alloc(SZ);
  float* tD = alloc(SZ);       // contiguous with tC
  float* sbuf = alloc(SZ);     // scores (ECA/ITDA) + o-proj temp
  float* cap1o = alloc(64 * 16 * 512);
  float* cap2o = alloc(64 * 16 * 512);
  float* qc1   = alloc(64 * 16 * 512);
  float* qc2   = alloc(64 * 16 * 512);
  float* attb  = alloc(64 * 16 * 512);
  float* cmat  = alloc(512 * 512);
  float* colsum1 = alloc(512); float* colsq1 = alloc(512);
  float* colsum2 = alloc(512); float* colsq2 = alloc(512);
  float* mean1 = alloc(512); float* istd1 = alloc(512);
  float* mean2 = alloc(512); float* istd2 = alloc(512);
  float* mask1 = alloc(1024); float* mask2 = alloc(1024);
  float* vdbef = alloc(64 * 512); float* vdaft = alloc(64 * 512);
  float* vsbef = alloc(64 * 512); float* vsaft = alloc(64 * 512);
  float* cm1 = alloc(64 * 512); float* cm2 = alloc(64 * 512);
  float* vdyn = alloc(64 * 512); float* vsta = alloc(64 * 512);
  float* valign = alloc(64 * 512); float* vtxt = alloc(64 * 512);
  float* ccat = alloc(64 * 1024);
  double* msepart = (double*)alloc(4096 * 2);   // 4096 doubles
  double* cdcrpart = (double*)alloc(1024);      // 512 doubles
  float* itkvw = alloc(1024 * 512); float* itkvb = alloc(1024);
  float* cakvw = alloc(1024 * 512); float* cakvb = alloc(1024);
  float* sakvw = alloc(1024 * 512); float* sakvb = alloc(1024);
  // x-save (optional, ws-size permitting): skip phase-4 embed recompute
  size_t used = (size_t)(w - (float*)d_ws);
  bool xsave = ws_size >= (used + 2 * SZ + 1024) * sizeof(float);
  float* x1 = nullptr;
  if (xsave) x1 = alloc(2 * SZ);   // [x1;x2] contiguous

  // GEMM router: 128^2 tile for big grids, 64^2 (bnt) for small grids.
  auto gemm = [&](const float* Aa, const float* Ww, const float* bb, float* Cc,
                  int M, int N, int K, int relu) {
    long g128 = ((M % 128) == 0 && (N % 128) == 0) ? (long)(N / 128) * (M / 128) : 0;
    if (g128 >= 784 && (K % 32) == 0)
      k_mfma_nt<<<dim3(N / 128, M / 128), 256, 0, stream>>>(Aa, Ww, bb, Cc, M, N, K, relu);
    else
      k_mfma_bnt<<<dim3(N / 64, (M + 63) / 64, 1), 256, 0, stream>>>(
          Aa, Ww, Cc, M, N, K, K, K, N, 1,
          0, 0, 0, 0, 0, 0, 1.0f, 0, bb, relu);
  };
  auto embed2 = [&](const float* s1, const float* s2, float* C1p, float* C2p,
                    float* D1p, float* D2p) {
    k_mfma_embed<<<dim3(4, BS / 128, 2), 256, 0, stream>>>(
        in1, in2, imgw, imgb, wemb, hemb, s1, s2, C1p, C2p, D1p, D2p);
  };
  const int64_t RB = (int64_t)SS * 512;   // 100352
  const int64_t QB = 16 * 512;            // 8192
  // GEMM-ized attention, D=512 single-head, K|V packed in one [*,1024] buffer.
  auto attn512 = [&](const float* Qp, int64_t qZ, const float* KVp, int64_t kvZ,
                     float* Op, int64_t oZ, int M, float scale) {
    int mt = (M + 63) / 64;
    int64_t sS = (int64_t)M * SLD;
    k_mfma_bnt<<<dim3(4, mt, 64), 256, 0, stream>>>(
        Qp, KVp, sbuf, M, 196, 512, 512, 1024, SLD, 1,
        qZ, 0, kvZ, 0, sS, 0, scale, 1, nullptr, 0);
    k_softmax_rows<<<(64 * M + 3) / 4, 256, 0, stream>>>(sbuf, 64 * M);
    k_mfma_bnn<<<dim3(8, mt, 64), 256, 0, stream>>>(
        sbuf, KVp + 512, Op, M, 512, SLD, 196, SLD, 1024, 512, 1,
        sS, 0, kvZ, 0, oZ, 0);
  };
  auto attn_mha = [&](const float* Qp, const float* KVp, float* Op) {
    k_fmha<<<dim3(64, 8), 256, 0, stream>>>(Qp, KVp, Op);
  };
  auto efc64 = [&](const float* Aa, float* Cc) {
    k_mfma_bnt<<<dim3(8, 1, 1), 256, 0, stream>>>(
        Aa, efcw, Cc, 64, 512, 1024, 1024, 1024, 512, 1,
        0, 0, 0, 0, 0, 0, 1.0f, 0, efcb, 1);
  };

  const float scalE = 1.0f / sqrtf(512.0f);

  // ---- Phase 0: build concat K|V weights for itda/ca/sa ----
  k_catkv<<<2048, 256, 0, stream>>>(itkvw, itkw, itvw, itkvb, itkb, itvb);
  k_catkv<<<2048, 256, 0, stream>>>(cakvw, cakw, cavw, cakvb, cakb, cavb);
  k_catkv<<<2048, 256, 0, stream>>>(sakvw, sakw, savw, sakvb, sakb, savb);

  // ---- Phase 1: embed (h starts as x; dup into x-save) + caption projections ----
  if (xsave) embed2(nullptr, nullptr, h1, h2, x1, x1 + SZ);
  else       embed2(nullptr, nullptr, h1, h2, nullptr, nullptr);
  gemm(cap1, fcw, fcb, cap1o, 1024, 512, 768, 0);
  gemm(cap2, fcw, fcb, cap2o, 1024, 512, 768, 0);
  k_meannc<<<dim3(2, 64), 256, 0, stream>>>(cap1o, nullptr, cm1);
  k_meannc<<<dim3(2, 64), 256, 0, stream>>>(cap2o, nullptr, cm2);

  // ---- Phase 2: CDCR loss (f1->tA, f2->tB, hidden chunk in tC..tD) ----
  for (int c = 0; c < 2; ++c) {
    const size_t off = (size_t)c * 6272 * 512;
    gemm(h1 + off, mlpw1, mlpb1, tC, 6272, 2048, 512, 1);
    gemm(tC, mlpw2, mlpb2, tA + off, 6272, 512, 2048, 0);
  }
  for (int c = 0; c < 2; ++c) {
    const size_t off = (size_t)c * 6272 * 512;
    gemm(h2 + off, mlpw1, mlpb1, tC, 6272, 2048, 512, 1);
    gemm(tC, mlpw2, mlpb2, tB + off, 6272, 512, 2048, 0);
  }
  k_zero<<<8, 256, 0, stream>>>(colsum1, 2048);  // colsum1..colsq2 contiguous
  k_colstats<<<dim3(16, 49), 256, 0, stream>>>(tA, colsum1, colsq1);
  k_colstats<<<dim3(16, 49), 256, 0, stream>>>(tB, colsum2, colsq2);
  k_finstats<<<2, 256, 0, stream>>>(colsum1, colsq1, mean1, istd1);
  k_finstats<<<2, 256, 0, stream>>>(colsum2, colsq2, mean2, istd2);
  k_znorm<<<25088, 256, 0, stream>>>(tA, mean1, istd1);
  k_znorm<<<25088, 256, 0, stream>>>(tB, mean2, istd2);
  k_zero<<<1024, 256, 0, stream>>>(cmat, 262144);
  k_mfma_corr<<<dim3(8, 8, 14), 256, 0, stream>>>(tA, tB, cmat, BS / 14, 1.0f / (float)BS);
  k_cdcr_part<<<256, 256, 0, stream>>>(cmat, cdcrpart);
  k_cdcr_fin<<<1, 256, 0, stream>>>(cdcrpart, out + NOUT);

  // ---- Phase 3: cross-transformer (2 layers, simultaneous update) ----
  // q fused across directions (h1,h2 contiguous -> M=2BS); K|V fused per source.
  for (int l = 0; l < 2; ++l) {
    const float* Wq = trinw + (size_t)l * 1536 * 512;
    const float* Wkv = Wq + 512 * 512;               // [Wk;Wv] 1024 rows
    const float* bq = trinb + l * 1536;
    const float* bkv = bq + 512;                     // [bk|bv] 1024
    const float* Wo = troutw + (size_t)l * 512 * 512;
    const float* bo = troutb + l * 512;
    const float* g  = trlng + l * 512;
    const float* be = trlnb + l * 512;
    gemm(h1, Wq, bq, tA, 2 * BS, 512, 512, 0);       // q1|q2 -> tA..tB
    gemm(h2, Wkv, bkv, tC, BS, 1024, 512, 0);        // kv1 (from h2) -> tC..tD
    attn_mha(tA, tC, tA);                            // dir1 attn -> tA in place
    gemm(tA, Wo, bo, sbuf, BS, 512, 512, 0);         // o1 -> sbuf
    gemm(h1, Wkv, bkv, tC, BS, 1024, 512, 0);        // kv2 (from ORIGINAL h1)
    k_addln<<<BS, 256, 0, stream>>>(h1, sbuf, g, be);  // update h1 now
    attn_mha(tA + SZ, tC, tA + SZ);                  // dir2: q2 = tB
    gemm(tA + SZ, Wo, bo, sbuf, BS, 512, 512, 0);    // o2 -> sbuf
    k_addln<<<BS, 256, 0, stream>>>(h2, sbuf, g, be);
  }

  // ---- Phase 4: diffs (x-save path: one elementwise kernel; else recompute) ----
  if (xsave) {
    k_diff<<<12544, 256, 0, stream>>>(tC, x1, h1);   // [tC;tD] = [x1;x2]-[h1;h2]
  } else {
    embed2(h1, h2, tC, tD, nullptr, nullptr);
  }
  // h1, h2 now free

  // ---- Phase 5: ITDA (queries constant over S -> per-(b,nc) attention + masked mean) ----
  gemm(cap1o, itqw, itqb, qc1, 1024, 512, 512, 0);
  gemm(cap2o, itqw, itqb, qc2, 1024, 512, 512, 0);
  k_mask<<<1024, 64, 0, stream>>>(cap1o, mask1);
  k_mask<<<1024, 64, 0, stream>>>(cap2o, mask2);
  gemm(tC, itkvw, itkvb, tA, BS, 1024, 512, 0);      // kv from diff1 -> tA..tB
  attn512(qc2, QB, tA, 2 * RB, attb, QB, 16, scalE);
  k_meannc<<<dim3(2, 64), 256, 0, stream>>>(attb, mask2, vdbef);   // d_bef
  attn512(qc1, QB, tA, 2 * RB, attb, QB, 16, scalE);
  k_meannc<<<dim3(2, 64), 256, 0, stream>>>(attb, mask1, vsbef);   // s_bef
  gemm(tD, itkvw, itkvb, tA, BS, 1024, 512, 0);      // kv from diff2
  attn512(qc1, QB, tA, 2 * RB, attb, QB, 16, scalE);
  k_meannc<<<dim3(2, 64), 256, 0, stream>>>(attb, mask1, vdaft);   // d_aft
  attn512(qc2, QB, tA, 2 * RB, attb, QB, 16, scalE);
  k_meannc<<<dim3(2, 64), 256, 0, stream>>>(attb, mask2, vsaft);   // s_aft

  // ---- Phase 6: ECA x4 with immediate MSE vs ITDA vector ----
  auto eca_mse = [&](const float* xq, const float* xkv,
                     const float* qw2, const float* qb2,
                     const float* kvw2, const float* kvb2,
                     const float* vec, double* part) {
    gemm(xq,  qw2, qb2, h1, BS, 512, 512, 0);        // Q -> h1
    gemm(xkv, kvw2, kvb2, tA, BS, 1024, 512, 0);     // K|V -> tA..tB
    attn512(h1, RB, tA, 2 * RB, h2, RB, 196, scalE); // out -> h2
    k_mse<<<1024, 256, 0, stream>>>(h2, vec, part);
  };
  eca_mse(tC, tD, caqw, caqb, cakvw, cakvb, vdbef, msepart);          // c12 vs d_bef
  eca_mse(tD, tC, caqw, caqb, cakvw, cakvb, vdaft, msepart + 1024);   // c21 vs d_aft
  eca_mse(tC, tC, saqw, saqb, sakvw, sakvb, vsbef, msepart + 2048);   // s11 vs s_bef
  eca_mse(tD, tD, saqw, saqb, sakvw, sakvb, vsaft, msepart + 3072);   // s22 vs s_aft
  k_finloss<<<1, 256, 0, stream>>>(msepart, out + NOUT + 1);

  // ---- Phase 7: efc chain (per-batch vectors, MFMA path M=64) ----
  k_concat2<<<256, 256, 0, stream>>>(ccat, vdbef, vdaft);
  efc64(ccat, vdyn);
  k_concat2<<<256, 256, 0, stream>>>(ccat, vsbef, vsaft);
  efc64(ccat, vsta);
  k_concat2<<<256, 256, 0, stream>>>(ccat, vdyn, vsta);
  efc64(ccat, valign);
  k_concat2<<<256, 256, 0, stream>>>(ccat, cm1, cm2);
  efc64(ccat, vtxt);

  // ---- Phase 8: final projection, single full-M GEMM (comb in h1..tB, 4*SZ) ----
  k_comb_chunk<<<100352, 256, 0, stream>>>(h1, tC, tD, vtxt, valign, 0);
  gemm(h1, efc2w, efc2b, out, BS, 512, 2048, 1);
}

// Round 8
// 2383.237 us; speedup vs baseline: 1.5974x; 1.0676x over previous
//
#include <hip/hip_runtime.h>
#include <hip/hip_bf16.h>
#include <stdint.h>
#include <math.h>

// Problem constants
#define BB   64
#define SS   196
#define BS   12544            // BB*SS
#define NOUT 6422528L         // BS*512
#define SLD  224              // score row ld (7*32)

typedef __attribute__((ext_vector_type(8))) short bf16x8;
typedef __attribute__((ext_vector_type(4))) float f32x4;

// ---------------- device helpers ----------------
__device__ __forceinline__ float block_red256(float v, float* red, bool ismax) {
#pragma unroll
  for (int o = 32; o > 0; o >>= 1) {
    float t = __shfl_down(v, o, 64);
    v = ismax ? fmaxf(v, t) : v + t;
  }
  int lane = threadIdx.x & 63, wid = threadIdx.x >> 6;
  if (lane == 0) red[wid] = v;
  __syncthreads();
  float r = ismax ? fmaxf(fmaxf(red[0], red[1]), fmaxf(red[2], red[3]))
                  : (red[0] + red[1]) + (red[2] + red[3]);
  __syncthreads();
  return r;
}

// HW RNE conversion — bit-identical to the add-0x7fff bit-trick.
__device__ __forceinline__ short f2bf(float f) {
  __hip_bfloat16 h = __float2bfloat16(f);
  short s;
  __builtin_memcpy(&s, &h, 2);
  return s;
}

__device__ __forceinline__ void cvt8(short* dst, float4 a, float4 b) {
  union { short s[8]; int4 v; } u;
  u.s[0] = f2bf(a.x); u.s[1] = f2bf(a.y); u.s[2] = f2bf(a.z); u.s[3] = f2bf(a.w);
  u.s[4] = f2bf(b.x); u.s[5] = f2bf(b.y); u.s[6] = f2bf(b.z); u.s[7] = f2bf(b.w);
  *(int4*)dst = u.v;
}

// Raw barrier: ds ops drained, global loads stay in flight (no vmcnt drain).
__device__ __forceinline__ void lds_barrier() {
  asm volatile("s_waitcnt lgkmcnt(0)" ::: "memory");
  __builtin_amdgcn_s_barrier();
  __builtin_amdgcn_sched_barrier(0);
}

// Bijective XCD-chunked swizzle (m204).
__device__ __forceinline__ int xcd_swizzle(int flat, int nwg) {
  int q = nwg >> 3, r = nwg & 7;
  int xcd = flat & 7, pos = flat >> 3;
  return (xcd < r ? xcd * (q + 1) : r * (q + 1) + (xcd - r) * q) + pos;
}

// ---- bf16 MFMA GEMM: C[M,N] = A[M,K] @ W[N,K]^T + bias (opt relu, opt bf16 out) ----
// 128x128 tile, BK=32, 4 waves (2x2). 2-phase pipeline + XCD swizzle.
__global__ __launch_bounds__(256) void k_mfma_nt(
    const float* __restrict__ A, const float* __restrict__ W,
    const float* __restrict__ bias, float* __restrict__ C,
    int M, int N, int K, int relu, int obf) {
  __shared__ short As[2][128][40];
  __shared__ short Bs[2][128][40];
  const int tid = threadIdx.x;
  const int lane = tid & 63, wave = tid >> 6;
  const int wm = wave >> 1, wn = wave & 1;
  const int NX = gridDim.x;
  const int wg = xcd_swizzle(blockIdx.y * NX + blockIdx.x, NX * gridDim.y);
  const int m0 = (wg / NX) * 128, n0 = (wg % NX) * 128;
  const int srow = tid >> 1, skh = (tid & 1) * 16;
  const float* Ap = A + (long)(m0 + srow) * K + skh;
  const float* Wp = W + (long)(n0 + srow) * K + skh;
  const int fr = lane & 15, fq = lane >> 4;
  const int NK = K >> 5;
  f32x4 acc[4][4] = {};
  float4 xa[4], xw[4], ya[4], yw[4];

  auto ldt = [&](float4 (&ta)[4], float4 (&tw)[4], int t) {
    const float* ap = Ap + t * 32;
    const float* wp = Wp + t * 32;
#pragma unroll
    for (int i = 0; i < 4; ++i) {
      ta[i] = *(const float4*)(ap + i * 4);
      tw[i] = *(const float4*)(wp + i * 4);
    }
  };
  auto stage = [&](float4 (&ta)[4], float4 (&tw)[4], int p) {
    cvt8(&As[p][srow][skh], ta[0], ta[1]);
    cvt8(&As[p][srow][skh + 8], ta[2], ta[3]);
    cvt8(&Bs[p][srow][skh], tw[0], tw[1]);
    cvt8(&Bs[p][srow][skh + 8], tw[2], tw[3]);
  };
  auto step = [&](int t, float4 (&la)[4], float4 (&lw)[4],
                  float4 (&ca)[4], float4 (&cw)[4]) {
    const int par = t & 1;
    if (t + 2 < NK) ldt(la, lw, t + 2);            // prefetch tile t+2
    bf16x8 af[4], bfr[4];
#pragma unroll
    for (int i = 0; i < 4; ++i) af[i] = *(const bf16x8*)&As[par][wm * 64 + i * 16 + fr][fq * 8];
#pragma unroll
    for (int j = 0; j < 4; ++j) bfr[j] = *(const bf16x8*)&Bs[par][wn * 64 + j * 16 + fr][fq * 8];
    if (t + 1 < NK) stage(ca, cw, par ^ 1);        // stage tile t+1
#pragma unroll
    for (int i = 0; i < 4; ++i)
#pragma unroll
      for (int j = 0; j < 4; ++j)
        acc[i][j] = __builtin_amdgcn_mfma_f32_16x16x32_bf16(af[i], bfr[j], acc[i][j], 0, 0, 0);
    lds_barrier();
  };

  ldt(xa, xw, 0);
  stage(xa, xw, 0);
  if (NK > 1) ldt(xa, xw, 1);
  lds_barrier();
  int t = 0;
  for (; t + 1 < NK; t += 2) { step(t, ya, yw, xa, xw); step(t + 1, xa, xw, ya, yw); }
  if (t < NK) step(t, ya, yw, xa, xw);

  short* Cs = (short*)C;
#pragma unroll
  for (int i = 0; i < 4; ++i) {
    int mB = m0 + wm * 64 + i * 16 + fq * 4;
#pragma unroll
    for (int j = 0; j < 4; ++j) {
      int n = n0 + wn * 64 + j * 16 + fr;
      float bz = bias[n];
#pragma unroll
      for (int r2 = 0; r2 < 4; ++r2) {
        float v = acc[i][j][r2] + bz;
        if (relu) v = fmaxf(v, 0.f);
        if (obf) Cs[(long)(mB + r2) * N + n] = f2bf(v);
        else     C[(long)(mB + r2) * N + n] = v;
      }
    }
  }
}

// ---- bf16 MFMA embed (z=2 fused): C = X@W^T + bias + pe ----
__global__ __launch_bounds__(256) void k_mfma_embed(
    const float* __restrict__ X1, const float* __restrict__ X2,  // [B,1024,196]
    const float* __restrict__ W,   // [512,1024]
    const float* __restrict__ bias,
    const float* __restrict__ wemb, const float* __restrict__ hemb,
    float* __restrict__ C1, float* __restrict__ C2) {
  __shared__ short As[2][128][40];
  __shared__ short Bs[2][128][40];
  const float* X = blockIdx.z ? X2 : X1;
  float* C = blockIdx.z ? C2 : C1;
  const int tid = threadIdx.x;
  const int lane = tid & 63, wave = tid >> 6;
  const int wm = wave >> 1, wn = wave & 1;
  const int NX = gridDim.x;
  const int wg = xcd_swizzle(blockIdx.y * NX + blockIdx.x, NX * gridDim.y);
  const int m0 = (wg / NX) * 128, n0 = (wg % NX) * 128;
  const int K = 1024, N = 512;
  const int srow = tid >> 1, skh = (tid & 1) * 16;
  const float* Wp = W + (long)(n0 + srow) * K + skh;
  const int arow = tid & 127, khalf = tid >> 7;
  const int am = m0 + arow;
  const int ab = am / 196, as_ = am % 196;
  const float* Xp = X + (long)ab * 200704 + as_;
  const int fr = lane & 15, fq = lane >> 4;
  const int NK = K >> 5;   // 32
  f32x4 acc[4][4] = {};
  float xx[16], yx[16];
  float4 xw[4], yw[4];

  auto ldt = [&](float (&tx)[16], float4 (&tw)[4], int t) {
    const int kb = t * 32 + khalf * 16;
#pragma unroll
    for (int i = 0; i < 16; ++i) tx[i] = Xp[(long)(kb + i) * 196];
    const float* wp = Wp + t * 32;
#pragma unroll
    for (int i = 0; i < 4; ++i) tw[i] = *(const float4*)(wp + i * 4);
  };
  auto stage = [&](float (&tx)[16], float4 (&tw)[4], int p) {
    union { short s[16]; int4 v[2]; } u;
#pragma unroll
    for (int i = 0; i < 16; ++i) u.s[i] = f2bf(tx[i]);
    int4* dst = (int4*)&As[p][arow][khalf * 16];
    dst[0] = u.v[0]; dst[1] = u.v[1];
    cvt8(&Bs[p][srow][skh], tw[0], tw[1]);
    cvt8(&Bs[p][srow][skh + 8], tw[2], tw[3]);
  };
  auto step = [&](int t, float (&lx)[16], float4 (&lw)[4],
                  float (&cx)[16], float4 (&cw)[4]) {
    const int par = t & 1;
    if (t + 2 < NK) ldt(lx, lw, t + 2);
    bf16x8 af[4], bfr[4];
#pragma unroll
    for (int i = 0; i < 4; ++i) af[i] = *(const bf16x8*)&As[par][wm * 64 + i * 16 + fr][fq * 8];
#pragma unroll
    for (int j = 0; j < 4; ++j) bfr[j] = *(const bf16x8*)&Bs[par][wn * 64 + j * 16 + fr][fq * 8];
    if (t + 1 < NK) stage(cx, cw, par ^ 1);
#pragma unroll
    for (int i = 0; i < 4; ++i)
#pragma unroll
      for (int j = 0; j < 4; ++j)
        acc[i][j] = __builtin_amdgcn_mfma_f32_16x16x32_bf16(af[i], bfr[j], acc[i][j], 0, 0, 0);
    lds_barrier();
  };

  ldt(xx, xw, 0);
  stage(xx, xw, 0);
  if (NK > 1) ldt(xx, xw, 1);
  lds_barrier();
  int t = 0;
  for (; t + 1 < NK; t += 2) { step(t, yx, yw, xx, xw); step(t + 1, xx, xw, yx, yw); }
  if (t < NK) step(t, yx, yw, xx, xw);

#pragma unroll
  for (int i = 0; i < 4; ++i) {
    int mB = m0 + wm * 64 + i * 16 + fq * 4;
#pragma unroll
    for (int j = 0; j < 4; ++j) {
      int n = n0 + wn * 64 + j * 16 + fr;
      float bz = bias[n];
#pragma unroll
      for (int r2 = 0; r2 < 4; ++r2) {
        int m = mB + r2;
        int s = m % 196;
        float pe = (n < 256) ? wemb[(s % 14) * 256 + n] : hemb[(s / 14) * 256 + (n - 256)];
        C[(long)m * N + n] = acc[i][j][r2] + bz + pe;
      }
    }
  }
}

// ---- Fused flash MHA, bf16 inputs: B=64,H=8,S=196,D=64. One block per (b,h). ----
// Q bf16 [rows,512] head col h*64; KV bf16 [rows,1024]; O fp32 [rows,512].
__global__ __launch_bounds__(256) void k_fmha_bf(
    const short* __restrict__ Q, const short* __restrict__ KV,
    float* __restrict__ O) {
  __shared__ short Vt[64][240];     // V^T bf16 (keys 196..223 zeroed)
  __shared__ short Pt[4][16][40];   // per-wave P staging
  const int tid = threadIdx.x;
  const int lane = tid & 63, wave = tid >> 6;
  const int b = blockIdx.x, h = blockIdx.y;
  const long brow = (long)b * 196;
  const short* Qb = Q + brow * 512 + h * 64;
  const short* Kb = KV + brow * 1024 + h * 64;
  const short* Vb = KV + brow * 1024 + 512 + h * 64;
  float* Ob = O + brow * 512 + h * 64;
  const int fr = lane & 15, fq = lane >> 4;

  for (int i = tid; i < 64 * 32; i += 256) {
    int d = i >> 5, k = 192 + (i & 31);
    if (k >= 196) Vt[d][k] = 0;
  }
  for (int i = tid; i < 196 * 8; i += 256) {
    int s = i >> 3, c8 = (i & 7) * 8;
    bf16x8 v = *(const bf16x8*)(Vb + (long)s * 1024 + c8);
#pragma unroll
    for (int j = 0; j < 8; ++j) Vt[c8 + j][s] = v[j];
  }
  __syncthreads();

  for (int qt = wave; qt < 13; qt += 4) {
    const int q0 = qt * 16;
    const int qr = (q0 + fr < 196) ? q0 + fr : 195;
    const short* qp = Qb + (long)qr * 512 + fq * 8;
    bf16x8 aq0 = *(const bf16x8*)(qp);
    bf16x8 aq1 = *(const bf16x8*)(qp + 32);
    f32x4 sc[13];
#pragma unroll
    for (int t = 0; t < 13; ++t) {
      int kr = (t * 16 + fr < 196) ? t * 16 + fr : 195;
      const short* kp = Kb + (long)kr * 1024 + fq * 8;
      bf16x8 bk0 = *(const bf16x8*)(kp);
      bf16x8 bk1 = *(const bf16x8*)(kp + 32);
      f32x4 z = {};
      z = __builtin_amdgcn_mfma_f32_16x16x32_bf16(aq0, bk0, z, 0, 0, 0);
      z = __builtin_amdgcn_mfma_f32_16x16x32_bf16(aq1, bk1, z, 0, 0, 0);
      sc[t] = z;
    }
#pragma unroll
    for (int t = 0; t < 13; ++t)
#pragma unroll
      for (int r2 = 0; r2 < 4; ++r2) sc[t][r2] *= 0.125f;
    if (fr >= 4) {
#pragma unroll
      for (int r2 = 0; r2 < 4; ++r2) sc[12][r2] = -1e30f;
    }
#pragma unroll
    for (int r2 = 0; r2 < 4; ++r2) {
      float m = sc[0][r2];
#pragma unroll
      for (int t = 1; t < 13; ++t) m = fmaxf(m, sc[t][r2]);
#pragma unroll
      for (int o = 1; o < 16; o <<= 1) m = fmaxf(m, __shfl_xor(m, o, 64));
      float s = 0.f;
#pragma unroll
      for (int t = 0; t < 13; ++t) { float e = expf(sc[t][r2] - m); sc[t][r2] = e; s += e; }
#pragma unroll
      for (int o = 1; o < 16; o <<= 1) s += __shfl_xor(s, o, 64);
      float inv = 1.0f / s;
#pragma unroll
      for (int t = 0; t < 13; ++t) sc[t][r2] *= inv;
    }
    f32x4 acc_o[4] = {};
#pragma unroll
    for (int s7 = 0; s7 < 7; ++s7) {
      const int t0 = 2 * s7, t1 = 2 * s7 + 1;
#pragma unroll
      for (int r2 = 0; r2 < 4; ++r2) {
        Pt[wave][fq * 4 + r2][fr] = f2bf(sc[t0][r2]);
        Pt[wave][fq * 4 + r2][16 + fr] = (t1 < 13) ? f2bf(sc[t1][r2]) : (short)0;
      }
      asm volatile("s_waitcnt lgkmcnt(0)" ::: "memory");
      bf16x8 ap = *(const bf16x8*)&Pt[wave][fr][fq * 8];
#pragma unroll
      for (int dt = 0; dt < 4; ++dt) {
        bf16x8 bv = *(const bf16x8*)&Vt[dt * 16 + fr][32 * s7 + fq * 8];
        acc_o[dt] = __builtin_amdgcn_mfma_f32_16x16x32_bf16(ap, bv, acc_o[dt], 0, 0, 0);
      }
    }
#pragma unroll
    for (int r2 = 0; r2 < 4; ++r2) {
      int qrow = q0 + fq * 4 + r2;
      if (qrow < 196) {
        float* op = Ob + (long)qrow * 512;
#pragma unroll
        for (int dt = 0; dt < 4; ++dt) op[dt * 16 + fr] = acc_o[dt][r2];
      }
    }
  }
}

// ---- Batched bf16 MFMA NT: C[z][m,n] = scale*sum_k A[z][m,k]*B[z][n,k] ----
__global__ __launch_bounds__(256) void k_mfma_bnt(
    const float* __restrict__ A, const float* __restrict__ B, float* __restrict__ C,
    int M, int N, int K, int lda, int ldb, int ldc, int nz2,
    int64_t sA1, int64_t sA2, int64_t sB1, int64_t sB2, int64_t sC1, int64_t sC2,
    float scale, int clampf, const float* __restrict__ bias2, int relu2) {
  __shared__ short As[2][64][40];
  __shared__ short Bs[2][64][40];
  const int tid = threadIdx.x;
  const int lane = tid & 63, wave = tid >> 6;
  const int NX = gridDim.x;
  const int wg = xcd_swizzle(blockIdx.y * NX + blockIdx.x, NX * gridDim.y);
  const int m0 = (wg / NX) * 64, n0 = (wg % NX) * 64;
  const int z = blockIdx.z, z1 = z / nz2, z2 = z % nz2;
  const float* Ab = A + z1 * sA1 + z2 * sA2;
  const float* Bb = B + z1 * sB1 + z2 * sB2;
  float* Cb = C + z1 * sC1 + z2 * sC2;
  const int sr = tid >> 2, skh = (tid & 3) * 8;
  const int ar = (m0 + sr < M) ? m0 + sr : M - 1;
  const int br = (n0 + sr < N) ? n0 + sr : N - 1;
  const float* Ap = Ab + (long)ar * lda + skh;
  const float* Bp = Bb + (long)br * ldb + skh;
  const int fr = lane & 15, fq = lane >> 4;
  const int NK = K >> 5;
  f32x4 acc[4] = {};
  float4 xa[2], xb[2], ya[2], yb[2];

  auto ldt = [&](float4 (&ta)[2], float4 (&tb)[2], int t) {
    const int kb = t * 32;
#pragma unroll
    for (int i = 0; i < 2; ++i) {
      ta[i] = *(const float4*)(Ap + kb + i * 4);
      tb[i] = *(const float4*)(Bp + kb + i * 4);
    }
  };
  auto stage = [&](float4 (&ta)[2], float4 (&tb)[2], int p) {
    cvt8(&As[p][sr][skh], ta[0], ta[1]);
    cvt8(&Bs[p][sr][skh], tb[0], tb[1]);
  };
  auto step = [&](int t, float4 (&la)[2], float4 (&lb)[2],
                  float4 (&ca)[2], float4 (&cb)[2]) {
    const int par = t & 1;
    if (t + 2 < NK) ldt(la, lb, t + 2);
    bf16x8 bfr = *(const bf16x8*)&Bs[par][wave * 16 + fr][fq * 8];
    bf16x8 af[4];
#pragma unroll
    for (int i = 0; i < 4; ++i) af[i] = *(const bf16x8*)&As[par][i * 16 + fr][fq * 8];
    if (t + 1 < NK) stage(ca, cb, par ^ 1);
#pragma unroll
    for (int i = 0; i < 4; ++i)
      acc[i] = __builtin_amdgcn_mfma_f32_16x16x32_bf16(af[i], bfr, acc[i], 0, 0, 0);
    lds_barrier();
  };

  ldt(xa, xb, 0);
  stage(xa, xb, 0);
  if (NK > 1) ldt(xa, xb, 1);
  lds_barrier();
  int t = 0;
  for (; t + 1 < NK; t += 2) { step(t, ya, yb, xa, xb); step(t + 1, xa, xb, ya, yb); }
  if (t < NK) step(t, ya, yb, xa, xb);

  const int n = n0 + wave * 16 + fr;
  if (n < N) {
    float bz = bias2 ? bias2[n] : 0.f;
#pragma unroll
    for (int i = 0; i < 4; ++i) {
      int mb = m0 + i * 16 + fq * 4;
#pragma unroll
      for (int r2 = 0; r2 < 4; ++r2) {
        int m = mb + r2;
        if (m < M) {
          float v = acc[i][r2] * scale + bz;
          if (relu2) v = fmaxf(v, 0.f);
          if (clampf) v = fminf(fmaxf(v, -100.f), 100.f);
          Cb[(long)m * ldc + n] = v;
        }
      }
    }
  }
}

// ---- NT GEMM with bf16 A-input: C[m,n] = sum_k A[m,k]*B[n,k] + bias (opt relu) ----
__global__ __launch_bounds__(256) void k_mfma_bnt_abf(
    const short* __restrict__ A, const float* __restrict__ B, float* __restrict__ C,
    int M, int N, int K, int lda, int ldb, int ldc,
    const float* __restrict__ bias2, int relu2) {
  __shared__ short As[2][64][40];
  __shared__ short Bs[2][64][40];
  const int tid = threadIdx.x;
  const int lane = tid & 63, wave = tid >> 6;
  const int NX = gridDim.x;
  const int wg = xcd_swizzle(blockIdx.y * NX + blockIdx.x, NX * gridDim.y);
  const int m0 = (wg / NX) * 64, n0 = (wg % NX) * 64;
  const int sr = tid >> 2, skh = (tid & 3) * 8;
  const int ar = (m0 + sr < M) ? m0 + sr : M - 1;
  const int br = (n0 + sr < N) ? n0 + sr : N - 1;
  const short* Ap = A + (long)ar * lda + skh;
  const float* Bp = B + (long)br * ldb + skh;
  const int fr = lane & 15, fq = lane >> 4;
  const int NK = K >> 5;
  f32x4 acc[4] = {};
  int4 xa, ya;
  float4 xb[2], yb[2];

  auto ldt = [&](int4& ta, float4 (&tb)[2], int t) {
    const int kb = t * 32;
    ta = *(const int4*)(Ap + kb);
#pragma unroll
    for (int i = 0; i < 2; ++i) tb[i] = *(const float4*)(Bp + kb + i * 4);
  };
  auto stage = [&](int4& ta, float4 (&tb)[2], int p) {
    *(int4*)&As[p][sr][skh] = ta;
    cvt8(&Bs[p][sr][skh], tb[0], tb[1]);
  };
  auto step = [&](int t, int4& la, float4 (&lb)[2], int4& ca, float4 (&cb)[2]) {
    const int par = t & 1;
    if (t + 2 < NK) ldt(la, lb, t + 2);
    bf16x8 bfr = *(const bf16x8*)&Bs[par][wave * 16 + fr][fq * 8];
    bf16x8 af[4];
#pragma unroll
    for (int i = 0; i < 4; ++i) af[i] = *(const bf16x8*)&As[par][i * 16 + fr][fq * 8];
    if (t + 1 < NK) stage(ca, cb, par ^ 1);
#pragma unroll
    for (int i = 0; i < 4; ++i)
      acc[i] = __builtin_amdgcn_mfma_f32_16x16x32_bf16(af[i], bfr, acc[i], 0, 0, 0);
    lds_barrier();
  };

  ldt(xa, xb, 0);
  stage(xa, xb, 0);
  if (NK > 1) ldt(xa, xb, 1);
  lds_barrier();
  int t = 0;
  for (; t + 1 < NK; t += 2) { step(t, ya, yb, xa, xb); step(t + 1, xa, xb, ya, yb); }
  if (t < NK) step(t, ya, yb, xa, xb);

  const int n = n0 + wave * 16 + fr;
  if (n < N) {
    float bz = bias2 ? bias2[n] : 0.f;
#pragma unroll
    for (int i = 0; i < 4; ++i) {
      int mb = m0 + i * 16 + fq * 4;
#pragma unroll
      for (int r2 = 0; r2 < 4; ++r2) {
        int m = mb + r2;
        if (m < M) {
          float v = acc[i][r2] + bz;
          if (relu2) v = fmaxf(v, 0.f);
          C[(long)m * ldc + n] = v;
        }
      }
    }
  }
}

// ---- Batched bf16 MFMA NN: C[z][m,n] = sum_k A[z][m,k]*B[z][k,n] ----
__global__ __launch_bounds__(256) void k_mfma_bnn(
    const float* __restrict__ A, const float* __restrict__ B, float* __restrict__ C,
    int M, int N, int K, int KBvalid, int lda, int ldb, int ldc, int nz2,
    int64_t sA1, int64_t sA2, int64_t sB1, int64_t sB2, int64_t sC1, int64_t sC2) {
  __shared__ short As[2][64][40];
  __shared__ short Bs[2][64][40];
  const int tid = threadIdx.x;
  const int lane = tid & 63, wave = tid >> 6;
  const int m0 = blockIdx.y * 64, n0 = blockIdx.x * 64;
  const int z = blockIdx.z, z1 = z / nz2, z2 = z % nz2;
  const float* Ab = A + z1 * sA1 + z2 * sA2;
  const float* Bb = B + z1 * sB1 + z2 * sB2;
  float* Cb = C + z1 * sC1 + z2 * sC2;
  const int sr = tid >> 2, skh = (tid & 3) * 8;
  const int ar = (m0 + sr < M) ? m0 + sr : M - 1;
  const float* Ap = Ab + (long)ar * lda + skh;
  const int bk = tid >> 3, bn = (tid & 7) * 8;   // B transposed staging
  const int fr = lane & 15, fq = lane >> 4;
  const int NK = K >> 5;
  f32x4 acc[4] = {};
  float4 xa[2], xb[2], ya[2], yb[2];

  auto ldt = [&](float4 (&ta)[2], float4 (&tb)[2], int t) {
    const int kb = t * 32;
#pragma unroll
    for (int i = 0; i < 2; ++i) ta[i] = *(const float4*)(Ap + kb + i * 4);
    int kc = kb + bk;
    if (kc >= KBvalid) kc = KBvalid - 1;
    const float* bp = Bb + (long)kc * ldb + n0 + bn;
#pragma unroll
    for (int i = 0; i < 2; ++i) tb[i] = *(const float4*)(bp + i * 4);
  };
  auto stage = [&](float4 (&ta)[2], float4 (&tb)[2], int p) {
    cvt8(&As[p][sr][skh], ta[0], ta[1]);
    short tmp[8];
    cvt8(tmp, tb[0], tb[1]);
#pragma unroll
    for (int j = 0; j < 8; ++j) Bs[p][bn + j][bk] = tmp[j];
  };
  auto step = [&](int t, float4 (&la)[2], float4 (&lb)[2],
                  float4 (&ca)[2], float4 (&cb)[2]) {
    const int par = t & 1;
    if (t + 2 < NK) ldt(la, lb, t + 2);
    bf16x8 bfr = *(const bf16x8*)&Bs[par][wave * 16 + fr][fq * 8];
    bf16x8 af[4];
#pragma unroll
    for (int i = 0; i < 4; ++i) af[i] = *(const bf16x8*)&As[par][i * 16 + fr][fq * 8];
    if (t + 1 < NK) stage(ca, cb, par ^ 1);
#pragma unroll
    for (int i = 0; i < 4; ++i)
      acc[i] = __builtin_amdgcn_mfma_f32_16x16x32_bf16(af[i], bfr, acc[i], 0, 0, 0);
    lds_barrier();
  };

  ldt(xa, xb, 0);
  stage(xa, xb, 0);
  if (NK > 1) ldt(xa, xb, 1);
  lds_barrier();
  int t = 0;
  for (; t + 1 < NK; t += 2) { step(t, ya, yb, xa, xb); step(t + 1, xa, xb, ya, yb); }
  if (t < NK) step(t, ya, yb, xa, xb);

  const int n = n0 + wave * 16 + fr;
  if (n < N) {
#pragma unroll
    for (int i = 0; i < 4; ++i) {
      int mb = m0 + i * 16 + fq * 4;
#pragma unroll
      for (int r2 = 0; r2 < 4; ++r2) {
        int m = mb + r2;
        if (m < M) Cb[(long)m * ldc + n] = acc[i][r2];
      }
    }
  }
}

// ---- MFMA correlation: C[i,j] += scale * sum_m Za[m,i]*Zb[m,j] (split-K atomic) ----
__global__ __launch_bounds__(256) void k_mfma_corr(
    const float* __restrict__ Za, const float* __restrict__ Zb,
    float* __restrict__ C, int mchunk, float scale) {
  __shared__ short As[2][64][40];
  __shared__ short Bs[2][64][40];
  const int tid = threadIdx.x;
  const int lane = tid & 63, wave = tid >> 6;
  const int i0 = blockIdx.y * 64, j0 = blockIdx.x * 64;
  const int mstart = blockIdx.z * mchunk;
  const int tm = tid >> 3, tcb = (tid & 7) * 8;
  const int fr = lane & 15, fq = lane >> 4;
  const int NK = mchunk >> 5;   // 28
  f32x4 acc[4] = {};
  float4 xa[2], xb[2], ya[2], yb[2];

  auto ldt = [&](float4 (&ta)[2], float4 (&tb)[2], int t) {
    const float* za = Za + (long)(mstart + t * 32 + tm) * 512;
    const float* zb = Zb + (long)(mstart + t * 32 + tm) * 512;
    ta[0] = *(const float4*)(za + i0 + tcb);
    ta[1] = *(const float4*)(za + i0 + tcb + 4);
    tb[0] = *(const float4*)(zb + j0 + tcb);
    tb[1] = *(const float4*)(zb + j0 + tcb + 4);
  };
  auto stage = [&](float4 (&ta)[2], float4 (&tb)[2], int p) {
    short u[8], v[8];
    cvt8(u, ta[0], ta[1]);
    cvt8(v, tb[0], tb[1]);
#pragma unroll
    for (int j = 0; j < 8; ++j) { As[p][tcb + j][tm] = u[j]; Bs[p][tcb + j][tm] = v[j]; }
  };
  auto step = [&](int t, float4 (&la)[2], float4 (&lb)[2],
                  float4 (&ca)[2], float4 (&cb)[2]) {
    const int par = t & 1;
    if (t + 2 < NK) ldt(la, lb, t + 2);
    bf16x8 bfr = *(const bf16x8*)&Bs[par][wave * 16 + fr][fq * 8];
    bf16x8 af[4];
#pragma unroll
    for (int i = 0; i < 4; ++i) af[i] = *(const bf16x8*)&As[par][i * 16 + fr][fq * 8];
    if (t + 1 < NK) stage(ca, cb, par ^ 1);
#pragma unroll
    for (int i = 0; i < 4; ++i)
      acc[i] = __builtin_amdgcn_mfma_f32_16x16x32_bf16(af[i], bfr, acc[i], 0, 0, 0);
    lds_barrier();
  };

  ldt(xa, xb, 0);
  stage(xa, xb, 0);
  if (NK > 1) ldt(xa, xb, 1);
  lds_barrier();
  int t = 0;
  for (; t + 1 < NK; t += 2) { step(t, ya, yb, xa, xb); step(t + 1, xa, xb, ya, yb); }
  if (t < NK) step(t, ya, yb, xa, xb);

  const int j = j0 + wave * 16 + fr;
#pragma unroll
  for (int i = 0; i < 4; ++i) {
    int ib = i0 + i * 16 + fq * 4;
#pragma unroll
    for (int r2 = 0; r2 < 4; ++r2)
      atomicAdd(&C[(long)(ib + r2) * 512 + j], acc[i][r2] * scale);
  }
}

// ---- Row softmax over rows of width 196, ld=SLD(224); zeroes pad cols. ----
__global__ __launch_bounds__(256) void k_softmax_rows(float* __restrict__ S, int nrows) {
  int row = blockIdx.x * 4 + (threadIdx.x >> 6);
  int lane = threadIdx.x & 63;
  if (row >= nrows) return;
  float* p = S + (long)row * SLD;
  float v0 = p[lane];
  float v1 = p[lane + 64];
  float v2 = p[lane + 128];
  float v3 = (lane + 192 < 196) ? p[lane + 192] : -1e30f;
  float mx = fmaxf(fmaxf(v0, v1), fmaxf(v2, v3));
#pragma unroll
  for (int o = 32; o > 0; o >>= 1) mx = fmaxf(mx, __shfl_down(mx, o, 64));
  mx = __shfl(mx, 0, 64);
  float e0 = expf(v0 - mx), e1 = expf(v1 - mx), e2 = expf(v2 - mx);
  float e3 = (lane + 192 < 196) ? expf(v3 - mx) : 0.f;
  float s = e0 + e1 + e2 + e3;
#pragma unroll
  for (int o = 32; o > 0; o >>= 1) s += __shfl_down(s, o, 64);
  s = __shfl(s, 0, 64);
  float inv = 1.0f / s;
  p[lane] = e0 * inv;
  p[lane + 64] = e1 * inv;
  p[lane + 128] = e2 * inv;
  if (lane + 192 < SLD) p[lane + 192] = (lane + 192 < 196) ? e3 * inv : 0.f;
}

// ---- dst = LayerNorm(src + o) (src may equal dst) ----
__global__ __launch_bounds__(256) void k_addln2(
    float* __restrict__ dst, const float* __restrict__ src, const float* __restrict__ o,
    const float* __restrict__ g, const float* __restrict__ be) {
  __shared__ float red[4];
  long row = blockIdx.x;
  const float* sr_ = src + row * 512;
  const float* orow = o + row * 512;
  float* dr = dst + row * 512;
  int t = threadIdx.x;
  float v0 = sr_[t] + orow[t];
  float v1 = sr_[t + 256] + orow[t + 256];
  float mean = block_red256(v0 + v1, red, false) * (1.0f / 512.0f);
  float d0 = v0 - mean, d1 = v1 - mean;
  float var = block_red256(d0 * d0 + d1 * d1, red, false) * (1.0f / 512.0f);
  float inv = 1.0f / sqrtf(var + 1e-5f);
  dr[t] = d0 * inv * g[t] + be[t];
  dr[t + 256] = d1 * inv * g[t + 256] + be[t + 256];
}

// ---- small utility kernels ----
__global__ void k_zero(float* __restrict__ p, int n) {
  int i = blockIdx.x * 256 + threadIdx.x;
  if (i < n) p[i] = 0.f;
}

// d = x - h (vectorized)
__global__ __launch_bounds__(256) void k_diff(
    float* __restrict__ d, const float* __restrict__ x, const float* __restrict__ h) {
  long i = ((long)blockIdx.x * 256 + threadIdx.x) * 4;
  float4 xv = *(const float4*)(x + i);
  float4 hv = *(const float4*)(h + i);
  float4 r; r.x = xv.x - hv.x; r.y = xv.y - hv.y; r.z = xv.z - hv.z; r.w = xv.w - hv.w;
  *(float4*)(d + i) = r;
}

// concat two [512,512] weights into [1024,512] (+ biases into [1024])
__global__ __launch_bounds__(256) void k_catkv(
    float* __restrict__ dw, const float* __restrict__ kw, const float* __restrict__ vw,
    float* __restrict__ db, const float* __restrict__ kb, const float* __restrict__ vb) {
  int i = blockIdx.x * 256 + threadIdx.x;      // 1024*512
  int r = i >> 9;
  dw[i] = (r < 512) ? kw[i] : vw[i - 262144];
  if (i < 1024) db[i] = (i < 512) ? kb[i] : vb[i - 512];
}

__global__ __launch_bounds__(256) void k_colstats(
    const float* __restrict__ f, float* __restrict__ sums, float* __restrict__ sqs) {
  int c = blockIdx.x * 32 + (threadIdx.x & 31);
  int rbase = blockIdx.y * 256;
  int r0 = rbase + (threadIdx.x >> 5);
  float s = 0.f, s2 = 0.f;
  for (int r = r0; r < rbase + 256; r += 8) {
    float v = f[(long)r * 512 + c];
    s += v; s2 += v * v;
  }
  __shared__ float sh[256], sh2[256];
  sh[threadIdx.x] = s; sh2[threadIdx.x] = s2;
  __syncthreads();
  if (threadIdx.x < 32) {
    for (int i = 1; i < 8; ++i) { s += sh[i * 32 + threadIdx.x]; s2 += sh2[i * 32 + threadIdx.x]; }
    atomicAdd(&sums[c], s);
    atomicAdd(&sqs[c], s2);
  }
}

__global__ void k_finstats(const float* __restrict__ sums, const float* __restrict__ sqs,
                           float* __restrict__ mean, float* __restrict__ istd) {
  int c = blockIdx.x * 256 + threadIdx.x;
  float mu = sums[c] / 12544.0f;
  float var = (sqs[c] - 12544.0f * mu * mu) / 12543.0f;
  mean[c] = mu;
  istd[c] = 1.0f / sqrtf(var);
}

__global__ __launch_bounds__(256) void k_znorm(float* __restrict__ f, const float* __restrict__ mean,
                                               const float* __restrict__ istd) {
  long i = (long)blockIdx.x * 256 + threadIdx.x;
  int c = (int)(i & 511);
  f[i] = (f[i] - mean[c]) * istd[c];
}

// CDCR loss: 256-block partial reduce + final combine
__global__ __launch_bounds__(256) void k_cdcr_part(const float* __restrict__ Cm,
                                                   double* __restrict__ part) {
  int base = blockIdx.x * 1024;
  double on = 0, off = 0;
  for (int i = base + threadIdx.x; i < base + 1024; i += 256) {
    float v = Cm[i];
    int r = i >> 9, c = i & 511;
    if (r == c) { double d = (double)v - 1.0; on += d * d; }
    else        { off += (double)v * (double)v; }
  }
  __shared__ double s_on[256], s_off[256];
  s_on[threadIdx.x] = on; s_off[threadIdx.x] = off;
  __syncthreads();
  for (int st = 128; st > 0; st >>= 1) {
    if (threadIdx.x < st) { s_on[threadIdx.x] += s_on[threadIdx.x + st]; s_off[threadIdx.x] += s_off[threadIdx.x + st]; }
    __syncthreads();
  }
  if (threadIdx.x == 0) { part[blockIdx.x] = s_on[0]; part[256 + blockIdx.x] = s_off[0]; }
}

__global__ void k_cdcr_fin(const double* __restrict__ part, float* __restrict__ out) {
  __shared__ double s_on[256], s_off[256];
  s_on[threadIdx.x] = part[threadIdx.x];
  s_off[threadIdx.x] = part[256 + threadIdx.x];
  __syncthreads();
  for (int st = 128; st > 0; st >>= 1) {
    if (threadIdx.x < st) { s_on[threadIdx.x] += s_on[threadIdx.x + st]; s_off[threadIdx.x] += s_off[threadIdx.x + st]; }
    __syncthreads();
  }
  if (threadIdx.x == 0) out[0] = (float)(s_on[0] + 0.003 * s_off[0]);
}

__global__ __launch_bounds__(64) void k_mask(const float* __restrict__ capo, float* __restrict__ mask) {
  int pidx = blockIdx.x;
  float s = 0.f;
  for (int i = threadIdx.x; i < 512; i += 64) s += capo[(long)pidx * 512 + i];
#pragma unroll
  for (int o = 32; o > 0; o >>= 1) s += __shfl_down(s, o, 64);
  if (threadIdx.x == 0) mask[pidx] = (s != 0.f) ? 1.f : 0.f;
}

__global__ __launch_bounds__(256) void k_meannc(const float* __restrict__ src, const float* __restrict__ mask,
                                                float* __restrict__ vec) {
  int d = blockIdx.x * 256 + threadIdx.x;
  int b = blockIdx.y;
  float acc = 0.f, ms = 0.f;
  for (int nc = 0; nc < 16; ++nc) {
    float mk = mask ? mask[b * 16 + nc] : 1.f;
    acc += src[((long)b * 16 + nc) * 512 + d] * mk;
    ms += mk;
  }
  vec[(long)b * 512 + d] = acc / fmaxf(ms, 1e-6f);
}

__global__ __launch_bounds__(256) void k_mse(const float* __restrict__ full, const float* __restrict__ vec,
                                             double* __restrict__ part) {
  double loc = 0;
  const long n = NOUT;
  for (long i = (long)blockIdx.x * 256 + threadIdx.x; i < n; i += 256L * 1024) {
    int d = (int)(i & 511);
    int b = (int)(i >> 9) / 196;
    float df = full[i] - vec[b * 512 + d];
    loc += (double)df * (double)df;
  }
  __shared__ double sh[256];
  sh[threadIdx.x] = loc;
  __syncthreads();
  for (int st = 128; st > 0; st >>= 1) {
    if (threadIdx.x < st) sh[threadIdx.x] += sh[threadIdx.x + st];
    __syncthreads();
  }
  if (threadIdx.x == 0) part[blockIdx.x] = sh[0];
}

__global__ void k_finloss(const double* __restrict__ part, float* __restrict__ out) {
  __shared__ double sh[256];
  double s = 0;
  for (int i = threadIdx.x; i < 4096; i += 256) s += part[i];
  sh[threadIdx.x] = s;
  __syncthreads();
  for (int st = 128; st > 0; st >>= 1) {
    if (threadIdx.x < st) sh[threadIdx.x] += sh[threadIdx.x + st];
    __syncthreads();
  }
  if (threadIdx.x == 0) out[0] = (float)(sh[0] / (64.0 * 196.0 * 512.0));
}

__global__ __launch_bounds__(256) void k_concat2(float* __restrict__ dst, const float* __restrict__ a,
                                                 const float* __restrict__ b) {
  int i = blockIdx.x * 256 + threadIdx.x;   // 64*1024
  int col = i & 1023, row = i >> 10;
  dst[i] = (col < 512) ? a[row * 512 + col] : b[row * 512 + col - 512];
}

// comb: [BS,2048] bf16 into dst (short*)
__global__ __launch_bounds__(256) void k_comb_bf(
    short* __restrict__ dst, const float* __restrict__ d1, const float* __restrict__ d2,
    const float* __restrict__ txt, const float* __restrict__ al) {
  long i = (long)blockIdx.x * 256 + threadIdx.x;  // BS*2048
  int col = (int)(i & 2047);
  long m = i >> 11;
  int b = (int)(m / 196);
  float v;
  if (col < 512)       v = d1[m * 512 + col];
  else if (col < 1024) v = d2[m * 512 + col - 512];
  else if (col < 1536) v = txt[(long)b * 512 + col - 1024];
  else                 v = al[(long)b * 512 + col - 1536];
  dst[i] = f2bf(v);
}

// ---------------- host ----------------
extern "C" void kernel_launch(void* const* d_in, const int* in_sizes, int n_in,
                              void* d_out, int out_size, void* d_ws, size_t ws_size,
                              hipStream_t stream) {
  (void)in_sizes; (void)n_in; (void)out_size; (void)ws_size;
  const float* in1    = (const float*)d_in[0];
  const float* in2    = (const float*)d_in[1];
  const float* cap1   = (const float*)d_in[2];
  const float* cap2   = (const float*)d_in[3];
  const float* imgw   = (const float*)d_in[4];
  const float* imgb   = (const float*)d_in[5];
  const float* wemb   = (const float*)d_in[6];
  const float* hemb   = (const float*)d_in[7];
  const float* mlpw1  = (const float*)d_in[8];
  const float* mlpb1  = (const float*)d_in[9];
  const float* mlpw2  = (const float*)d_in[10];
  const float* mlpb2  = (const float*)d_in[11];
  const float* fcw    = (const float*)d_in[12];
  const float* fcb    = (const float*)d_in[13];
  const float* efcw   = (const float*)d_in[14];
  const float* efcb   = (const float*)d_in[15];
  const float* efc2w  = (const float*)d_in[16];
  const float* efc2b  = (const float*)d_in[17];
  const float* trinw  = (const float*)d_in[18];
  const float* trinb  = (const float*)d_in[19];
  const float* troutw = (const float*)d_in[20];
  const float* troutb = (const float*)d_in[21];
  const float* trlng  = (const float*)d_in[22];
  const float* trlnb  = (const float*)d_in[23];
  const float* itqw = (const float*)d_in[24]; const float* itqb = (const float*)d_in[25];
  const float* itkw = (const float*)d_in[26]; const float* itkb = (const float*)d_in[27];
  const float* itvw = (const float*)d_in[28]; const float* itvb = (const float*)d_in[29];
  const float* caqw = (const float*)d_in[30]; const float* caqb = (const float*)d_in[31];
  const float* cakw = (const float*)d_in[32]; const float* cakb = (const float*)d_in[33];
  const float* cavw = (const float*)d_in[34]; const float* cavb = (const float*)d_in[35];
  const float* saqw = (const float*)d_in[36]; const float* saqb = (const float*)d_in[37];
  const float* sakw = (const float*)d_in[38]; const float* sakb = (const float*)d_in[39];
  const float* savw = (const float*)d_in[40]; const float* savb = (const float*)d_in[41];

  float* out = (float*)d_out;

  // ---- workspace carve ----
  const size_t SZ = (size_t)BS * 512;        // 6,422,528 floats (24.5 MB)
  float* w = (float*)d_ws;
  auto alloc = [&](size_t n) { float* p = w; w += n; return p; };
  float* h1 = alloc(SZ);
  float* h2 = alloc(SZ);       // contiguous with h1
  float* tA = alloc(SZ);
  float* tB = alloc(SZ);       // contiguous with tA
  float* tC = alloc(SZ);
  float* tD = alloc(SZ);       // contiguous with tC
  float* sbuf = alloc(SZ);     // scores (ECA/ITDA) + o-proj temp
  float* cap1o = alloc(64 * 16 * 512);
  float* cap2o = alloc(64 * 16 * 512);   // contiguous with cap1o
  float* qc1   = alloc(64 * 16 * 512);
  float* qc2   = alloc(64 * 16 * 512);   // contiguous with qc1
  float* attb  = alloc(64 * 16 * 512);
  float* attb2 = alloc(64 * 16 * 512);   // contiguous with attb
  float* cmat  = alloc(512 * 512);
  float* colsum1 = alloc(512); float* colsq1 = alloc(512);
  float* colsum2 = alloc(512); float* colsq2 = alloc(512);
  float* mean1 = alloc(512); float* istd1 = alloc(512);
  float* mean2 = alloc(512); float* istd2 = alloc(512);
  float* mask1 = alloc(1024); float* mask2 = alloc(1024);
  float* vdbef = alloc(64 * 512); float* vdaft = alloc(64 * 512);
  float* vsbef = alloc(64 * 512); float* vsaft = alloc(64 * 512);
  float* cm1 = alloc(64 * 512); float* cm2 = alloc(64 * 512);
  float* vdyn = alloc(64 * 512); float* vsta = alloc(64 * 512);
  float* valign = alloc(64 * 512); float* vtxt = alloc(64 * 512);
  float* ccat = alloc(64 * 1024);
  double* msepart = (double*)alloc(4096 * 2);   // 4096 doubles
  double* cdcrpart = (double*)alloc(1024);      // 512 doubles
  float* itkvw = alloc(1024 * 512); float* itkvb = alloc(1024);
  float* cakvw = alloc(1024 * 512); float* cakvb = alloc(1024);
  float* sakvw = alloc(1024 * 512); float* sakvb = alloc(1024);
  float* x1 = alloc(2 * SZ);   // [x1;x2] contiguous (embed result)
  float* x2 = x1 + SZ;

  // GEMM router: 128^2 tile for big grids, 64^2 (bnt) for small grids.
  auto gemm = [&](const float* Aa, const float* Ww, const float* bb, float* Cc,
                  int M, int N, int K, int relu) {
    long g128 = ((M % 128) == 0 && (N % 128) == 0) ? (long)(N / 128) * (M / 128) : 0;
    if (g128 >= 784 && (K % 32) == 0)
      k_mfma_nt<<<dim3(N / 128, M / 128), 256, 0, stream>>>(Aa, Ww, bb, Cc, M, N, K, relu, 0);
    else
      k_mfma_bnt<<<dim3(N / 64, (M + 63) / 64, 1), 256, 0, stream>>>(
          Aa, Ww, Cc, M, N, K, K, K, N, 1,
          0, 0, 0, 0, 0, 0, 1.0f, 0, bb, relu);
  };
  const int64_t RB = (int64_t)SS * 512;   // 100352
  const int64_t QB = 16 * 512;            // 8192
  // GEMM-ized attention, D=512 single-head, K|V packed [*,1024]. zq: #Q-variants (share KV).
  auto attn512 = [&](const float* Qp, int64_t qZ1, int64_t qZ2, const float* KVp, int64_t kvZ,
                     float* Op, int64_t oZ1, int64_t oZ2, int M, int zq, float scale) {
    int mt = (M + 63) / 64;
    int64_t sS2 = (int64_t)M * SLD;
    int64_t sS1 = 64 * sS2;
    k_mfma_bnt<<<dim3(4, mt, 64 * zq), 256, 0, stream>>>(
        Qp, KVp, sbuf, M, 196, 512, 512, 1024, SLD, 64,
        qZ1, qZ2, 0, kvZ, sS1, sS2, scale, 1, nullptr, 0);
    k_softmax_rows<<<(64 * zq * M + 3) / 4, 256, 0, stream>>>(sbuf, 64 * zq * M);
    k_mfma_bnn<<<dim3(8, mt, 64 * zq), 256, 0, stream>>>(
        sbuf, KVp + 512, Op, M, 512, SLD, 196, SLD, 1024, 512, 64,
        sS1, sS2, 0, kvZ, oZ1, oZ2);
  };
  auto attn_mha = [&](const short* Qp, const short* KVp, float* Op) {
    k_fmha_bf<<<dim3(64, 8), 256, 0, stream>>>(Qp, KVp, Op);
  };
  auto efc64 = [&](const float* Aa, float* Cc) {
    k_mfma_bnt<<<dim3(8, 1, 1), 256, 0, stream>>>(
        Aa, efcw, Cc, 64, 512, 1024, 1024, 1024, 512, 1,
        0, 0, 0, 0, 0, 0, 1.0f, 0, efcb, 1);
  };

  const float scalE = 1.0f / sqrtf(512.0f);

  // ---- Phase 0: build concat K|V weights for itda/ca/sa ----
  k_catkv<<<2048, 256, 0, stream>>>(itkvw, itkw, itvw, itkvb, itkb, itvb);
  k_catkv<<<2048, 256, 0, stream>>>(cakvw, cakw, cavw, cakvb, cakb, cavb);
  k_catkv<<<2048, 256, 0, stream>>>(sakvw, sakw, savw, sakvb, sakb, savb);

  // ---- Phase 1: embed -> x only (h == x until layer-0 addln) + caption projections ----
  k_mfma_embed<<<dim3(4, BS / 128, 2), 256, 0, stream>>>(
      in1, in2, imgw, imgb, wemb, hemb, x1, x2);
  gemm(cap1, fcw, fcb, cap1o, 1024, 512, 768, 0);
  gemm(cap2, fcw, fcb, cap2o, 1024, 512, 768, 0);
  k_meannc<<<dim3(2, 64), 256, 0, stream>>>(cap1o, nullptr, cm1);
  k_meannc<<<dim3(2, 64), 256, 0, stream>>>(cap2o, nullptr, cm2);

  // ---- Phase 2: CDCR loss (full-M MLP, bf16 hidden in tC..tD) ----
  k_mfma_nt<<<dim3(16, 98), 256, 0, stream>>>(x1, mlpw1, mlpb1, tC, BS, 2048, 512, 1, 1);
  k_mfma_bnt_abf<<<dim3(8, 196), 256, 0, stream>>>(
      (const short*)tC, mlpw2, tA, BS, 512, 2048, 2048, 2048, 512, mlpb2, 0);
  k_mfma_nt<<<dim3(16, 98), 256, 0, stream>>>(x2, mlpw1, mlpb1, tC, BS, 2048, 512, 1, 1);
  k_mfma_bnt_abf<<<dim3(8, 196), 256, 0, stream>>>(
      (const short*)tC, mlpw2, tB, BS, 512, 2048, 2048, 2048, 512, mlpb2, 0);
  k_zero<<<8, 256, 0, stream>>>(colsum1, 2048);  // colsum1..colsq2 contiguous
  k_colstats<<<dim3(16, 49), 256, 0, stream>>>(tA, colsum1, colsq1);
  k_colstats<<<dim3(16, 49), 256, 0, stream>>>(tB, colsum2, colsq2);
  k_finstats<<<2, 256, 0, stream>>>(colsum1, colsq1, mean1, istd1);
  k_finstats<<<2, 256, 0, stream>>>(colsum2, colsq2, mean2, istd2);
  k_znorm<<<25088, 256, 0, stream>>>(tA, mean1, istd1);
  k_znorm<<<25088, 256, 0, stream>>>(tB, mean2, istd2);
  k_zero<<<1024, 256, 0, stream>>>(cmat, 262144);
  k_mfma_corr<<<dim3(8, 8, 14), 256, 0, stream>>>(tA, tB, cmat, BS / 14, 1.0f / (float)BS);
  k_cdcr_part<<<256, 256, 0, stream>>>(cmat, cdcrpart);
  k_cdcr_fin<<<1, 256, 0, stream>>>(cdcrpart, out + NOUT);

  // ---- Phase 3: cross-transformer (bf16 Q/KV, all projections from pre-update h) ----
  for (int l = 0; l < 2; ++l) {
    const float* Wq = trinw + (size_t)l * 1536 * 512;
    const float* Wkv = Wq + 512 * 512;               // [Wk;Wv] 1024 rows
    const float* bq = trinb + l * 1536;
    const float* bkv = bq + 512;                     // [bk|bv] 1024
    const float* Wo = troutw + (size_t)l * 512 * 512;
    const float* bo = troutb + l * 512;
    const float* g  = trlng + l * 512;
    const float* be = trlnb + l * 512;
    const float* s1 = l ? h1 : x1;
    const float* s2 = l ? h2 : x2;
    // all projections read pre-update state (s1,s2 contiguous in both cases)
    k_mfma_nt<<<dim3(4, 196), 256, 0, stream>>>(s1, Wq, bq, tA, 2 * BS, 512, 512, 0, 1);   // q1|q2 bf16 -> tA
    k_mfma_nt<<<dim3(8, 98), 256, 0, stream>>>(s2, Wkv, bkv, tC, BS, 1024, 512, 0, 1);     // kv1 bf16 -> tC
    k_mfma_nt<<<dim3(8, 98), 256, 0, stream>>>(s1, Wkv, bkv, tD, BS, 1024, 512, 0, 1);     // kv2 bf16 -> tD
    attn_mha((const short*)tA, (const short*)tC, tB);                                      // dir1 -> tB fp32
    k_mfma_bnt<<<dim3(8, 196, 1), 256, 0, stream>>>(tB, Wo, sbuf, BS, 512, 512, 512, 512, 512, 1,
                                                    0, 0, 0, 0, 0, 0, 1.0f, 0, bo, 0);     // o1
    k_addln2<<<BS, 256, 0, stream>>>(h1, s1, sbuf, g, be);
    attn_mha((const short*)tA + (size_t)BS * 512, (const short*)tD, tB);                   // dir2
    k_mfma_bnt<<<dim3(8, 196, 1), 256, 0, stream>>>(tB, Wo, sbuf, BS, 512, 512, 512, 512, 512, 1,
                                                    0, 0, 0, 0, 0, 0, 1.0f, 0, bo, 0);     // o2
    k_addln2<<<BS, 256, 0, stream>>>(h2, s2, sbuf, g, be);
  }

  // ---- Phase 4: diffs ----
  k_diff<<<12544, 256, 0, stream>>>(tC, x1, h1);   // [tC;tD] = [x1;x2]-[h1;h2]
  // h1, h2 now free

  // ---- Phase 5: ITDA (fused itq, z=128 batched attention per KV set) ----
  gemm(cap1o, itqw, itqb, qc1, 2048, 512, 512, 0);  // qc1|qc2 (cap1o,cap2o contiguous)
  k_mask<<<1024, 64, 0, stream>>>(cap1o, mask1);
  k_mask<<<1024, 64, 0, stream>>>(cap2o, mask2);
  // KV from diff1: instances z1=0 (qc1 -> s_bef), z1=1 (qc2 -> d_bef)
  gemm(tC, itkvw, itkvb, tA, BS, 1024, 512, 0);      // kv1 -> tA..tB
  attn512(qc1, 524288, QB, tA, 2 * RB, attb, 524288, QB, 16, 2, scalE);
  k_meannc<<<dim3(2, 64), 256, 0, stream>>>(attb,  mask1, vsbef);   // s_bef (qc1)
  k_meannc<<<dim3(2, 64), 256, 0, stream>>>(attb2, mask2, vdbef);   // d_bef (qc2)
  // KV from diff2: z1=0 (qc1 -> d_aft), z1=1 (qc2 -> s_aft)
  gemm(tD, itkvw, itkvb, tA, BS, 1024, 512, 0);
  attn512(qc1, 524288, QB, tA, 2 * RB, attb, 524288, QB, 16, 2, scalE);
  k_meannc<<<dim3(2, 64), 256, 0, stream>>>(attb,  mask1, vdaft);   // d_aft (qc1)
  k_meannc<<<dim3(2, 64), 256, 0, stream>>>(attb2, mask2, vsaft);   // s_aft (qc2)

  // ---- Phase 6: ECA x4 with immediate MSE vs ITDA vector ----
  auto eca_mse = [&](const float* xq, const float* xkv,
                     const float* qw2, const float* qb2,
                     const float* kvw2, const float* kvb2,
                     const float* vec, double* part) {
    gemm(xq,  qw2, qb2, h1, BS, 512, 512, 0);        // Q -> h1
    gemm(xkv, kvw2, kvb2, tA, BS, 1024, 512, 0);     // K|V -> tA..tB
    attn512(h1, 0, RB, tA, 2 * RB, h2, 0, RB, 196, 1, scalE); // out -> h2
    k_mse<<<1024, 256, 0, stream>>>(h2, vec, part);
  };
  eca_mse(tC, tD, caqw, caqb, cakvw, cakvb, vdbef, msepart);          // c12 vs d_bef
  eca_mse(tD, tC, caqw, caqb, cakvw, cakvb, vdaft, msepart + 1024);   // c21 vs d_aft
  eca_mse(tC, tC, saqw, saqb, sakvw, sakvb, vsbef, msepart + 2048);   // s11 vs s_bef
  eca_mse(tD, tD, saqw, saqb, sakvw, sakvb, vsaft, msepart + 3072);   // s22 vs s_aft
  k_finloss<<<1, 256, 0, stream>>>(msepart, out + NOUT + 1);

  // ---- Phase 7: efc chain (per-batch vectors, MFMA path M=64) ----
  k_concat2<<<256, 256, 0, stream>>>(ccat, vdbef, vdaft);
  efc64(ccat, vdyn);
  k_concat2<<<256, 256, 0, stream>>>(ccat, vsbef, vsaft);
  efc64(ccat, vsta);
  k_concat2<<<256, 256, 0, stream>>>(ccat, vdyn, vsta);
  efc64(ccat, valign);
  k_concat2<<<256, 256, 0, stream>>>(ccat, cm1, cm2);
  efc64(ccat, vtxt);

  // ---- Phase 8: comb as bf16 into h1..h2, single bf16-A GEMM ----
  k_comb_bf<<<100352, 256, 0, stream>>>((short*)h1, tC, tD, vtxt, valign);
  k_mfma_bnt_abf<<<dim3(8, 196), 256, 0, stream>>>(
      (const short*)h1, efc2w, out, BS, 512, 2048, 2048, 2048, 512, efc2b, 1);
}

// Round 9
// 2177.090 us; speedup vs baseline: 1.7487x; 1.0947x over previous
//
#include <hip/hip_runtime.h>
#include <hip/hip_bf16.h>
#include <stdint.h>
#include <math.h>

// Problem constants
#define BB   64
#define SS   196
#define BS   12544            // BB*SS
#define NOUT 6422528L         // BS*512
#define SLD  224              // score row ld (7*32)

typedef __attribute__((ext_vector_type(8))) short bf16x8;
typedef __attribute__((ext_vector_type(4))) float f32x4;

// ---------------- device helpers ----------------
__device__ __forceinline__ float block_red256(float v, float* red, bool ismax) {
#pragma unroll
  for (int o = 32; o > 0; o >>= 1) {
    float t = __shfl_down(v, o, 64);
    v = ismax ? fmaxf(v, t) : v + t;
  }
  int lane = threadIdx.x & 63, wid = threadIdx.x >> 6;
  if (lane == 0) red[wid] = v;
  __syncthreads();
  float r = ismax ? fmaxf(fmaxf(red[0], red[1]), fmaxf(red[2], red[3]))
                  : (red[0] + red[1]) + (red[2] + red[3]);
  __syncthreads();
  return r;
}

// HW RNE conversion — bit-identical to the add-0x7fff bit-trick.
__device__ __forceinline__ short f2bf(float f) {
  __hip_bfloat16 h = __float2bfloat16(f);
  short s;
  __builtin_memcpy(&s, &h, 2);
  return s;
}

__device__ __forceinline__ void cvt8(short* dst, float4 a, float4 b) {
  union { short s[8]; int4 v; } u;
  u.s[0] = f2bf(a.x); u.s[1] = f2bf(a.y); u.s[2] = f2bf(a.z); u.s[3] = f2bf(a.w);
  u.s[4] = f2bf(b.x); u.s[5] = f2bf(b.y); u.s[6] = f2bf(b.z); u.s[7] = f2bf(b.w);
  *(int4*)dst = u.v;
}

// Raw barrier: ds ops drained, global loads stay in flight (no vmcnt drain).
__device__ __forceinline__ void lds_barrier() {
  asm volatile("s_waitcnt lgkmcnt(0)" ::: "memory");
  __builtin_amdgcn_s_barrier();
  __builtin_amdgcn_sched_barrier(0);
}

// Bijective XCD-chunked swizzle (m204).
__device__ __forceinline__ int xcd_swizzle(int flat, int nwg) {
  int q = nwg >> 3, r = nwg & 7;
  int xcd = flat & 7, pos = flat >> 3;
  return (xcd < r ? xcd * (q + 1) : r * (q + 1) + (xcd - r) * q) + pos;
}

// ---- bf16 MFMA GEMM: C[M,N] = A[M,K] @ W[N,K]^T + bias (opt relu, opt bf16 out) ----
// 128x128 tile, BK=32, 4 waves (2x2). 2-phase pipeline + XCD swizzle.
__global__ __launch_bounds__(256) void k_mfma_nt(
    const float* __restrict__ A, const float* __restrict__ W,
    const float* __restrict__ bias, float* __restrict__ C,
    int M, int N, int K, int relu, int obf) {
  __shared__ short As[2][128][40];
  __shared__ short Bs[2][128][40];
  const int tid = threadIdx.x;
  const int lane = tid & 63, wave = tid >> 6;
  const int wm = wave >> 1, wn = wave & 1;
  const int NX = gridDim.x;
  const int wg = xcd_swizzle(blockIdx.y * NX + blockIdx.x, NX * gridDim.y);
  const int m0 = (wg / NX) * 128, n0 = (wg % NX) * 128;
  const int srow = tid >> 1, skh = (tid & 1) * 16;
  const float* Ap = A + (long)(m0 + srow) * K + skh;
  const float* Wp = W + (long)(n0 + srow) * K + skh;
  const int fr = lane & 15, fq = lane >> 4;
  const int NK = K >> 5;
  f32x4 acc[4][4] = {};
  float4 xa[4], xw[4], ya[4], yw[4];

  auto ldt = [&](float4 (&ta)[4], float4 (&tw)[4], int t) {
    const float* ap = Ap + t * 32;
    const float* wp = Wp + t * 32;
#pragma unroll
    for (int i = 0; i < 4; ++i) {
      ta[i] = *(const float4*)(ap + i * 4);
      tw[i] = *(const float4*)(wp + i * 4);
    }
  };
  auto stage = [&](float4 (&ta)[4], float4 (&tw)[4], int p) {
    cvt8(&As[p][srow][skh], ta[0], ta[1]);
    cvt8(&As[p][srow][skh + 8], ta[2], ta[3]);
    cvt8(&Bs[p][srow][skh], tw[0], tw[1]);
    cvt8(&Bs[p][srow][skh + 8], tw[2], tw[3]);
  };
  auto step = [&](int t, float4 (&la)[4], float4 (&lw)[4],
                  float4 (&ca)[4], float4 (&cw)[4]) {
    const int par = t & 1;
    if (t + 2 < NK) ldt(la, lw, t + 2);            // prefetch tile t+2
    bf16x8 af[4], bfr[4];
#pragma unroll
    for (int i = 0; i < 4; ++i) af[i] = *(const bf16x8*)&As[par][wm * 64 + i * 16 + fr][fq * 8];
#pragma unroll
    for (int j = 0; j < 4; ++j) bfr[j] = *(const bf16x8*)&Bs[par][wn * 64 + j * 16 + fr][fq * 8];
    if (t + 1 < NK) stage(ca, cw, par ^ 1);        // stage tile t+1
#pragma unroll
    for (int i = 0; i < 4; ++i)
#pragma unroll
      for (int j = 0; j < 4; ++j)
        acc[i][j] = __builtin_amdgcn_mfma_f32_16x16x32_bf16(af[i], bfr[j], acc[i][j], 0, 0, 0);
    lds_barrier();
  };

  ldt(xa, xw, 0);
  stage(xa, xw, 0);
  if (NK > 1) ldt(xa, xw, 1);
  lds_barrier();
  int t = 0;
  for (; t + 1 < NK; t += 2) { step(t, ya, yw, xa, xw); step(t + 1, xa, xw, ya, yw); }
  if (t < NK) step(t, ya, yw, xa, xw);

  short* Cs = (short*)C;
#pragma unroll
  for (int i = 0; i < 4; ++i) {
    int mB = m0 + wm * 64 + i * 16 + fq * 4;
#pragma unroll
    for (int j = 0; j < 4; ++j) {
      int n = n0 + wn * 64 + j * 16 + fr;
      float bz = bias[n];
#pragma unroll
      for (int r2 = 0; r2 < 4; ++r2) {
        float v = acc[i][j][r2] + bz;
        if (relu) v = fmaxf(v, 0.f);
        if (obf) Cs[(long)(mB + r2) * N + n] = f2bf(v);
        else     C[(long)(mB + r2) * N + n] = v;
      }
    }
  }
}

// ---- bf16 MFMA embed (z=2 fused): C = X@W^T + bias + pe ----
__global__ __launch_bounds__(256) void k_mfma_embed(
    const float* __restrict__ X1, const float* __restrict__ X2,  // [B,1024,196]
    const float* __restrict__ W,   // [512,1024]
    const float* __restrict__ bias,
    const float* __restrict__ wemb, const float* __restrict__ hemb,
    float* __restrict__ C1, float* __restrict__ C2) {
  __shared__ short As[2][128][40];
  __shared__ short Bs[2][128][40];
  const float* X = blockIdx.z ? X2 : X1;
  float* C = blockIdx.z ? C2 : C1;
  const int tid = threadIdx.x;
  const int lane = tid & 63, wave = tid >> 6;
  const int wm = wave >> 1, wn = wave & 1;
  const int NX = gridDim.x;
  const int wg = xcd_swizzle(blockIdx.y * NX + blockIdx.x, NX * gridDim.y);
  const int m0 = (wg / NX) * 128, n0 = (wg % NX) * 128;
  const int K = 1024, N = 512;
  const int srow = tid >> 1, skh = (tid & 1) * 16;
  const float* Wp = W + (long)(n0 + srow) * K + skh;
  const int arow = tid & 127, khalf = tid >> 7;
  const int am = m0 + arow;
  const int ab = am / 196, as_ = am % 196;
  const float* Xp = X + (long)ab * 200704 + as_;
  const int fr = lane & 15, fq = lane >> 4;
  const int NK = K >> 5;   // 32
  f32x4 acc[4][4] = {};
  float xx[16], yx[16];
  float4 xw[4], yw[4];

  auto ldt = [&](float (&tx)[16], float4 (&tw)[4], int t) {
    const int kb = t * 32 + khalf * 16;
#pragma unroll
    for (int i = 0; i < 16; ++i) tx[i] = Xp[(long)(kb + i) * 196];
    const float* wp = Wp + t * 32;
#pragma unroll
    for (int i = 0; i < 4; ++i) tw[i] = *(const float4*)(wp + i * 4);
  };
  auto stage = [&](float (&tx)[16], float4 (&tw)[4], int p) {
    union { short s[16]; int4 v[2]; } u;
#pragma unroll
    for (int i = 0; i < 16; ++i) u.s[i] = f2bf(tx[i]);
    int4* dst = (int4*)&As[p][arow][khalf * 16];
    dst[0] = u.v[0]; dst[1] = u.v[1];
    cvt8(&Bs[p][srow][skh], tw[0], tw[1]);
    cvt8(&Bs[p][srow][skh + 8], tw[2], tw[3]);
  };
  auto step = [&](int t, float (&lx)[16], float4 (&lw)[4],
                  float (&cx)[16], float4 (&cw)[4]) {
    const int par = t & 1;
    if (t + 2 < NK) ldt(lx, lw, t + 2);
    bf16x8 af[4], bfr[4];
#pragma unroll
    for (int i = 0; i < 4; ++i) af[i] = *(const bf16x8*)&As[par][wm * 64 + i * 16 + fr][fq * 8];
#pragma unroll
    for (int j = 0; j < 4; ++j) bfr[j] = *(const bf16x8*)&Bs[par][wn * 64 + j * 16 + fr][fq * 8];
    if (t + 1 < NK) stage(cx, cw, par ^ 1);
#pragma unroll
    for (int i = 0; i < 4; ++i)
#pragma unroll
      for (int j = 0; j < 4; ++j)
        acc[i][j] = __builtin_amdgcn_mfma_f32_16x16x32_bf16(af[i], bfr[j], acc[i][j], 0, 0, 0);
    lds_barrier();
  };

  ldt(xx, xw, 0);
  stage(xx, xw, 0);
  if (NK > 1) ldt(xx, xw, 1);
  lds_barrier();
  int t = 0;
  for (; t + 1 < NK; t += 2) { step(t, yx, yw, xx, xw); step(t + 1, xx, xw, yx, yw); }
  if (t < NK) step(t, yx, yw, xx, xw);

#pragma unroll
  for (int i = 0; i < 4; ++i) {
    int mB = m0 + wm * 64 + i * 16 + fq * 4;
#pragma unroll
    for (int j = 0; j < 4; ++j) {
      int n = n0 + wn * 64 + j * 16 + fr;
      float bz = bias[n];
#pragma unroll
      for (int r2 = 0; r2 < 4; ++r2) {
        int m = mB + r2;
        int s = m % 196;
        float pe = (n < 256) ? wemb[(s % 14) * 256 + n] : hemb[(s / 14) * 256 + (n - 256)];
        C[(long)m * N + n] = acc[i][j][r2] + bz + pe;
      }
    }
  }
}

// ---- Fused flash MHA (both dirs in one launch): B=64,H=8,S=196,D=64. ----
// z=0: Q part0, KV=KVd1; z=1: Q part1, KV=KVd2. O bf16 [2BS,512].
__global__ __launch_bounds__(256) void k_fmha_bf2(
    const short* __restrict__ Q, const short* __restrict__ KVd1,
    const short* __restrict__ KVd2, short* __restrict__ O) {
  __shared__ short Vt[64][240];     // V^T bf16 (keys 196..223 zeroed)
  __shared__ short Pt[4][16][40];   // per-wave P staging
  const int tid = threadIdx.x;
  const int lane = tid & 63, wave = tid >> 6;
  const int b = blockIdx.x, h = blockIdx.y, z = blockIdx.z;
  const short* KV = z ? KVd2 : KVd1;
  const long brow = (long)b * 196;
  const size_t zo = (size_t)z * BS * 512;
  const short* Qb = Q + zo + brow * 512 + h * 64;
  const short* Kb = KV + brow * 1024 + h * 64;
  const short* Vb = KV + brow * 1024 + 512 + h * 64;
  short* Ob = O + zo + brow * 512 + h * 64;
  const int fr = lane & 15, fq = lane >> 4;

  for (int i = tid; i < 64 * 32; i += 256) {
    int d = i >> 5, k = 192 + (i & 31);
    if (k >= 196) Vt[d][k] = 0;
  }
  for (int i = tid; i < 196 * 8; i += 256) {
    int s = i >> 3, c8 = (i & 7) * 8;
    bf16x8 v = *(const bf16x8*)(Vb + (long)s * 1024 + c8);
#pragma unroll
    for (int j = 0; j < 8; ++j) Vt[c8 + j][s] = v[j];
  }
  __syncthreads();

  for (int qt = wave; qt < 13; qt += 4) {
    const int q0 = qt * 16;
    const int qr = (q0 + fr < 196) ? q0 + fr : 195;
    const short* qp = Qb + (long)qr * 512 + fq * 8;
    bf16x8 aq0 = *(const bf16x8*)(qp);
    bf16x8 aq1 = *(const bf16x8*)(qp + 32);
    f32x4 sc[13];
#pragma unroll
    for (int t = 0; t < 13; ++t) {
      int kr = (t * 16 + fr < 196) ? t * 16 + fr : 195;
      const short* kp = Kb + (long)kr * 1024 + fq * 8;
      bf16x8 bk0 = *(const bf16x8*)(kp);
      bf16x8 bk1 = *(const bf16x8*)(kp + 32);
      f32x4 zz = {};
      zz = __builtin_amdgcn_mfma_f32_16x16x32_bf16(aq0, bk0, zz, 0, 0, 0);
      zz = __builtin_amdgcn_mfma_f32_16x16x32_bf16(aq1, bk1, zz, 0, 0, 0);
      sc[t] = zz;
    }
#pragma unroll
    for (int t = 0; t < 13; ++t)
#pragma unroll
      for (int r2 = 0; r2 < 4; ++r2) sc[t][r2] *= 0.125f;
    if (fr >= 4) {
#pragma unroll
      for (int r2 = 0; r2 < 4; ++r2) sc[12][r2] = -1e30f;
    }
#pragma unroll
    for (int r2 = 0; r2 < 4; ++r2) {
      float m = sc[0][r2];
#pragma unroll
      for (int t = 1; t < 13; ++t) m = fmaxf(m, sc[t][r2]);
#pragma unroll
      for (int o = 1; o < 16; o <<= 1) m = fmaxf(m, __shfl_xor(m, o, 64));
      float s = 0.f;
#pragma unroll
      for (int t = 0; t < 13; ++t) { float e = expf(sc[t][r2] - m); sc[t][r2] = e; s += e; }
#pragma unroll
      for (int o = 1; o < 16; o <<= 1) s += __shfl_xor(s, o, 64);
      float inv = 1.0f / s;
#pragma unroll
      for (int t = 0; t < 13; ++t) sc[t][r2] *= inv;
    }
    f32x4 acc_o[4] = {};
#pragma unroll
    for (int s7 = 0; s7 < 7; ++s7) {
      const int t0 = 2 * s7, t1 = 2 * s7 + 1;
#pragma unroll
      for (int r2 = 0; r2 < 4; ++r2) {
        Pt[wave][fq * 4 + r2][fr] = f2bf(sc[t0][r2]);
        Pt[wave][fq * 4 + r2][16 + fr] = (t1 < 13) ? f2bf(sc[t1][r2]) : (short)0;
      }
      asm volatile("s_waitcnt lgkmcnt(0)" ::: "memory");
      bf16x8 ap = *(const bf16x8*)&Pt[wave][fr][fq * 8];
#pragma unroll
      for (int dt = 0; dt < 4; ++dt) {
        bf16x8 bv = *(const bf16x8*)&Vt[dt * 16 + fr][32 * s7 + fq * 8];
        acc_o[dt] = __builtin_amdgcn_mfma_f32_16x16x32_bf16(ap, bv, acc_o[dt], 0, 0, 0);
      }
    }
#pragma unroll
    for (int r2 = 0; r2 < 4; ++r2) {
      int qrow = q0 + fq * 4 + r2;
      if (qrow < 196) {
        short* op = Ob + (long)qrow * 512;
#pragma unroll
        for (int dt = 0; dt < 4; ++dt) op[dt * 16 + fr] = f2bf(acc_o[dt][r2]);
      }
    }
  }
}

// ---- Batched bf16 MFMA NT: C[z][m,n] = scale*sum_k A[z][m,k]*B[z][n,k] ----
__global__ __launch_bounds__(256) void k_mfma_bnt(
    const float* __restrict__ A, const float* __restrict__ B, float* __restrict__ C,
    int M, int N, int K, int lda, int ldb, int ldc, int nz2,
    int64_t sA1, int64_t sA2, int64_t sB1, int64_t sB2, int64_t sC1, int64_t sC2,
    float scale, int clampf, const float* __restrict__ bias2, int relu2) {
  __shared__ short As[2][64][40];
  __shared__ short Bs[2][64][40];
  const int tid = threadIdx.x;
  const int lane = tid & 63, wave = tid >> 6;
  const int NX = gridDim.x;
  const int wg = xcd_swizzle(blockIdx.y * NX + blockIdx.x, NX * gridDim.y);
  const int m0 = (wg / NX) * 64, n0 = (wg % NX) * 64;
  const int z = blockIdx.z, z1 = z / nz2, z2 = z % nz2;
  const float* Ab = A + z1 * sA1 + z2 * sA2;
  const float* Bb = B + z1 * sB1 + z2 * sB2;
  float* Cb = C + z1 * sC1 + z2 * sC2;
  const int sr = tid >> 2, skh = (tid & 3) * 8;
  const int ar = (m0 + sr < M) ? m0 + sr : M - 1;
  const int br = (n0 + sr < N) ? n0 + sr : N - 1;
  const float* Ap = Ab + (long)ar * lda + skh;
  const float* Bp = Bb + (long)br * ldb + skh;
  const int fr = lane & 15, fq = lane >> 4;
  const int NK = K >> 5;
  f32x4 acc[4] = {};
  float4 xa[2], xb[2], ya[2], yb[2];

  auto ldt = [&](float4 (&ta)[2], float4 (&tb)[2], int t) {
    const int kb = t * 32;
#pragma unroll
    for (int i = 0; i < 2; ++i) {
      ta[i] = *(const float4*)(Ap + kb + i * 4);
      tb[i] = *(const float4*)(Bp + kb + i * 4);
    }
  };
  auto stage = [&](float4 (&ta)[2], float4 (&tb)[2], int p) {
    cvt8(&As[p][sr][skh], ta[0], ta[1]);
    cvt8(&Bs[p][sr][skh], tb[0], tb[1]);
  };
  auto step = [&](int t, float4 (&la)[2], float4 (&lb)[2],
                  float4 (&ca)[2], float4 (&cb)[2]) {
    const int par = t & 1;
    if (t + 2 < NK) ldt(la, lb, t + 2);
    bf16x8 bfr = *(const bf16x8*)&Bs[par][wave * 16 + fr][fq * 8];
    bf16x8 af[4];
#pragma unroll
    for (int i = 0; i < 4; ++i) af[i] = *(const bf16x8*)&As[par][i * 16 + fr][fq * 8];
    if (t + 1 < NK) stage(ca, cb, par ^ 1);
#pragma unroll
    for (int i = 0; i < 4; ++i)
      acc[i] = __builtin_amdgcn_mfma_f32_16x16x32_bf16(af[i], bfr, acc[i], 0, 0, 0);
    lds_barrier();
  };

  ldt(xa, xb, 0);
  stage(xa, xb, 0);
  if (NK > 1) ldt(xa, xb, 1);
  lds_barrier();
  int t = 0;
  for (; t + 1 < NK; t += 2) { step(t, ya, yb, xa, xb); step(t + 1, xa, xb, ya, yb); }
  if (t < NK) step(t, ya, yb, xa, xb);

  const int n = n0 + wave * 16 + fr;
  if (n < N) {
    float bz = bias2 ? bias2[n] : 0.f;
#pragma unroll
    for (int i = 0; i < 4; ++i) {
      int mb = m0 + i * 16 + fq * 4;
#pragma unroll
      for (int r2 = 0; r2 < 4; ++r2) {
        int m = mb + r2;
        if (m < M) {
          float v = acc[i][r2] * scale + bz;
          if (relu2) v = fmaxf(v, 0.f);
          if (clampf) v = fminf(fmaxf(v, -100.f), 100.f);
          Cb[(long)m * ldc + n] = v;
        }
      }
    }
  }
}

// ---- NT GEMM with bf16 A-input: C[m,n] = sum_k A[m,k]*B[n,k] + bias (opt relu) ----
__global__ __launch_bounds__(256) void k_mfma_bnt_abf(
    const short* __restrict__ A, const float* __restrict__ B, float* __restrict__ C,
    int M, int N, int K, int lda, int ldb, int ldc,
    const float* __restrict__ bias2, int relu2) {
  __shared__ short As[2][64][40];
  __shared__ short Bs[2][64][40];
  const int tid = threadIdx.x;
  const int lane = tid & 63, wave = tid >> 6;
  const int NX = gridDim.x;
  const int wg = xcd_swizzle(blockIdx.y * NX + blockIdx.x, NX * gridDim.y);
  const int m0 = (wg / NX) * 64, n0 = (wg % NX) * 64;
  const int sr = tid >> 2, skh = (tid & 3) * 8;
  const int ar = (m0 + sr < M) ? m0 + sr : M - 1;
  const int br = (n0 + sr < N) ? n0 + sr : N - 1;
  const short* Ap = A + (long)ar * lda + skh;
  const float* Bp = B + (long)br * ldb + skh;
  const int fr = lane & 15, fq = lane >> 4;
  const int NK = K >> 5;
  f32x4 acc[4] = {};
  int4 xa, ya;
  float4 xb[2], yb[2];

  auto ldt = [&](int4& ta, float4 (&tb)[2], int t) {
    const int kb = t * 32;
    ta = *(const int4*)(Ap + kb);
#pragma unroll
    for (int i = 0; i < 2; ++i) tb[i] = *(const float4*)(Bp + kb + i * 4);
  };
  auto stage = [&](int4& ta, float4 (&tb)[2], int p) {
    *(int4*)&As[p][sr][skh] = ta;
    cvt8(&Bs[p][sr][skh], tb[0], tb[1]);
  };
  auto step = [&](int t, int4& la, float4 (&lb)[2], int4& ca, float4 (&cb)[2]) {
    const int par = t & 1;
    if (t + 2 < NK) ldt(la, lb, t + 2);
    bf16x8 bfr = *(const bf16x8*)&Bs[par][wave * 16 + fr][fq * 8];
    bf16x8 af[4];
#pragma unroll
    for (int i = 0; i < 4; ++i) af[i] = *(const bf16x8*)&As[par][i * 16 + fr][fq * 8];
    if (t + 1 < NK) stage(ca, cb, par ^ 1);
#pragma unroll
    for (int i = 0; i < 4; ++i)
      acc[i] = __builtin_amdgcn_mfma_f32_16x16x32_bf16(af[i], bfr, acc[i], 0, 0, 0);
    lds_barrier();
  };

  ldt(xa, xb, 0);
  stage(xa, xb, 0);
  if (NK > 1) ldt(xa, xb, 1);
  lds_barrier();
  int t = 0;
  for (; t + 1 < NK; t += 2) { step(t, ya, yb, xa, xb); step(t + 1, xa, xb, ya, yb); }
  if (t < NK) step(t, ya, yb, xa, xb);

  const int n = n0 + wave * 16 + fr;
  if (n < N) {
    float bz = bias2 ? bias2[n] : 0.f;
#pragma unroll
    for (int i = 0; i < 4; ++i) {
      int mb = m0 + i * 16 + fq * 4;
#pragma unroll
      for (int r2 = 0; r2 < 4; ++r2) {
        int m = mb + r2;
        if (m < M) {
          float v = acc[i][r2] + bz;
          if (relu2) v = fmaxf(v, 0.f);
          C[(long)m * ldc + n] = v;
        }
      }
    }
  }
}

// ---- Batched bf16 MFMA NN: C[z][m,n] = sum_k A[z][m,k]*B[z][k,n] ----
__global__ __launch_bounds__(256) void k_mfma_bnn(
    const float* __restrict__ A, const float* __restrict__ B, float* __restrict__ C,
    int M, int N, int K, int KBvalid, int lda, int ldb, int ldc, int nz2,
    int64_t sA1, int64_t sA2, int64_t sB1, int64_t sB2, int64_t sC1, int64_t sC2) {
  __shared__ short As[2][64][40];
  __shared__ short Bs[2][64][40];
  const int tid = threadIdx.x;
  const int lane = tid & 63, wave = tid >> 6;
  const int m0 = blockIdx.y * 64, n0 = blockIdx.x * 64;
  const int z = blockIdx.z, z1 = z / nz2, z2 = z % nz2;
  const float* Ab = A + z1 * sA1 + z2 * sA2;
  const float* Bb = B + z1 * sB1 + z2 * sB2;
  float* Cb = C + z1 * sC1 + z2 * sC2;
  const int sr = tid >> 2, skh = (tid & 3) * 8;
  const int ar = (m0 + sr < M) ? m0 + sr : M - 1;
  const float* Ap = Ab + (long)ar * lda + skh;
  const int bk = tid >> 3, bn = (tid & 7) * 8;   // B transposed staging
  const int fr = lane & 15, fq = lane >> 4;
  const int NK = K >> 5;
  f32x4 acc[4] = {};
  float4 xa[2], xb[2], ya[2], yb[2];

  auto ldt = [&](float4 (&ta)[2], float4 (&tb)[2], int t) {
    const int kb = t * 32;
#pragma unroll
    for (int i = 0; i < 2; ++i) ta[i] = *(const float4*)(Ap + kb + i * 4);
    int kc = kb + bk;
    if (kc >= KBvalid) kc = KBvalid - 1;
    const float* bp = Bb + (long)kc * ldb + n0 + bn;
#pragma unroll
    for (int i = 0; i < 2; ++i) tb[i] = *(const float4*)(bp + i * 4);
  };
  auto stage = [&](float4 (&ta)[2], float4 (&tb)[2], int p) {
    cvt8(&As[p][sr][skh], ta[0], ta[1]);
    short tmp[8];
    cvt8(tmp, tb[0], tb[1]);
#pragma unroll
    for (int j = 0; j < 8; ++j) Bs[p][bn + j][bk] = tmp[j];
  };
  auto step = [&](int t, float4 (&la)[2], float4 (&lb)[2],
                  float4 (&ca)[2], float4 (&cb)[2]) {
    const int par = t & 1;
    if (t + 2 < NK) ldt(la, lb, t + 2);
    bf16x8 bfr = *(const bf16x8*)&Bs[par][wave * 16 + fr][fq * 8];
    bf16x8 af[4];
#pragma unroll
    for (int i = 0; i < 4; ++i) af[i] = *(const bf16x8*)&As[par][i * 16 + fr][fq * 8];
    if (t + 1 < NK) stage(ca, cb, par ^ 1);
#pragma unroll
    for (int i = 0; i < 4; ++i)
      acc[i] = __builtin_amdgcn_mfma_f32_16x16x32_bf16(af[i], bfr, acc[i], 0, 0, 0);
    lds_barrier();
  };

  ldt(xa, xb, 0);
  stage(xa, xb, 0);
  if (NK > 1) ldt(xa, xb, 1);
  lds_barrier();
  int t = 0;
  for (; t + 1 < NK; t += 2) { step(t, ya, yb, xa, xb); step(t + 1, xa, xb, ya, yb); }
  if (t < NK) step(t, ya, yb, xa, xb);

  const int n = n0 + wave * 16 + fr;
  if (n < N) {
#pragma unroll
    for (int i = 0; i < 4; ++i) {
      int mb = m0 + i * 16 + fq * 4;
#pragma unroll
      for (int r2 = 0; r2 < 4; ++r2) {
        int m = mb + r2;
        if (m < M) Cb[(long)m * ldc + n] = acc[i][r2];
      }
    }
  }
}

// ---- MFMA correlation: C[i,j] += scale * sum_m Za[m,i]*Zb[m,j] (split-K atomic) ----
__global__ __launch_bounds__(256) void k_mfma_corr(
    const float* __restrict__ Za, const float* __restrict__ Zb,
    float* __restrict__ C, int mchunk, float scale) {
  __shared__ short As[2][64][40];
  __shared__ short Bs[2][64][40];
  const int tid = threadIdx.x;
  const int lane = tid & 63, wave = tid >> 6;
  const int i0 = blockIdx.y * 64, j0 = blockIdx.x * 64;
  const int mstart = blockIdx.z * mchunk;
  const int tm = tid >> 3, tcb = (tid & 7) * 8;
  const int fr = lane & 15, fq = lane >> 4;
  const int NK = mchunk >> 5;   // 28
  f32x4 acc[4] = {};
  float4 xa[2], xb[2], ya[2], yb[2];

  auto ldt = [&](float4 (&ta)[2], float4 (&tb)[2], int t) {
    const float* za = Za + (long)(mstart + t * 32 + tm) * 512;
    const float* zb = Zb + (long)(mstart + t * 32 + tm) * 512;
    ta[0] = *(const float4*)(za + i0 + tcb);
    ta[1] = *(const float4*)(za + i0 + tcb + 4);
    tb[0] = *(const float4*)(zb + j0 + tcb);
    tb[1] = *(const float4*)(zb + j0 + tcb + 4);
  };
  auto stage = [&](float4 (&ta)[2], float4 (&tb)[2], int p) {
    short u[8], v[8];
    cvt8(u, ta[0], ta[1]);
    cvt8(v, tb[0], tb[1]);
#pragma unroll
    for (int j = 0; j < 8; ++j) { As[p][tcb + j][tm] = u[j]; Bs[p][tcb + j][tm] = v[j]; }
  };
  auto step = [&](int t, float4 (&la)[2], float4 (&lb)[2],
                  float4 (&ca)[2], float4 (&cb)[2]) {
    const int par = t & 1;
    if (t + 2 < NK) ldt(la, lb, t + 2);
    bf16x8 bfr = *(const bf16x8*)&Bs[par][wave * 16 + fr][fq * 8];
    bf16x8 af[4];
#pragma unroll
    for (int i = 0; i < 4; ++i) af[i] = *(const bf16x8*)&As[par][i * 16 + fr][fq * 8];
    if (t + 1 < NK) stage(ca, cb, par ^ 1);
#pragma unroll
    for (int i = 0; i < 4; ++i)
      acc[i] = __builtin_amdgcn_mfma_f32_16x16x32_bf16(af[i], bfr, acc[i], 0, 0, 0);
    lds_barrier();
  };

  ldt(xa, xb, 0);
  stage(xa, xb, 0);
  if (NK > 1) ldt(xa, xb, 1);
  lds_barrier();
  int t = 0;
  for (; t + 1 < NK; t += 2) { step(t, ya, yb, xa, xb); step(t + 1, xa, xb, ya, yb); }
  if (t < NK) step(t, ya, yb, xa, xb);

  const int j = j0 + wave * 16 + fr;
#pragma unroll
  for (int i = 0; i < 4; ++i) {
    int ib = i0 + i * 16 + fq * 4;
#pragma unroll
    for (int r2 = 0; r2 < 4; ++r2)
      atomicAdd(&C[(long)(ib + r2) * 512 + j], acc[i][r2] * scale);
  }
}

// ---- Row softmax over rows of width 196, ld=SLD(224); zeroes pad cols. ----
__global__ __launch_bounds__(256) void k_softmax_rows(float* __restrict__ S, int nrows) {
  int row = blockIdx.x * 4 + (threadIdx.x >> 6);
  int lane = threadIdx.x & 63;
  if (row >= nrows) return;
  float* p = S + (long)row * SLD;
  float v0 = p[lane];
  float v1 = p[lane + 64];
  float v2 = p[lane + 128];
  float v3 = (lane + 192 < 196) ? p[lane + 192] : -1e30f;
  float mx = fmaxf(fmaxf(v0, v1), fmaxf(v2, v3));
#pragma unroll
  for (int o = 32; o > 0; o >>= 1) mx = fmaxf(mx, __shfl_down(mx, o, 64));
  mx = __shfl(mx, 0, 64);
  float e0 = expf(v0 - mx), e1 = expf(v1 - mx), e2 = expf(v2 - mx);
  float e3 = (lane + 192 < 196) ? expf(v3 - mx) : 0.f;
  float s = e0 + e1 + e2 + e3;
#pragma unroll
  for (int o = 32; o > 0; o >>= 1) s += __shfl_down(s, o, 64);
  s = __shfl(s, 0, 64);
  float inv = 1.0f / s;
  p[lane] = e0 * inv;
  p[lane + 64] = e1 * inv;
  p[lane + 128] = e2 * inv;
  if (lane + 192 < SLD) p[lane + 192] = (lane + 192 < 196) ? e3 * inv : 0.f;
}

// ---- dst = LayerNorm(src + o) (src may equal dst) ----
__global__ __launch_bounds__(256) void k_addln2(
    float* __restrict__ dst, const float* __restrict__ src, const float* __restrict__ o,
    const float* __restrict__ g, const float* __restrict__ be) {
  __shared__ float red[4];
  long row = blockIdx.x;
  const float* sr_ = src + row * 512;
  const float* orow = o + row * 512;
  float* dr = dst + row * 512;
  int t = threadIdx.x;
  float v0 = sr_[t] + orow[t];
  float v1 = sr_[t + 256] + orow[t + 256];
  float mean = block_red256(v0 + v1, red, false) * (1.0f / 512.0f);
  float d0 = v0 - mean, d1 = v1 - mean;
  float var = block_red256(d0 * d0 + d1 * d1, red, false) * (1.0f / 512.0f);
  float inv = 1.0f / sqrtf(var + 1e-5f);
  dr[t] = d0 * inv * g[t] + be[t];
  dr[t + 256] = d1 * inv * g[t + 256] + be[t + 256];
}

// ---- small utility kernels ----
__global__ void k_zero(float* __restrict__ p, int n) {
  int i = blockIdx.x * 256 + threadIdx.x;
  if (i < n) p[i] = 0.f;
}

// d = x - h (vectorized)
__global__ __launch_bounds__(256) void k_diff(
    float* __restrict__ d, const float* __restrict__ x, const float* __restrict__ h) {
  long i = ((long)blockIdx.x * 256 + threadIdx.x) * 4;
  float4 xv = *(const float4*)(x + i);
  float4 hv = *(const float4*)(h + i);
  float4 r; r.x = xv.x - hv.x; r.y = xv.y - hv.y; r.z = xv.z - hv.z; r.w = xv.w - hv.w;
  *(float4*)(d + i) = r;
}

// concat two [512,512] weights into [1024,512] (+ biases into [1024])
__global__ __launch_bounds__(256) void k_catkv(
    float* __restrict__ dw, const float* __restrict__ kw, const float* __restrict__ vw,
    float* __restrict__ db, const float* __restrict__ kb, const float* __restrict__ vb) {
  int i = blockIdx.x * 256 + threadIdx.x;      // 1024*512
  int r = i >> 9;
  dw[i] = (r < 512) ? kw[i] : vw[i - 262144];
  if (i < 1024) db[i] = (i < 512) ? kb[i] : vb[i - 512];
}

__global__ __launch_bounds__(256) void k_colstats(
    const float* __restrict__ f, float* __restrict__ sums, float* __restrict__ sqs) {
  int c = blockIdx.x * 32 + (threadIdx.x & 31);
  int rbase = blockIdx.y * 256;
  int r0 = rbase + (threadIdx.x >> 5);
  float s = 0.f, s2 = 0.f;
  for (int r = r0; r < rbase + 256; r += 8) {
    float v = f[(long)r * 512 + c];
    s += v; s2 += v * v;
  }
  __shared__ float sh[256], sh2[256];
  sh[threadIdx.x] = s; sh2[threadIdx.x] = s2;
  __syncthreads();
  if (threadIdx.x < 32) {
    for (int i = 1; i < 8; ++i) { s += sh[i * 32 + threadIdx.x]; s2 += sh2[i * 32 + threadIdx.x]; }
    atomicAdd(&sums[c], s);
    atomicAdd(&sqs[c], s2);
  }
}

__global__ void k_finstats(const float* __restrict__ sums, const float* __restrict__ sqs,
                           float* __restrict__ mean, float* __restrict__ istd) {
  int c = blockIdx.x * 256 + threadIdx.x;
  float mu = sums[c] / 12544.0f;
  float var = (sqs[c] - 12544.0f * mu * mu) / 12543.0f;
  mean[c] = mu;
  istd[c] = 1.0f / sqrtf(var);
}

__global__ __launch_bounds__(256) void k_znorm(float* __restrict__ f, const float* __restrict__ mean,
                                               const float* __restrict__ istd) {
  long i = (long)blockIdx.x * 256 + threadIdx.x;
  int c = (int)(i & 511);
  f[i] = (f[i] - mean[c]) * istd[c];
}

// CDCR loss: 256-block partial reduce + final combine
__global__ __launch_bounds__(256) void k_cdcr_part(const float* __restrict__ Cm,
                                                   double* __restrict__ part) {
  int base = blockIdx.x * 1024;
  double on = 0, off = 0;
  for (int i = base + threadIdx.x; i < base + 1024; i += 256) {
    float v = Cm[i];
    int r = i >> 9, c = i & 511;
    if (r == c) { double d = (double)v - 1.0; on += d * d; }
    else        { off += (double)v * (double)v; }
  }
  __shared__ double s_on[256], s_off[256];
  s_on[threadIdx.x] = on; s_off[threadIdx.x] = off;
  __syncthreads();
  for (int st = 128; st > 0; st >>= 1) {
    if (threadIdx.x < st) { s_on[threadIdx.x] += s_on[threadIdx.x + st]; s_off[threadIdx.x] += s_off[threadIdx.x + st]; }
    __syncthreads();
  }
  if (threadIdx.x == 0) { part[blockIdx.x] = s_on[0]; part[256 + blockIdx.x] = s_off[0]; }
}

__global__ void k_cdcr_fin(const double* __restrict__ part, float* __restrict__ out) {
  __shared__ double s_on[256], s_off[256];
  s_on[threadIdx.x] = part[threadIdx.x];
  s_off[threadIdx.x] = part[256 + threadIdx.x];
  __syncthreads();
  for (int st = 128; st > 0; st >>= 1) {
    if (threadIdx.x < st) { s_on[threadIdx.x] += s_on[threadIdx.x + st]; s_off[threadIdx.x] += s_off[threadIdx.x + st]; }
    __syncthreads();
  }
  if (threadIdx.x == 0) out[0] = (float)(s_on[0] + 0.003 * s_off[0]);
}

__global__ __launch_bounds__(64) void k_mask(const float* __restrict__ capo, float* __restrict__ mask) {
  int pidx = blockIdx.x;
  float s = 0.f;
  for (int i = threadIdx.x; i < 512; i += 64) s += capo[(long)pidx * 512 + i];
#pragma unroll
  for (int o = 32; o > 0; o >>= 1) s += __shfl_down(s, o, 64);
  if (threadIdx.x == 0) mask[pidx] = (s != 0.f) ? 1.f : 0.f;
}

__global__ __launch_bounds__(256) void k_meannc(const float* __restrict__ src, const float* __restrict__ mask,
                                                float* __restrict__ vec) {
  int d = blockIdx.x * 256 + threadIdx.x;
  int b = blockIdx.y;
  float acc = 0.f, ms = 0.f;
  for (int nc = 0; nc < 16; ++nc) {
    float mk = mask ? mask[b * 16 + nc] : 1.f;
    acc += src[((long)b * 16 + nc) * 512 + d] * mk;
    ms += mk;
  }
  vec[(long)b * 512 + d] = acc / fmaxf(ms, 1e-6f);
}

__global__ __launch_bounds__(256) void k_mse(const float* __restrict__ full, const float* __restrict__ vec,
                                             double* __restrict__ part) {
  double loc = 0;
  const long n = NOUT;
  for (long i = (long)blockIdx.x * 256 + threadIdx.x; i < n; i += 256L * 1024) {
    int d = (int)(i & 511);
    int b = (int)(i >> 9) / 196;
    float df = full[i] - vec[b * 512 + d];
    loc += (double)df * (double)df;
  }
  __shared__ double sh[256];
  sh[threadIdx.x] = loc;
  __syncthreads();
  for (int st = 128; st > 0; st >>= 1) {
    if (threadIdx.x < st) sh[threadIdx.x] += sh[threadIdx.x + st];
    __syncthreads();
  }
  if (threadIdx.x == 0) part[blockIdx.x] = sh[0];
}

__global__ void k_finloss(const double* __restrict__ part, float* __restrict__ out) {
  __shared__ double sh[256];
  double s = 0;
  for (int i = threadIdx.x; i < 4096; i += 256) s += part[i];
  sh[threadIdx.x] = s;
  __syncthreads();
  for (int st = 128; st > 0; st >>= 1) {
    if (threadIdx.x < st) sh[threadIdx.x] += sh[threadIdx.x + st];
    __syncthreads();
  }
  if (threadIdx.x == 0) out[0] = (float)(sh[0] / (64.0 * 196.0 * 512.0));
}

__global__ __launch_bounds__(256) void k_concat2(float* __restrict__ dst, const float* __restrict__ a,
                                                 const float* __restrict__ b) {
  int i = blockIdx.x * 256 + threadIdx.x;   // 64*1024
  int col = i & 1023, row = i >> 10;
  dst[i] = (col < 512) ? a[row * 512 + col] : b[row * 512 + col - 512];
}

// three stacked 64-row concats: dst[192,1024]
__global__ __launch_bounds__(256) void k_concat6(
    float* __restrict__ dst,
    const float* __restrict__ a0, const float* __restrict__ b0,
    const float* __restrict__ a1, const float* __restrict__ b1,
    const float* __restrict__ a2, const float* __restrict__ b2) {
  int i = blockIdx.x * 256 + threadIdx.x;   // 192*1024
  int col = i & 1023, row = i >> 10;
  int grp = row >> 6, r = row & 63;
  const float* a = grp == 0 ? a0 : (grp == 1 ? a1 : a2);
  const float* b = grp == 0 ? b0 : (grp == 1 ? b1 : b2);
  dst[i] = (col < 512) ? a[r * 512 + col] : b[r * 512 + col - 512];
}

// comb: [BS,2048] bf16 into dst (short*)
__global__ __launch_bounds__(256) void k_comb_bf(
    short* __restrict__ dst, const float* __restrict__ d1, const float* __restrict__ d2,
    const float* __restrict__ txt, const float* __restrict__ al) {
  long i = (long)blockIdx.x * 256 + threadIdx.x;  // BS*2048
  int col = (int)(i & 2047);
  long m = i >> 11;
  int b = (int)(m / 196);
  float v;
  if (col < 512)       v = d1[m * 512 + col];
  else if (col < 1024) v = d2[m * 512 + col - 512];
  else if (col < 1536) v = txt[(long)b * 512 + col - 1024];
  else                 v = al[(long)b * 512 + col - 1536];
  dst[i] = f2bf(v);
}

// ---------------- host ----------------
extern "C" void kernel_launch(void* const* d_in, const int* in_sizes, int n_in,
                              void* d_out, int out_size, void* d_ws, size_t ws_size,
                              hipStream_t stream) {
  (void)in_sizes; (void)n_in; (void)out_size; (void)ws_size;
  const float* in1    = (const float*)d_in[0];
  const float* in2    = (const float*)d_in[1];
  const float* cap1   = (const float*)d_in[2];
  const float* cap2   = (const float*)d_in[3];
  const float* imgw   = (const float*)d_in[4];
  const float* imgb   = (const float*)d_in[5];
  const float* wemb   = (const float*)d_in[6];
  const float* hemb   = (const float*)d_in[7];
  const float* mlpw1  = (const float*)d_in[8];
  const float* mlpb1  = (const float*)d_in[9];
  const float* mlpw2  = (const float*)d_in[10];
  const float* mlpb2  = (const float*)d_in[11];
  const float* fcw    = (const float*)d_in[12];
  const float* fcb    = (const float*)d_in[13];
  const float* efcw   = (const float*)d_in[14];
  const float* efcb   = (const float*)d_in[15];
  const float* efc2w  = (const float*)d_in[16];
  const float* efc2b  = (const float*)d_in[17];
  const float* trinw  = (const float*)d_in[18];
  const float* trinb  = (const float*)d_in[19];
  const float* troutw = (const float*)d_in[20];
  const float* troutb = (const float*)d_in[21];
  const float* trlng  = (const float*)d_in[22];
  const float* trlnb  = (const float*)d_in[23];
  const float* itqw = (const float*)d_in[24]; const float* itqb = (const float*)d_in[25];
  const float* itkw = (const float*)d_in[26]; const float* itkb = (const float*)d_in[27];
  const float* itvw = (const float*)d_in[28]; const float* itvb = (const float*)d_in[29];
  const float* caqw = (const float*)d_in[30]; const float* caqb = (const float*)d_in[31];
  const float* cakw = (const float*)d_in[32]; const float* cakb = (const float*)d_in[33];
  const float* cavw = (const float*)d_in[34]; const float* cavb = (const float*)d_in[35];
  const float* saqw = (const float*)d_in[36]; const float* saqb = (const float*)d_in[37];
  const float* sakw = (const float*)d_in[38]; const float* sakb = (const float*)d_in[39];
  const float* savw = (const float*)d_in[40]; const float* savb = (const float*)d_in[41];

  float* out = (float*)d_out;

  // ---- workspace carve ----
  const size_t SZ = (size_t)BS * 512;        // 6,422,528 floats (24.5 MB)
  const int64_t SZl = (int64_t)SZ;
  float* w = (float*)d_ws;
  auto alloc = [&](size_t n) { float* p = w; w += n; return p; };
  float* h1 = alloc(SZ);
  float* h2 = alloc(SZ);       // h1..tB = 4 contiguous SZ
  float* tA = alloc(SZ);
  float* tB = alloc(SZ);
  float* tC = alloc(SZ);
  float* tD = alloc(SZ);       // tA..tD = 4 contiguous SZ
  float* sbuf = alloc(SZ);     // scores / bf16 attn-out scratch
  float* cap1o = alloc(64 * 16 * 512);
  float* cap2o = alloc(64 * 16 * 512);   // contiguous with cap1o
  float* qc1   = alloc(64 * 16 * 512);
  float* qc2   = alloc(64 * 16 * 512);   // contiguous with qc1
  float* attb  = alloc(64 * 16 * 512);
  float* attb2 = alloc(64 * 16 * 512);   // contiguous with attb
  float* cmat  = alloc(512 * 512);
  float* colsum1 = alloc(512); float* colsq1 = alloc(512);
  float* colsum2 = alloc(512); float* colsq2 = alloc(512);
  float* mean1 = alloc(512); float* istd1 = alloc(512);
  float* mean2 = alloc(512); float* istd2 = alloc(512);
  float* mask1 = alloc(1024); float* mask2 = alloc(1024);
  float* vdbef = alloc(64 * 512); float* vdaft = alloc(64 * 512);
  float* vsbef = alloc(64 * 512); float* vsaft = alloc(64 * 512);
  float* cm1 = alloc(64 * 512); float* cm2 = alloc(64 * 512);
  float* vdyn = alloc(64 * 512); float* vsta = alloc(64 * 512);
  float* vtxt = alloc(64 * 512); float* valign = alloc(64 * 512);  // vdyn..vtxt contiguous (M=192 out)
  float* ccat = alloc(192 * 1024);
  double* msepart = (double*)alloc(4096 * 2);   // 4096 doubles
  double* cdcrpart = (double*)alloc(1024);      // 512 doubles
  float* itkvw = alloc(1024 * 512); float* itkvb = alloc(1024);
  float* cakvw = alloc(1024 * 512); float* cakvb = alloc(1024);
  float* sakvw = alloc(1024 * 512); float* sakvb = alloc(1024);
  float* x1 = alloc(2 * SZ);   // [x1;x2] contiguous (embed result)
  float* x2 = x1 + SZ;

  // GEMM router: 128^2 tile for big grids, 64^2 (bnt) for small grids.
  auto gemm = [&](const float* Aa, const float* Ww, const float* bb, float* Cc,
                  int M, int N, int K, int relu) {
    long g128 = ((M % 128) == 0 && (N % 128) == 0) ? (long)(N / 128) * (M / 128) : 0;
    if (g128 >= 784 && (K % 32) == 0)
      k_mfma_nt<<<dim3(N / 128, M / 128), 256, 0, stream>>>(Aa, Ww, bb, Cc, M, N, K, relu, 0);
    else
      k_mfma_bnt<<<dim3(N / 64, (M + 63) / 64, 1), 256, 0, stream>>>(
          Aa, Ww, Cc, M, N, K, K, K, N, 1,
          0, 0, 0, 0, 0, 0, 1.0f, 0, bb, relu);
  };
  const int64_t RB = (int64_t)SS * 512;   // 100352
  const int64_t QB = 16 * 512;            // 8192
  // Batched attention, D=512 single-head, K|V packed [*,1024], zq Q-variants.
  auto attn512 = [&](const float* Qp, int64_t qZ1, int64_t qZ2,
                     const float* KVp, int64_t kvZ1, int64_t kvZ2,
                     float* Op, int64_t oZ1, int64_t oZ2, int M, int zq, float scale) {
    int mt = (M + 63) / 64;
    int64_t sS2 = (int64_t)M * SLD;
    int64_t sS1 = 64 * sS2;
    k_mfma_bnt<<<dim3(4, mt, 64 * zq), 256, 0, stream>>>(
        Qp, KVp, sbuf, M, 196, 512, 512, 1024, SLD, 64,
        qZ1, qZ2, kvZ1, kvZ2, sS1, sS2, scale, 1, nullptr, 0);
    k_softmax_rows<<<(64 * zq * M + 3) / 4, 256, 0, stream>>>(sbuf, 64 * zq * M);
    k_mfma_bnn<<<dim3(8, mt, 64 * zq), 256, 0, stream>>>(
        sbuf, KVp + 512, Op, M, 512, SLD, 196, SLD, 1024, 512, 64,
        sS1, sS2, kvZ1, kvZ2, oZ1, oZ2);
  };
  auto efcM = [&](const float* Aa, float* Cc, int M) {
    k_mfma_bnt<<<dim3(8, (M + 63) / 64, 1), 256, 0, stream>>>(
        Aa, efcw, Cc, M, 512, 1024, 1024, 1024, 512, 1,
        0, 0, 0, 0, 0, 0, 1.0f, 0, efcb, 1);
  };

  const float scalE = 1.0f / sqrtf(512.0f);

  // ---- Phase 0: build concat K|V weights for itda/ca/sa ----
  k_catkv<<<2048, 256, 0, stream>>>(itkvw, itkw, itvw, itkvb, itkb, itvb);
  k_catkv<<<2048, 256, 0, stream>>>(cakvw, cakw, cavw, cakvb, cakb, cavb);
  k_catkv<<<2048, 256, 0, stream>>>(sakvw, sakw, savw, sakvb, sakb, savb);

  // ---- Phase 1: embed -> x + caption projections ----
  k_mfma_embed<<<dim3(4, BS / 128, 2), 256, 0, stream>>>(
      in1, in2, imgw, imgb, wemb, hemb, x1, x2);
  gemm(cap1, fcw, fcb, cap1o, 1024, 512, 768, 0);
  gemm(cap2, fcw, fcb, cap2o, 1024, 512, 768, 0);
  k_meannc<<<dim3(2, 64), 256, 0, stream>>>(cap1o, nullptr, cm1);
  k_meannc<<<dim3(2, 64), 256, 0, stream>>>(cap2o, nullptr, cm2);

  // ---- Phase 2: CDCR loss (fused M=2BS MLP; hidden bf16 in tA..tD, f in h1..h2) ----
  k_mfma_nt<<<dim3(16, 196), 256, 0, stream>>>(x1, mlpw1, mlpb1, tA, 2 * BS, 2048, 512, 1, 1);
  k_mfma_bnt_abf<<<dim3(8, 392), 256, 0, stream>>>(
      (const short*)tA, mlpw2, h1, 2 * BS, 512, 2048, 2048, 2048, 512, mlpb2, 0);
  k_zero<<<8, 256, 0, stream>>>(colsum1, 2048);  // colsum1..colsq2 contiguous
  k_colstats<<<dim3(16, 49), 256, 0, stream>>>(h1, colsum1, colsq1);
  k_colstats<<<dim3(16, 49), 256, 0, stream>>>(h2, colsum2, colsq2);
  k_finstats<<<2, 256, 0, stream>>>(colsum1, colsq1, mean1, istd1);
  k_finstats<<<2, 256, 0, stream>>>(colsum2, colsq2, mean2, istd2);
  k_znorm<<<25088, 256, 0, stream>>>(h1, mean1, istd1);
  k_znorm<<<25088, 256, 0, stream>>>(h2, mean2, istd2);
  k_zero<<<1024, 256, 0, stream>>>(cmat, 262144);
  k_mfma_corr<<<dim3(8, 8, 14), 256, 0, stream>>>(h1, h2, cmat, BS / 14, 1.0f / (float)BS);
  k_cdcr_part<<<256, 256, 0, stream>>>(cmat, cdcrpart);
  k_cdcr_fin<<<1, 256, 0, stream>>>(cdcrpart, out + NOUT);

  // ---- Phase 3: cross-transformer (fused q, kv, fmha, o-proj, addln) ----
  for (int l = 0; l < 2; ++l) {
    const float* Wq = trinw + (size_t)l * 1536 * 512;
    const float* Wkv = Wq + 512 * 512;               // [Wk;Wv] 1024 rows
    const float* bq = trinb + l * 1536;
    const float* bkv = bq + 512;                     // [bk|bv] 1024
    const float* Wo = troutw + (size_t)l * 512 * 512;
    const float* bo = troutb + l * 512;
    const float* g  = trlng + l * 512;
    const float* be = trlnb + l * 512;
    const float* s1 = l ? h1 : x1;                   // [s1;s2] contiguous both layers
    // q1|q2 bf16 -> tA (1 SZ)
    k_mfma_nt<<<dim3(4, 196), 256, 0, stream>>>(s1, Wq, bq, tA, 2 * BS, 512, 512, 0, 1);
    // [KV(s1);KV(s2)] bf16 -> tC..tD (2 SZ)
    k_mfma_nt<<<dim3(8, 196), 256, 0, stream>>>(s1, Wkv, bkv, tC, 2 * BS, 1024, 512, 0, 1);
    // fused fmha: z=0 (q1, KV(s2)=part1), z=1 (q2, KV(s1)=part0); out bf16 -> sbuf
    k_fmha_bf2<<<dim3(64, 8, 2), 256, 0, stream>>>(
        (const short*)tA, (const short*)tC + (size_t)BS * 1024, (const short*)tC,
        (short*)sbuf);
    // fused o-proj M=2BS -> tB..tC fp32 (overwrites consumed KV part0)
    k_mfma_bnt_abf<<<dim3(8, 392), 256, 0, stream>>>(
        (const short*)sbuf, Wo, tB, 2 * BS, 512, 512, 512, 512, 512, bo, 0);
    // fused addln: [h1;h2] = LN([s1;s2] + [o1;o2])
    k_addln2<<<2 * BS, 256, 0, stream>>>(h1, s1, tB, g, be);
  }

  // ---- Phase 4: diffs ----
  k_diff<<<12544, 256, 0, stream>>>(tC, x1, h1);   // [tC;tD] = [x1;x2]-[h1;h2]
  // h1..tB, x1..x2 now free

  // ---- Phase 5: ITDA (fused itq, fused KV M=2BS, z=128 batched attention) ----
  gemm(cap1o, itqw, itqb, qc1, 2048, 512, 512, 0);  // qc1|qc2
  k_mask<<<1024, 64, 0, stream>>>(cap1o, mask1);
  k_mask<<<1024, 64, 0, stream>>>(cap2o, mask2);
  gemm(tC, itkvw, itkvb, h1, 2 * BS, 1024, 512, 0); // [KV1;KV2] fp32 -> h1..tB (4 SZ)
  // KV1 (diff1): z1=0 (qc1 -> s_bef), z1=1 (qc2 -> d_bef)
  attn512(qc1, 524288, QB, h1, 0, 2 * RB, attb, 524288, QB, 16, 2, scalE);
  k_meannc<<<dim3(2, 64), 256, 0, stream>>>(attb,  mask1, vsbef);
  k_meannc<<<dim3(2, 64), 256, 0, stream>>>(attb2, mask2, vdbef);
  // KV2 (diff2): z1=0 (qc1 -> d_aft), z1=1 (qc2 -> s_aft)
  attn512(qc1, 524288, QB, h1 + 2 * SZ, 0, 2 * RB, attb, 524288, QB, 16, 2, scalE);
  k_meannc<<<dim3(2, 64), 256, 0, stream>>>(attb,  mask1, vdaft);
  k_meannc<<<dim3(2, 64), 256, 0, stream>>>(attb2, mask2, vsaft);

  // ---- Phase 6: ECA pairs batched (z=128) with immediate MSE ----
  // pair(qw,qb,kvw,kvb, kvbase_z0_offset, kvZ1, vec0, part0, vec1, part1)
  auto eca_pair = [&](const float* qw2, const float* qb2,
                      const float* kvw2, const float* kvb2,
                      const float* kvbase, int64_t kvZ1,
                      const float* vec0, double* part0,
                      const float* vec1, double* part1) {
    gemm(tC, qw2, qb2, x1, 2 * BS, 512, 512, 0);      // Q[diff1;diff2] -> x1..x2
    gemm(tC, kvw2, kvb2, h1, 2 * BS, 1024, 512, 0);   // KV[diff1;diff2] -> h1..tB
    attn512(x1, SZl, RB, kvbase, kvZ1, 2 * RB, x1, SZl, RB, 196, 2, scalE);
    k_mse<<<1024, 256, 0, stream>>>(x1, vec0, part0);
    k_mse<<<1024, 256, 0, stream>>>(x1 + SZ, vec1, part1);
  };
  // ca: z1=0 c12 (Q=diff1, KV=diff2 -> base h1+2SZ, stride -2SZ); z1=1 c21
  eca_pair(caqw, caqb, cakvw, cakvb, h1 + 2 * SZ, -2 * SZl,
           vdbef, msepart, vdaft, msepart + 1024);
  // sa: z1=0 s11 (Q=diff1, KV=diff1 -> base h1, stride +2SZ); z1=1 s22
  eca_pair(saqw, saqb, sakvw, sakvb, h1, 2 * SZl,
           vsbef, msepart + 2048, vsaft, msepart + 3072);
  k_finloss<<<1, 256, 0, stream>>>(msepart, out + NOUT + 1);

  // ---- Phase 7: efc chain (vdyn,vsta,vtxt batched M=192; then valign) ----
  k_concat6<<<768, 256, 0, stream>>>(ccat, vdbef, vdaft, vsbef, vsaft, cm1, cm2);
  efcM(ccat, vdyn, 192);                      // -> vdyn,vsta,vtxt (contiguous)
  k_concat2<<<256, 256, 0, stream>>>(ccat, vdyn, vsta);
  efcM(ccat, valign, 64);

  // ---- Phase 8: comb as bf16 into h1..h2, single bf16-A GEMM ----
  k_comb_bf<<<100352, 256, 0, stream>>>((short*)h1, tC, tD, vtxt, valign);
  k_mfma_bnt_abf<<<dim3(8, 196), 256, 0, stream>>>(
      (const short*)h1, efc2w, out, BS, 512, 2048, 2048, 2048, 512, efc2b, 1);
}

// Round 10
// 2150.277 us; speedup vs baseline: 1.7705x; 1.0125x over previous
//
#include <hip/hip_runtime.h>
#include <hip/hip_bf16.h>
#include <stdint.h>
#include <math.h>

// Problem constants
#define BB   64
#define SS   196
#define BS   12544            // BB*SS
#define NOUT 6422528L         // BS*512
#define SLD  224              // score row ld (7*32)

typedef __attribute__((ext_vector_type(8))) short bf16x8;
typedef __attribute__((ext_vector_type(4))) float f32x4;

// ---------------- device helpers ----------------
__device__ __forceinline__ float block_red256(float v, float* red, bool ismax) {
#pragma unroll
  for (int o = 32; o > 0; o >>= 1) {
    float t = __shfl_down(v, o, 64);
    v = ismax ? fmaxf(v, t) : v + t;
  }
  int lane = threadIdx.x & 63, wid = threadIdx.x >> 6;
  if (lane == 0) red[wid] = v;
  __syncthreads();
  float r = ismax ? fmaxf(fmaxf(red[0], red[1]), fmaxf(red[2], red[3]))
                  : (red[0] + red[1]) + (red[2] + red[3]);
  __syncthreads();
  return r;
}

// HW RNE conversion — bit-identical to the add-0x7fff bit-trick.
__device__ __forceinline__ short f2bf(float f) {
  __hip_bfloat16 h = __float2bfloat16(f);
  short s;
  __builtin_memcpy(&s, &h, 2);
  return s;
}

__device__ __forceinline__ void cvt8(short* dst, float4 a, float4 b) {
  union { short s[8]; int4 v; } u;
  u.s[0] = f2bf(a.x); u.s[1] = f2bf(a.y); u.s[2] = f2bf(a.z); u.s[3] = f2bf(a.w);
  u.s[4] = f2bf(b.x); u.s[5] = f2bf(b.y); u.s[6] = f2bf(b.z); u.s[7] = f2bf(b.w);
  *(int4*)dst = u.v;
}

// Raw barrier: ds ops drained, global loads stay in flight (no vmcnt drain).
__device__ __forceinline__ void lds_barrier() {
  asm volatile("s_waitcnt lgkmcnt(0)" ::: "memory");
  __builtin_amdgcn_s_barrier();
  __builtin_amdgcn_sched_barrier(0);
}

// Bijective XCD-chunked swizzle (m204).
__device__ __forceinline__ int xcd_swizzle(int flat, int nwg) {
  int q = nwg >> 3, r = nwg & 7;
  int xcd = flat & 7, pos = flat >> 3;
  return (xcd < r ? xcd * (q + 1) : r * (q + 1) + (xcd - r) * q) + pos;
}

// ---- bf16 MFMA GEMM: C[M,N] = A[M,K] @ W[N,K]^T + bias (opt relu, opt bf16 out) ----
// 128x128 tile, BK=32, 4 waves (2x2). 2-phase pipeline + XCD swizzle.
// obf epilogue stages tile in LDS -> int4 stores (full 64B sectors, no RMW fetch).
__global__ __launch_bounds__(256) void k_mfma_nt(
    const float* __restrict__ A, const float* __restrict__ W,
    const float* __restrict__ bias, float* __restrict__ C,
    int M, int N, int K, int relu, int obf) {
  __shared__ short As[2][128][40];
  __shared__ short Bs[2][128][40];
  const int tid = threadIdx.x;
  const int lane = tid & 63, wave = tid >> 6;
  const int wm = wave >> 1, wn = wave & 1;
  const int NX = gridDim.x;
  const int wg = xcd_swizzle(blockIdx.y * NX + blockIdx.x, NX * gridDim.y);
  const int m0 = (wg / NX) * 128, n0 = (wg % NX) * 128;
  const int srow = tid >> 1, skh = (tid & 1) * 16;
  const float* Ap = A + (long)(m0 + srow) * K + skh;
  const float* Wp = W + (long)(n0 + srow) * K + skh;
  const int fr = lane & 15, fq = lane >> 4;
  const int NK = K >> 5;
  f32x4 acc[4][4] = {};
  float4 xa[4], xw[4], ya[4], yw[4];

  auto ldt = [&](float4 (&ta)[4], float4 (&tw)[4], int t) {
    const float* ap = Ap + t * 32;
    const float* wp = Wp + t * 32;
#pragma unroll
    for (int i = 0; i < 4; ++i) {
      ta[i] = *(const float4*)(ap + i * 4);
      tw[i] = *(const float4*)(wp + i * 4);
    }
  };
  auto stage = [&](float4 (&ta)[4], float4 (&tw)[4], int p) {
    cvt8(&As[p][srow][skh], ta[0], ta[1]);
    cvt8(&As[p][srow][skh + 8], ta[2], ta[3]);
    cvt8(&Bs[p][srow][skh], tw[0], tw[1]);
    cvt8(&Bs[p][srow][skh + 8], tw[2], tw[3]);
  };
  auto step = [&](int t, float4 (&la)[4], float4 (&lw)[4],
                  float4 (&ca)[4], float4 (&cw)[4]) {
    const int par = t & 1;
    if (t + 2 < NK) ldt(la, lw, t + 2);            // prefetch tile t+2
    bf16x8 af[4], bfr[4];
#pragma unroll
    for (int i = 0; i < 4; ++i) af[i] = *(const bf16x8*)&As[par][wm * 64 + i * 16 + fr][fq * 8];
#pragma unroll
    for (int j = 0; j < 4; ++j) bfr[j] = *(const bf16x8*)&Bs[par][wn * 64 + j * 16 + fr][fq * 8];
    if (t + 1 < NK) stage(ca, cw, par ^ 1);        // stage tile t+1
#pragma unroll
    for (int i = 0; i < 4; ++i)
#pragma unroll
      for (int j = 0; j < 4; ++j)
        acc[i][j] = __builtin_amdgcn_mfma_f32_16x16x32_bf16(af[i], bfr[j], acc[i][j], 0, 0, 0);
    lds_barrier();
  };

  ldt(xa, xw, 0);
  stage(xa, xw, 0);
  if (NK > 1) ldt(xa, xw, 1);
  lds_barrier();
  int t = 0;
  for (; t + 1 < NK; t += 2) { step(t, ya, yw, xa, xw); step(t + 1, xa, xw, ya, yw); }
  if (t < NK) step(t, ya, yw, xa, xw);

  if (obf) {
    // stage bf16 tile in LDS: rows 0..63 in As, 64..127 in Bs, ld=132 shorts
    short* baseA = &As[0][0][0];
    short* baseB = &Bs[0][0][0];
#pragma unroll
    for (int i = 0; i < 4; ++i) {
      int row = wm * 64 + i * 16 + fq * 4;
#pragma unroll
      for (int j = 0; j < 4; ++j) {
        int c = wn * 64 + j * 16 + fr;
        float bz = bias[n0 + c];
#pragma unroll
        for (int r2 = 0; r2 < 4; ++r2) {
          float v = acc[i][j][r2] + bz;
          if (relu) v = fmaxf(v, 0.f);
          int r = row + r2;
          short* ct = (r < 64) ? baseA + r * 132 : baseB + (r - 64) * 132;
          ct[c] = f2bf(v);
        }
      }
    }
    __syncthreads();
    short* Cs = (short*)C;
#pragma unroll
    for (int k = 0; k < 8; ++k) {
      int idx = tid + 256 * k;
      int row = idx >> 4, g = idx & 15;
      short* ct = (row < 64) ? baseA + row * 132 : baseB + (row - 64) * 132;
      *(int4*)(Cs + (long)(m0 + row) * N + n0 + g * 8) = *(const int4*)(ct + g * 8);
    }
  } else {
#pragma unroll
    for (int i = 0; i < 4; ++i) {
      int mB = m0 + wm * 64 + i * 16 + fq * 4;
#pragma unroll
      for (int j = 0; j < 4; ++j) {
        int n = n0 + wn * 64 + j * 16 + fr;
        float bz = bias[n];
#pragma unroll
        for (int r2 = 0; r2 < 4; ++r2) {
          float v = acc[i][j][r2] + bz;
          if (relu) v = fmaxf(v, 0.f);
          C[(long)(mB + r2) * N + n] = v;
        }
      }
    }
  }
}

// ---- bf16 MFMA embed (z=2 fused): C = X@W^T + bias + pe ----
__global__ __launch_bounds__(256) void k_mfma_embed(
    const float* __restrict__ X1, const float* __restrict__ X2,  // [B,1024,196]
    const float* __restrict__ W,   // [512,1024]
    const float* __restrict__ bias,
    const float* __restrict__ wemb, const float* __restrict__ hemb,
    float* __restrict__ C1, float* __restrict__ C2) {
  __shared__ short As[2][128][40];
  __shared__ short Bs[2][128][40];
  const float* X = blockIdx.z ? X2 : X1;
  float* C = blockIdx.z ? C2 : C1;
  const int tid = threadIdx.x;
  const int lane = tid & 63, wave = tid >> 6;
  const int wm = wave >> 1, wn = wave & 1;
  const int NX = gridDim.x;
  const int wg = xcd_swizzle(blockIdx.y * NX + blockIdx.x, NX * gridDim.y);
  const int m0 = (wg / NX) * 128, n0 = (wg % NX) * 128;
  const int K = 1024, N = 512;
  const int srow = tid >> 1, skh = (tid & 1) * 16;
  const float* Wp = W + (long)(n0 + srow) * K + skh;
  const int arow = tid & 127, khalf = tid >> 7;
  const int am = m0 + arow;
  const int ab = am / 196, as_ = am % 196;
  const float* Xp = X + (long)ab * 200704 + as_;
  const int fr = lane & 15, fq = lane >> 4;
  const int NK = K >> 5;   // 32
  f32x4 acc[4][4] = {};
  float xx[16], yx[16];
  float4 xw[4], yw[4];

  auto ldt = [&](float (&tx)[16], float4 (&tw)[4], int t) {
    const int kb = t * 32 + khalf * 16;
#pragma unroll
    for (int i = 0; i < 16; ++i) tx[i] = Xp[(long)(kb + i) * 196];
    const float* wp = Wp + t * 32;
#pragma unroll
    for (int i = 0; i < 4; ++i) tw[i] = *(const float4*)(wp + i * 4);
  };
  auto stage = [&](float (&tx)[16], float4 (&tw)[4], int p) {
    union { short s[16]; int4 v[2]; } u;
#pragma unroll
    for (int i = 0; i < 16; ++i) u.s[i] = f2bf(tx[i]);
    int4* dst = (int4*)&As[p][arow][khalf * 16];
    dst[0] = u.v[0]; dst[1] = u.v[1];
    cvt8(&Bs[p][srow][skh], tw[0], tw[1]);
    cvt8(&Bs[p][srow][skh + 8], tw[2], tw[3]);
  };
  auto step = [&](int t, float (&lx)[16], float4 (&lw)[4],
                  float (&cx)[16], float4 (&cw)[4]) {
    const int par = t & 1;
    if (t + 2 < NK) ldt(lx, lw, t + 2);
    bf16x8 af[4], bfr[4];
#pragma unroll
    for (int i = 0; i < 4; ++i) af[i] = *(const bf16x8*)&As[par][wm * 64 + i * 16 + fr][fq * 8];
#pragma unroll
    for (int j = 0; j < 4; ++j) bfr[j] = *(const bf16x8*)&Bs[par][wn * 64 + j * 16 + fr][fq * 8];
    if (t + 1 < NK) stage(cx, cw, par ^ 1);
#pragma unroll
    for (int i = 0; i < 4; ++i)
#pragma unroll
      for (int j = 0; j < 4; ++j)
        acc[i][j] = __builtin_amdgcn_mfma_f32_16x16x32_bf16(af[i], bfr[j], acc[i][j], 0, 0, 0);
    lds_barrier();
  };

  ldt(xx, xw, 0);
  stage(xx, xw, 0);
  if (NK > 1) ldt(xx, xw, 1);
  lds_barrier();
  int t = 0;
  for (; t + 1 < NK; t += 2) { step(t, yx, yw, xx, xw); step(t + 1, xx, xw, yx, yw); }
  if (t < NK) step(t, yx, yw, xx, xw);

#pragma unroll
  for (int i = 0; i < 4; ++i) {
    int mB = m0 + wm * 64 + i * 16 + fq * 4;
#pragma unroll
    for (int j = 0; j < 4; ++j) {
      int n = n0 + wn * 64 + j * 16 + fr;
      float bz = bias[n];
#pragma unroll
      for (int r2 = 0; r2 < 4; ++r2) {
        int m = mB + r2;
        int s = m % 196;
        float pe = (n < 256) ? wemb[(s % 14) * 256 + n] : hemb[(s / 14) * 256 + (n - 256)];
        C[(long)m * N + n] = acc[i][j][r2] + bz + pe;
      }
    }
  }
}

// ---- Fused flash MHA (both dirs in one launch): B=64,H=8,S=196,D=64. ----
// z=0: Q part0, KV=KVd1; z=1: Q part1, KV=KVd2. O bf16 [2BS,512].
__global__ __launch_bounds__(256) void k_fmha_bf2(
    const short* __restrict__ Q, const short* __restrict__ KVd1,
    const short* __restrict__ KVd2, short* __restrict__ O) {
  __shared__ short Vt[64][240];     // V^T bf16 (keys 196..223 zeroed)
  __shared__ short Pt[4][16][40];   // per-wave P staging
  const int tid = threadIdx.x;
  const int lane = tid & 63, wave = tid >> 6;
  const int b = blockIdx.x, h = blockIdx.y, z = blockIdx.z;
  const short* KV = z ? KVd2 : KVd1;
  const long brow = (long)b * 196;
  const size_t zo = (size_t)z * BS * 512;
  const short* Qb = Q + zo + brow * 512 + h * 64;
  const short* Kb = KV + brow * 1024 + h * 64;
  const short* Vb = KV + brow * 1024 + 512 + h * 64;
  short* Ob = O + zo + brow * 512 + h * 64;
  const int fr = lane & 15, fq = lane >> 4;

  for (int i = tid; i < 64 * 32; i += 256) {
    int d = i >> 5, k = 192 + (i & 31);
    if (k >= 196) Vt[d][k] = 0;
  }
  for (int i = tid; i < 196 * 8; i += 256) {
    int s = i >> 3, c8 = (i & 7) * 8;
    bf16x8 v = *(const bf16x8*)(Vb + (long)s * 1024 + c8);
#pragma unroll
    for (int j = 0; j < 8; ++j) Vt[c8 + j][s] = v[j];
  }
  __syncthreads();

  for (int qt = wave; qt < 13; qt += 4) {
    const int q0 = qt * 16;
    const int qr = (q0 + fr < 196) ? q0 + fr : 195;
    const short* qp = Qb + (long)qr * 512 + fq * 8;
    bf16x8 aq0 = *(const bf16x8*)(qp);
    bf16x8 aq1 = *(const bf16x8*)(qp + 32);
    f32x4 sc[13];
#pragma unroll
    for (int t = 0; t < 13; ++t) {
      int kr = (t * 16 + fr < 196) ? t * 16 + fr : 195;
      const short* kp = Kb + (long)kr * 1024 + fq * 8;
      bf16x8 bk0 = *(const bf16x8*)(kp);
      bf16x8 bk1 = *(const bf16x8*)(kp + 32);
      f32x4 zz = {};
      zz = __builtin_amdgcn_mfma_f32_16x16x32_bf16(aq0, bk0, zz, 0, 0, 0);
      zz = __builtin_amdgcn_mfma_f32_16x16x32_bf16(aq1, bk1, zz, 0, 0, 0);
      sc[t] = zz;
    }
#pragma unroll
    for (int t = 0; t < 13; ++t)
#pragma unroll
      for (int r2 = 0; r2 < 4; ++r2) sc[t][r2] *= 0.125f;
    if (fr >= 4) {
#pragma unroll
      for (int r2 = 0; r2 < 4; ++r2) sc[12][r2] = -1e30f;
    }
#pragma unroll
    for (int r2 = 0; r2 < 4; ++r2) {
      float m = sc[0][r2];
#pragma unroll
      for (int t = 1; t < 13; ++t) m = fmaxf(m, sc[t][r2]);
#pragma unroll
      for (int o = 1; o < 16; o <<= 1) m = fmaxf(m, __shfl_xor(m, o, 64));
      float s = 0.f;
#pragma unroll
      for (int t = 0; t < 13; ++t) { float e = expf(sc[t][r2] - m); sc[t][r2] = e; s += e; }
#pragma unroll
      for (int o = 1; o < 16; o <<= 1) s += __shfl_xor(s, o, 64);
      float inv = 1.0f / s;
#pragma unroll
      for (int t = 0; t < 13; ++t) sc[t][r2] *= inv;
    }
    f32x4 acc_o[4] = {};
#pragma unroll
    for (int s7 = 0; s7 < 7; ++s7) {
      const int t0 = 2 * s7, t1 = 2 * s7 + 1;
#pragma unroll
      for (int r2 = 0; r2 < 4; ++r2) {
        Pt[wave][fq * 4 + r2][fr] = f2bf(sc[t0][r2]);
        Pt[wave][fq * 4 + r2][16 + fr] = (t1 < 13) ? f2bf(sc[t1][r2]) : (short)0;
      }
      asm volatile("s_waitcnt lgkmcnt(0)" ::: "memory");
      bf16x8 ap = *(const bf16x8*)&Pt[wave][fr][fq * 8];
#pragma unroll
      for (int dt = 0; dt < 4; ++dt) {
        bf16x8 bv = *(const bf16x8*)&Vt[dt * 16 + fr][32 * s7 + fq * 8];
        acc_o[dt] = __builtin_amdgcn_mfma_f32_16x16x32_bf16(ap, bv, acc_o[dt], 0, 0, 0);
      }
    }
#pragma unroll
    for (int r2 = 0; r2 < 4; ++r2) {
      int qrow = q0 + fq * 4 + r2;
      if (qrow < 196) {
        short* op = Ob + (long)qrow * 512;
#pragma unroll
        for (int dt = 0; dt < 4; ++dt) op[dt * 16 + fr] = f2bf(acc_o[dt][r2]);
      }
    }
  }
}

// ---- Batched bf16 MFMA NT: C[z][m,n] = scale*sum_k A[z][m,k]*B[z][n,k] ----
__global__ __launch_bounds__(256) void k_mfma_bnt(
    const float* __restrict__ A, const float* __restrict__ B, float* __restrict__ C,
    int M, int N, int K, int lda, int ldb, int ldc, int nz2,
    int64_t sA1, int64_t sA2, int64_t sB1, int64_t sB2, int64_t sC1, int64_t sC2,
    float scale, int clampf, const float* __restrict__ bias2, int relu2) {
  __shared__ short As[2][64][40];
  __shared__ short Bs[2][64][40];
  const int tid = threadIdx.x;
  const int lane = tid & 63, wave = tid >> 6;
  const int NX = gridDim.x;
  const int wg = xcd_swizzle(blockIdx.y * NX + blockIdx.x, NX * gridDim.y);
  const int m0 = (wg / NX) * 64, n0 = (wg % NX) * 64;
  const int z = blockIdx.z, z1 = z / nz2, z2 = z % nz2;
  const float* Ab = A + z1 * sA1 + z2 * sA2;
  const float* Bb = B + z1 * sB1 + z2 * sB2;
  float* Cb = C + z1 * sC1 + z2 * sC2;
  const int sr = tid >> 2, skh = (tid & 3) * 8;
  const int ar = (m0 + sr < M) ? m0 + sr : M - 1;
  const int br = (n0 + sr < N) ? n0 + sr : N - 1;
  const float* Ap = Ab + (long)ar * lda + skh;
  const float* Bp = Bb + (long)br * ldb + skh;
  const int fr = lane & 15, fq = lane >> 4;
  const int NK = K >> 5;
  f32x4 acc[4] = {};
  float4 xa[2], xb[2], ya[2], yb[2];

  auto ldt = [&](float4 (&ta)[2], float4 (&tb)[2], int t) {
    const int kb = t * 32;
#pragma unroll
    for (int i = 0; i < 2; ++i) {
      ta[i] = *(const float4*)(Ap + kb + i * 4);
      tb[i] = *(const float4*)(Bp + kb + i * 4);
    }
  };
  auto stage = [&](float4 (&ta)[2], float4 (&tb)[2], int p) {
    cvt8(&As[p][sr][skh], ta[0], ta[1]);
    cvt8(&Bs[p][sr][skh], tb[0], tb[1]);
  };
  auto step = [&](int t, float4 (&la)[2], float4 (&lb)[2],
                  float4 (&ca)[2], float4 (&cb)[2]) {
    const int par = t & 1;
    if (t + 2 < NK) ldt(la, lb, t + 2);
    bf16x8 bfr = *(const bf16x8*)&Bs[par][wave * 16 + fr][fq * 8];
    bf16x8 af[4];
#pragma unroll
    for (int i = 0; i < 4; ++i) af[i] = *(const bf16x8*)&As[par][i * 16 + fr][fq * 8];
    if (t + 1 < NK) stage(ca, cb, par ^ 1);
#pragma unroll
    for (int i = 0; i < 4; ++i)
      acc[i] = __builtin_amdgcn_mfma_f32_16x16x32_bf16(af[i], bfr, acc[i], 0, 0, 0);
    lds_barrier();
  };

  ldt(xa, xb, 0);
  stage(xa, xb, 0);
  if (NK > 1) ldt(xa, xb, 1);
  lds_barrier();
  int t = 0;
  for (; t + 1 < NK; t += 2) { step(t, ya, yb, xa, xb); step(t + 1, xa, xb, ya, yb); }
  if (t < NK) step(t, ya, yb, xa, xb);

  const int n = n0 + wave * 16 + fr;
  if (n < N) {
    float bz = bias2 ? bias2[n] : 0.f;
#pragma unroll
    for (int i = 0; i < 4; ++i) {
      int mb = m0 + i * 16 + fq * 4;
#pragma unroll
      for (int r2 = 0; r2 < 4; ++r2) {
        int m = mb + r2;
        if (m < M) {
          float v = acc[i][r2] * scale + bz;
          if (relu2) v = fmaxf(v, 0.f);
          if (clampf) v = fminf(fmaxf(v, -100.f), 100.f);
          Cb[(long)m * ldc + n] = v;
        }
      }
    }
  }
}

// ---- NT GEMM with bf16 A-input: C[m,n] = sum_k A[m,k]*B[n,k] + bias (opt relu) ----
__global__ __launch_bounds__(256) void k_mfma_bnt_abf(
    const short* __restrict__ A, const float* __restrict__ B, float* __restrict__ C,
    int M, int N, int K, int lda, int ldb, int ldc,
    const float* __restrict__ bias2, int relu2) {
  __shared__ short As[2][64][40];
  __shared__ short Bs[2][64][40];
  const int tid = threadIdx.x;
  const int lane = tid & 63, wave = tid >> 6;
  const int NX = gridDim.x;
  const int wg = xcd_swizzle(blockIdx.y * NX + blockIdx.x, NX * gridDim.y);
  const int m0 = (wg / NX) * 64, n0 = (wg % NX) * 64;
  const int sr = tid >> 2, skh = (tid & 3) * 8;
  const int ar = (m0 + sr < M) ? m0 + sr : M - 1;
  const int br = (n0 + sr < N) ? n0 + sr : N - 1;
  const short* Ap = A + (long)ar * lda + skh;
  const float* Bp = B + (long)br * ldb + skh;
  const int fr = lane & 15, fq = lane >> 4;
  const int NK = K >> 5;
  f32x4 acc[4] = {};
  int4 xa, ya;
  float4 xb[2], yb[2];

  auto ldt = [&](int4& ta, float4 (&tb)[2], int t) {
    const int kb = t * 32;
    ta = *(const int4*)(Ap + kb);
#pragma unroll
    for (int i = 0; i < 2; ++i) tb[i] = *(const float4*)(Bp + kb + i * 4);
  };
  auto stage = [&](int4& ta, float4 (&tb)[2], int p) {
    *(int4*)&As[p][sr][skh] = ta;
    cvt8(&Bs[p][sr][skh], tb[0], tb[1]);
  };
  auto step = [&](int t, int4& la, float4 (&lb)[2], int4& ca, float4 (&cb)[2]) {
    const int par = t & 1;
    if (t + 2 < NK) ldt(la, lb, t + 2);
    bf16x8 bfr = *(const bf16x8*)&Bs[par][wave * 16 + fr][fq * 8];
    bf16x8 af[4];
#pragma unroll
    for (int i = 0; i < 4; ++i) af[i] = *(const bf16x8*)&As[par][i * 16 + fr][fq * 8];
    if (t + 1 < NK) stage(ca, cb, par ^ 1);
#pragma unroll
    for (int i = 0; i < 4; ++i)
      acc[i] = __builtin_amdgcn_mfma_f32_16x16x32_bf16(af[i], bfr, acc[i], 0, 0, 0);
    lds_barrier();
  };

  ldt(xa, xb, 0);
  stage(xa, xb, 0);
  if (NK > 1) ldt(xa, xb, 1);
  lds_barrier();
  int t = 0;
  for (; t + 1 < NK; t += 2) { step(t, ya, yb, xa, xb); step(t + 1, xa, xb, ya, yb); }
  if (t < NK) step(t, ya, yb, xa, xb);

  const int n = n0 + wave * 16 + fr;
  if (n < N) {
    float bz = bias2 ? bias2[n] : 0.f;
#pragma unroll
    for (int i = 0; i < 4; ++i) {
      int mb = m0 + i * 16 + fq * 4;
#pragma unroll
      for (int r2 = 0; r2 < 4; ++r2) {
        int m = mb + r2;
        if (m < M) {
          float v = acc[i][r2] + bz;
          if (relu2) v = fmaxf(v, 0.f);
          C[(long)m * ldc + n] = v;
        }
      }
    }
  }
}

// ---- Batched bf16 MFMA NN: C[z][m,n] = sum_k A[z][m,k]*B[z][k,n] ----
__global__ __launch_bounds__(256) void k_mfma_bnn(
    const float* __restrict__ A, const float* __restrict__ B, float* __restrict__ C,
    int M, int N, int K, int KBvalid, int lda, int ldb, int ldc, int nz2,
    int64_t sA1, int64_t sA2, int64_t sB1, int64_t sB2, int64_t sC1, int64_t sC2) {
  __shared__ short As[2][64][40];
  __shared__ short Bs[2][64][40];
  const int tid = threadIdx.x;
  const int lane = tid & 63, wave = tid >> 6;
  const int m0 = blockIdx.y * 64, n0 = blockIdx.x * 64;
  const int z = blockIdx.z, z1 = z / nz2, z2 = z % nz2;
  const float* Ab = A + z1 * sA1 + z2 * sA2;
  const float* Bb = B + z1 * sB1 + z2 * sB2;
  float* Cb = C + z1 * sC1 + z2 * sC2;
  const int sr = tid >> 2, skh = (tid & 3) * 8;
  const int ar = (m0 + sr < M) ? m0 + sr : M - 1;
  const float* Ap = Ab + (long)ar * lda + skh;
  const int bk = tid >> 3, bn = (tid & 7) * 8;   // B transposed staging
  const int fr = lane & 15, fq = lane >> 4;
  const int NK = K >> 5;
  f32x4 acc[4] = {};
  float4 xa[2], xb[2], ya[2], yb[2];

  auto ldt = [&](float4 (&ta)[2], float4 (&tb)[2], int t) {
    const int kb = t * 32;
#pragma unroll
    for (int i = 0; i < 2; ++i) ta[i] = *(const float4*)(Ap + kb + i * 4);
    int kc = kb + bk;
    if (kc >= KBvalid) kc = KBvalid - 1;
    const float* bp = Bb + (long)kc * ldb + n0 + bn;
#pragma unroll
    for (int i = 0; i < 2; ++i) tb[i] = *(const float4*)(bp + i * 4);
  };
  auto stage = [&](float4 (&ta)[2], float4 (&tb)[2], int p) {
    cvt8(&As[p][sr][skh], ta[0], ta[1]);
    short tmp[8];
    cvt8(tmp, tb[0], tb[1]);
#pragma unroll
    for (int j = 0; j < 8; ++j) Bs[p][bn + j][bk] = tmp[j];
  };
  auto step = [&](int t, float4 (&la)[2], float4 (&lb)[2],
                  float4 (&ca)[2], float4 (&cb)[2]) {
    const int par = t & 1;
    if (t + 2 < NK) ldt(la, lb, t + 2);
    bf16x8 bfr = *(const bf16x8*)&Bs[par][wave * 16 + fr][fq * 8];
    bf16x8 af[4];
#pragma unroll
    for (int i = 0; i < 4; ++i) af[i] = *(const bf16x8*)&As[par][i * 16 + fr][fq * 8];
    if (t + 1 < NK) stage(ca, cb, par ^ 1);
#pragma unroll
    for (int i = 0; i < 4; ++i)
      acc[i] = __builtin_amdgcn_mfma_f32_16x16x32_bf16(af[i], bfr, acc[i], 0, 0, 0);
    lds_barrier();
  };

  ldt(xa, xb, 0);
  stage(xa, xb, 0);
  if (NK > 1) ldt(xa, xb, 1);
  lds_barrier();
  int t = 0;
  for (; t + 1 < NK; t += 2) { step(t, ya, yb, xa, xb); step(t + 1, xa, xb, ya, yb); }
  if (t < NK) step(t, ya, yb, xa, xb);

  const int n = n0 + wave * 16 + fr;
  if (n < N) {
#pragma unroll
    for (int i = 0; i < 4; ++i) {
      int mb = m0 + i * 16 + fq * 4;
#pragma unroll
      for (int r2 = 0; r2 < 4; ++r2) {
        int m = mb + r2;
        if (m < M) Cb[(long)m * ldc + n] = acc[i][r2];
      }
    }
  }
}

// ---- MFMA correlation: C[i,j] += scale * sum_m Za[m,i]*Zb[m,j] (split-K atomic) ----
__global__ __launch_bounds__(256) void k_mfma_corr(
    const float* __restrict__ Za, const float* __restrict__ Zb,
    float* __restrict__ C, int mchunk, float scale) {
  __shared__ short As[2][64][40];
  __shared__ short Bs[2][64][40];
  const int tid = threadIdx.x;
  const int lane = tid & 63, wave = tid >> 6;
  const int i0 = blockIdx.y * 64, j0 = blockIdx.x * 64;
  const int mstart = blockIdx.z * mchunk;
  const int tm = tid >> 3, tcb = (tid & 7) * 8;
  const int fr = lane & 15, fq = lane >> 4;
  const int NK = mchunk >> 5;   // 28
  f32x4 acc[4] = {};
  float4 xa[2], xb[2], ya[2], yb[2];

  auto ldt = [&](float4 (&ta)[2], float4 (&tb)[2], int t) {
    const float* za = Za + (long)(mstart + t * 32 + tm) * 512;
    const float* zb = Zb + (long)(mstart + t * 32 + tm) * 512;
    ta[0] = *(const float4*)(za + i0 + tcb);
    ta[1] = *(const float4*)(za + i0 + tcb + 4);
    tb[0] = *(const float4*)(zb + j0 + tcb);
    tb[1] = *(const float4*)(zb + j0 + tcb + 4);
  };
  auto stage = [&](float4 (&ta)[2], float4 (&tb)[2], int p) {
    short u[8], v[8];
    cvt8(u, ta[0], ta[1]);
    cvt8(v, tb[0], tb[1]);
#pragma unroll
    for (int j = 0; j < 8; ++j) { As[p][tcb + j][tm] = u[j]; Bs[p][tcb + j][tm] = v[j]; }
  };
  auto step = [&](int t, float4 (&la)[2], float4 (&lb)[2],
                  float4 (&ca)[2], float4 (&cb)[2]) {
    const int par = t & 1;
    if (t + 2 < NK) ldt(la, lb, t + 2);
    bf16x8 bfr = *(const bf16x8*)&Bs[par][wave * 16 + fr][fq * 8];
    bf16x8 af[4];
#pragma unroll
    for (int i = 0; i < 4; ++i) af[i] = *(const bf16x8*)&As[par][i * 16 + fr][fq * 8];
    if (t + 1 < NK) stage(ca, cb, par ^ 1);
#pragma unroll
    for (int i = 0; i < 4; ++i)
      acc[i] = __builtin_amdgcn_mfma_f32_16x16x32_bf16(af[i], bfr, acc[i], 0, 0, 0);
    lds_barrier();
  };

  ldt(xa, xb, 0);
  stage(xa, xb, 0);
  if (NK > 1) ldt(xa, xb, 1);
  lds_barrier();
  int t = 0;
  for (; t + 1 < NK; t += 2) { step(t, ya, yb, xa, xb); step(t + 1, xa, xb, ya, yb); }
  if (t < NK) step(t, ya, yb, xa, xb);

  const int j = j0 + wave * 16 + fr;
#pragma unroll
  for (int i = 0; i < 4; ++i) {
    int ib = i0 + i * 16 + fq * 4;
#pragma unroll
    for (int r2 = 0; r2 < 4; ++r2)
      atomicAdd(&C[(long)(ib + r2) * 512 + j], acc[i][r2] * scale);
  }
}

// ---- Row softmax over rows of width 196, ld=SLD(224); zeroes pad cols. ----
__global__ __launch_bounds__(256) void k_softmax_rows(float* __restrict__ S, int nrows) {
  int row = blockIdx.x * 4 + (threadIdx.x >> 6);
  int lane = threadIdx.x & 63;
  if (row >= nrows) return;
  float* p = S + (long)row * SLD;
  float v0 = p[lane];
  float v1 = p[lane + 64];
  float v2 = p[lane + 128];
  float v3 = (lane + 192 < 196) ? p[lane + 192] : -1e30f;
  float mx = fmaxf(fmaxf(v0, v1), fmaxf(v2, v3));
#pragma unroll
  for (int o = 32; o > 0; o >>= 1) mx = fmaxf(mx, __shfl_down(mx, o, 64));
  mx = __shfl(mx, 0, 64);
  float e0 = expf(v0 - mx), e1 = expf(v1 - mx), e2 = expf(v2 - mx);
  float e3 = (lane + 192 < 196) ? expf(v3 - mx) : 0.f;
  float s = e0 + e1 + e2 + e3;
#pragma unroll
  for (int o = 32; o > 0; o >>= 1) s += __shfl_down(s, o, 64);
  s = __shfl(s, 0, 64);
  float inv = 1.0f / s;
  p[lane] = e0 * inv;
  p[lane + 64] = e1 * inv;
  p[lane + 128] = e2 * inv;
  if (lane + 192 < SLD) p[lane + 192] = (lane + 192 < 196) ? e3 * inv : 0.f;
}

// ---- dst = LayerNorm(src + o) (src may equal dst) ----
__global__ __launch_bounds__(256) void k_addln2(
    float* __restrict__ dst, const float* __restrict__ src, const float* __restrict__ o,
    const float* __restrict__ g, const float* __restrict__ be) {
  __shared__ float red[4];
  long row = blockIdx.x;
  const float* sr_ = src + row * 512;
  const float* orow = o + row * 512;
  float* dr = dst + row * 512;
  int t = threadIdx.x;
  float v0 = sr_[t] + orow[t];
  float v1 = sr_[t + 256] + orow[t + 256];
  float mean = block_red256(v0 + v1, red, false) * (1.0f / 512.0f);
  float d0 = v0 - mean, d1 = v1 - mean;
  float var = block_red256(d0 * d0 + d1 * d1, red, false) * (1.0f / 512.0f);
  float inv = 1.0f / sqrtf(var + 1e-5f);
  dr[t] = d0 * inv * g[t] + be[t];
  dr[t + 256] = d1 * inv * g[t + 256] + be[t + 256];
}

// ---- small utility kernels ----
__global__ void k_zero(float* __restrict__ p, int n) {
  int i = blockIdx.x * 256 + threadIdx.x;
  if (i < n) p[i] = 0.f;
}

// d = x - h (vectorized)
__global__ __launch_bounds__(256) void k_diff(
    float* __restrict__ d, const float* __restrict__ x, const float* __restrict__ h) {
  long i = ((long)blockIdx.x * 256 + threadIdx.x) * 4;
  float4 xv = *(const float4*)(x + i);
  float4 hv = *(const float4*)(h + i);
  float4 r; r.x = xv.x - hv.x; r.y = xv.y - hv.y; r.z = xv.z - hv.z; r.w = xv.w - hv.w;
  *(float4*)(d + i) = r;
}

// concat two [512,512] weights into [1024,512] (+ biases into [1024])
__global__ __launch_bounds__(256) void k_catkv(
    float* __restrict__ dw, const float* __restrict__ kw, const float* __restrict__ vw,
    float* __restrict__ db, const float* __restrict__ kb, const float* __restrict__ vb) {
  int i = blockIdx.x * 256 + threadIdx.x;      // 1024*512
  int r = i >> 9;
  dw[i] = (r < 512) ? kw[i] : vw[i - 262144];
  if (i < 1024) db[i] = (i < 512) ? kb[i] : vb[i - 512];
}

__global__ __launch_bounds__(256) void k_colstats(
    const float* __restrict__ f, float* __restrict__ sums, float* __restrict__ sqs) {
  int c = blockIdx.x * 32 + (threadIdx.x & 31);
  int rbase = blockIdx.y * 256;
  int r0 = rbase + (threadIdx.x >> 5);
  float s = 0.f, s2 = 0.f;
  for (int r = r0; r < rbase + 256; r += 8) {
    float v = f[(long)r * 512 + c];
    s += v; s2 += v * v;
  }
  __shared__ float sh[256], sh2[256];
  sh[threadIdx.x] = s; sh2[threadIdx.x] = s2;
  __syncthreads();
  if (threadIdx.x < 32) {
    for (int i = 1; i < 8; ++i) { s += sh[i * 32 + threadIdx.x]; s2 += sh2[i * 32 + threadIdx.x]; }
    atomicAdd(&sums[c], s);
    atomicAdd(&sqs[c], s2);
  }
}

__global__ void k_finstats(const float* __restrict__ sums, const float* __restrict__ sqs,
                           float* __restrict__ mean, float* __restrict__ istd) {
  int c = blockIdx.x * 256 + threadIdx.x;
  float mu = sums[c] / 12544.0f;
  float var = (sqs[c] - 12544.0f * mu * mu) / 12543.0f;
  mean[c] = mu;
  istd[c] = 1.0f / sqrtf(var);
}

__global__ __launch_bounds__(256) void k_znorm(float* __restrict__ f, const float* __restrict__ mean,
                                               const float* __restrict__ istd) {
  long i = (long)blockIdx.x * 256 + threadIdx.x;
  int c = (int)(i & 511);
  f[i] = (f[i] - mean[c]) * istd[c];
}

// CDCR loss: 256-block partial reduce + final combine
__global__ __launch_bounds__(256) void k_cdcr_part(const float* __restrict__ Cm,
                                                   double* __restrict__ part) {
  int base = blockIdx.x * 1024;
  double on = 0, off = 0;
  for (int i = base + threadIdx.x; i < base + 1024; i += 256) {
    float v = Cm[i];
    int r = i >> 9, c = i & 511;
    if (r == c) { double d = (double)v - 1.0; on += d * d; }
    else        { off += (double)v * (double)v; }
  }
  __shared__ double s_on[256], s_off[256];
  s_on[threadIdx.x] = on; s_off[threadIdx.x] = off;
  __syncthreads();
  for (int st = 128; st > 0; st >>= 1) {
    if (threadIdx.x < st) { s_on[threadIdx.x] += s_on[threadIdx.x + st]; s_off[threadIdx.x] += s_off[threadIdx.x + st]; }
    __syncthreads();
  }
  if (threadIdx.x == 0) { part[blockIdx.x] = s_on[0]; part[256 + blockIdx.x] = s_off[0]; }
}

__global__ void k_cdcr_fin(const double* __restrict__ part, float* __restrict__ out) {
  __shared__ double s_on[256], s_off[256];
  s_on[threadIdx.x] = part[threadIdx.x];
  s_off[threadIdx.x] = part[256 + threadIdx.x];
  __syncthreads();
  for (int st = 128; st > 0; st >>= 1) {
    if (threadIdx.x < st) { s_on[threadIdx.x] += s_on[threadIdx.x + st]; s_off[threadIdx.x] += s_off[threadIdx.x + st]; }
    __syncthreads();
  }
  if (threadIdx.x == 0) out[0] = (float)(s_on[0] + 0.003 * s_off[0]);
}

__global__ __launch_bounds__(64) void k_mask(const float* __restrict__ capo, float* __restrict__ mask) {
  int pidx = blockIdx.x;
  float s = 0.f;
  for (int i = threadIdx.x; i < 512; i += 64) s += capo[(long)pidx * 512 + i];
#pragma unroll
  for (int o = 32; o > 0; o >>= 1) s += __shfl_down(s, o, 64);
  if (threadIdx.x == 0) mask[pidx] = (s != 0.f) ? 1.f : 0.f;
}

__global__ __launch_bounds__(256) void k_meannc(const float* __restrict__ src, const float* __restrict__ mask,
                                                float* __restrict__ vec) {
  int d = blockIdx.x * 256 + threadIdx.x;
  int b = blockIdx.y;
  float acc = 0.f, ms = 0.f;
  for (int nc = 0; nc < 16; ++nc) {
    float mk = mask ? mask[b * 16 + nc] : 1.f;
    acc += src[((long)b * 16 + nc) * 512 + d] * mk;
    ms += mk;
  }
  vec[(long)b * 512 + d] = acc / fmaxf(ms, 1e-6f);
}

__global__ __launch_bounds__(256) void k_mse(const float* __restrict__ full, const float* __restrict__ vec,
                                             double* __restrict__ part) {
  double loc = 0;
  const long n = NOUT;
  for (long i = (long)blockIdx.x * 256 + threadIdx.x; i < n; i += 256L * 1024) {
    int d = (int)(i & 511);
    int b = (int)(i >> 9) / 196;
    float df = full[i] - vec[b * 512 + d];
    loc += (double)df * (double)df;
  }
  __shared__ double sh[256];
  sh[threadIdx.x] = loc;
  __syncthreads();
  for (int st = 128; st > 0; st >>= 1) {
    if (threadIdx.x < st) sh[threadIdx.x] += sh[threadIdx.x + st];
    __syncthreads();
  }
  if (threadIdx.x == 0) part[blockIdx.x] = sh[0];
}

__global__ void k_finloss(const double* __restrict__ part, float* __restrict__ out) {
  __shared__ double sh[256];
  double s = 0;
  for (int i = threadIdx.x; i < 4096; i += 256) s += part[i];
  sh[threadIdx.x] = s;
  __syncthreads();
  for (int st = 128; st > 0; st >>= 1) {
    if (threadIdx.x < st) sh[threadIdx.x] += sh[threadIdx.x + st];
    __syncthreads();
  }
  if (threadIdx.x == 0) out[0] = (float)(sh[0] / (64.0 * 196.0 * 512.0));
}

__global__ __launch_bounds__(256) void k_concat2(float* __restrict__ dst, const float* __restrict__ a,
                                                 const float* __restrict__ b) {
  int i = blockIdx.x * 256 + threadIdx.x;   // 64*1024
  int col = i & 1023, row = i >> 10;
  dst[i] = (col < 512) ? a[row * 512 + col] : b[row * 512 + col - 512];
}

// three stacked 64-row concats: dst[192,1024]
__global__ __launch_bounds__(256) void k_concat6(
    float* __restrict__ dst,
    const float* __restrict__ a0, const float* __restrict__ b0,
    const float* __restrict__ a1, const float* __restrict__ b1,
    const float* __restrict__ a2, const float* __restrict__ b2) {
  int i = blockIdx.x * 256 + threadIdx.x;   // 192*1024
  int col = i & 1023, row = i >> 10;
  int grp = row >> 6, r = row & 63;
  const float* a = grp == 0 ? a0 : (grp == 1 ? a1 : a2);
  const float* b = grp == 0 ? b0 : (grp == 1 ? b1 : b2);
  dst[i] = (col < 512) ? a[r * 512 + col] : b[r * 512 + col - 512];
}

// comb: [BS,2048] bf16 into dst (short*)
__global__ __launch_bounds__(256) void k_comb_bf(
    short* __restrict__ dst, const float* __restrict__ d1, const float* __restrict__ d2,
    const float* __restrict__ txt, const float* __restrict__ al) {
  long i = (long)blockIdx.x * 256 + threadIdx.x;  // BS*2048
  int col = (int)(i & 2047);
  long m = i >> 11;
  int b = (int)(m / 196);
  float v;
  if (col < 512)       v = d1[m * 512 + col];
  else if (col < 1024) v = d2[m * 512 + col - 512];
  else if (col < 1536) v = txt[(long)b * 512 + col - 1024];
  else                 v = al[(long)b * 512 + col - 1536];
  dst[i] = f2bf(v);
}

// ---------------- host ----------------
extern "C" void kernel_launch(void* const* d_in, const int* in_sizes, int n_in,
                              void* d_out, int out_size, void* d_ws, size_t ws_size,
                              hipStream_t stream) {
  (void)in_sizes; (void)n_in; (void)out_size; (void)ws_size;
  const float* in1    = (const float*)d_in[0];
  const float* in2    = (const float*)d_in[1];
  const float* cap1   = (const float*)d_in[2];
  const float* cap2   = (const float*)d_in[3];
  const float* imgw   = (const float*)d_in[4];
  const float* imgb   = (const float*)d_in[5];
  const float* wemb   = (const float*)d_in[6];
  const float* hemb   = (const float*)d_in[7];
  const float* mlpw1  = (const float*)d_in[8];
  const float* mlpb1  = (const float*)d_in[9];
  const float* mlpw2  = (const float*)d_in[10];
  const float* mlpb2  = (const float*)d_in[11];
  const float* fcw    = (const float*)d_in[12];
  const float* fcb    = (const float*)d_in[13];
  const float* efcw   = (const float*)d_in[14];
  const float* efcb   = (const float*)d_in[15];
  const float* efc2w  = (const float*)d_in[16];
  const float* efc2b  = (const float*)d_in[17];
  const float* trinw  = (const float*)d_in[18];
  const float* trinb  = (const float*)d_in[19];
  const float* troutw = (const float*)d_in[20];
  const float* troutb = (const float*)d_in[21];
  const float* trlng  = (const float*)d_in[22];
  const float* trlnb  = (const float*)d_in[23];
  const float* itqw = (const float*)d_in[24]; const float* itqb = (const float*)d_in[25];
  const float* itkw = (const float*)d_in[26]; const float* itkb = (const float*)d_in[27];
  const float* itvw = (const float*)d_in[28]; const float* itvb = (const float*)d_in[29];
  const float* caqw = (const float*)d_in[30]; const float* caqb = (const float*)d_in[31];
  const float* cakw = (const float*)d_in[32]; const float* cakb = (const float*)d_in[33];
  const float* cavw = (const float*)d_in[34]; const float* cavb = (const float*)d_in[35];
  const float* saqw = (const float*)d_in[36]; const float* saqb = (const float*)d_in[37];
  const float* sakw = (const float*)d_in[38]; const float* sakb = (const float*)d_in[39];
  const float* savw = (const float*)d_in[40]; const float* savb = (const float*)d_in[41];

  float* out = (float*)d_out;

  // ---- workspace carve ----
  const size_t SZ = (size_t)BS * 512;        // 6,422,528 floats (24.5 MB)
  const int64_t SZl = (int64_t)SZ;
  float* w = (float*)d_ws;
  auto alloc = [&](size_t n) { float* p = w; w += n; return p; };
  float* h1 = alloc(SZ);
  float* h2 = alloc(SZ);       // h1..tB = 4 contiguous SZ
  float* tA = alloc(SZ);
  float* tB = alloc(SZ);
  float* tC = alloc(SZ);
  float* tD = alloc(SZ);       // tA..tD = 4 contiguous SZ
  float* sbuf = alloc(SZ);     // scores / bf16 attn-out scratch
  float* cap1o = alloc(64 * 16 * 512);
  float* cap2o = alloc(64 * 16 * 512);   // contiguous with cap1o
  float* qc1   = alloc(64 * 16 * 512);
  float* qc2   = alloc(64 * 16 * 512);   // contiguous with qc1
  float* attb  = alloc(64 * 16 * 512);
  float* attb2 = alloc(64 * 16 * 512);   // contiguous with attb
  float* cmat  = alloc(512 * 512);
  float* colsum1 = alloc(512); float* colsq1 = alloc(512);
  float* colsum2 = alloc(512); float* colsq2 = alloc(512);
  float* mean1 = alloc(512); float* istd1 = alloc(512);
  float* mean2 = alloc(512); float* istd2 = alloc(512);
  float* mask1 = alloc(1024); float* mask2 = alloc(1024);
  float* vdbef = alloc(64 * 512); float* vdaft = alloc(64 * 512);
  float* vsbef = alloc(64 * 512); float* vsaft = alloc(64 * 512);
  float* cm1 = alloc(64 * 512); float* cm2 = alloc(64 * 512);
  float* vdyn = alloc(64 * 512); float* vsta = alloc(64 * 512);
  float* vtxt = alloc(64 * 512); float* valign = alloc(64 * 512);  // vdyn..vtxt contiguous (M=192 out)
  float* ccat = alloc(192 * 1024);
  double* msepart = (double*)alloc(4096 * 2);   // 4096 doubles
  double* cdcrpart = (double*)alloc(1024);      // 512 doubles
  float* itkvw = alloc(1024 * 512); float* itkvb = alloc(1024);
  float* cakvw = alloc(1024 * 512); float* cakvb = alloc(1024);
  float* sakvw = alloc(1024 * 512); float* sakvb = alloc(1024);
  float* x1 = alloc(2 * SZ);   // [x1;x2] contiguous (embed result)
  float* x2 = x1 + SZ;

  // GEMM router: 128^2 tile for big grids, 64^2 (bnt) for small grids.
  auto gemm = [&](const float* Aa, const float* Ww, const float* bb, float* Cc,
                  int M, int N, int K, int relu) {
    long g128 = ((M % 128) == 0 && (N % 128) == 0) ? (long)(N / 128) * (M / 128) : 0;
    if (g128 >= 784 && (K % 32) == 0)
      k_mfma_nt<<<dim3(N / 128, M / 128), 256, 0, stream>>>(Aa, Ww, bb, Cc, M, N, K, relu, 0);
    else
      k_mfma_bnt<<<dim3(N / 64, (M + 63) / 64, 1), 256, 0, stream>>>(
          Aa, Ww, Cc, M, N, K, K, K, N, 1,
          0, 0, 0, 0, 0, 0, 1.0f, 0, bb, relu);
  };
  const int64_t RB = (int64_t)SS * 512;   // 100352
  const int64_t QB = 16 * 512;            // 8192
  // Batched attention, D=512 single-head, K|V packed [*,1024], zq Q-variants.
  auto attn512 = [&](const float* Qp, int64_t qZ1, int64_t qZ2,
                     const float* KVp, int64_t kvZ1, int64_t kvZ2,
                     float* Op, int64_t oZ1, int64_t oZ2, int M, int zq, float scale) {
    int mt = (M + 63) / 64;
    int64_t sS2 = (int64_t)M * SLD;
    int64_t sS1 = 64 * sS2;
    k_mfma_bnt<<<dim3(4, mt, 64 * zq), 256, 0, stream>>>(
        Qp, KVp, sbuf, M, 196, 512, 512, 1024, SLD, 64,
        qZ1, qZ2, kvZ1, kvZ2, sS1, sS2, scale, 1, nullptr, 0);
    k_softmax_rows<<<(64 * zq * M + 3) / 4, 256, 0, stream>>>(sbuf, 64 * zq * M);
    k_mfma_bnn<<<dim3(8, mt, 64 * zq), 256, 0, stream>>>(
        sbuf, KVp + 512, Op, M, 512, SLD, 196, SLD, 1024, 512, 64,
        sS1, sS2, kvZ1, kvZ2, oZ1, oZ2);
  };
  auto efcM = [&](const float* Aa, float* Cc, int M) {
    k_mfma_bnt<<<dim3(8, (M + 63) / 64, 1), 256, 0, stream>>>(
        Aa, efcw, Cc, M, 512, 1024, 1024, 1024, 512, 1,
        0, 0, 0, 0, 0, 0, 1.0f, 0, efcb, 1);
  };

  const float scalE = 1.0f / sqrtf(512.0f);

  // ---- Phase 0: build concat K|V weights for itda/ca/sa ----
  k_catkv<<<2048, 256, 0, stream>>>(itkvw, itkw, itvw, itkvb, itkb, itvb);
  k_catkv<<<2048, 256, 0, stream>>>(cakvw, cakw, cavw, cakvb, cakb, cavb);
  k_catkv<<<2048, 256, 0, stream>>>(sakvw, sakw, savw, sakvb, sakb, savb);

  // ---- Phase 1: embed -> x + caption projections ----
  k_mfma_embed<<<dim3(4, BS / 128, 2), 256, 0, stream>>>(
      in1, in2, imgw, imgb, wemb, hemb, x1, x2);
  gemm(cap1, fcw, fcb, cap1o, 1024, 512, 768, 0);
  gemm(cap2, fcw, fcb, cap2o, 1024, 512, 768, 0);
  k_meannc<<<dim3(2, 64), 256, 0, stream>>>(cap1o, nullptr, cm1);
  k_meannc<<<dim3(2, 64), 256, 0, stream>>>(cap2o, nullptr, cm2);

  // ---- Phase 2: CDCR loss (fused M=2BS MLP; hidden bf16 in tA..tD, f in h1..h2) ----
  k_mfma_nt<<<dim3(16, 196), 256, 0, stream>>>(x1, mlpw1, mlpb1, tA, 2 * BS, 2048, 512, 1, 1);
  k_mfma_bnt_abf<<<dim3(8, 392), 256, 0, stream>>>(
      (const short*)tA, mlpw2, h1, 2 * BS, 512, 2048, 2048, 2048, 512, mlpb2, 0);
  k_zero<<<8, 256, 0, stream>>>(colsum1, 2048);  // colsum1..colsq2 contiguous
  k_colstats<<<dim3(16, 49), 256, 0, stream>>>(h1, colsum1, colsq1);
  k_colstats<<<dim3(16, 49), 256, 0, stream>>>(h2, colsum2, colsq2);
  k_finstats<<<2, 256, 0, stream>>>(colsum1, colsq1, mean1, istd1);
  k_finstats<<<2, 256, 0, stream>>>(colsum2, colsq2, mean2, istd2);
  k_znorm<<<25088, 256, 0, stream>>>(h1, mean1, istd1);
  k_znorm<<<25088, 256, 0, stream>>>(h2, mean2, istd2);
  k_zero<<<1024, 256, 0, stream>>>(cmat, 262144);
  k_mfma_corr<<<dim3(8, 8, 14), 256, 0, stream>>>(h1, h2, cmat, BS / 14, 1.0f / (float)BS);
  k_cdcr_part<<<256, 256, 0, stream>>>(cmat, cdcrpart);
  k_cdcr_fin<<<1, 256, 0, stream>>>(cdcrpart, out + NOUT);

  // ---- Phase 3: cross-transformer (fused q, kv, fmha, o-proj, addln) ----
  for (int l = 0; l < 2; ++l) {
    const float* Wq = trinw + (size_t)l * 1536 * 512;
    const float* Wkv = Wq + 512 * 512;               // [Wk;Wv] 1024 rows
    const float* bq = trinb + l * 1536;
    const float* bkv = bq + 512;                     // [bk|bv] 1024
    const float* Wo = troutw + (size_t)l * 512 * 512;
    const float* bo = troutb + l * 512;
    const float* g  = trlng + l * 512;
    const float* be = trlnb + l * 512;
    const float* s1 = l ? h1 : x1;                   // [s1;s2] contiguous both layers
    // q1|q2 bf16 -> tA (1 SZ)
    k_mfma_nt<<<dim3(4, 196), 256, 0, stream>>>(s1, Wq, bq, tA, 2 * BS, 512, 512, 0, 1);
    // [KV(s1);KV(s2)] bf16 -> tC..tD (2 SZ)
    k_mfma_nt<<<dim3(8, 196), 256, 0, stream>>>(s1, Wkv, bkv, tC, 2 * BS, 1024, 512, 0, 1);
    // fused fmha: z=0 (q1, KV(s2)=part1), z=1 (q2, KV(s1)=part0); out bf16 -> sbuf
    k_fmha_bf2<<<dim3(64, 8, 2), 256, 0, stream>>>(
        (const short*)tA, (const short*)tC + (size_t)BS * 1024, (const short*)tC,
        (short*)sbuf);
    // fused o-proj M=2BS -> tB..tC fp32 (overwrites consumed KV part0)
    k_mfma_bnt_abf<<<dim3(8, 392), 256, 0, stream>>>(
        (const short*)sbuf, Wo, tB, 2 * BS, 512, 512, 512, 512, 512, bo, 0);
    // fused addln: [h1;h2] = LN([s1;s2] + [o1;o2])
    k_addln2<<<2 * BS, 256, 0, stream>>>(h1, s1, tB, g, be);
  }

  // ---- Phase 4: diffs ----
  k_diff<<<12544, 256, 0, stream>>>(tC, x1, h1);   // [tC;tD] = [x1;x2]-[h1;h2]
  // h1..tB, x1..x2 now free

  // ---- Phase 5: ITDA (fused itq, fused KV M=2BS, z=128 batched attention) ----
  gemm(cap1o, itqw, itqb, qc1, 2048, 512, 512, 0);  // qc1|qc2
  k_mask<<<1024, 64, 0, stream>>>(cap1o, mask1);
  k_mask<<<1024, 64, 0, stream>>>(cap2o, mask2);
  gemm(tC, itkvw, itkvb, h1, 2 * BS, 1024, 512, 0); // [KV1;KV2] fp32 -> h1..tB (4 SZ)
  // KV1 (diff1): z1=0 (qc1 -> s_bef), z1=1 (qc2 -> d_bef)
  attn512(qc1, 524288, QB, h1, 0, 2 * RB, attb, 524288, QB, 16, 2, scalE);
  k_meannc<<<dim3(2, 64), 256, 0, stream>>>(attb,  mask1, vsbef);
  k_meannc<<<dim3(2, 64), 256, 0, stream>>>(attb2, mask2, vdbef);
  // KV2 (diff2): z1=0 (qc1 -> d_aft), z1=1 (qc2 -> s_aft)
  attn512(qc1, 524288, QB, h1 + 2 * SZ, 0, 2 * RB, attb, 524288, QB, 16, 2, scalE);
  k_meannc<<<dim3(2, 64), 256, 0, stream>>>(attb,  mask1, vdaft);
  k_meannc<<<dim3(2, 64), 256, 0, stream>>>(attb2, mask2, vsaft);

  // ---- Phase 6: ECA pairs batched (z=128) with immediate MSE ----
  auto eca_pair = [&](const float* qw2, const float* qb2,
                      const float* kvw2, const float* kvb2,
                      const float* kvbase, int64_t kvZ1,
                      const float* vec0, double* part0,
                      const float* vec1, double* part1) {
    gemm(tC, qw2, qb2, x1, 2 * BS, 512, 512, 0);      // Q[diff1;diff2] -> x1..x2
    gemm(tC, kvw2, kvb2, h1, 2 * BS, 1024, 512, 0);   // KV[diff1;diff2] -> h1..tB
    attn512(x1, SZl, RB, kvbase, kvZ1, 2 * RB, x1, SZl, RB, 196, 2, scalE);
    k_mse<<<1024, 256, 0, stream>>>(x1, vec0, part0);
    k_mse<<<1024, 256, 0, stream>>>(x1 + SZ, vec1, part1);
  };
  // ca: z1=0 c12 (Q=diff1, KV=diff2 -> base h1+2SZ, stride -2SZ); z1=1 c21
  eca_pair(caqw, caqb, cakvw, cakvb, h1 + 2 * SZ, -2 * SZl,
           vdbef, msepart, vdaft, msepart + 1024);
  // sa: z1=0 s11 (Q=diff1, KV=diff1 -> base h1, stride +2SZ); z1=1 s22
  eca_pair(saqw, saqb, sakvw, sakvb, h1, 2 * SZl,
           vsbef, msepart + 2048, vsaft, msepart + 3072);
  k_finloss<<<1, 256, 0, stream>>>(msepart, out + NOUT + 1);

  // ---- Phase 7: efc chain (vdyn,vsta,vtxt batched M=192; then valign) ----
  k_concat6<<<768, 256, 0, stream>>>(ccat, vdbef, vdaft, vsbef, vsaft, cm1, cm2);
  efcM(ccat, vdyn, 192);                      // -> vdyn,vsta,vtxt (contiguous)
  k_concat2<<<256, 256, 0, stream>>>(ccat, vdyn, vsta);
  efcM(ccat, valign, 64);

  // ---- Phase 8: comb as bf16 into h1..h2, single bf16-A GEMM ----
  k_comb_bf<<<100352, 256, 0, stream>>>((short*)h1, tC, tD, vtxt, valign);
  k_mfma_bnt_abf<<<dim3(8, 196), 256, 0, stream>>>(
      (const short*)h1, efc2w, out, BS, 512, 2048, 2048, 2048, 512, efc2b, 1);
}